// Round 1
// baseline (14794.791 us; speedup 1.0000x reference)
//
#include <hip/hip_runtime.h>
#include <cstddef>
#include <utility>

// ---------------- problem constants ----------------
constexpr int N0  = 4096;
constexpr int E   = 65536;
constexpr int DIN = 128;
constexpr int HD  = 256;   // H
constexpr int NC  = 10;
constexpr int UHD = 64;    // UH
constexpr int K1  = 3277;  // ceil(0.8*4096)
constexpr int K2  = 656;   // ceil(0.2*3277)
constexpr int PMN = K2 * K2; // 430336

// expm(A): A = 64*B, exp(B) via Taylor m=10 Horner, then square 6 times.
constexpr int EXPM_S = 6;
constexpr int EXPM_M = 10;

// ---------------- workspace layout (all chunks multiple of 256 B) ----------------
#define F4(n) ((size_t)(n) * 4)
constexpr size_t O_H1    = 0;
constexpr size_t O_OUT1  = O_H1    + F4(N0 * HD);
constexpr size_t O_DEG1  = O_OUT1  + F4(N0 * HD);
constexpr size_t O_DIS1  = O_DEG1  + F4(N0);
constexpr size_t O_SC1   = O_DIS1  + F4(N0);
constexpr size_t O_PERM1 = O_SC1   + F4(N0);
constexpr size_t O_MAP1  = O_PERM1 + F4(N0);
constexpr size_t O_H1P   = O_MAP1  + F4(N0);
constexpr size_t O_SRC2  = O_H1P   + F4(K1 * HD);
constexpr size_t O_DST2  = O_SRC2  + F4(E);
constexpr size_t O_EM2   = O_DST2  + F4(E);
constexpr size_t O_H2    = O_EM2   + F4(E);
constexpr size_t O_OUT2  = O_H2    + F4(K1 * HD);
constexpr size_t O_DEG2  = O_OUT2  + F4(K1 * HD);
constexpr size_t O_DIS2  = O_DEG2  + F4(N0);
constexpr size_t O_SC2   = O_DIS2  + F4(N0);
constexpr size_t O_PERM2 = O_SC2   + F4(N0);
constexpr size_t O_MAP2  = O_PERM2 + F4(N0);
constexpr size_t O_H2P   = O_MAP2  + F4(N0);
constexpr size_t O_SRC3  = O_H2P   + F4(K2 * HD);
constexpr size_t O_DST3  = O_SRC3  + F4(E);
constexpr size_t O_EM3   = O_DST3  + F4(E);
constexpr size_t O_XR    = O_EM3   + F4(E);
constexpr size_t O_XI    = O_XR    + F4(K2 * HD);
constexpr size_t O_DEG3  = O_XI    + F4(K2 * HD);
constexpr size_t O_DIS3  = O_DEG3  + F4(1024);
constexpr size_t O_SCOEF = O_DIS3  + F4(1024);
constexpr size_t O_XG1   = O_SCOEF + F4(1024);
constexpr size_t O_XG2H  = O_XG1   + F4(K2 * UHD);
constexpr size_t O_XG2   = O_XG2H  + F4(K2 * UHD);
constexpr size_t O_EMB   = O_XG2   + F4(K2 * UHD);
constexpr size_t O_T1    = O_EMB   + F4(64);
constexpr size_t O_T2    = O_T1    + F4(64);
constexpr size_t O_NORM  = O_T2    + F4(64);   // [0]=norm1, [1]=norm2
constexpr size_t O_PM    = O_NORM  + F4(64);
constexpr size_t O_BM    = O_PM    + F4(PMN);          // float2
constexpr size_t O_P0    = O_BM    + F4(PMN) * 2;      // float2
constexpr size_t O_P1    = O_P0    + F4(PMN) * 2;      // float2
constexpr size_t O_XRT   = O_P1    + F4(PMN) * 2;
constexpr size_t O_XIT   = O_XRT   + F4(K2 * HD);
constexpr size_t O_XC    = O_XIT   + F4(K2 * HD);      // float2
constexpr size_t O_EVO   = O_XC    + F4(K2 * HD) * 2;  // float2
constexpr size_t O_AGG0  = O_EVO   + F4(K2 * HD) * 2;  // float2
constexpr size_t O_WC    = O_AGG0  + F4(K2 * HD) * 2;  // float2 256x256
constexpr size_t O_AGG1  = O_WC    + F4(HD * HD) * 2;  // float2
constexpr size_t O_MAG   = O_AGG1  + F4(K2 * HD) * 2;
constexpr size_t O_PH    = O_MAG   + F4(K2 * HD);
constexpr size_t O_GM    = O_PH    + F4(K2 * HD);
constexpr size_t O_GP    = O_GM    + F4(256);
constexpr size_t O_HM    = O_GP    + F4(256);
constexpr size_t O_HP    = O_HM    + F4(256);
constexpr size_t O_LM    = O_HP    + F4(256);
constexpr size_t O_LP    = O_LM    + F4(64);
constexpr size_t WS_NEED = O_LP    + F4(64);

// ---------------- kernels ----------------

// real GEMM: C[M,N] = act(A[M,K] @ B[K,N] + bias). 64x64 tile, 4x4 per thread.
// Requires K % 16 == 0 and N % 16 == 0 (true for all call sites).
template <int ACT>
__global__ void rmm64(const float* __restrict__ A, const float* __restrict__ B,
                      const float* __restrict__ bias, float* __restrict__ C,
                      int M, int N, int K) {
  __shared__ float As[64][17];
  __shared__ float Bs[16][64];
  int t  = threadIdx.x;
  int tx = t & 15, ty = t >> 4;
  int bm = blockIdx.y * 64, bn = blockIdx.x * 64;
  float acc[4][4] = {};
  for (int kt = 0; kt < K; kt += 16) {
#pragma unroll
    for (int i = 0; i < 4; i++) {
      int l = t + i * 256;
      int kk = l & 15, mm = l >> 4;
      int gr = bm + mm;
      As[mm][kk] = (gr < M) ? A[(size_t)gr * K + kt + kk] : 0.f;
    }
#pragma unroll
    for (int i = 0; i < 4; i++) {
      int l = t + i * 256;
      int cc = l & 63, kk = l >> 6;
      int gc = bn + cc;
      Bs[kk][cc] = (gc < N) ? B[(size_t)(kt + kk) * N + gc] : 0.f;
    }
    __syncthreads();
#pragma unroll
    for (int kk = 0; kk < 16; kk++) {
      float a[4], b[4];
#pragma unroll
      for (int i = 0; i < 4; i++) a[i] = As[ty + 16 * i][kk];
#pragma unroll
      for (int j = 0; j < 4; j++) b[j] = Bs[kk][tx + 16 * j];
#pragma unroll
      for (int i = 0; i < 4; i++)
#pragma unroll
        for (int j = 0; j < 4; j++) acc[i][j] += a[i] * b[j];
    }
    __syncthreads();
  }
#pragma unroll
  for (int i = 0; i < 4; i++) {
    int r = bm + ty + 16 * i;
    if (r >= M) continue;
#pragma unroll
    for (int j = 0; j < 4; j++) {
      int c = bn + tx + 16 * j;
      if (c >= N) continue;
      float v = acc[i][j] + (bias ? bias[c] : 0.f);
      if (ACT == 1) v = fmaxf(v, 0.f);
      C[(size_t)r * N + c] = v;
    }
  }
}

// complex GEMM: C = alpha*(A@B) (+I if ADDI). float2 interleaved, row-major.
template <int ADDI>
__global__ void cmm64(const float2* __restrict__ A, const float2* __restrict__ B,
                      float2* __restrict__ C, int M, int N, int K, float alpha) {
  __shared__ float2 As[64][17];
  __shared__ float2 Bs[16][64];
  int t  = threadIdx.x;
  int tx = t & 15, ty = t >> 4;
  int bm = blockIdx.y * 64, bn = blockIdx.x * 64;
  float accr[4][4] = {}, acci[4][4] = {};
  for (int kt = 0; kt < K; kt += 16) {
#pragma unroll
    for (int i = 0; i < 4; i++) {
      int l = t + i * 256;
      int kk = l & 15, mm = l >> 4;
      int gr = bm + mm;
      As[mm][kk] = (gr < M) ? A[(size_t)gr * K + kt + kk] : make_float2(0.f, 0.f);
    }
#pragma unroll
    for (int i = 0; i < 4; i++) {
      int l = t + i * 256;
      int cc = l & 63, kk = l >> 6;
      int gc = bn + cc;
      Bs[kk][cc] = (gc < N) ? B[(size_t)(kt + kk) * N + gc] : make_float2(0.f, 0.f);
    }
    __syncthreads();
#pragma unroll
    for (int kk = 0; kk < 16; kk++) {
      float2 a[4], b[4];
#pragma unroll
      for (int i = 0; i < 4; i++) a[i] = As[ty + 16 * i][kk];
#pragma unroll
      for (int j = 0; j < 4; j++) b[j] = Bs[kk][tx + 16 * j];
#pragma unroll
      for (int i = 0; i < 4; i++)
#pragma unroll
        for (int j = 0; j < 4; j++) {
          accr[i][j] += a[i].x * b[j].x - a[i].y * b[j].y;
          acci[i][j] += a[i].x * b[j].y + a[i].y * b[j].x;
        }
    }
    __syncthreads();
  }
#pragma unroll
  for (int i = 0; i < 4; i++) {
    int r = bm + ty + 16 * i;
    if (r >= M) continue;
#pragma unroll
    for (int j = 0; j < 4; j++) {
      int c = bn + tx + 16 * j;
      if (c >= N) continue;
      float vr = alpha * accr[i][j];
      float vi = alpha * acci[i][j];
      if (ADDI && r == c) vr += 1.0f;
      C[(size_t)r * N + c] = make_float2(vr, vi);
    }
  }
}

// deg[dst[e]] += em (em==nullptr -> 1.0)
__global__ void edge_deg(const int* __restrict__ dst, const float* __restrict__ em,
                         float* __restrict__ deg) {
  int e = blockIdx.x * 256 + threadIdx.x;
  if (e >= E) return;
  float m = em ? em[e] : 1.0f;
  if (m != 0.f) atomicAdd(&deg[dst[e]], m);
}

__global__ void deg_to_dis(const float* __restrict__ deg, float* __restrict__ dis, int n) {
  int i = blockIdx.x * 256 + threadIdx.x;
  if (i >= n) return;
  dis[i] = 1.0f / sqrtf(deg[i] + 1.0f);
}

// out[i,f] = dis[i]^2 * Hm[i,f] + bias[f]
__global__ void gcn_self(const float* __restrict__ Hm, const float* __restrict__ dis,
                         const float* __restrict__ bias, float* __restrict__ out, int F) {
  int i = blockIdx.x;
  float d2 = dis[i] * dis[i];
  for (int f = threadIdx.x; f < F; f += blockDim.x)
    out[(size_t)i * F + f] = d2 * Hm[(size_t)i * F + f] + bias[f];
}

// out[dst,f] += dis[src]*dis[dst]*em * Hm[src,f]
__global__ void gcn_scatter(const int* __restrict__ src, const int* __restrict__ dst,
                            const float* __restrict__ em, const float* __restrict__ dis,
                            const float* __restrict__ Hm, float* __restrict__ out, int F) {
  int e = blockIdx.x;
  float m = em ? em[e] : 1.0f;
  if (m == 0.f) return;
  int s = src[e], d = dst[e];
  float c = dis[s] * dis[d] * m;
  for (int f = threadIdx.x; f < F; f += blockDim.x)
    atomicAdd(&out[(size_t)d * F + f], c * Hm[(size_t)s * F + f]);
}

__global__ void relu_ip(float* __restrict__ x, int n) {
  int i = blockIdx.x * 256 + threadIdx.x;
  if (i < n) x[i] = fmaxf(x[i], 0.f);
}

// norm of weight vector (n<=256), one block
__global__ void wnorm(const float* __restrict__ w, int n, float* __restrict__ out) {
  __shared__ float red[256];
  float s = 0.f;
  for (int k = threadIdx.x; k < n; k += 256) s += w[k] * w[k];
  red[threadIdx.x] = s;
  __syncthreads();
  for (int off = 128; off > 0; off >>= 1) {
    if (threadIdx.x < off) red[threadIdx.x] += red[threadIdx.x + off];
    __syncthreads();
  }
  if (threadIdx.x == 0) out[0] = sqrtf(red[0]);
}

// per-row dot with w (raw, pre-division by norm)
__global__ void rowdot(const float* __restrict__ X, const float* __restrict__ w,
                       float* __restrict__ out, int F) {
  int i = blockIdx.x;
  __shared__ float red[256];
  float s = 0.f;
  for (int f = threadIdx.x; f < F; f += 256) s += X[(size_t)i * F + f] * w[f];
  red[threadIdx.x] = s;
  __syncthreads();
  for (int off = 128; off > 0; off >>= 1) {
    if (threadIdx.x < off) red[threadIdx.x] += red[threadIdx.x + off];
    __syncthreads();
  }
  if (threadIdx.x == 0) out[i] = red[0];
}

// exact-total-order descending bitonic sort over 4096 packed keys; emits top-k indices.
// key = (sortable_float(score) << 32) | ~index  -> ties broken toward lower index.
__global__ __launch_bounds__(1024) void bitonic_topk(const float* __restrict__ score,
                                                     int n, int* __restrict__ perm, int k) {
  __shared__ unsigned long long keys[4096];
  int t = threadIdx.x;
  for (int i = t; i < 4096; i += 1024) {
    unsigned long long kk = 0ull;
    if (i < n) {
      float f = score[i];
      unsigned u = __float_as_uint(f);
      u = (f >= 0.0f) ? (u | 0x80000000u) : ~u;
      kk = ((unsigned long long)u << 32) | (unsigned)(~(unsigned)i);
    }
    keys[i] = kk;
  }
  __syncthreads();
  for (int size = 2; size <= 4096; size <<= 1) {
    for (int stride = size >> 1; stride > 0; stride >>= 1) {
      for (int i = t; i < 2048; i += 1024) {
        int pos = ((i & ~(stride - 1)) << 1) | (i & (stride - 1));
        int partner = pos + stride;
        bool desc = (pos & size) == 0;
        unsigned long long a = keys[pos], b = keys[partner];
        if ((a < b) == desc) { keys[pos] = b; keys[partner] = a; }
      }
      __syncthreads();
    }
  }
  for (int i = t; i < k; i += 1024)
    perm[i] = (int)(~(unsigned)(keys[i] & 0xFFFFFFFFull));
}

__global__ void set_map(const int* __restrict__ perm, int* __restrict__ map, int k) {
  int i = blockIdx.x * 256 + threadIdx.x;
  if (i < k) map[perm[i]] = i;
}

// Xn[i,:] = X[perm[i],:] * tanh(dot[perm[i]] / norm)
__global__ void pool_gather(const float* __restrict__ X, const int* __restrict__ perm,
                            const float* __restrict__ dot, const float* __restrict__ normbuf,
                            float* __restrict__ Xn, int F) {
  int i = blockIdx.x;
  int p = perm[i];
  float sc = tanhf(dot[p] / normbuf[0]);
  for (int f = threadIdx.x; f < F; f += blockDim.x)
    Xn[(size_t)i * F + f] = X[(size_t)p * F + f] * sc;
}

__global__ void remap_edges(const int* __restrict__ srcIn, const int* __restrict__ dstIn,
                            const float* __restrict__ emIn, const int* __restrict__ map,
                            int* __restrict__ srcOut, int* __restrict__ dstOut,
                            float* __restrict__ emOut) {
  int e = blockIdx.x * 256 + threadIdx.x;
  if (e >= E) return;
  int ns = map[srcIn[e]], nd = map[dstIn[e]];
  float m = emIn ? emIn[e] : 1.0f;
  if (ns < 0 || nd < 0) m = 0.f;
  srcOut[e] = ns < 0 ? 0 : ns;
  dstOut[e] = nd < 0 ? 0 : nd;
  emOut[e] = m;
}

// scoef[dst] += dis[src]*dis[dst]*em
__global__ void enc_scoef(const int* __restrict__ src, const int* __restrict__ dst,
                          const float* __restrict__ em, const float* __restrict__ dis,
                          float* __restrict__ scoef) {
  int e = blockIdx.x * 256 + threadIdx.x;
  if (e >= E) return;
  float m = em[e];
  if (m == 0.f) return;
  atomicAdd(&scoef[dst[e]], dis[src[e]] * dis[dst[e]] * m);
}

// xg1[i,f] = relu((scoef[i]+dis[i]^2)*w[f] + b[f]) ; F = 64
__global__ void enc1_out(const float* __restrict__ scoef, const float* __restrict__ dis,
                         const float* __restrict__ w, const float* __restrict__ b,
                         float* __restrict__ xg1) {
  int i = blockIdx.x;
  int f = threadIdx.x;
  float s = scoef[i] + dis[i] * dis[i];
  xg1[(size_t)i * UHD + f] = fmaxf(s * w[f] + b[f], 0.f);
}

// column mean: out[c] = mean over rows of X[:,c]
__global__ void col_mean(const float* __restrict__ X, float* __restrict__ out,
                         int rows, int cols) {
  int c = blockIdx.x;
  __shared__ float red[256];
  float s = 0.f;
  for (int r = threadIdx.x; r < rows; r += 256) s += X[(size_t)r * cols + c];
  red[threadIdx.x] = s;
  __syncthreads();
  for (int off = 128; off > 0; off >>= 1) {
    if (threadIdx.x < off) red[threadIdx.x] += red[threadIdx.x + off];
    __syncthreads();
  }
  if (threadIdx.x == 0) out[c] = red[0] / (float)rows;
}

// small vec @ mat single-block: out[j] = act(sum_k v[k]*W[k*N+j] + b[j]); K,N <= 256
template <int ACT>
__global__ void vecmat(const float* __restrict__ v, const float* __restrict__ W,
                       const float* __restrict__ b, float* __restrict__ out,
                       int Kdim, int Ndim) {
  __shared__ float vs[256];
  for (int k = threadIdx.x; k < Kdim; k += blockDim.x) vs[k] = v[k];
  __syncthreads();
  for (int j = threadIdx.x; j < Ndim; j += blockDim.x) {
    float acc = b ? b[j] : 0.f;
    for (int k = 0; k < Kdim; k++) acc += vs[k] * W[(size_t)k * Ndim + j];
    out[j] = (ACT == 1) ? fmaxf(acc, 0.f) : acc;
  }
}

// wide vec @ mat with tanh: out[j] = tanh(sum_k v[k]*W[k*N+j] + b[j]); K<=64
__global__ void vecmat_tanh_wide(const float* __restrict__ v, const float* __restrict__ W,
                                 const float* __restrict__ b, float* __restrict__ out,
                                 int Kdim, int Ndim) {
  __shared__ float vs[64];
  if (threadIdx.x < Kdim) vs[threadIdx.x] = v[threadIdx.x];
  __syncthreads();
  int j = blockIdx.x * 256 + threadIdx.x;
  if (j >= Ndim) return;
  float acc = b[j];
  for (int k = 0; k < Kdim; k++) acc += vs[k] * W[(size_t)k * Ndim + j];
  out[j] = tanhf(acc);
}

// B[i,j] = scale*((pm_ij - pm_ji) + i*(pm_ij + pm_ji)), scale = 0.05*0.5/2^s
__global__ void build_B(const float* __restrict__ pm, float2* __restrict__ Bm,
                        int n, float scale) {
  int idx = blockIdx.x * 256 + threadIdx.x;
  if (idx >= n * n) return;
  int r = idx / n, c = idx - r * n;
  float pij = pm[(size_t)r * n + c];
  float pji = pm[(size_t)c * n + r];
  Bm[idx] = make_float2(scale * (pij - pji), scale * (pij + pji));
}

// R = I + B/m
__global__ void expm_init(const float2* __restrict__ Bm, float2* __restrict__ R,
                          int n, float inv_m) {
  int idx = blockIdx.x * 256 + threadIdx.x;
  if (idx >= n * n) return;
  int r = idx / n, c = idx - r * n;
  float2 b = Bm[idx];
  R[idx] = make_float2(b.x * inv_m + (r == c ? 1.f : 0.f), b.y * inv_m);
}

__global__ void pack2(const float* __restrict__ a, const float* __restrict__ b,
                      float2* __restrict__ out, int n) {
  int i = blockIdx.x * 256 + threadIdx.x;
  if (i < n) out[i] = make_float2(a[i], b[i]);
}

// agg[dst,f] += em * evo[src,f]  (complex)
__global__ void agg_scatter(const int* __restrict__ src, const int* __restrict__ dst,
                            const float* __restrict__ em, const float2* __restrict__ evo,
                            float2* __restrict__ agg, int F) {
  int e = blockIdx.x;
  float m = em[e];
  if (m == 0.f) return;
  int s = src[e], d = dst[e];
  for (int f = threadIdx.x; f < F; f += blockDim.x) {
    float2 v = evo[(size_t)s * F + f];
    atomicAdd(&agg[(size_t)d * F + f].x, m * v.x);
    atomicAdd(&agg[(size_t)d * F + f].y, m * v.y);
  }
}

// outc = agg + (xr + i*xi); mag/ph
__global__ void magph(const float2* __restrict__ agg, const float* __restrict__ xr,
                      const float* __restrict__ xi, float* __restrict__ mag,
                      float* __restrict__ ph, int n) {
  int idx = blockIdx.x * 256 + threadIdx.x;
  if (idx >= n) return;
  float2 a = agg[idx];
  float r = a.x + xr[idx];
  float im = a.y + xi[idx];
  mag[idx] = sqrtf(r * r + im * im);
  ph[idx] = atan2f(im, r);
}

__global__ void add_out(const float* __restrict__ lm, const float* __restrict__ lp,
                        float* __restrict__ out, int n) {
  int i = threadIdx.x;
  if (i < n) out[i] = lm[i] + lp[i];
}

// ---------------- host ----------------
extern "C" void kernel_launch(void* const* d_in, const int* in_sizes, int n_in,
                              void* d_out, int out_size, void* d_ws, size_t ws_size,
                              hipStream_t stream) {
  if (ws_size < WS_NEED) return;

  const float* x       = (const float*)d_in[0];
  const int*   ei      = (const int*)d_in[1];
  const float* gcn1_w  = (const float*)d_in[2];
  const float* gcn1_b  = (const float*)d_in[3];
  const float* pool1_w = (const float*)d_in[4];
  const float* gcn2_w  = (const float*)d_in[5];
  const float* gcn2_b  = (const float*)d_in[6];
  const float* pool2_w = (const float*)d_in[7];
  const float* inr_w   = (const float*)d_in[8];
  const float* inr_b   = (const float*)d_in[9];
  const float* ini_w   = (const float*)d_in[10];
  const float* ini_b   = (const float*)d_in[11];
  const float* enc1_w  = (const float*)d_in[12];
  const float* enc1_b  = (const float*)d_in[13];
  const float* enc2_w  = (const float*)d_in[14];
  const float* enc2_b  = (const float*)d_in[15];
  const float* p1_w    = (const float*)d_in[16];
  const float* p1_b    = (const float*)d_in[17];
  const float* p2_w    = (const float*)d_in[18];
  const float* p2_b    = (const float*)d_in[19];
  const float* p3_w    = (const float*)d_in[20];
  const float* p3_b    = (const float*)d_in[21];
  const float* rt_w    = (const float*)d_in[22];
  const float* rt_b    = (const float*)d_in[23];
  const float* it_w    = (const float*)d_in[24];
  const float* it_b    = (const float*)d_in[25];
  const float* msg_wr  = (const float*)d_in[26];
  const float* msg_wi  = (const float*)d_in[27];
  const float* mc1_w   = (const float*)d_in[28];
  const float* mc1_b   = (const float*)d_in[29];
  const float* mc2_w   = (const float*)d_in[30];
  const float* mc2_b   = (const float*)d_in[31];
  const float* pc1_w   = (const float*)d_in[32];
  const float* pc1_b   = (const float*)d_in[33];
  const float* pc2_w   = (const float*)d_in[34];
  const float* pc2_b   = (const float*)d_in[35];

  char* ws = (char*)d_ws;
  float*  H1    = (float*)(ws + O_H1);
  float*  OUT1  = (float*)(ws + O_OUT1);
  float*  DEG1  = (float*)(ws + O_DEG1);
  float*  DIS1  = (float*)(ws + O_DIS1);
  float*  SC1   = (float*)(ws + O_SC1);
  int*    PERM1 = (int*)(ws + O_PERM1);
  int*    MAP1  = (int*)(ws + O_MAP1);
  float*  H1P   = (float*)(ws + O_H1P);
  int*    SRC2  = (int*)(ws + O_SRC2);
  int*    DST2  = (int*)(ws + O_DST2);
  float*  EM2   = (float*)(ws + O_EM2);
  float*  H2    = (float*)(ws + O_H2);
  float*  OUT2  = (float*)(ws + O_OUT2);
  float*  DEG2  = (float*)(ws + O_DEG2);
  float*  DIS2  = (float*)(ws + O_DIS2);
  float*  SC2   = (float*)(ws + O_SC2);
  int*    PERM2 = (int*)(ws + O_PERM2);
  int*    MAP2  = (int*)(ws + O_MAP2);
  float*  H2P   = (float*)(ws + O_H2P);
  int*    SRC3  = (int*)(ws + O_SRC3);
  int*    DST3  = (int*)(ws + O_DST3);
  float*  EM3   = (float*)(ws + O_EM3);
  float*  XRb   = (float*)(ws + O_XR);
  float*  XIb   = (float*)(ws + O_XI);
  float*  DEG3  = (float*)(ws + O_DEG3);
  float*  DIS3  = (float*)(ws + O_DIS3);
  float*  SCOEF = (float*)(ws + O_SCOEF);
  float*  XG1   = (float*)(ws + O_XG1);
  float*  XG2H  = (float*)(ws + O_XG2H);
  float*  XG2   = (float*)(ws + O_XG2);
  float*  EMB   = (float*)(ws + O_EMB);
  float*  T1    = (float*)(ws + O_T1);
  float*  T2    = (float*)(ws + O_T2);
  float*  NORM  = (float*)(ws + O_NORM);
  float*  PMV   = (float*)(ws + O_PM);
  float2* BM    = (float2*)(ws + O_BM);
  float2* P0v   = (float2*)(ws + O_P0);
  float2* P1v   = (float2*)(ws + O_P1);
  float*  XRT   = (float*)(ws + O_XRT);
  float*  XIT   = (float*)(ws + O_XIT);
  float2* XC    = (float2*)(ws + O_XC);
  float2* EVO   = (float2*)(ws + O_EVO);
  float2* AGG0  = (float2*)(ws + O_AGG0);
  float2* WC    = (float2*)(ws + O_WC);
  float2* AGG1  = (float2*)(ws + O_AGG1);
  float*  MAGB  = (float*)(ws + O_MAG);
  float*  PHB   = (float*)(ws + O_PH);
  float*  GM    = (float*)(ws + O_GM);
  float*  GP    = (float*)(ws + O_GP);
  float*  HM    = (float*)(ws + O_HM);
  float*  HP    = (float*)(ws + O_HP);
  float*  LM    = (float*)(ws + O_LM);
  float*  LP    = (float*)(ws + O_LP);

  const int* SRC1 = ei;
  const int* DST1 = ei + E;

  // ---------- Stage A: gcn1 + relu ----------
  rmm64<0><<<dim3(HD / 64, N0 / 64), 256, 0, stream>>>(x, gcn1_w, nullptr, H1, N0, HD, DIN);
  hipMemsetAsync(DEG1, 0, F4(N0), stream);
  edge_deg<<<E / 256, 256, 0, stream>>>(DST1, nullptr, DEG1);
  deg_to_dis<<<N0 / 256, 256, 0, stream>>>(DEG1, DIS1, N0);
  gcn_self<<<N0, 256, 0, stream>>>(H1, DIS1, gcn1_b, OUT1, HD);
  gcn_scatter<<<E, 256, 0, stream>>>(SRC1, DST1, nullptr, DIS1, H1, OUT1, HD);
  relu_ip<<<(N0 * HD) / 256, 256, 0, stream>>>(OUT1, N0 * HD);

  // ---------- pool1 ----------
  wnorm<<<1, 256, 0, stream>>>(pool1_w, HD, NORM);
  rowdot<<<N0, 256, 0, stream>>>(OUT1, pool1_w, SC1, HD);
  bitonic_topk<<<1, 1024, 0, stream>>>(SC1, N0, PERM1, K1);
  hipMemsetAsync(MAP1, 0xFF, F4(N0), stream);
  set_map<<<(K1 + 255) / 256, 256, 0, stream>>>(PERM1, MAP1, K1);
  pool_gather<<<K1, 256, 0, stream>>>(OUT1, PERM1, SC1, NORM, H1P, HD);
  remap_edges<<<E / 256, 256, 0, stream>>>(SRC1, DST1, nullptr, MAP1, SRC2, DST2, EM2);

  // ---------- Stage C: gcn2 + relu ----------
  rmm64<0><<<dim3(HD / 64, (K1 + 63) / 64), 256, 0, stream>>>(H1P, gcn2_w, nullptr, H2, K1, HD, HD);
  hipMemsetAsync(DEG2, 0, F4(N0), stream);
  edge_deg<<<E / 256, 256, 0, stream>>>(DST2, EM2, DEG2);
  deg_to_dis<<<(K1 + 255) / 256, 256, 0, stream>>>(DEG2, DIS2, K1);
  gcn_self<<<K1, 256, 0, stream>>>(H2, DIS2, gcn2_b, OUT2, HD);
  gcn_scatter<<<E, 256, 0, stream>>>(SRC2, DST2, EM2, DIS2, H2, OUT2, HD);
  relu_ip<<<(K1 * HD + 255) / 256, 256, 0, stream>>>(OUT2, K1 * HD);

  // ---------- pool2 ----------
  wnorm<<<1, 256, 0, stream>>>(pool2_w, HD, NORM + 1);
  rowdot<<<K1, 256, 0, stream>>>(OUT2, pool2_w, SC2, HD);
  bitonic_topk<<<1, 1024, 0, stream>>>(SC2, K1, PERM2, K2);
  hipMemsetAsync(MAP2, 0xFF, F4(N0), stream);
  set_map<<<(K2 + 255) / 256, 256, 0, stream>>>(PERM2, MAP2, K2);
  pool_gather<<<K2, 256, 0, stream>>>(OUT2, PERM2, SC2, NORM + 1, H2P, HD);
  remap_edges<<<E / 256, 256, 0, stream>>>(SRC2, DST2, EM2, MAP2, SRC3, DST3, EM3);

  // ---------- xr / xi ----------
  rmm64<0><<<dim3(HD / 64, (K2 + 63) / 64), 256, 0, stream>>>(H2P, inr_w, inr_b, XRb, K2, HD, HD);
  rmm64<0><<<dim3(HD / 64, (K2 + 63) / 64), 256, 0, stream>>>(H2P, ini_w, ini_b, XIb, K2, HD, HD);

  // ---------- encoder GCNs on pooled graph ----------
  hipMemsetAsync(DEG3, 0, F4(K2), stream);
  edge_deg<<<E / 256, 256, 0, stream>>>(DST3, EM3, DEG3);
  deg_to_dis<<<(K2 + 255) / 256, 256, 0, stream>>>(DEG3, DIS3, K2);
  hipMemsetAsync(SCOEF, 0, F4(K2), stream);
  enc_scoef<<<E / 256, 256, 0, stream>>>(SRC3, DST3, EM3, DIS3, SCOEF);
  enc1_out<<<K2, UHD, 0, stream>>>(SCOEF, DIS3, enc1_w, enc1_b, XG1);
  rmm64<0><<<dim3(UHD / 64, (K2 + 63) / 64), 256, 0, stream>>>(XG1, enc2_w, nullptr, XG2H, K2, UHD, UHD);
  gcn_self<<<K2, UHD, 0, stream>>>(XG2H, DIS3, enc2_b, XG2, UHD);
  gcn_scatter<<<E, UHD, 0, stream>>>(SRC3, DST3, EM3, DIS3, XG2H, XG2, UHD);
  col_mean<<<UHD, 256, 0, stream>>>(XG2, EMB, K2, UHD);

  // ---------- parameter MLP -> pm -> B ----------
  vecmat<1><<<1, 256, 0, stream>>>(EMB, p1_w, p1_b, T1, UHD, UHD);
  vecmat<1><<<1, 256, 0, stream>>>(T1, p2_w, p2_b, T2, UHD, UHD / 2);
  vecmat_tanh_wide<<<(PMN + 255) / 256, 256, 0, stream>>>(T2, p3_w, p3_b, PMV, UHD / 2, PMN);
  {
    const float scale = 0.05f * 0.5f / (float)(1 << EXPM_S);
    build_B<<<(PMN + 255) / 256, 256, 0, stream>>>(PMV, BM, K2, scale);
  }

  // ---------- expm(A) = (Taylor_m(B))^(2^s) ----------
  expm_init<<<(PMN + 255) / 256, 256, 0, stream>>>(BM, P0v, K2, 1.0f / (float)EXPM_M);
  float2* cur = P0v;
  float2* nxt = P1v;
  for (int j = EXPM_M - 1; j >= 1; --j) {
    cmm64<1><<<dim3(11, 11), 256, 0, stream>>>(BM, cur, nxt, K2, K2, K2, 1.0f / (float)j);
    std::swap(cur, nxt);
  }
  for (int t = 0; t < EXPM_S; ++t) {
    cmm64<0><<<dim3(11, 11), 256, 0, stream>>>(cur, cur, nxt, K2, K2, K2, 1.0f);
    std::swap(cur, nxt);
  }
  float2* U = cur;

  // ---------- quantum message passing ----------
  rmm64<1><<<dim3(HD / 64, (K2 + 63) / 64), 256, 0, stream>>>(XRb, rt_w, rt_b, XRT, K2, HD, HD);
  rmm64<1><<<dim3(HD / 64, (K2 + 63) / 64), 256, 0, stream>>>(XIb, it_w, it_b, XIT, K2, HD, HD);
  pack2<<<(K2 * HD + 255) / 256, 256, 0, stream>>>(XRT, XIT, XC, K2 * HD);
  cmm64<0><<<dim3(HD / 64, (K2 + 63) / 64), 256, 0, stream>>>(U, XC, EVO, K2, HD, K2, 1.0f);
  hipMemsetAsync(AGG0, 0, F4(K2 * HD) * 2, stream);
  agg_scatter<<<E, 256, 0, stream>>>(SRC3, DST3, EM3, EVO, AGG0, HD);
  pack2<<<(HD * HD + 255) / 256, 256, 0, stream>>>(msg_wr, msg_wi, WC, HD * HD);
  cmm64<0><<<dim3(HD / 64, (K2 + 63) / 64), 256, 0, stream>>>(AGG0, WC, AGG1, K2, HD, HD, 1.0f);
  magph<<<(K2 * HD + 255) / 256, 256, 0, stream>>>(AGG1, XRb, XIb, MAGB, PHB, K2 * HD);
  col_mean<<<HD, 256, 0, stream>>>(MAGB, GM, K2, HD);
  col_mean<<<HD, 256, 0, stream>>>(PHB, GP, K2, HD);

  // ---------- classifier heads ----------
  vecmat<1><<<1, 256, 0, stream>>>(GM, mc1_w, mc1_b, HM, HD, HD / 2);
  vecmat<0><<<1, 256, 0, stream>>>(HM, mc2_w, mc2_b, LM, HD / 2, NC);
  vecmat<1><<<1, 256, 0, stream>>>(GP, pc1_w, pc1_b, HP, HD, HD / 2);
  vecmat<0><<<1, 256, 0, stream>>>(HP, pc2_w, pc2_b, LP, HD / 2, NC);
  add_out<<<1, 64, 0, stream>>>(LM, LP, (float*)d_out, NC);
}

// Round 2
// 4622.805 us; speedup vs baseline: 3.2004x; 3.2004x over previous
//
#include <hip/hip_runtime.h>
#include <cstddef>
#include <utility>

// ---------------- problem constants ----------------
constexpr int N0  = 4096;
constexpr int E   = 65536;
constexpr int DIN = 128;
constexpr int HD  = 256;   // H
constexpr int NC  = 10;
constexpr int UHD = 64;    // UH
constexpr int K1  = 3277;  // ceil(0.8*4096)
constexpr int K2  = 656;   // ceil(0.2*3277)
constexpr int PMN = K2 * K2; // 430336

// expm(A): A = 64*B, exp(B) via Taylor m=10 Horner, then square 6 times.
constexpr int EXPM_S = 6;
constexpr int EXPM_M = 10;

// ---------------- workspace layout (all chunks multiple of 256 B) ----------------
#define F4(n) ((size_t)(n) * 4)
constexpr size_t O_H1    = 0;
constexpr size_t O_OUT1  = O_H1    + F4(N0 * HD);
constexpr size_t O_DEG1  = O_OUT1  + F4(N0 * HD);
constexpr size_t O_DIS1  = O_DEG1  + F4(N0);
constexpr size_t O_SC1   = O_DIS1  + F4(N0);
constexpr size_t O_PERM1 = O_SC1   + F4(N0);
constexpr size_t O_MAP1  = O_PERM1 + F4(N0);
constexpr size_t O_H1P   = O_MAP1  + F4(N0);
constexpr size_t O_SRC2  = O_H1P   + F4(K1 * HD);
constexpr size_t O_DST2  = O_SRC2  + F4(E);
constexpr size_t O_EM2   = O_DST2  + F4(E);
constexpr size_t O_H2    = O_EM2   + F4(E);
constexpr size_t O_OUT2  = O_H2    + F4(K1 * HD);
constexpr size_t O_DEG2  = O_OUT2  + F4(K1 * HD);
constexpr size_t O_DIS2  = O_DEG2  + F4(N0);
constexpr size_t O_SC2   = O_DIS2  + F4(N0);
constexpr size_t O_PERM2 = O_SC2   + F4(N0);
constexpr size_t O_MAP2  = O_PERM2 + F4(N0);
constexpr size_t O_H2P   = O_MAP2  + F4(N0);
constexpr size_t O_SRC3  = O_H2P   + F4(K2 * HD);
constexpr size_t O_DST3  = O_SRC3  + F4(E);
constexpr size_t O_EM3   = O_DST3  + F4(E);
constexpr size_t O_XR    = O_EM3   + F4(E);
constexpr size_t O_XI    = O_XR    + F4(K2 * HD);
constexpr size_t O_DEG3  = O_XI    + F4(K2 * HD);
constexpr size_t O_DIS3  = O_DEG3  + F4(1024);
constexpr size_t O_SCOEF = O_DIS3  + F4(1024);
constexpr size_t O_XG1   = O_SCOEF + F4(1024);
constexpr size_t O_XG2H  = O_XG1   + F4(K2 * UHD);
constexpr size_t O_XG2   = O_XG2H  + F4(K2 * UHD);
constexpr size_t O_EMB   = O_XG2   + F4(K2 * UHD);
constexpr size_t O_T1    = O_EMB   + F4(64);
constexpr size_t O_T2    = O_T1    + F4(64);
constexpr size_t O_NORM  = O_T2    + F4(64);   // [0]=norm1, [1]=norm2
constexpr size_t O_PM    = O_NORM  + F4(64);
constexpr size_t O_BM    = O_PM    + F4(PMN);          // float2
constexpr size_t O_P0    = O_BM    + F4(PMN) * 2;      // float2
constexpr size_t O_P1    = O_P0    + F4(PMN) * 2;      // float2
constexpr size_t O_XRT   = O_P1    + F4(PMN) * 2;
constexpr size_t O_XIT   = O_XRT   + F4(K2 * HD);
constexpr size_t O_XC    = O_XIT   + F4(K2 * HD);      // float2
constexpr size_t O_EVO   = O_XC    + F4(K2 * HD) * 2;  // float2
constexpr size_t O_AGG0  = O_EVO   + F4(K2 * HD) * 2;  // float2
constexpr size_t O_WC    = O_AGG0  + F4(K2 * HD) * 2;  // float2 256x256
constexpr size_t O_AGG1  = O_WC    + F4(HD * HD) * 2;  // float2
constexpr size_t O_MAG   = O_AGG1  + F4(K2 * HD) * 2;
constexpr size_t O_PH    = O_MAG   + F4(K2 * HD);
constexpr size_t O_GM    = O_PH    + F4(K2 * HD);
constexpr size_t O_GP    = O_GM    + F4(256);
constexpr size_t O_HM    = O_GP    + F4(256);
constexpr size_t O_HP    = O_HM    + F4(256);
constexpr size_t O_LM    = O_HP    + F4(256);
constexpr size_t O_LP    = O_LM    + F4(64);
constexpr size_t WS_NEED = O_LP    + F4(64);

// ---------------- kernels ----------------

// real GEMM: C[M,N] = act(A[M,K] @ B[K,N] + bias). 64x64 tile, 4x4 per thread.
// Requires K % 16 == 0 and N % 16 == 0 (true for all call sites).
template <int ACT>
__global__ void rmm64(const float* __restrict__ A, const float* __restrict__ B,
                      const float* __restrict__ bias, float* __restrict__ C,
                      int M, int N, int K) {
  __shared__ float As[64][17];
  __shared__ float Bs[16][64];
  int t  = threadIdx.x;
  int tx = t & 15, ty = t >> 4;
  int bm = blockIdx.y * 64, bn = blockIdx.x * 64;
  float acc[4][4] = {};
  for (int kt = 0; kt < K; kt += 16) {
#pragma unroll
    for (int i = 0; i < 4; i++) {
      int l = t + i * 256;
      int kk = l & 15, mm = l >> 4;
      int gr = bm + mm;
      As[mm][kk] = (gr < M) ? A[(size_t)gr * K + kt + kk] : 0.f;
    }
#pragma unroll
    for (int i = 0; i < 4; i++) {
      int l = t + i * 256;
      int cc = l & 63, kk = l >> 6;
      int gc = bn + cc;
      Bs[kk][cc] = (gc < N) ? B[(size_t)(kt + kk) * N + gc] : 0.f;
    }
    __syncthreads();
#pragma unroll
    for (int kk = 0; kk < 16; kk++) {
      float a[4], b[4];
#pragma unroll
      for (int i = 0; i < 4; i++) a[i] = As[ty + 16 * i][kk];
#pragma unroll
      for (int j = 0; j < 4; j++) b[j] = Bs[kk][tx + 16 * j];
#pragma unroll
      for (int i = 0; i < 4; i++)
#pragma unroll
        for (int j = 0; j < 4; j++) acc[i][j] += a[i] * b[j];
    }
    __syncthreads();
  }
#pragma unroll
  for (int i = 0; i < 4; i++) {
    int r = bm + ty + 16 * i;
    if (r >= M) continue;
#pragma unroll
    for (int j = 0; j < 4; j++) {
      int c = bn + tx + 16 * j;
      if (c >= N) continue;
      float v = acc[i][j] + (bias ? bias[c] : 0.f);
      if (ACT == 1) v = fmaxf(v, 0.f);
      C[(size_t)r * N + c] = v;
    }
  }
}

// complex GEMM: C = alpha*(A@B) (+I if ADDI). float2 interleaved, row-major.
// __launch_bounds__(256, 2): without it the compiler caps VGPRs at 64 targeting
// 8 waves/EU, which spills the 32-float accumulator array inside the k-loop
// (rocprof R1: WRITE_SIZE 1.3 GB/dispatch of scratch traffic, 1300 us each).
// (256,2) raises the budget to 256 VGPRs/wave; ~110 needed -> no spill.
template <int ADDI>
__global__ __launch_bounds__(256, 2) void cmm64(
    const float2* __restrict__ A, const float2* __restrict__ B,
    float2* __restrict__ C, int M, int N, int K, float alpha) {
  __shared__ float2 As[64][17];
  __shared__ float2 Bs[16][64];
  int t  = threadIdx.x;
  int tx = t & 15, ty = t >> 4;
  int bm = blockIdx.y * 64, bn = blockIdx.x * 64;
  float accr[4][4] = {}, acci[4][4] = {};
  for (int kt = 0; kt < K; kt += 16) {
#pragma unroll
    for (int i = 0; i < 4; i++) {
      int l = t + i * 256;
      int kk = l & 15, mm = l >> 4;
      int gr = bm + mm;
      As[mm][kk] = (gr < M) ? A[(size_t)gr * K + kt + kk] : make_float2(0.f, 0.f);
    }
#pragma unroll
    for (int i = 0; i < 4; i++) {
      int l = t + i * 256;
      int cc = l & 63, kk = l >> 6;
      int gc = bn + cc;
      Bs[kk][cc] = (gc < N) ? B[(size_t)(kt + kk) * N + gc] : make_float2(0.f, 0.f);
    }
    __syncthreads();
#pragma unroll
    for (int kk = 0; kk < 16; kk++) {
      float2 a[4], b[4];
#pragma unroll
      for (int i = 0; i < 4; i++) a[i] = As[ty + 16 * i][kk];
#pragma unroll
      for (int j = 0; j < 4; j++) b[j] = Bs[kk][tx + 16 * j];
#pragma unroll
      for (int i = 0; i < 4; i++)
#pragma unroll
        for (int j = 0; j < 4; j++) {
          accr[i][j] += a[i].x * b[j].x - a[i].y * b[j].y;
          acci[i][j] += a[i].x * b[j].y + a[i].y * b[j].x;
        }
    }
    __syncthreads();
  }
#pragma unroll
  for (int i = 0; i < 4; i++) {
    int r = bm + ty + 16 * i;
    if (r >= M) continue;
#pragma unroll
    for (int j = 0; j < 4; j++) {
      int c = bn + tx + 16 * j;
      if (c >= N) continue;
      float vr = alpha * accr[i][j];
      float vi = alpha * acci[i][j];
      if (ADDI && r == c) vr += 1.0f;
      C[(size_t)r * N + c] = make_float2(vr, vi);
    }
  }
}

// deg[dst[e]] += em (em==nullptr -> 1.0)
__global__ void edge_deg(const int* __restrict__ dst, const float* __restrict__ em,
                         float* __restrict__ deg) {
  int e = blockIdx.x * 256 + threadIdx.x;
  if (e >= E) return;
  float m = em ? em[e] : 1.0f;
  if (m != 0.f) atomicAdd(&deg[dst[e]], m);
}

__global__ void deg_to_dis(const float* __restrict__ deg, float* __restrict__ dis, int n) {
  int i = blockIdx.x * 256 + threadIdx.x;
  if (i >= n) return;
  dis[i] = 1.0f / sqrtf(deg[i] + 1.0f);
}

// out[i,f] = dis[i]^2 * Hm[i,f] + bias[f]
__global__ void gcn_self(const float* __restrict__ Hm, const float* __restrict__ dis,
                         const float* __restrict__ bias, float* __restrict__ out, int F) {
  int i = blockIdx.x;
  float d2 = dis[i] * dis[i];
  for (int f = threadIdx.x; f < F; f += blockDim.x)
    out[(size_t)i * F + f] = d2 * Hm[(size_t)i * F + f] + bias[f];
}

// out[dst,f] += dis[src]*dis[dst]*em * Hm[src,f]
__global__ void gcn_scatter(const int* __restrict__ src, const int* __restrict__ dst,
                            const float* __restrict__ em, const float* __restrict__ dis,
                            const float* __restrict__ Hm, float* __restrict__ out, int F) {
  int e = blockIdx.x;
  float m = em ? em[e] : 1.0f;
  if (m == 0.f) return;
  int s = src[e], d = dst[e];
  float c = dis[s] * dis[d] * m;
  for (int f = threadIdx.x; f < F; f += blockDim.x)
    atomicAdd(&out[(size_t)d * F + f], c * Hm[(size_t)s * F + f]);
}

__global__ void relu_ip(float* __restrict__ x, int n) {
  int i = blockIdx.x * 256 + threadIdx.x;
  if (i < n) x[i] = fmaxf(x[i], 0.f);
}

// norm of weight vector (n<=256), one block
__global__ void wnorm(const float* __restrict__ w, int n, float* __restrict__ out) {
  __shared__ float red[256];
  float s = 0.f;
  for (int k = threadIdx.x; k < n; k += 256) s += w[k] * w[k];
  red[threadIdx.x] = s;
  __syncthreads();
  for (int off = 128; off > 0; off >>= 1) {
    if (threadIdx.x < off) red[threadIdx.x] += red[threadIdx.x + off];
    __syncthreads();
  }
  if (threadIdx.x == 0) out[0] = sqrtf(red[0]);
}

// per-row dot with w (raw, pre-division by norm)
__global__ void rowdot(const float* __restrict__ X, const float* __restrict__ w,
                       float* __restrict__ out, int F) {
  int i = blockIdx.x;
  __shared__ float red[256];
  float s = 0.f;
  for (int f = threadIdx.x; f < F; f += 256) s += X[(size_t)i * F + f] * w[f];
  red[threadIdx.x] = s;
  __syncthreads();
  for (int off = 128; off > 0; off >>= 1) {
    if (threadIdx.x < off) red[threadIdx.x] += red[threadIdx.x + off];
    __syncthreads();
  }
  if (threadIdx.x == 0) out[i] = red[0];
}

// exact-total-order descending bitonic sort over 4096 packed keys; emits top-k indices.
// key = (sortable_float(score) << 32) | ~index  -> ties broken toward lower index.
__global__ __launch_bounds__(1024) void bitonic_topk(const float* __restrict__ score,
                                                     int n, int* __restrict__ perm, int k) {
  __shared__ unsigned long long keys[4096];
  int t = threadIdx.x;
  for (int i = t; i < 4096; i += 1024) {
    unsigned long long kk = 0ull;
    if (i < n) {
      float f = score[i];
      unsigned u = __float_as_uint(f);
      u = (f >= 0.0f) ? (u | 0x80000000u) : ~u;
      kk = ((unsigned long long)u << 32) | (unsigned)(~(unsigned)i);
    }
    keys[i] = kk;
  }
  __syncthreads();
  for (int size = 2; size <= 4096; size <<= 1) {
    for (int stride = size >> 1; stride > 0; stride >>= 1) {
      for (int i = t; i < 2048; i += 1024) {
        int pos = ((i & ~(stride - 1)) << 1) | (i & (stride - 1));
        int partner = pos + stride;
        bool desc = (pos & size) == 0;
        unsigned long long a = keys[pos], b = keys[partner];
        if ((a < b) == desc) { keys[pos] = b; keys[partner] = a; }
      }
      __syncthreads();
    }
  }
  for (int i = t; i < k; i += 1024)
    perm[i] = (int)(~(unsigned)(keys[i] & 0xFFFFFFFFull));
}

__global__ void set_map(const int* __restrict__ perm, int* __restrict__ map, int k) {
  int i = blockIdx.x * 256 + threadIdx.x;
  if (i < k) map[perm[i]] = i;
}

// Xn[i,:] = X[perm[i],:] * tanh(dot[perm[i]] / norm)
__global__ void pool_gather(const float* __restrict__ X, const int* __restrict__ perm,
                            const float* __restrict__ dot, const float* __restrict__ normbuf,
                            float* __restrict__ Xn, int F) {
  int i = blockIdx.x;
  int p = perm[i];
  float sc = tanhf(dot[p] / normbuf[0]);
  for (int f = threadIdx.x; f < F; f += blockDim.x)
    Xn[(size_t)i * F + f] = X[(size_t)p * F + f] * sc;
}

__global__ void remap_edges(const int* __restrict__ srcIn, const int* __restrict__ dstIn,
                            const float* __restrict__ emIn, const int* __restrict__ map,
                            int* __restrict__ srcOut, int* __restrict__ dstOut,
                            float* __restrict__ emOut) {
  int e = blockIdx.x * 256 + threadIdx.x;
  if (e >= E) return;
  int ns = map[srcIn[e]], nd = map[dstIn[e]];
  float m = emIn ? emIn[e] : 1.0f;
  if (ns < 0 || nd < 0) m = 0.f;
  srcOut[e] = ns < 0 ? 0 : ns;
  dstOut[e] = nd < 0 ? 0 : nd;
  emOut[e] = m;
}

// scoef[dst] += dis[src]*dis[dst]*em
__global__ void enc_scoef(const int* __restrict__ src, const int* __restrict__ dst,
                          const float* __restrict__ em, const float* __restrict__ dis,
                          float* __restrict__ scoef) {
  int e = blockIdx.x * 256 + threadIdx.x;
  if (e >= E) return;
  float m = em[e];
  if (m == 0.f) return;
  atomicAdd(&scoef[dst[e]], dis[src[e]] * dis[dst[e]] * m);
}

// xg1[i,f] = relu((scoef[i]+dis[i]^2)*w[f] + b[f]) ; F = 64
__global__ void enc1_out(const float* __restrict__ scoef, const float* __restrict__ dis,
                         const float* __restrict__ w, const float* __restrict__ b,
                         float* __restrict__ xg1) {
  int i = blockIdx.x;
  int f = threadIdx.x;
  float s = scoef[i] + dis[i] * dis[i];
  xg1[(size_t)i * UHD + f] = fmaxf(s * w[f] + b[f], 0.f);
}

// column mean: out[c] = mean over rows of X[:,c]
__global__ void col_mean(const float* __restrict__ X, float* __restrict__ out,
                         int rows, int cols) {
  int c = blockIdx.x;
  __shared__ float red[256];
  float s = 0.f;
  for (int r = threadIdx.x; r < rows; r += 256) s += X[(size_t)r * cols + c];
  red[threadIdx.x] = s;
  __syncthreads();
  for (int off = 128; off > 0; off >>= 1) {
    if (threadIdx.x < off) red[threadIdx.x] += red[threadIdx.x + off];
    __syncthreads();
  }
  if (threadIdx.x == 0) out[c] = red[0] / (float)rows;
}

// small vec @ mat single-block: out[j] = act(sum_k v[k]*W[k*N+j] + b[j]); K,N <= 256
template <int ACT>
__global__ void vecmat(const float* __restrict__ v, const float* __restrict__ W,
                       const float* __restrict__ b, float* __restrict__ out,
                       int Kdim, int Ndim) {
  __shared__ float vs[256];
  for (int k = threadIdx.x; k < Kdim; k += blockDim.x) vs[k] = v[k];
  __syncthreads();
  for (int j = threadIdx.x; j < Ndim; j += blockDim.x) {
    float acc = b ? b[j] : 0.f;
    for (int k = 0; k < Kdim; k++) acc += vs[k] * W[(size_t)k * Ndim + j];
    out[j] = (ACT == 1) ? fmaxf(acc, 0.f) : acc;
  }
}

// wide vec @ mat with tanh: out[j] = tanh(sum_k v[k]*W[k*N+j] + b[j]); K<=64
__global__ void vecmat_tanh_wide(const float* __restrict__ v, const float* __restrict__ W,
                                 const float* __restrict__ b, float* __restrict__ out,
                                 int Kdim, int Ndim) {
  __shared__ float vs[64];
  if (threadIdx.x < Kdim) vs[threadIdx.x] = v[threadIdx.x];
  __syncthreads();
  int j = blockIdx.x * 256 + threadIdx.x;
  if (j >= Ndim) return;
  float acc = b[j];
  for (int k = 0; k < Kdim; k++) acc += vs[k] * W[(size_t)k * Ndim + j];
  out[j] = tanhf(acc);
}

// B[i,j] = scale*((pm_ij - pm_ji) + i*(pm_ij + pm_ji)), scale = 0.05*0.5/2^s
__global__ void build_B(const float* __restrict__ pm, float2* __restrict__ Bm,
                        int n, float scale) {
  int idx = blockIdx.x * 256 + threadIdx.x;
  if (idx >= n * n) return;
  int r = idx / n, c = idx - r * n;
  float pij = pm[(size_t)r * n + c];
  float pji = pm[(size_t)c * n + r];
  Bm[idx] = make_float2(scale * (pij - pji), scale * (pij + pji));
}

// R = I + B/m
__global__ void expm_init(const float2* __restrict__ Bm, float2* __restrict__ R,
                          int n, float inv_m) {
  int idx = blockIdx.x * 256 + threadIdx.x;
  if (idx >= n * n) return;
  int r = idx / n, c = idx - r * n;
  float2 b = Bm[idx];
  R[idx] = make_float2(b.x * inv_m + (r == c ? 1.f : 0.f), b.y * inv_m);
}

__global__ void pack2(const float* __restrict__ a, const float* __restrict__ b,
                      float2* __restrict__ out, int n) {
  int i = blockIdx.x * 256 + threadIdx.x;
  if (i < n) out[i] = make_float2(a[i], b[i]);
}

// agg[dst,f] += em * evo[src,f]  (complex)
__global__ void agg_scatter(const int* __restrict__ src, const int* __restrict__ dst,
                            const float* __restrict__ em, const float2* __restrict__ evo,
                            float2* __restrict__ agg, int F) {
  int e = blockIdx.x;
  float m = em[e];
  if (m == 0.f) return;
  int s = src[e], d = dst[e];
  for (int f = threadIdx.x; f < F; f += blockDim.x) {
    float2 v = evo[(size_t)s * F + f];
    atomicAdd(&agg[(size_t)d * F + f].x, m * v.x);
    atomicAdd(&agg[(size_t)d * F + f].y, m * v.y);
  }
}

// outc = agg + (xr + i*xi); mag/ph
__global__ void magph(const float2* __restrict__ agg, const float* __restrict__ xr,
                      const float* __restrict__ xi, float* __restrict__ mag,
                      float* __restrict__ ph, int n) {
  int idx = blockIdx.x * 256 + threadIdx.x;
  if (idx >= n) return;
  float2 a = agg[idx];
  float r = a.x + xr[idx];
  float im = a.y + xi[idx];
  mag[idx] = sqrtf(r * r + im * im);
  ph[idx] = atan2f(im, r);
}

__global__ void add_out(const float* __restrict__ lm, const float* __restrict__ lp,
                        float* __restrict__ out, int n) {
  int i = threadIdx.x;
  if (i < n) out[i] = lm[i] + lp[i];
}

// ---------------- host ----------------
extern "C" void kernel_launch(void* const* d_in, const int* in_sizes, int n_in,
                              void* d_out, int out_size, void* d_ws, size_t ws_size,
                              hipStream_t stream) {
  if (ws_size < WS_NEED) return;

  const float* x       = (const float*)d_in[0];
  const int*   ei      = (const int*)d_in[1];
  const float* gcn1_w  = (const float*)d_in[2];
  const float* gcn1_b  = (const float*)d_in[3];
  const float* pool1_w = (const float*)d_in[4];
  const float* gcn2_w  = (const float*)d_in[5];
  const float* gcn2_b  = (const float*)d_in[6];
  const float* pool2_w = (const float*)d_in[7];
  const float* inr_w   = (const float*)d_in[8];
  const float* inr_b   = (const float*)d_in[9];
  const float* ini_w   = (const float*)d_in[10];
  const float* ini_b   = (const float*)d_in[11];
  const float* enc1_w  = (const float*)d_in[12];
  const float* enc1_b  = (const float*)d_in[13];
  const float* enc2_w  = (const float*)d_in[14];
  const float* enc2_b  = (const float*)d_in[15];
  const float* p1_w    = (const float*)d_in[16];
  const float* p1_b    = (const float*)d_in[17];
  const float* p2_w    = (const float*)d_in[18];
  const float* p2_b    = (const float*)d_in[19];
  const float* p3_w    = (const float*)d_in[20];
  const float* p3_b    = (const float*)d_in[21];
  const float* rt_w    = (const float*)d_in[22];
  const float* rt_b    = (const float*)d_in[23];
  const float* it_w    = (const float*)d_in[24];
  const float* it_b    = (const float*)d_in[25];
  const float* msg_wr  = (const float*)d_in[26];
  const float* msg_wi  = (const float*)d_in[27];
  const float* mc1_w   = (const float*)d_in[28];
  const float* mc1_b   = (const float*)d_in[29];
  const float* mc2_w   = (const float*)d_in[30];
  const float* mc2_b   = (const float*)d_in[31];
  const float* pc1_w   = (const float*)d_in[32];
  const float* pc1_b   = (const float*)d_in[33];
  const float* pc2_w   = (const float*)d_in[34];
  const float* pc2_b   = (const float*)d_in[35];

  char* ws = (char*)d_ws;
  float*  H1    = (float*)(ws + O_H1);
  float*  OUT1  = (float*)(ws + O_OUT1);
  float*  DEG1  = (float*)(ws + O_DEG1);
  float*  DIS1  = (float*)(ws + O_DIS1);
  float*  SC1   = (float*)(ws + O_SC1);
  int*    PERM1 = (int*)(ws + O_PERM1);
  int*    MAP1  = (int*)(ws + O_MAP1);
  float*  H1P   = (float*)(ws + O_H1P);
  int*    SRC2  = (int*)(ws + O_SRC2);
  int*    DST2  = (int*)(ws + O_DST2);
  float*  EM2   = (float*)(ws + O_EM2);
  float*  H2    = (float*)(ws + O_H2);
  float*  OUT2  = (float*)(ws + O_OUT2);
  float*  DEG2  = (float*)(ws + O_DEG2);
  float*  DIS2  = (float*)(ws + O_DIS2);
  float*  SC2   = (float*)(ws + O_SC2);
  int*    PERM2 = (int*)(ws + O_PERM2);
  int*    MAP2  = (int*)(ws + O_MAP2);
  float*  H2P   = (float*)(ws + O_H2P);
  int*    SRC3  = (int*)(ws + O_SRC3);
  int*    DST3  = (int*)(ws + O_DST3);
  float*  EM3   = (float*)(ws + O_EM3);
  float*  XRb   = (float*)(ws + O_XR);
  float*  XIb   = (float*)(ws + O_XI);
  float*  DEG3  = (float*)(ws + O_DEG3);
  float*  DIS3  = (float*)(ws + O_DIS3);
  float*  SCOEF = (float*)(ws + O_SCOEF);
  float*  XG1   = (float*)(ws + O_XG1);
  float*  XG2H  = (float*)(ws + O_XG2H);
  float*  XG2   = (float*)(ws + O_XG2);
  float*  EMB   = (float*)(ws + O_EMB);
  float*  T1    = (float*)(ws + O_T1);
  float*  T2    = (float*)(ws + O_T2);
  float*  NORM  = (float*)(ws + O_NORM);
  float*  PMV   = (float*)(ws + O_PM);
  float2* BM    = (float2*)(ws + O_BM);
  float2* P0v   = (float2*)(ws + O_P0);
  float2* P1v   = (float2*)(ws + O_P1);
  float*  XRT   = (float*)(ws + O_XRT);
  float*  XIT   = (float*)(ws + O_XIT);
  float2* XC    = (float2*)(ws + O_XC);
  float2* EVO   = (float2*)(ws + O_EVO);
  float2* AGG0  = (float2*)(ws + O_AGG0);
  float2* WC    = (float2*)(ws + O_WC);
  float2* AGG1  = (float2*)(ws + O_AGG1);
  float*  MAGB  = (float*)(ws + O_MAG);
  float*  PHB   = (float*)(ws + O_PH);
  float*  GM    = (float*)(ws + O_GM);
  float*  GP    = (float*)(ws + O_GP);
  float*  HM    = (float*)(ws + O_HM);
  float*  HP    = (float*)(ws + O_HP);
  float*  LM    = (float*)(ws + O_LM);
  float*  LP    = (float*)(ws + O_LP);

  const int* SRC1 = ei;
  const int* DST1 = ei + E;

  // ---------- Stage A: gcn1 + relu ----------
  rmm64<0><<<dim3(HD / 64, N0 / 64), 256, 0, stream>>>(x, gcn1_w, nullptr, H1, N0, HD, DIN);
  hipMemsetAsync(DEG1, 0, F4(N0), stream);
  edge_deg<<<E / 256, 256, 0, stream>>>(DST1, nullptr, DEG1);
  deg_to_dis<<<N0 / 256, 256, 0, stream>>>(DEG1, DIS1, N0);
  gcn_self<<<N0, 256, 0, stream>>>(H1, DIS1, gcn1_b, OUT1, HD);
  gcn_scatter<<<E, 256, 0, stream>>>(SRC1, DST1, nullptr, DIS1, H1, OUT1, HD);
  relu_ip<<<(N0 * HD) / 256, 256, 0, stream>>>(OUT1, N0 * HD);

  // ---------- pool1 ----------
  wnorm<<<1, 256, 0, stream>>>(pool1_w, HD, NORM);
  rowdot<<<N0, 256, 0, stream>>>(OUT1, pool1_w, SC1, HD);
  bitonic_topk<<<1, 1024, 0, stream>>>(SC1, N0, PERM1, K1);
  hipMemsetAsync(MAP1, 0xFF, F4(N0), stream);
  set_map<<<(K1 + 255) / 256, 256, 0, stream>>>(PERM1, MAP1, K1);
  pool_gather<<<K1, 256, 0, stream>>>(OUT1, PERM1, SC1, NORM, H1P, HD);
  remap_edges<<<E / 256, 256, 0, stream>>>(SRC1, DST1, nullptr, MAP1, SRC2, DST2, EM2);

  // ---------- Stage C: gcn2 + relu ----------
  rmm64<0><<<dim3(HD / 64, (K1 + 63) / 64), 256, 0, stream>>>(H1P, gcn2_w, nullptr, H2, K1, HD, HD);
  hipMemsetAsync(DEG2, 0, F4(N0), stream);
  edge_deg<<<E / 256, 256, 0, stream>>>(DST2, EM2, DEG2);
  deg_to_dis<<<(K1 + 255) / 256, 256, 0, stream>>>(DEG2, DIS2, K1);
  gcn_self<<<K1, 256, 0, stream>>>(H2, DIS2, gcn2_b, OUT2, HD);
  gcn_scatter<<<E, 256, 0, stream>>>(SRC2, DST2, EM2, DIS2, H2, OUT2, HD);
  relu_ip<<<(K1 * HD + 255) / 256, 256, 0, stream>>>(OUT2, K1 * HD);

  // ---------- pool2 ----------
  wnorm<<<1, 256, 0, stream>>>(pool2_w, HD, NORM + 1);
  rowdot<<<K1, 256, 0, stream>>>(OUT2, pool2_w, SC2, HD);
  bitonic_topk<<<1, 1024, 0, stream>>>(SC2, K1, PERM2, K2);
  hipMemsetAsync(MAP2, 0xFF, F4(N0), stream);
  set_map<<<(K2 + 255) / 256, 256, 0, stream>>>(PERM2, MAP2, K2);
  pool_gather<<<K2, 256, 0, stream>>>(OUT2, PERM2, SC2, NORM + 1, H2P, HD);
  remap_edges<<<E / 256, 256, 0, stream>>>(SRC2, DST2, EM2, MAP2, SRC3, DST3, EM3);

  // ---------- xr / xi ----------
  rmm64<0><<<dim3(HD / 64, (K2 + 63) / 64), 256, 0, stream>>>(H2P, inr_w, inr_b, XRb, K2, HD, HD);
  rmm64<0><<<dim3(HD / 64, (K2 + 63) / 64), 256, 0, stream>>>(H2P, ini_w, ini_b, XIb, K2, HD, HD);

  // ---------- encoder GCNs on pooled graph ----------
  hipMemsetAsync(DEG3, 0, F4(K2), stream);
  edge_deg<<<E / 256, 256, 0, stream>>>(DST3, EM3, DEG3);
  deg_to_dis<<<(K2 + 255) / 256, 256, 0, stream>>>(DEG3, DIS3, K2);
  hipMemsetAsync(SCOEF, 0, F4(K2), stream);
  enc_scoef<<<E / 256, 256, 0, stream>>>(SRC3, DST3, EM3, DIS3, SCOEF);
  enc1_out<<<K2, UHD, 0, stream>>>(SCOEF, DIS3, enc1_w, enc1_b, XG1);
  rmm64<0><<<dim3(UHD / 64, (K2 + 63) / 64), 256, 0, stream>>>(XG1, enc2_w, nullptr, XG2H, K2, UHD, UHD);
  gcn_self<<<K2, UHD, 0, stream>>>(XG2H, DIS3, enc2_b, XG2, UHD);
  gcn_scatter<<<E, UHD, 0, stream>>>(SRC3, DST3, EM3, DIS3, XG2H, XG2, UHD);
  col_mean<<<UHD, 256, 0, stream>>>(XG2, EMB, K2, UHD);

  // ---------- parameter MLP -> pm -> B ----------
  vecmat<1><<<1, 256, 0, stream>>>(EMB, p1_w, p1_b, T1, UHD, UHD);
  vecmat<1><<<1, 256, 0, stream>>>(T1, p2_w, p2_b, T2, UHD, UHD / 2);
  vecmat_tanh_wide<<<(PMN + 255) / 256, 256, 0, stream>>>(T2, p3_w, p3_b, PMV, UHD / 2, PMN);
  {
    const float scale = 0.05f * 0.5f / (float)(1 << EXPM_S);
    build_B<<<(PMN + 255) / 256, 256, 0, stream>>>(PMV, BM, K2, scale);
  }

  // ---------- expm(A) = (Taylor_m(B))^(2^s) ----------
  expm_init<<<(PMN + 255) / 256, 256, 0, stream>>>(BM, P0v, K2, 1.0f / (float)EXPM_M);
  float2* cur = P0v;
  float2* nxt = P1v;
  for (int j = EXPM_M - 1; j >= 1; --j) {
    cmm64<1><<<dim3(11, 11), 256, 0, stream>>>(BM, cur, nxt, K2, K2, K2, 1.0f / (float)j);
    std::swap(cur, nxt);
  }
  for (int t = 0; t < EXPM_S; ++t) {
    cmm64<0><<<dim3(11, 11), 256, 0, stream>>>(cur, cur, nxt, K2, K2, K2, 1.0f);
    std::swap(cur, nxt);
  }
  float2* U = cur;

  // ---------- quantum message passing ----------
  rmm64<1><<<dim3(HD / 64, (K2 + 63) / 64), 256, 0, stream>>>(XRb, rt_w, rt_b, XRT, K2, HD, HD);
  rmm64<1><<<dim3(HD / 64, (K2 + 63) / 64), 256, 0, stream>>>(XIb, it_w, it_b, XIT, K2, HD, HD);
  pack2<<<(K2 * HD + 255) / 256, 256, 0, stream>>>(XRT, XIT, XC, K2 * HD);
  cmm64<0><<<dim3(HD / 64, (K2 + 63) / 64), 256, 0, stream>>>(U, XC, EVO, K2, HD, K2, 1.0f);
  hipMemsetAsync(AGG0, 0, F4(K2 * HD) * 2, stream);
  agg_scatter<<<E, 256, 0, stream>>>(SRC3, DST3, EM3, EVO, AGG0, HD);
  pack2<<<(HD * HD + 255) / 256, 256, 0, stream>>>(msg_wr, msg_wi, WC, HD * HD);
  cmm64<0><<<dim3(HD / 64, (K2 + 63) / 64), 256, 0, stream>>>(AGG0, WC, AGG1, K2, HD, HD, 1.0f);
  magph<<<(K2 * HD + 255) / 256, 256, 0, stream>>>(AGG1, XRb, XIb, MAGB, PHB, K2 * HD);
  col_mean<<<HD, 256, 0, stream>>>(MAGB, GM, K2, HD);
  col_mean<<<HD, 256, 0, stream>>>(PHB, GP, K2, HD);

  // ---------- classifier heads ----------
  vecmat<1><<<1, 256, 0, stream>>>(GM, mc1_w, mc1_b, HM, HD, HD / 2);
  vecmat<0><<<1, 256, 0, stream>>>(HM, mc2_w, mc2_b, LM, HD / 2, NC);
  vecmat<1><<<1, 256, 0, stream>>>(GP, pc1_w, pc1_b, HP, HD, HD / 2);
  vecmat<0><<<1, 256, 0, stream>>>(HP, pc2_w, pc2_b, LP, HD / 2, NC);
  add_out<<<1, 64, 0, stream>>>(LM, LP, (float*)d_out, NC);
}

// Round 3
// 2967.334 us; speedup vs baseline: 4.9859x; 1.5579x over previous
//
#include <hip/hip_runtime.h>
#include <cstddef>
#include <utility>

// ---------------- problem constants ----------------
constexpr int N0  = 4096;
constexpr int E   = 65536;
constexpr int DIN = 128;
constexpr int HD  = 256;   // H
constexpr int NC  = 10;
constexpr int UHD = 64;    // UH
constexpr int K1  = 3277;  // ceil(0.8*4096)
constexpr int K2  = 656;   // ceil(0.2*3277)
constexpr int PMN = K2 * K2; // 430336

// expm(A): A = 64*B, exp(B) via Taylor m=10 Horner, then square 6 times.
constexpr int EXPM_S = 6;
constexpr int EXPM_M = 10;

// split-K factor for complex GEMMs (11x11=121 blocks alone -> half the chip
// idle at 1 wave/SIMD; R2 rocprof: VALUBusy 14.7%, Occupancy 5.3%).
constexpr int CSPLIT = 4;

// ---------------- workspace layout (all chunks multiple of 256 B) ----------------
#define F4(n) ((size_t)(n) * 4)
constexpr size_t O_H1    = 0;
constexpr size_t O_OUT1  = O_H1    + F4(N0 * HD);
constexpr size_t O_DEG1  = O_OUT1  + F4(N0 * HD);
constexpr size_t O_DIS1  = O_DEG1  + F4(N0);
constexpr size_t O_SC1   = O_DIS1  + F4(N0);
constexpr size_t O_PERM1 = O_SC1   + F4(N0);
constexpr size_t O_MAP1  = O_PERM1 + F4(N0);
constexpr size_t O_H1P   = O_MAP1  + F4(N0);
constexpr size_t O_SRC2  = O_H1P   + F4(K1 * HD);
constexpr size_t O_DST2  = O_SRC2  + F4(E);
constexpr size_t O_EM2   = O_DST2  + F4(E);
constexpr size_t O_H2    = O_EM2   + F4(E);
constexpr size_t O_OUT2  = O_H2    + F4(K1 * HD);
constexpr size_t O_DEG2  = O_OUT2  + F4(K1 * HD);
constexpr size_t O_DIS2  = O_DEG2  + F4(N0);
constexpr size_t O_SC2   = O_DIS2  + F4(N0);
constexpr size_t O_PERM2 = O_SC2   + F4(N0);
constexpr size_t O_MAP2  = O_PERM2 + F4(N0);
constexpr size_t O_H2P   = O_MAP2  + F4(N0);
constexpr size_t O_SRC3  = O_H2P   + F4(K2 * HD);
constexpr size_t O_DST3  = O_SRC3  + F4(E);
constexpr size_t O_EM3   = O_DST3  + F4(E);
constexpr size_t O_XR    = O_EM3   + F4(E);
constexpr size_t O_XI    = O_XR    + F4(K2 * HD);
constexpr size_t O_DEG3  = O_XI    + F4(K2 * HD);
constexpr size_t O_DIS3  = O_DEG3  + F4(1024);
constexpr size_t O_SCOEF = O_DIS3  + F4(1024);
constexpr size_t O_XG1   = O_SCOEF + F4(1024);
constexpr size_t O_XG2H  = O_XG1   + F4(K2 * UHD);
constexpr size_t O_XG2   = O_XG2H  + F4(K2 * UHD);
constexpr size_t O_EMB   = O_XG2   + F4(K2 * UHD);
constexpr size_t O_T1    = O_EMB   + F4(64);
constexpr size_t O_T2    = O_T1    + F4(64);
constexpr size_t O_NORM  = O_T2    + F4(64);   // [0]=norm1, [1]=norm2
constexpr size_t O_PM    = O_NORM  + F4(64);
constexpr size_t O_BM    = O_PM    + F4(PMN);          // float2
constexpr size_t O_P0    = O_BM    + F4(PMN) * 2;      // float2
constexpr size_t O_P1    = O_P0    + F4(PMN) * 2;      // float2
constexpr size_t O_XRT   = O_P1    + F4(PMN) * 2;
constexpr size_t O_XIT   = O_XRT   + F4(K2 * HD);
constexpr size_t O_XC    = O_XIT   + F4(K2 * HD);      // float2
constexpr size_t O_EVO   = O_XC    + F4(K2 * HD) * 2;  // float2
constexpr size_t O_AGG0  = O_EVO   + F4(K2 * HD) * 2;  // float2
constexpr size_t O_WC    = O_AGG0  + F4(K2 * HD) * 2;  // float2 256x256
constexpr size_t O_AGG1  = O_WC    + F4(HD * HD) * 2;  // float2
constexpr size_t O_MAG   = O_AGG1  + F4(K2 * HD) * 2;
constexpr size_t O_PH    = O_MAG   + F4(K2 * HD);
constexpr size_t O_GM    = O_PH    + F4(K2 * HD);
constexpr size_t O_GP    = O_GM    + F4(256);
constexpr size_t O_HM    = O_GP    + F4(256);
constexpr size_t O_HP    = O_HM    + F4(256);
constexpr size_t O_LM    = O_HP    + F4(256);
constexpr size_t O_LP    = O_LM    + F4(64);
constexpr size_t WS_NEED = O_LP    + F4(64);

// ---------------- kernels ----------------

// real GEMM: C[M,N] = act(A[M,K] @ B[K,N] + bias). 64x64 tile, 4x4 per thread.
// Requires K % 16 == 0 and N % 16 == 0 (true for all call sites).
template <int ACT>
__global__ void rmm64(const float* __restrict__ A, const float* __restrict__ B,
                      const float* __restrict__ bias, float* __restrict__ C,
                      int M, int N, int K) {
  __shared__ float As[64][17];
  __shared__ float Bs[16][64];
  int t  = threadIdx.x;
  int tx = t & 15, ty = t >> 4;
  int bm = blockIdx.y * 64, bn = blockIdx.x * 64;
  float acc[4][4] = {};
  for (int kt = 0; kt < K; kt += 16) {
#pragma unroll
    for (int i = 0; i < 4; i++) {
      int l = t + i * 256;
      int kk = l & 15, mm = l >> 4;
      int gr = bm + mm;
      As[mm][kk] = (gr < M) ? A[(size_t)gr * K + kt + kk] : 0.f;
    }
#pragma unroll
    for (int i = 0; i < 4; i++) {
      int l = t + i * 256;
      int cc = l & 63, kk = l >> 6;
      int gc = bn + cc;
      Bs[kk][cc] = (gc < N) ? B[(size_t)(kt + kk) * N + gc] : 0.f;
    }
    __syncthreads();
#pragma unroll
    for (int kk = 0; kk < 16; kk++) {
      float a[4], b[4];
#pragma unroll
      for (int i = 0; i < 4; i++) a[i] = As[ty + 16 * i][kk];
#pragma unroll
      for (int j = 0; j < 4; j++) b[j] = Bs[kk][tx + 16 * j];
#pragma unroll
      for (int i = 0; i < 4; i++)
#pragma unroll
        for (int j = 0; j < 4; j++) acc[i][j] += a[i] * b[j];
    }
    __syncthreads();
  }
#pragma unroll
  for (int i = 0; i < 4; i++) {
    int r = bm + ty + 16 * i;
    if (r >= M) continue;
#pragma unroll
    for (int j = 0; j < 4; j++) {
      int c = bn + tx + 16 * j;
      if (c >= N) continue;
      float v = acc[i][j] + (bias ? bias[c] : 0.f);
      if (ACT == 1) v = fmaxf(v, 0.f);
      C[(size_t)r * N + c] = v;
    }
  }
}

// C init for split-K complex GEMM: C = I (addi=1) or 0 (addi=0).
__global__ void cinit(float2* __restrict__ C, int M, int N, int addi) {
  int idx = blockIdx.x * 256 + threadIdx.x;
  if (idx >= M * N) return;
  int r = idx / N, c = idx - r * N;
  C[idx] = make_float2((addi && r == c) ? 1.f : 0.f, 0.f);
}

// split-K complex GEMM: C += alpha*(A@B) via fp32 atomics. float2 interleaved.
// blockIdx.z selects k-chunk [z*chunk, min(K,(z+1)*chunk)); chunk % 16 == 0.
// __launch_bounds__(256,2): without it the compiler caps VGPRs at 64, spilling
// the 32-float accumulator (R1 rocprof: 1.3 GB scratch writes per dispatch).
__global__ __launch_bounds__(256, 2) void cmm64_sk(
    const float2* __restrict__ A, const float2* __restrict__ B,
    float2* __restrict__ C, int M, int N, int K, int chunk, float alpha) {
  int k0 = blockIdx.z * chunk;
  int kend = min(K, k0 + chunk);
  if (k0 >= kend) return;
  __shared__ float2 As[64][17];
  __shared__ float2 Bs[16][64];
  int t  = threadIdx.x;
  int tx = t & 15, ty = t >> 4;
  int bm = blockIdx.y * 64, bn = blockIdx.x * 64;
  float accr[4][4] = {}, acci[4][4] = {};
  for (int kt = k0; kt < kend; kt += 16) {
#pragma unroll
    for (int i = 0; i < 4; i++) {
      int l = t + i * 256;
      int kk = l & 15, mm = l >> 4;
      int gr = bm + mm;
      As[mm][kk] = (gr < M) ? A[(size_t)gr * K + kt + kk] : make_float2(0.f, 0.f);
    }
#pragma unroll
    for (int i = 0; i < 4; i++) {
      int l = t + i * 256;
      int cc = l & 63, kk = l >> 6;
      int gc = bn + cc;
      Bs[kk][cc] = (gc < N) ? B[(size_t)(kt + kk) * N + gc] : make_float2(0.f, 0.f);
    }
    __syncthreads();
#pragma unroll
    for (int kk = 0; kk < 16; kk++) {
      float2 a[4], b[4];
#pragma unroll
      for (int i = 0; i < 4; i++) a[i] = As[ty + 16 * i][kk];
#pragma unroll
      for (int j = 0; j < 4; j++) b[j] = Bs[kk][tx + 16 * j];
#pragma unroll
      for (int i = 0; i < 4; i++)
#pragma unroll
        for (int j = 0; j < 4; j++) {
          accr[i][j] += a[i].x * b[j].x - a[i].y * b[j].y;
          acci[i][j] += a[i].x * b[j].y + a[i].y * b[j].x;
        }
    }
    __syncthreads();
  }
  float* Cf = (float*)C;
#pragma unroll
  for (int i = 0; i < 4; i++) {
    int r = bm + ty + 16 * i;
    if (r >= M) continue;
#pragma unroll
    for (int j = 0; j < 4; j++) {
      int c = bn + tx + 16 * j;
      if (c >= N) continue;
      size_t o = 2 * ((size_t)r * N + c);
      atomicAdd(&Cf[o], alpha * accr[i][j]);
      atomicAdd(&Cf[o + 1], alpha * acci[i][j]);
    }
  }
}

// deg[dst[e]] += em (em==nullptr -> 1.0)
__global__ void edge_deg(const int* __restrict__ dst, const float* __restrict__ em,
                         float* __restrict__ deg) {
  int e = blockIdx.x * 256 + threadIdx.x;
  if (e >= E) return;
  float m = em ? em[e] : 1.0f;
  if (m != 0.f) atomicAdd(&deg[dst[e]], m);
}

__global__ void deg_to_dis(const float* __restrict__ deg, float* __restrict__ dis, int n) {
  int i = blockIdx.x * 256 + threadIdx.x;
  if (i >= n) return;
  dis[i] = 1.0f / sqrtf(deg[i] + 1.0f);
}

// out[i,f] = dis[i]^2 * Hm[i,f] + bias[f]
__global__ void gcn_self(const float* __restrict__ Hm, const float* __restrict__ dis,
                         const float* __restrict__ bias, float* __restrict__ out, int F) {
  int i = blockIdx.x;
  float d2 = dis[i] * dis[i];
  for (int f = threadIdx.x; f < F; f += blockDim.x)
    out[(size_t)i * F + f] = d2 * Hm[(size_t)i * F + f] + bias[f];
}

// out[dst,f] += dis[src]*dis[dst]*em * Hm[src,f]
__global__ void gcn_scatter(const int* __restrict__ src, const int* __restrict__ dst,
                            const float* __restrict__ em, const float* __restrict__ dis,
                            const float* __restrict__ Hm, float* __restrict__ out, int F) {
  int e = blockIdx.x;
  float m = em ? em[e] : 1.0f;
  if (m == 0.f) return;
  int s = src[e], d = dst[e];
  float c = dis[s] * dis[d] * m;
  for (int f = threadIdx.x; f < F; f += blockDim.x)
    atomicAdd(&out[(size_t)d * F + f], c * Hm[(size_t)s * F + f]);
}

__global__ void relu_ip(float* __restrict__ x, int n) {
  int i = blockIdx.x * 256 + threadIdx.x;
  if (i < n) x[i] = fmaxf(x[i], 0.f);
}

// norm of weight vector (n<=256), one block
__global__ void wnorm(const float* __restrict__ w, int n, float* __restrict__ out) {
  __shared__ float red[256];
  float s = 0.f;
  for (int k = threadIdx.x; k < n; k += 256) s += w[k] * w[k];
  red[threadIdx.x] = s;
  __syncthreads();
  for (int off = 128; off > 0; off >>= 1) {
    if (threadIdx.x < off) red[threadIdx.x] += red[threadIdx.x + off];
    __syncthreads();
  }
  if (threadIdx.x == 0) out[0] = sqrtf(red[0]);
}

// per-row dot with w (raw, pre-division by norm)
__global__ void rowdot(const float* __restrict__ X, const float* __restrict__ w,
                       float* __restrict__ out, int F) {
  int i = blockIdx.x;
  __shared__ float red[256];
  float s = 0.f;
  for (int f = threadIdx.x; f < F; f += 256) s += X[(size_t)i * F + f] * w[f];
  red[threadIdx.x] = s;
  __syncthreads();
  for (int off = 128; off > 0; off >>= 1) {
    if (threadIdx.x < off) red[threadIdx.x] += red[threadIdx.x + off];
    __syncthreads();
  }
  if (threadIdx.x == 0) out[i] = red[0];
}

// exact-total-order descending bitonic sort over 4096 packed keys; emits top-k indices.
// key = (sortable_float(score) << 32) | ~index  -> ties broken toward lower index.
__global__ __launch_bounds__(1024) void bitonic_topk(const float* __restrict__ score,
                                                     int n, int* __restrict__ perm, int k) {
  __shared__ unsigned long long keys[4096];
  int t = threadIdx.x;
  for (int i = t; i < 4096; i += 1024) {
    unsigned long long kk = 0ull;
    if (i < n) {
      float f = score[i];
      unsigned u = __float_as_uint(f);
      u = (f >= 0.0f) ? (u | 0x80000000u) : ~u;
      kk = ((unsigned long long)u << 32) | (unsigned)(~(unsigned)i);
    }
    keys[i] = kk;
  }
  __syncthreads();
  for (int size = 2; size <= 4096; size <<= 1) {
    for (int stride = size >> 1; stride > 0; stride >>= 1) {
      for (int i = t; i < 2048; i += 1024) {
        int pos = ((i & ~(stride - 1)) << 1) | (i & (stride - 1));
        int partner = pos + stride;
        bool desc = (pos & size) == 0;
        unsigned long long a = keys[pos], b = keys[partner];
        if ((a < b) == desc) { keys[pos] = b; keys[partner] = a; }
      }
      __syncthreads();
    }
  }
  for (int i = t; i < k; i += 1024)
    perm[i] = (int)(~(unsigned)(keys[i] & 0xFFFFFFFFull));
}

__global__ void set_map(const int* __restrict__ perm, int* __restrict__ map, int k) {
  int i = blockIdx.x * 256 + threadIdx.x;
  if (i < k) map[perm[i]] = i;
}

// Xn[i,:] = X[perm[i],:] * tanh(dot[perm[i]] / norm)
__global__ void pool_gather(const float* __restrict__ X, const int* __restrict__ perm,
                            const float* __restrict__ dot, const float* __restrict__ normbuf,
                            float* __restrict__ Xn, int F) {
  int i = blockIdx.x;
  int p = perm[i];
  float sc = tanhf(dot[p] / normbuf[0]);
  for (int f = threadIdx.x; f < F; f += blockDim.x)
    Xn[(size_t)i * F + f] = X[(size_t)p * F + f] * sc;
}

__global__ void remap_edges(const int* __restrict__ srcIn, const int* __restrict__ dstIn,
                            const float* __restrict__ emIn, const int* __restrict__ map,
                            int* __restrict__ srcOut, int* __restrict__ dstOut,
                            float* __restrict__ emOut) {
  int e = blockIdx.x * 256 + threadIdx.x;
  if (e >= E) return;
  int ns = map[srcIn[e]], nd = map[dstIn[e]];
  float m = emIn ? emIn[e] : 1.0f;
  if (ns < 0 || nd < 0) m = 0.f;
  srcOut[e] = ns < 0 ? 0 : ns;
  dstOut[e] = nd < 0 ? 0 : nd;
  emOut[e] = m;
}

// scoef[dst] += dis[src]*dis[dst]*em
__global__ void enc_scoef(const int* __restrict__ src, const int* __restrict__ dst,
                          const float* __restrict__ em, const float* __restrict__ dis,
                          float* __restrict__ scoef) {
  int e = blockIdx.x * 256 + threadIdx.x;
  if (e >= E) return;
  float m = em[e];
  if (m == 0.f) return;
  atomicAdd(&scoef[dst[e]], dis[src[e]] * dis[dst[e]] * m);
}

// xg1[i,f] = relu((scoef[i]+dis[i]^2)*w[f] + b[f]) ; F = 64
__global__ void enc1_out(const float* __restrict__ scoef, const float* __restrict__ dis,
                         const float* __restrict__ w, const float* __restrict__ b,
                         float* __restrict__ xg1) {
  int i = blockIdx.x;
  int f = threadIdx.x;
  float s = scoef[i] + dis[i] * dis[i];
  xg1[(size_t)i * UHD + f] = fmaxf(s * w[f] + b[f], 0.f);
}

// column mean: out[c] = mean over rows of X[:,c]
__global__ void col_mean(const float* __restrict__ X, float* __restrict__ out,
                         int rows, int cols) {
  int c = blockIdx.x;
  __shared__ float red[256];
  float s = 0.f;
  for (int r = threadIdx.x; r < rows; r += 256) s += X[(size_t)r * cols + c];
  red[threadIdx.x] = s;
  __syncthreads();
  for (int off = 128; off > 0; off >>= 1) {
    if (threadIdx.x < off) red[threadIdx.x] += red[threadIdx.x + off];
    __syncthreads();
  }
  if (threadIdx.x == 0) out[c] = red[0] / (float)rows;
}

// small vec @ mat single-block: out[j] = act(sum_k v[k]*W[k*N+j] + b[j]); K,N <= 256
template <int ACT>
__global__ void vecmat(const float* __restrict__ v, const float* __restrict__ W,
                       const float* __restrict__ b, float* __restrict__ out,
                       int Kdim, int Ndim) {
  __shared__ float vs[256];
  for (int k = threadIdx.x; k < Kdim; k += blockDim.x) vs[k] = v[k];
  __syncthreads();
  for (int j = threadIdx.x; j < Ndim; j += blockDim.x) {
    float acc = b ? b[j] : 0.f;
    for (int k = 0; k < Kdim; k++) acc += vs[k] * W[(size_t)k * Ndim + j];
    out[j] = (ACT == 1) ? fmaxf(acc, 0.f) : acc;
  }
}

// wide vec @ mat with tanh: out[j] = tanh(sum_k v[k]*W[k*N+j] + b[j]); K<=64
__global__ void vecmat_tanh_wide(const float* __restrict__ v, const float* __restrict__ W,
                                 const float* __restrict__ b, float* __restrict__ out,
                                 int Kdim, int Ndim) {
  __shared__ float vs[64];
  if (threadIdx.x < Kdim) vs[threadIdx.x] = v[threadIdx.x];
  __syncthreads();
  int j = blockIdx.x * 256 + threadIdx.x;
  if (j >= Ndim) return;
  float acc = b[j];
  for (int k = 0; k < Kdim; k++) acc += vs[k] * W[(size_t)k * Ndim + j];
  out[j] = tanhf(acc);
}

// B[i,j] = scale*((pm_ij - pm_ji) + i*(pm_ij + pm_ji)), scale = 0.05*0.5/2^s
__global__ void build_B(const float* __restrict__ pm, float2* __restrict__ Bm,
                        int n, float scale) {
  int idx = blockIdx.x * 256 + threadIdx.x;
  if (idx >= n * n) return;
  int r = idx / n, c = idx - r * n;
  float pij = pm[(size_t)r * n + c];
  float pji = pm[(size_t)c * n + r];
  Bm[idx] = make_float2(scale * (pij - pji), scale * (pij + pji));
}

// R = I + B/m
__global__ void expm_init(const float2* __restrict__ Bm, float2* __restrict__ R,
                          int n, float inv_m) {
  int idx = blockIdx.x * 256 + threadIdx.x;
  if (idx >= n * n) return;
  int r = idx / n, c = idx - r * n;
  float2 b = Bm[idx];
  R[idx] = make_float2(b.x * inv_m + (r == c ? 1.f : 0.f), b.y * inv_m);
}

__global__ void pack2(const float* __restrict__ a, const float* __restrict__ b,
                      float2* __restrict__ out, int n) {
  int i = blockIdx.x * 256 + threadIdx.x;
  if (i < n) out[i] = make_float2(a[i], b[i]);
}

// agg[dst,f] += em * evo[src,f]  (complex)
__global__ void agg_scatter(const int* __restrict__ src, const int* __restrict__ dst,
                            const float* __restrict__ em, const float2* __restrict__ evo,
                            float2* __restrict__ agg, int F) {
  int e = blockIdx.x;
  float m = em[e];
  if (m == 0.f) return;
  int s = src[e], d = dst[e];
  for (int f = threadIdx.x; f < F; f += blockDim.x) {
    float2 v = evo[(size_t)s * F + f];
    atomicAdd(&agg[(size_t)d * F + f].x, m * v.x);
    atomicAdd(&agg[(size_t)d * F + f].y, m * v.y);
  }
}

// outc = agg + (xr + i*xi); mag/ph
__global__ void magph(const float2* __restrict__ agg, const float* __restrict__ xr,
                      const float* __restrict__ xi, float* __restrict__ mag,
                      float* __restrict__ ph, int n) {
  int idx = blockIdx.x * 256 + threadIdx.x;
  if (idx >= n) return;
  float2 a = agg[idx];
  float r = a.x + xr[idx];
  float im = a.y + xi[idx];
  mag[idx] = sqrtf(r * r + im * im);
  ph[idx] = atan2f(im, r);
}

__global__ void add_out(const float* __restrict__ lm, const float* __restrict__ lp,
                        float* __restrict__ out, int n) {
  int i = threadIdx.x;
  if (i < n) out[i] = lm[i] + lp[i];
}

// ---------------- host helpers ----------------
static inline int sk_chunk(int K, int S) { return (((K + S - 1) / S) + 15) & ~15; }

// ---------------- host ----------------
extern "C" void kernel_launch(void* const* d_in, const int* in_sizes, int n_in,
                              void* d_out, int out_size, void* d_ws, size_t ws_size,
                              hipStream_t stream) {
  if (ws_size < WS_NEED) return;

  const float* x       = (const float*)d_in[0];
  const int*   ei      = (const int*)d_in[1];
  const float* gcn1_w  = (const float*)d_in[2];
  const float* gcn1_b  = (const float*)d_in[3];
  const float* pool1_w = (const float*)d_in[4];
  const float* gcn2_w  = (const float*)d_in[5];
  const float* gcn2_b  = (const float*)d_in[6];
  const float* pool2_w = (const float*)d_in[7];
  const float* inr_w   = (const float*)d_in[8];
  const float* inr_b   = (const float*)d_in[9];
  const float* ini_w   = (const float*)d_in[10];
  const float* ini_b   = (const float*)d_in[11];
  const float* enc1_w  = (const float*)d_in[12];
  const float* enc1_b  = (const float*)d_in[13];
  const float* enc2_w  = (const float*)d_in[14];
  const float* enc2_b  = (const float*)d_in[15];
  const float* p1_w    = (const float*)d_in[16];
  const float* p1_b    = (const float*)d_in[17];
  const float* p2_w    = (const float*)d_in[18];
  const float* p2_b    = (const float*)d_in[19];
  const float* p3_w    = (const float*)d_in[20];
  const float* p3_b    = (const float*)d_in[21];
  const float* rt_w    = (const float*)d_in[22];
  const float* rt_b    = (const float*)d_in[23];
  const float* it_w    = (const float*)d_in[24];
  const float* it_b    = (const float*)d_in[25];
  const float* msg_wr  = (const float*)d_in[26];
  const float* msg_wi  = (const float*)d_in[27];
  const float* mc1_w   = (const float*)d_in[28];
  const float* mc1_b   = (const float*)d_in[29];
  const float* mc2_w   = (const float*)d_in[30];
  const float* mc2_b   = (const float*)d_in[31];
  const float* pc1_w   = (const float*)d_in[32];
  const float* pc1_b   = (const float*)d_in[33];
  const float* pc2_w   = (const float*)d_in[34];
  const float* pc2_b   = (const float*)d_in[35];

  char* ws = (char*)d_ws;
  float*  H1    = (float*)(ws + O_H1);
  float*  OUT1  = (float*)(ws + O_OUT1);
  float*  DEG1  = (float*)(ws + O_DEG1);
  float*  DIS1  = (float*)(ws + O_DIS1);
  float*  SC1   = (float*)(ws + O_SC1);
  int*    PERM1 = (int*)(ws + O_PERM1);
  int*    MAP1  = (int*)(ws + O_MAP1);
  float*  H1P   = (float*)(ws + O_H1P);
  int*    SRC2  = (int*)(ws + O_SRC2);
  int*    DST2  = (int*)(ws + O_DST2);
  float*  EM2   = (float*)(ws + O_EM2);
  float*  H2    = (float*)(ws + O_H2);
  float*  OUT2  = (float*)(ws + O_OUT2);
  float*  DEG2  = (float*)(ws + O_DEG2);
  float*  DIS2  = (float*)(ws + O_DIS2);
  float*  SC2   = (float*)(ws + O_SC2);
  int*    PERM2 = (int*)(ws + O_PERM2);
  int*    MAP2  = (int*)(ws + O_MAP2);
  float*  H2P   = (float*)(ws + O_H2P);
  int*    SRC3  = (int*)(ws + O_SRC3);
  int*    DST3  = (int*)(ws + O_DST3);
  float*  EM3   = (float*)(ws + O_EM3);
  float*  XRb   = (float*)(ws + O_XR);
  float*  XIb   = (float*)(ws + O_XI);
  float*  DEG3  = (float*)(ws + O_DEG3);
  float*  DIS3  = (float*)(ws + O_DIS3);
  float*  SCOEF = (float*)(ws + O_SCOEF);
  float*  XG1   = (float*)(ws + O_XG1);
  float*  XG2H  = (float*)(ws + O_XG2H);
  float*  XG2   = (float*)(ws + O_XG2);
  float*  EMB   = (float*)(ws + O_EMB);
  float*  T1    = (float*)(ws + O_T1);
  float*  T2    = (float*)(ws + O_T2);
  float*  NORM  = (float*)(ws + O_NORM);
  float*  PMV   = (float*)(ws + O_PM);
  float2* BM    = (float2*)(ws + O_BM);
  float2* P0v   = (float2*)(ws + O_P0);
  float2* P1v   = (float2*)(ws + O_P1);
  float*  XRT   = (float*)(ws + O_XRT);
  float*  XIT   = (float*)(ws + O_XIT);
  float2* XC    = (float2*)(ws + O_XC);
  float2* EVO   = (float2*)(ws + O_EVO);
  float2* AGG0  = (float2*)(ws + O_AGG0);
  float2* WC    = (float2*)(ws + O_WC);
  float2* AGG1  = (float2*)(ws + O_AGG1);
  float*  MAGB  = (float*)(ws + O_MAG);
  float*  PHB   = (float*)(ws + O_PH);
  float*  GM    = (float*)(ws + O_GM);
  float*  GP    = (float*)(ws + O_GP);
  float*  HM    = (float*)(ws + O_HM);
  float*  HP    = (float*)(ws + O_HP);
  float*  LM    = (float*)(ws + O_LM);
  float*  LP    = (float*)(ws + O_LP);

  const int* SRC1 = ei;
  const int* DST1 = ei + E;

  // ---------- Stage A: gcn1 + relu ----------
  rmm64<0><<<dim3(HD / 64, N0 / 64), 256, 0, stream>>>(x, gcn1_w, nullptr, H1, N0, HD, DIN);
  hipMemsetAsync(DEG1, 0, F4(N0), stream);
  edge_deg<<<E / 256, 256, 0, stream>>>(DST1, nullptr, DEG1);
  deg_to_dis<<<N0 / 256, 256, 0, stream>>>(DEG1, DIS1, N0);
  gcn_self<<<N0, 256, 0, stream>>>(H1, DIS1, gcn1_b, OUT1, HD);
  gcn_scatter<<<E, 256, 0, stream>>>(SRC1, DST1, nullptr, DIS1, H1, OUT1, HD);
  relu_ip<<<(N0 * HD) / 256, 256, 0, stream>>>(OUT1, N0 * HD);

  // ---------- pool1 ----------
  wnorm<<<1, 256, 0, stream>>>(pool1_w, HD, NORM);
  rowdot<<<N0, 256, 0, stream>>>(OUT1, pool1_w, SC1, HD);
  bitonic_topk<<<1, 1024, 0, stream>>>(SC1, N0, PERM1, K1);
  hipMemsetAsync(MAP1, 0xFF, F4(N0), stream);
  set_map<<<(K1 + 255) / 256, 256, 0, stream>>>(PERM1, MAP1, K1);
  pool_gather<<<K1, 256, 0, stream>>>(OUT1, PERM1, SC1, NORM, H1P, HD);
  remap_edges<<<E / 256, 256, 0, stream>>>(SRC1, DST1, nullptr, MAP1, SRC2, DST2, EM2);

  // ---------- Stage C: gcn2 + relu ----------
  rmm64<0><<<dim3(HD / 64, (K1 + 63) / 64), 256, 0, stream>>>(H1P, gcn2_w, nullptr, H2, K1, HD, HD);
  hipMemsetAsync(DEG2, 0, F4(N0), stream);
  edge_deg<<<E / 256, 256, 0, stream>>>(DST2, EM2, DEG2);
  deg_to_dis<<<(K1 + 255) / 256, 256, 0, stream>>>(DEG2, DIS2, K1);
  gcn_self<<<K1, 256, 0, stream>>>(H2, DIS2, gcn2_b, OUT2, HD);
  gcn_scatter<<<E, 256, 0, stream>>>(SRC2, DST2, EM2, DIS2, H2, OUT2, HD);
  relu_ip<<<(K1 * HD + 255) / 256, 256, 0, stream>>>(OUT2, K1 * HD);

  // ---------- pool2 ----------
  wnorm<<<1, 256, 0, stream>>>(pool2_w, HD, NORM + 1);
  rowdot<<<K1, 256, 0, stream>>>(OUT2, pool2_w, SC2, HD);
  bitonic_topk<<<1, 1024, 0, stream>>>(SC2, K1, PERM2, K2);
  hipMemsetAsync(MAP2, 0xFF, F4(N0), stream);
  set_map<<<(K2 + 255) / 256, 256, 0, stream>>>(PERM2, MAP2, K2);
  pool_gather<<<K2, 256, 0, stream>>>(OUT2, PERM2, SC2, NORM + 1, H2P, HD);
  remap_edges<<<E / 256, 256, 0, stream>>>(SRC2, DST2, EM2, MAP2, SRC3, DST3, EM3);

  // ---------- xr / xi ----------
  rmm64<0><<<dim3(HD / 64, (K2 + 63) / 64), 256, 0, stream>>>(H2P, inr_w, inr_b, XRb, K2, HD, HD);
  rmm64<0><<<dim3(HD / 64, (K2 + 63) / 64), 256, 0, stream>>>(H2P, ini_w, ini_b, XIb, K2, HD, HD);

  // ---------- encoder GCNs on pooled graph ----------
  hipMemsetAsync(DEG3, 0, F4(K2), stream);
  edge_deg<<<E / 256, 256, 0, stream>>>(DST3, EM3, DEG3);
  deg_to_dis<<<(K2 + 255) / 256, 256, 0, stream>>>(DEG3, DIS3, K2);
  hipMemsetAsync(SCOEF, 0, F4(K2), stream);
  enc_scoef<<<E / 256, 256, 0, stream>>>(SRC3, DST3, EM3, DIS3, SCOEF);
  enc1_out<<<K2, UHD, 0, stream>>>(SCOEF, DIS3, enc1_w, enc1_b, XG1);
  rmm64<0><<<dim3(UHD / 64, (K2 + 63) / 64), 256, 0, stream>>>(XG1, enc2_w, nullptr, XG2H, K2, UHD, UHD);
  gcn_self<<<K2, UHD, 0, stream>>>(XG2H, DIS3, enc2_b, XG2, UHD);
  gcn_scatter<<<E, UHD, 0, stream>>>(SRC3, DST3, EM3, DIS3, XG2H, XG2, UHD);
  col_mean<<<UHD, 256, 0, stream>>>(XG2, EMB, K2, UHD);

  // ---------- parameter MLP -> pm -> B ----------
  vecmat<1><<<1, 256, 0, stream>>>(EMB, p1_w, p1_b, T1, UHD, UHD);
  vecmat<1><<<1, 256, 0, stream>>>(T1, p2_w, p2_b, T2, UHD, UHD / 2);
  vecmat_tanh_wide<<<(PMN + 255) / 256, 256, 0, stream>>>(T2, p3_w, p3_b, PMV, UHD / 2, PMN);
  {
    const float scale = 0.05f * 0.5f / (float)(1 << EXPM_S);
    build_B<<<(PMN + 255) / 256, 256, 0, stream>>>(PMV, BM, K2, scale);
  }

  // ---------- expm(A) = (Taylor_m(B))^(2^s), split-K GEMMs ----------
  const int chK2 = sk_chunk(K2, CSPLIT);
  const dim3 gK2(11, 11, CSPLIT);
  expm_init<<<(PMN + 255) / 256, 256, 0, stream>>>(BM, P0v, K2, 1.0f / (float)EXPM_M);
  float2* cur = P0v;
  float2* nxt = P1v;
  for (int j = EXPM_M - 1; j >= 1; --j) {
    cinit<<<(PMN + 255) / 256, 256, 0, stream>>>(nxt, K2, K2, 1);
    cmm64_sk<<<gK2, 256, 0, stream>>>(BM, cur, nxt, K2, K2, K2, chK2, 1.0f / (float)j);
    std::swap(cur, nxt);
  }
  for (int t = 0; t < EXPM_S; ++t) {
    cinit<<<(PMN + 255) / 256, 256, 0, stream>>>(nxt, K2, K2, 0);
    cmm64_sk<<<gK2, 256, 0, stream>>>(cur, cur, nxt, K2, K2, K2, chK2, 1.0f);
    std::swap(cur, nxt);
  }
  float2* U = cur;

  // ---------- quantum message passing ----------
  rmm64<1><<<dim3(HD / 64, (K2 + 63) / 64), 256, 0, stream>>>(XRb, rt_w, rt_b, XRT, K2, HD, HD);
  rmm64<1><<<dim3(HD / 64, (K2 + 63) / 64), 256, 0, stream>>>(XIb, it_w, it_b, XIT, K2, HD, HD);
  pack2<<<(K2 * HD + 255) / 256, 256, 0, stream>>>(XRT, XIT, XC, K2 * HD);
  hipMemsetAsync(EVO, 0, F4(K2 * HD) * 2, stream);
  cmm64_sk<<<dim3(HD / 64, (K2 + 63) / 64, CSPLIT), 256, 0, stream>>>(
      U, XC, EVO, K2, HD, K2, chK2, 1.0f);
  hipMemsetAsync(AGG0, 0, F4(K2 * HD) * 2, stream);
  agg_scatter<<<E, 256, 0, stream>>>(SRC3, DST3, EM3, EVO, AGG0, HD);
  pack2<<<(HD * HD + 255) / 256, 256, 0, stream>>>(msg_wr, msg_wi, WC, HD * HD);
  hipMemsetAsync(AGG1, 0, F4(K2 * HD) * 2, stream);
  cmm64_sk<<<dim3(HD / 64, (K2 + 63) / 64, CSPLIT), 256, 0, stream>>>(
      AGG0, WC, AGG1, K2, HD, HD, sk_chunk(HD, CSPLIT), 1.0f);
  magph<<<(K2 * HD + 255) / 256, 256, 0, stream>>>(AGG1, XRb, XIb, MAGB, PHB, K2 * HD);
  col_mean<<<HD, 256, 0, stream>>>(MAGB, GM, K2, HD);
  col_mean<<<HD, 256, 0, stream>>>(PHB, GP, K2, HD);

  // ---------- classifier heads ----------
  vecmat<1><<<1, 256, 0, stream>>>(GM, mc1_w, mc1_b, HM, HD, HD / 2);
  vecmat<0><<<1, 256, 0, stream>>>(HM, mc2_w, mc2_b, LM, HD / 2, NC);
  vecmat<1><<<1, 256, 0, stream>>>(GP, pc1_w, pc1_b, HP, HD, HD / 2);
  vecmat<0><<<1, 256, 0, stream>>>(HP, pc2_w, pc2_b, LP, HD / 2, NC);
  add_out<<<1, 64, 0, stream>>>(LM, LP, (float*)d_out, NC);
}

// Round 4
// 1940.512 us; speedup vs baseline: 7.6242x; 1.5292x over previous
//
#include <hip/hip_runtime.h>
#include <cstddef>
#include <utility>

// ---------------- problem constants ----------------
constexpr int N0  = 4096;
constexpr int E   = 65536;
constexpr int DIN = 128;
constexpr int HD  = 256;   // H
constexpr int NC  = 10;
constexpr int UHD = 64;    // UH
constexpr int K1  = 3277;  // ceil(0.8*4096)
constexpr int K2  = 656;   // ceil(0.2*3277)
constexpr int PMN = K2 * K2; // 430336

// expm(A): A = 64*B, exp(B) via Taylor m=8 Horner, then square 6 times.
// Worst case |A_ij| <= 0.05*sqrt(2), ||A||_2 <= 46 -> ||B|| <= 0.72;
// m=8 truncation ~0.72^9/9! ~ 3e-7, x2^6 squaring growth ~2e-5 << 1.5e-2.
constexpr int EXPM_S = 6;
constexpr int EXPM_M = 8;

// split-K factor for complex GEMMs. R3: atomic split-K hit 247 MB HBM write
// traffic/dispatch (device-scope fp32 atomics RMW at memory side, 64B/op).
// Now each z writes a private partial; creduce sums them (plain stores).
constexpr int CSPLIT = 4;

// ---------------- workspace layout (all chunks multiple of 256 B) ----------------
#define F4(n) ((size_t)(n) * 4)
constexpr size_t O_H1    = 0;
constexpr size_t O_OUT1  = O_H1    + F4(N0 * HD);
constexpr size_t O_DEG1  = O_OUT1  + F4(N0 * HD);
constexpr size_t O_DIS1  = O_DEG1  + F4(N0);
constexpr size_t O_SC1   = O_DIS1  + F4(N0);
constexpr size_t O_PERM1 = O_SC1   + F4(N0);
constexpr size_t O_MAP1  = O_PERM1 + F4(N0);
constexpr size_t O_H1P   = O_MAP1  + F4(N0);
constexpr size_t O_SRC2  = O_H1P   + F4(K1 * HD);
constexpr size_t O_DST2  = O_SRC2  + F4(E);
constexpr size_t O_EM2   = O_DST2  + F4(E);
constexpr size_t O_H2    = O_EM2   + F4(E);
constexpr size_t O_OUT2  = O_H2    + F4(K1 * HD);
constexpr size_t O_DEG2  = O_OUT2  + F4(K1 * HD);
constexpr size_t O_DIS2  = O_DEG2  + F4(N0);
constexpr size_t O_SC2   = O_DIS2  + F4(N0);
constexpr size_t O_PERM2 = O_SC2   + F4(N0);
constexpr size_t O_MAP2  = O_PERM2 + F4(N0);
constexpr size_t O_H2P   = O_MAP2  + F4(N0);
constexpr size_t O_SRC3  = O_H2P   + F4(K2 * HD);
constexpr size_t O_DST3  = O_SRC3  + F4(E);
constexpr size_t O_EM3   = O_DST3  + F4(E);
constexpr size_t O_XR    = O_EM3   + F4(E);
constexpr size_t O_XI    = O_XR    + F4(K2 * HD);
constexpr size_t O_DEG3  = O_XI    + F4(K2 * HD);
constexpr size_t O_DIS3  = O_DEG3  + F4(1024);
constexpr size_t O_SCOEF = O_DIS3  + F4(1024);
constexpr size_t O_XG1   = O_SCOEF + F4(1024);
constexpr size_t O_XG2H  = O_XG1   + F4(K2 * UHD);
constexpr size_t O_XG2   = O_XG2H  + F4(K2 * UHD);
constexpr size_t O_EMB   = O_XG2   + F4(K2 * UHD);
constexpr size_t O_T1    = O_EMB   + F4(64);
constexpr size_t O_T2    = O_T1    + F4(64);
constexpr size_t O_NORM  = O_T2    + F4(64);   // [0]=norm1, [1]=norm2
constexpr size_t O_PM    = O_NORM  + F4(64);
constexpr size_t O_BM    = O_PM    + F4(PMN);          // float2
constexpr size_t O_P0    = O_BM    + F4(PMN) * 2;      // float2
constexpr size_t O_P1    = O_P0    + F4(PMN) * 2;      // float2
constexpr size_t O_XRT   = O_P1    + F4(PMN) * 2;
constexpr size_t O_XIT   = O_XRT   + F4(K2 * HD);
constexpr size_t O_XC    = O_XIT   + F4(K2 * HD);      // float2
constexpr size_t O_EVO   = O_XC    + F4(K2 * HD) * 2;  // float2
constexpr size_t O_AGG0  = O_EVO   + F4(K2 * HD) * 2;  // float2
constexpr size_t O_WC    = O_AGG0  + F4(K2 * HD) * 2;  // float2 256x256
constexpr size_t O_AGG1  = O_WC    + F4(HD * HD) * 2;  // float2
constexpr size_t O_MAG   = O_AGG1  + F4(K2 * HD) * 2;
constexpr size_t O_PH    = O_MAG   + F4(K2 * HD);
constexpr size_t O_GM    = O_PH    + F4(K2 * HD);
constexpr size_t O_GP    = O_GM    + F4(256);
constexpr size_t O_HM    = O_GP    + F4(256);
constexpr size_t O_HP    = O_HM    + F4(256);
constexpr size_t O_LM    = O_HP    + F4(256);
constexpr size_t O_LP    = O_LM    + F4(64);
constexpr size_t WS_NEED = O_LP    + F4(64);

// Split-K partial buffers alias the dead stage-A/B region at offset 0:
// H1/OUT1/H1P/SRC2/DST2/EM2/H2 are all last touched before build_B, and
// everything read after the expm phase lives at offsets >= O_SRC3 (19.7 MB).
constexpr size_t O_PART  = 0;
constexpr size_t PART_SZ = (size_t)CSPLIT * PMN * 8;  // 13.77 MB
static_assert(PART_SZ <= O_SRC3, "partials must stay below live SRC3 region");

// ---------------- kernels ----------------

// real GEMM: C[M,N] = act(A[M,K] @ B[K,N] + bias). 64x64 tile, 4x4 per thread.
// Requires K % 16 == 0 and N % 16 == 0 (true for all call sites).
template <int ACT>
__global__ void rmm64(const float* __restrict__ A, const float* __restrict__ B,
                      const float* __restrict__ bias, float* __restrict__ C,
                      int M, int N, int K) {
  __shared__ float As[64][17];
  __shared__ float Bs[16][64];
  int t  = threadIdx.x;
  int tx = t & 15, ty = t >> 4;
  int bm = blockIdx.y * 64, bn = blockIdx.x * 64;
  float acc[4][4] = {};
  for (int kt = 0; kt < K; kt += 16) {
#pragma unroll
    for (int i = 0; i < 4; i++) {
      int l = t + i * 256;
      int kk = l & 15, mm = l >> 4;
      int gr = bm + mm;
      As[mm][kk] = (gr < M) ? A[(size_t)gr * K + kt + kk] : 0.f;
    }
#pragma unroll
    for (int i = 0; i < 4; i++) {
      int l = t + i * 256;
      int cc = l & 63, kk = l >> 6;
      int gc = bn + cc;
      Bs[kk][cc] = (gc < N) ? B[(size_t)(kt + kk) * N + gc] : 0.f;
    }
    __syncthreads();
#pragma unroll
    for (int kk = 0; kk < 16; kk++) {
      float a[4], b[4];
#pragma unroll
      for (int i = 0; i < 4; i++) a[i] = As[ty + 16 * i][kk];
#pragma unroll
      for (int j = 0; j < 4; j++) b[j] = Bs[kk][tx + 16 * j];
#pragma unroll
      for (int i = 0; i < 4; i++)
#pragma unroll
        for (int j = 0; j < 4; j++) acc[i][j] += a[i] * b[j];
    }
    __syncthreads();
  }
#pragma unroll
  for (int i = 0; i < 4; i++) {
    int r = bm + ty + 16 * i;
    if (r >= M) continue;
#pragma unroll
    for (int j = 0; j < 4; j++) {
      int c = bn + tx + 16 * j;
      if (c >= N) continue;
      float v = acc[i][j] + (bias ? bias[c] : 0.f);
      if (ACT == 1) v = fmaxf(v, 0.f);
      C[(size_t)r * N + c] = v;
    }
  }
}

// split-K complex GEMM, partial-store variant: Part[z] = A[:, kz]@B[kz, :].
// Plain stores (no atomics -> no memory-side RMW traffic; R3 post-mortem).
// blockIdx.z selects k-chunk [z*chunk, min(K,(z+1)*chunk)); chunk % 16 == 0,
// and chunk*(gridDim.z-1) < K so every z writes its full partial.
// __launch_bounds__(256,2): default VGPR cap of 64 spills the 32-float
// accumulator (R1: 1.3 GB scratch writes/dispatch).
__global__ __launch_bounds__(256, 2) void cmm64_ps(
    const float2* __restrict__ A, const float2* __restrict__ B,
    float2* __restrict__ Part, int M, int N, int K, int chunk) {
  int k0 = blockIdx.z * chunk;
  int kend = min(K, k0 + chunk);
  __shared__ float2 As[64][17];
  __shared__ float2 Bs[16][64];
  int t  = threadIdx.x;
  int tx = t & 15, ty = t >> 4;
  int bm = blockIdx.y * 64, bn = blockIdx.x * 64;
  float accr[4][4] = {}, acci[4][4] = {};
  for (int kt = k0; kt < kend; kt += 16) {
#pragma unroll
    for (int i = 0; i < 4; i++) {
      int l = t + i * 256;
      int kk = l & 15, mm = l >> 4;
      int gr = bm + mm;
      As[mm][kk] = (gr < M) ? A[(size_t)gr * K + kt + kk] : make_float2(0.f, 0.f);
    }
#pragma unroll
    for (int i = 0; i < 4; i++) {
      int l = t + i * 256;
      int cc = l & 63, kk = l >> 6;
      int gc = bn + cc;
      Bs[kk][cc] = (gc < N) ? B[(size_t)(kt + kk) * N + gc] : make_float2(0.f, 0.f);
    }
    __syncthreads();
#pragma unroll
    for (int kk = 0; kk < 16; kk++) {
      float2 a[4], b[4];
#pragma unroll
      for (int i = 0; i < 4; i++) a[i] = As[ty + 16 * i][kk];
#pragma unroll
      for (int j = 0; j < 4; j++) b[j] = Bs[kk][tx + 16 * j];
#pragma unroll
      for (int i = 0; i < 4; i++)
#pragma unroll
        for (int j = 0; j < 4; j++) {
          accr[i][j] += a[i].x * b[j].x - a[i].y * b[j].y;
          acci[i][j] += a[i].x * b[j].y + a[i].y * b[j].x;
        }
    }
    __syncthreads();
  }
  float2* P = Part + (size_t)blockIdx.z * M * N;
#pragma unroll
  for (int i = 0; i < 4; i++) {
    int r = bm + ty + 16 * i;
    if (r >= M) continue;
#pragma unroll
    for (int j = 0; j < 4; j++) {
      int c = bn + tx + 16 * j;
      if (c >= N) continue;
      P[(size_t)r * N + c] = make_float2(accr[i][j], acci[i][j]);
    }
  }
}

// C = (addi ? I : 0) + alpha * sum_z Part[z]
__global__ void creduce(const float2* __restrict__ Part, float2* __restrict__ C,
                        int MN, int N, int S, int addi, float alpha) {
  int idx = blockIdx.x * 256 + threadIdx.x;
  if (idx >= MN) return;
  float sr = 0.f, si = 0.f;
  for (int z = 0; z < S; z++) {
    float2 p = Part[(size_t)z * MN + idx];
    sr += p.x;
    si += p.y;
  }
  sr *= alpha;
  si *= alpha;
  if (addi) {
    int r = idx / N, c = idx - r * N;
    if (r == c) sr += 1.0f;
  }
  C[idx] = make_float2(sr, si);
}

// deg[dst[e]] += em (em==nullptr -> 1.0)
__global__ void edge_deg(const int* __restrict__ dst, const float* __restrict__ em,
                         float* __restrict__ deg) {
  int e = blockIdx.x * 256 + threadIdx.x;
  if (e >= E) return;
  float m = em ? em[e] : 1.0f;
  if (m != 0.f) atomicAdd(&deg[dst[e]], m);
}

__global__ void deg_to_dis(const float* __restrict__ deg, float* __restrict__ dis, int n) {
  int i = blockIdx.x * 256 + threadIdx.x;
  if (i >= n) return;
  dis[i] = 1.0f / sqrtf(deg[i] + 1.0f);
}

// out[i,f] = dis[i]^2 * Hm[i,f] + bias[f]
__global__ void gcn_self(const float* __restrict__ Hm, const float* __restrict__ dis,
                         const float* __restrict__ bias, float* __restrict__ out, int F) {
  int i = blockIdx.x;
  float d2 = dis[i] * dis[i];
  for (int f = threadIdx.x; f < F; f += blockDim.x)
    out[(size_t)i * F + f] = d2 * Hm[(size_t)i * F + f] + bias[f];
}

// out[dst,f] += dis[src]*dis[dst]*em * Hm[src,f]
__global__ void gcn_scatter(const int* __restrict__ src, const int* __restrict__ dst,
                            const float* __restrict__ em, const float* __restrict__ dis,
                            const float* __restrict__ Hm, float* __restrict__ out, int F) {
  int e = blockIdx.x;
  float m = em ? em[e] : 1.0f;
  if (m == 0.f) return;
  int s = src[e], d = dst[e];
  float c = dis[s] * dis[d] * m;
  for (int f = threadIdx.x; f < F; f += blockDim.x)
    atomicAdd(&out[(size_t)d * F + f], c * Hm[(size_t)s * F + f]);
}

__global__ void relu_ip(float* __restrict__ x, int n) {
  int i = blockIdx.x * 256 + threadIdx.x;
  if (i < n) x[i] = fmaxf(x[i], 0.f);
}

// norm of weight vector (n<=256), one block
__global__ void wnorm(const float* __restrict__ w, int n, float* __restrict__ out) {
  __shared__ float red[256];
  float s = 0.f;
  for (int k = threadIdx.x; k < n; k += 256) s += w[k] * w[k];
  red[threadIdx.x] = s;
  __syncthreads();
  for (int off = 128; off > 0; off >>= 1) {
    if (threadIdx.x < off) red[threadIdx.x] += red[threadIdx.x + off];
    __syncthreads();
  }
  if (threadIdx.x == 0) out[0] = sqrtf(red[0]);
}

// per-row dot with w (raw, pre-division by norm)
__global__ void rowdot(const float* __restrict__ X, const float* __restrict__ w,
                       float* __restrict__ out, int F) {
  int i = blockIdx.x;
  __shared__ float red[256];
  float s = 0.f;
  for (int f = threadIdx.x; f < F; f += 256) s += X[(size_t)i * F + f] * w[f];
  red[threadIdx.x] = s;
  __syncthreads();
  for (int off = 128; off > 0; off >>= 1) {
    if (threadIdx.x < off) red[threadIdx.x] += red[threadIdx.x + off];
    __syncthreads();
  }
  if (threadIdx.x == 0) out[i] = red[0];
}

// exact-total-order descending bitonic sort over 4096 packed keys; emits top-k indices.
// key = (sortable_float(score) << 32) | ~index  -> ties broken toward lower index.
__global__ __launch_bounds__(1024) void bitonic_topk(const float* __restrict__ score,
                                                     int n, int* __restrict__ perm, int k) {
  __shared__ unsigned long long keys[4096];
  int t = threadIdx.x;
  for (int i = t; i < 4096; i += 1024) {
    unsigned long long kk = 0ull;
    if (i < n) {
      float f = score[i];
      unsigned u = __float_as_uint(f);
      u = (f >= 0.0f) ? (u | 0x80000000u) : ~u;
      kk = ((unsigned long long)u << 32) | (unsigned)(~(unsigned)i);
    }
    keys[i] = kk;
  }
  __syncthreads();
  for (int size = 2; size <= 4096; size <<= 1) {
    for (int stride = size >> 1; stride > 0; stride >>= 1) {
      for (int i = t; i < 2048; i += 1024) {
        int pos = ((i & ~(stride - 1)) << 1) | (i & (stride - 1));
        int partner = pos + stride;
        bool desc = (pos & size) == 0;
        unsigned long long a = keys[pos], b = keys[partner];
        if ((a < b) == desc) { keys[pos] = b; keys[partner] = a; }
      }
      __syncthreads();
    }
  }
  for (int i = t; i < k; i += 1024)
    perm[i] = (int)(~(unsigned)(keys[i] & 0xFFFFFFFFull));
}

__global__ void set_map(const int* __restrict__ perm, int* __restrict__ map, int k) {
  int i = blockIdx.x * 256 + threadIdx.x;
  if (i < k) map[perm[i]] = i;
}

// Xn[i,:] = X[perm[i],:] * tanh(dot[perm[i]] / norm)
__global__ void pool_gather(const float* __restrict__ X, const int* __restrict__ perm,
                            const float* __restrict__ dot, const float* __restrict__ normbuf,
                            float* __restrict__ Xn, int F) {
  int i = blockIdx.x;
  int p = perm[i];
  float sc = tanhf(dot[p] / normbuf[0]);
  for (int f = threadIdx.x; f < F; f += blockDim.x)
    Xn[(size_t)i * F + f] = X[(size_t)p * F + f] * sc;
}

__global__ void remap_edges(const int* __restrict__ srcIn, const int* __restrict__ dstIn,
                            const float* __restrict__ emIn, const int* __restrict__ map,
                            int* __restrict__ srcOut, int* __restrict__ dstOut,
                            float* __restrict__ emOut) {
  int e = blockIdx.x * 256 + threadIdx.x;
  if (e >= E) return;
  int ns = map[srcIn[e]], nd = map[dstIn[e]];
  float m = emIn ? emIn[e] : 1.0f;
  if (ns < 0 || nd < 0) m = 0.f;
  srcOut[e] = ns < 0 ? 0 : ns;
  dstOut[e] = nd < 0 ? 0 : nd;
  emOut[e] = m;
}

// scoef[dst] += dis[src]*dis[dst]*em
__global__ void enc_scoef(const int* __restrict__ src, const int* __restrict__ dst,
                          const float* __restrict__ em, const float* __restrict__ dis,
                          float* __restrict__ scoef) {
  int e = blockIdx.x * 256 + threadIdx.x;
  if (e >= E) return;
  float m = em[e];
  if (m == 0.f) return;
  atomicAdd(&scoef[dst[e]], dis[src[e]] * dis[dst[e]] * m);
}

// xg1[i,f] = relu((scoef[i]+dis[i]^2)*w[f] + b[f]) ; F = 64
__global__ void enc1_out(const float* __restrict__ scoef, const float* __restrict__ dis,
                         const float* __restrict__ w, const float* __restrict__ b,
                         float* __restrict__ xg1) {
  int i = blockIdx.x;
  int f = threadIdx.x;
  float s = scoef[i] + dis[i] * dis[i];
  xg1[(size_t)i * UHD + f] = fmaxf(s * w[f] + b[f], 0.f);
}

// column mean: out[c] = mean over rows of X[:,c]
__global__ void col_mean(const float* __restrict__ X, float* __restrict__ out,
                         int rows, int cols) {
  int c = blockIdx.x;
  __shared__ float red[256];
  float s = 0.f;
  for (int r = threadIdx.x; r < rows; r += 256) s += X[(size_t)r * cols + c];
  red[threadIdx.x] = s;
  __syncthreads();
  for (int off = 128; off > 0; off >>= 1) {
    if (threadIdx.x < off) red[threadIdx.x] += red[threadIdx.x + off];
    __syncthreads();
  }
  if (threadIdx.x == 0) out[c] = red[0] / (float)rows;
}

// small vec @ mat single-block: out[j] = act(sum_k v[k]*W[k*N+j] + b[j]); K,N <= 256
template <int ACT>
__global__ void vecmat(const float* __restrict__ v, const float* __restrict__ W,
                       const float* __restrict__ b, float* __restrict__ out,
                       int Kdim, int Ndim) {
  __shared__ float vs[256];
  for (int k = threadIdx.x; k < Kdim; k += blockDim.x) vs[k] = v[k];
  __syncthreads();
  for (int j = threadIdx.x; j < Ndim; j += blockDim.x) {
    float acc = b ? b[j] : 0.f;
    for (int k = 0; k < Kdim; k++) acc += vs[k] * W[(size_t)k * Ndim + j];
    out[j] = (ACT == 1) ? fmaxf(acc, 0.f) : acc;
  }
}

// wide vec @ mat with tanh: out[j] = tanh(sum_k v[k]*W[k*N+j] + b[j]); K<=64
__global__ void vecmat_tanh_wide(const float* __restrict__ v, const float* __restrict__ W,
                                 const float* __restrict__ b, float* __restrict__ out,
                                 int Kdim, int Ndim) {
  __shared__ float vs[64];
  if (threadIdx.x < Kdim) vs[threadIdx.x] = v[threadIdx.x];
  __syncthreads();
  int j = blockIdx.x * 256 + threadIdx.x;
  if (j >= Ndim) return;
  float acc = b[j];
  for (int k = 0; k < Kdim; k++) acc += vs[k] * W[(size_t)k * Ndim + j];
  out[j] = tanhf(acc);
}

// B[i,j] = scale*((pm_ij - pm_ji) + i*(pm_ij + pm_ji)), scale = 0.05*0.5/2^s
__global__ void build_B(const float* __restrict__ pm, float2* __restrict__ Bm,
                        int n, float scale) {
  int idx = blockIdx.x * 256 + threadIdx.x;
  if (idx >= n * n) return;
  int r = idx / n, c = idx - r * n;
  float pij = pm[(size_t)r * n + c];
  float pji = pm[(size_t)c * n + r];
  Bm[idx] = make_float2(scale * (pij - pji), scale * (pij + pji));
}

// R = I + B/m
__global__ void expm_init(const float2* __restrict__ Bm, float2* __restrict__ R,
                          int n, float inv_m) {
  int idx = blockIdx.x * 256 + threadIdx.x;
  if (idx >= n * n) return;
  int r = idx / n, c = idx - r * n;
  float2 b = Bm[idx];
  R[idx] = make_float2(b.x * inv_m + (r == c ? 1.f : 0.f), b.y * inv_m);
}

__global__ void pack2(const float* __restrict__ a, const float* __restrict__ b,
                      float2* __restrict__ out, int n) {
  int i = blockIdx.x * 256 + threadIdx.x;
  if (i < n) out[i] = make_float2(a[i], b[i]);
}

// agg[dst,f] += em * evo[src,f]  (complex)
__global__ void agg_scatter(const int* __restrict__ src, const int* __restrict__ dst,
                            const float* __restrict__ em, const float2* __restrict__ evo,
                            float2* __restrict__ agg, int F) {
  int e = blockIdx.x;
  float m = em[e];
  if (m == 0.f) return;
  int s = src[e], d = dst[e];
  for (int f = threadIdx.x; f < F; f += blockDim.x) {
    float2 v = evo[(size_t)s * F + f];
    atomicAdd(&agg[(size_t)d * F + f].x, m * v.x);
    atomicAdd(&agg[(size_t)d * F + f].y, m * v.y);
  }
}

// outc = agg + (xr + i*xi); mag/ph
__global__ void magph(const float2* __restrict__ agg, const float* __restrict__ xr,
                      const float* __restrict__ xi, float* __restrict__ mag,
                      float* __restrict__ ph, int n) {
  int idx = blockIdx.x * 256 + threadIdx.x;
  if (idx >= n) return;
  float2 a = agg[idx];
  float r = a.x + xr[idx];
  float im = a.y + xi[idx];
  mag[idx] = sqrtf(r * r + im * im);
  ph[idx] = atan2f(im, r);
}

__global__ void add_out(const float* __restrict__ lm, const float* __restrict__ lp,
                        float* __restrict__ out, int n) {
  int i = threadIdx.x;
  if (i < n) out[i] = lm[i] + lp[i];
}

// ---------------- host helpers ----------------
static inline int sk_chunk(int K, int S) { return (((K + S - 1) / S) + 15) & ~15; }

// ---------------- host ----------------
extern "C" void kernel_launch(void* const* d_in, const int* in_sizes, int n_in,
                              void* d_out, int out_size, void* d_ws, size_t ws_size,
                              hipStream_t stream) {
  if (ws_size < WS_NEED) return;

  const float* x       = (const float*)d_in[0];
  const int*   ei      = (const int*)d_in[1];
  const float* gcn1_w  = (const float*)d_in[2];
  const float* gcn1_b  = (const float*)d_in[3];
  const float* pool1_w = (const float*)d_in[4];
  const float* gcn2_w  = (const float*)d_in[5];
  const float* gcn2_b  = (const float*)d_in[6];
  const float* pool2_w = (const float*)d_in[7];
  const float* inr_w   = (const float*)d_in[8];
  const float* inr_b   = (const float*)d_in[9];
  const float* ini_w   = (const float*)d_in[10];
  const float* ini_b   = (const float*)d_in[11];
  const float* enc1_w  = (const float*)d_in[12];
  const float* enc1_b  = (const float*)d_in[13];
  const float* enc2_w  = (const float*)d_in[14];
  const float* enc2_b  = (const float*)d_in[15];
  const float* p1_w    = (const float*)d_in[16];
  const float* p1_b    = (const float*)d_in[17];
  const float* p2_w    = (const float*)d_in[18];
  const float* p2_b    = (const float*)d_in[19];
  const float* p3_w    = (const float*)d_in[20];
  const float* p3_b    = (const float*)d_in[21];
  const float* rt_w    = (const float*)d_in[22];
  const float* rt_b    = (const float*)d_in[23];
  const float* it_w    = (const float*)d_in[24];
  const float* it_b    = (const float*)d_in[25];
  const float* msg_wr  = (const float*)d_in[26];
  const float* msg_wi  = (const float*)d_in[27];
  const float* mc1_w   = (const float*)d_in[28];
  const float* mc1_b   = (const float*)d_in[29];
  const float* mc2_w   = (const float*)d_in[30];
  const float* mc2_b   = (const float*)d_in[31];
  const float* pc1_w   = (const float*)d_in[32];
  const float* pc1_b   = (const float*)d_in[33];
  const float* pc2_w   = (const float*)d_in[34];
  const float* pc2_b   = (const float*)d_in[35];

  char* ws = (char*)d_ws;
  float*  H1    = (float*)(ws + O_H1);
  float*  OUT1  = (float*)(ws + O_OUT1);
  float*  DEG1  = (float*)(ws + O_DEG1);
  float*  DIS1  = (float*)(ws + O_DIS1);
  float*  SC1   = (float*)(ws + O_SC1);
  int*    PERM1 = (int*)(ws + O_PERM1);
  int*    MAP1  = (int*)(ws + O_MAP1);
  float*  H1P   = (float*)(ws + O_H1P);
  int*    SRC2  = (int*)(ws + O_SRC2);
  int*    DST2  = (int*)(ws + O_DST2);
  float*  EM2   = (float*)(ws + O_EM2);
  float*  H2    = (float*)(ws + O_H2);
  float*  OUT2  = (float*)(ws + O_OUT2);
  float*  DEG2  = (float*)(ws + O_DEG2);
  float*  DIS2  = (float*)(ws + O_DIS2);
  float*  SC2   = (float*)(ws + O_SC2);
  int*    PERM2 = (int*)(ws + O_PERM2);
  int*    MAP2  = (int*)(ws + O_MAP2);
  float*  H2P   = (float*)(ws + O_H2P);
  int*    SRC3  = (int*)(ws + O_SRC3);
  int*    DST3  = (int*)(ws + O_DST3);
  float*  EM3   = (float*)(ws + O_EM3);
  float*  XRb   = (float*)(ws + O_XR);
  float*  XIb   = (float*)(ws + O_XI);
  float*  DEG3  = (float*)(ws + O_DEG3);
  float*  DIS3  = (float*)(ws + O_DIS3);
  float*  SCOEF = (float*)(ws + O_SCOEF);
  float*  XG1   = (float*)(ws + O_XG1);
  float*  XG2H  = (float*)(ws + O_XG2H);
  float*  XG2   = (float*)(ws + O_XG2);
  float*  EMB   = (float*)(ws + O_EMB);
  float*  T1    = (float*)(ws + O_T1);
  float*  T2    = (float*)(ws + O_T2);
  float*  NORM  = (float*)(ws + O_NORM);
  float*  PMV   = (float*)(ws + O_PM);
  float2* BM    = (float2*)(ws + O_BM);
  float2* P0v   = (float2*)(ws + O_P0);
  float2* P1v   = (float2*)(ws + O_P1);
  float*  XRT   = (float*)(ws + O_XRT);
  float*  XIT   = (float*)(ws + O_XIT);
  float2* XC    = (float2*)(ws + O_XC);
  float2* EVO   = (float2*)(ws + O_EVO);
  float2* AGG0  = (float2*)(ws + O_AGG0);
  float2* WC    = (float2*)(ws + O_WC);
  float2* AGG1  = (float2*)(ws + O_AGG1);
  float*  MAGB  = (float*)(ws + O_MAG);
  float*  PHB   = (float*)(ws + O_PH);
  float*  GM    = (float*)(ws + O_GM);
  float*  GP    = (float*)(ws + O_GP);
  float*  HM    = (float*)(ws + O_HM);
  float*  HP    = (float*)(ws + O_HP);
  float*  LM    = (float*)(ws + O_LM);
  float*  LP    = (float*)(ws + O_LP);
  float2* PART  = (float2*)(ws + O_PART);  // aliases dead stage-A/B buffers

  const int* SRC1 = ei;
  const int* DST1 = ei + E;

  // ---------- Stage A: gcn1 + relu ----------
  rmm64<0><<<dim3(HD / 64, N0 / 64), 256, 0, stream>>>(x, gcn1_w, nullptr, H1, N0, HD, DIN);
  hipMemsetAsync(DEG1, 0, F4(N0), stream);
  edge_deg<<<E / 256, 256, 0, stream>>>(DST1, nullptr, DEG1);
  deg_to_dis<<<N0 / 256, 256, 0, stream>>>(DEG1, DIS1, N0);
  gcn_self<<<N0, 256, 0, stream>>>(H1, DIS1, gcn1_b, OUT1, HD);
  gcn_scatter<<<E, 256, 0, stream>>>(SRC1, DST1, nullptr, DIS1, H1, OUT1, HD);
  relu_ip<<<(N0 * HD) / 256, 256, 0, stream>>>(OUT1, N0 * HD);

  // ---------- pool1 ----------
  wnorm<<<1, 256, 0, stream>>>(pool1_w, HD, NORM);
  rowdot<<<N0, 256, 0, stream>>>(OUT1, pool1_w, SC1, HD);
  bitonic_topk<<<1, 1024, 0, stream>>>(SC1, N0, PERM1, K1);
  hipMemsetAsync(MAP1, 0xFF, F4(N0), stream);
  set_map<<<(K1 + 255) / 256, 256, 0, stream>>>(PERM1, MAP1, K1);
  pool_gather<<<K1, 256, 0, stream>>>(OUT1, PERM1, SC1, NORM, H1P, HD);
  remap_edges<<<E / 256, 256, 0, stream>>>(SRC1, DST1, nullptr, MAP1, SRC2, DST2, EM2);

  // ---------- Stage C: gcn2 + relu ----------
  rmm64<0><<<dim3(HD / 64, (K1 + 63) / 64), 256, 0, stream>>>(H1P, gcn2_w, nullptr, H2, K1, HD, HD);
  hipMemsetAsync(DEG2, 0, F4(N0), stream);
  edge_deg<<<E / 256, 256, 0, stream>>>(DST2, EM2, DEG2);
  deg_to_dis<<<(K1 + 255) / 256, 256, 0, stream>>>(DEG2, DIS2, K1);
  gcn_self<<<K1, 256, 0, stream>>>(H2, DIS2, gcn2_b, OUT2, HD);
  gcn_scatter<<<E, 256, 0, stream>>>(SRC2, DST2, EM2, DIS2, H2, OUT2, HD);
  relu_ip<<<(K1 * HD + 255) / 256, 256, 0, stream>>>(OUT2, K1 * HD);

  // ---------- pool2 ----------
  wnorm<<<1, 256, 0, stream>>>(pool2_w, HD, NORM + 1);
  rowdot<<<K1, 256, 0, stream>>>(OUT2, pool2_w, SC2, HD);
  bitonic_topk<<<1, 1024, 0, stream>>>(SC2, K1, PERM2, K2);
  hipMemsetAsync(MAP2, 0xFF, F4(N0), stream);
  set_map<<<(K2 + 255) / 256, 256, 0, stream>>>(PERM2, MAP2, K2);
  pool_gather<<<K2, 256, 0, stream>>>(OUT2, PERM2, SC2, NORM + 1, H2P, HD);
  remap_edges<<<E / 256, 256, 0, stream>>>(SRC2, DST2, EM2, MAP2, SRC3, DST3, EM3);

  // ---------- xr / xi ----------
  rmm64<0><<<dim3(HD / 64, (K2 + 63) / 64), 256, 0, stream>>>(H2P, inr_w, inr_b, XRb, K2, HD, HD);
  rmm64<0><<<dim3(HD / 64, (K2 + 63) / 64), 256, 0, stream>>>(H2P, ini_w, ini_b, XIb, K2, HD, HD);

  // ---------- encoder GCNs on pooled graph ----------
  hipMemsetAsync(DEG3, 0, F4(K2), stream);
  edge_deg<<<E / 256, 256, 0, stream>>>(DST3, EM3, DEG3);
  deg_to_dis<<<(K2 + 255) / 256, 256, 0, stream>>>(DEG3, DIS3, K2);
  hipMemsetAsync(SCOEF, 0, F4(K2), stream);
  enc_scoef<<<E / 256, 256, 0, stream>>>(SRC3, DST3, EM3, DIS3, SCOEF);
  enc1_out<<<K2, UHD, 0, stream>>>(SCOEF, DIS3, enc1_w, enc1_b, XG1);
  rmm64<0><<<dim3(UHD / 64, (K2 + 63) / 64), 256, 0, stream>>>(XG1, enc2_w, nullptr, XG2H, K2, UHD, UHD);
  gcn_self<<<K2, UHD, 0, stream>>>(XG2H, DIS3, enc2_b, XG2, UHD);
  gcn_scatter<<<E, UHD, 0, stream>>>(SRC3, DST3, EM3, DIS3, XG2H, XG2, UHD);
  col_mean<<<UHD, 256, 0, stream>>>(XG2, EMB, K2, UHD);

  // ---------- parameter MLP -> pm -> B ----------
  vecmat<1><<<1, 256, 0, stream>>>(EMB, p1_w, p1_b, T1, UHD, UHD);
  vecmat<1><<<1, 256, 0, stream>>>(T1, p2_w, p2_b, T2, UHD, UHD / 2);
  vecmat_tanh_wide<<<(PMN + 255) / 256, 256, 0, stream>>>(T2, p3_w, p3_b, PMV, UHD / 2, PMN);
  {
    const float scale = 0.05f * 0.5f / (float)(1 << EXPM_S);
    build_B<<<(PMN + 255) / 256, 256, 0, stream>>>(PMV, BM, K2, scale);
  }

  // ---------- expm(A) = (Taylor_m(B))^(2^s), split-K partial-sum GEMMs ----------
  const int chK2 = sk_chunk(K2, CSPLIT);          // 176; 176*3=528 < 656 ok
  const dim3 gK2(11, 11, CSPLIT);
  const int rgrid = (PMN + 255) / 256;
  expm_init<<<rgrid, 256, 0, stream>>>(BM, P0v, K2, 1.0f / (float)EXPM_M);
  float2* cur = P0v;
  float2* nxt = P1v;
  for (int j = EXPM_M - 1; j >= 1; --j) {
    cmm64_ps<<<gK2, 256, 0, stream>>>(BM, cur, PART, K2, K2, K2, chK2);
    creduce<<<rgrid, 256, 0, stream>>>(PART, nxt, PMN, K2, CSPLIT, 1, 1.0f / (float)j);
    std::swap(cur, nxt);
  }
  for (int t = 0; t < EXPM_S; ++t) {
    cmm64_ps<<<gK2, 256, 0, stream>>>(cur, cur, PART, K2, K2, K2, chK2);
    creduce<<<rgrid, 256, 0, stream>>>(PART, nxt, PMN, K2, CSPLIT, 0, 1.0f);
    std::swap(cur, nxt);
  }
  float2* U = cur;

  // ---------- quantum message passing ----------
  rmm64<1><<<dim3(HD / 64, (K2 + 63) / 64), 256, 0, stream>>>(XRb, rt_w, rt_b, XRT, K2, HD, HD);
  rmm64<1><<<dim3(HD / 64, (K2 + 63) / 64), 256, 0, stream>>>(XIb, it_w, it_b, XIT, K2, HD, HD);
  pack2<<<(K2 * HD + 255) / 256, 256, 0, stream>>>(XRT, XIT, XC, K2 * HD);
  {
    const int mn = K2 * HD;
    const int rg = (mn + 255) / 256;
    cmm64_ps<<<dim3(HD / 64, (K2 + 63) / 64, CSPLIT), 256, 0, stream>>>(
        U, XC, PART, K2, HD, K2, chK2);
    creduce<<<rg, 256, 0, stream>>>(PART, EVO, mn, HD, CSPLIT, 0, 1.0f);
    hipMemsetAsync(AGG0, 0, F4(K2 * HD) * 2, stream);
    agg_scatter<<<E, 256, 0, stream>>>(SRC3, DST3, EM3, EVO, AGG0, HD);
    pack2<<<(HD * HD + 255) / 256, 256, 0, stream>>>(msg_wr, msg_wi, WC, HD * HD);
    cmm64_ps<<<dim3(HD / 64, (K2 + 63) / 64, CSPLIT), 256, 0, stream>>>(
        AGG0, WC, PART, K2, HD, HD, sk_chunk(HD, CSPLIT));
    creduce<<<rg, 256, 0, stream>>>(PART, AGG1, mn, HD, CSPLIT, 0, 1.0f);
  }
  magph<<<(K2 * HD + 255) / 256, 256, 0, stream>>>(AGG1, XRb, XIb, MAGB, PHB, K2 * HD);
  col_mean<<<HD, 256, 0, stream>>>(MAGB, GM, K2, HD);
  col_mean<<<HD, 256, 0, stream>>>(PHB, GP, K2, HD);

  // ---------- classifier heads ----------
  vecmat<1><<<1, 256, 0, stream>>>(GM, mc1_w, mc1_b, HM, HD, HD / 2);
  vecmat<0><<<1, 256, 0, stream>>>(HM, mc2_w, mc2_b, LM, HD / 2, NC);
  vecmat<1><<<1, 256, 0, stream>>>(GP, pc1_w, pc1_b, HP, HD, HD / 2);
  vecmat<0><<<1, 256, 0, stream>>>(HP, pc2_w, pc2_b, LP, HD / 2, NC);
  add_out<<<1, 64, 0, stream>>>(LM, LP, (float*)d_out, NC);
}

// Round 5
// 1561.820 us; speedup vs baseline: 9.4728x; 1.2425x over previous
//
#include <hip/hip_runtime.h>
#include <cstddef>
#include <utility>

// ---------------- problem constants ----------------
constexpr int N0  = 4096;
constexpr int E   = 65536;
constexpr int DIN = 128;
constexpr int HD  = 256;   // H
constexpr int NC  = 10;
constexpr int UHD = 64;    // UH
constexpr int K1  = 3277;  // ceil(0.8*4096)
constexpr int K2  = 656;   // ceil(0.2*3277)
constexpr int PMN = K2 * K2; // 430336

// expm(A): A = 2^5*B, exp(B) via degree-11 Taylor (Paterson-Stockmeyer,
// 5 mults: B2, B3, 3 Horner steps in y=B3), then square 5 times.
// Worst case ||A||_2 <= 656*0.05*sqrt(2) = 46.4 -> ||B|| <= 1.45;
// remainder ~ 1.45^12/12! * e^1.45 ~ 8e-7, x2^5 growth ~ 2.5e-5 << 1.5e-2.
constexpr int EXPM_S = 5;

// split-K factor for complex GEMMs. R3: atomic split-K cost 247 MB/dispatch of
// memory-side RMW; R4: private partials + creduce fixed it (93 us/GEMM).
constexpr int CSPLIT = 4;

// ---------------- workspace layout (all chunks multiple of 256 B) ----------------
#define F4(n) ((size_t)(n) * 4)
constexpr size_t O_H1    = 0;
constexpr size_t O_OUT1  = O_H1    + F4(N0 * HD);
constexpr size_t O_DEG1  = O_OUT1  + F4(N0 * HD);
constexpr size_t O_DIS1  = O_DEG1  + F4(N0);
constexpr size_t O_SC1   = O_DIS1  + F4(N0);
constexpr size_t O_PERM1 = O_SC1   + F4(N0);
constexpr size_t O_MAP1  = O_PERM1 + F4(N0);
constexpr size_t O_H1P   = O_MAP1  + F4(N0);
constexpr size_t O_SRC2  = O_H1P   + F4(K1 * HD);
constexpr size_t O_DST2  = O_SRC2  + F4(E);
constexpr size_t O_EM2   = O_DST2  + F4(E);
constexpr size_t O_H2    = O_EM2   + F4(E);
constexpr size_t O_OUT2  = O_H2    + F4(K1 * HD);
constexpr size_t O_DEG2  = O_OUT2  + F4(K1 * HD);
constexpr size_t O_DIS2  = O_DEG2  + F4(N0);
constexpr size_t O_SC2   = O_DIS2  + F4(N0);
constexpr size_t O_PERM2 = O_SC2   + F4(N0);
constexpr size_t O_MAP2  = O_PERM2 + F4(N0);
constexpr size_t O_H2P   = O_MAP2  + F4(N0);
constexpr size_t O_SRC3  = O_H2P   + F4(K2 * HD);
constexpr size_t O_DST3  = O_SRC3  + F4(E);
constexpr size_t O_EM3   = O_DST3  + F4(E);
constexpr size_t O_XR    = O_EM3   + F4(E);
constexpr size_t O_XI    = O_XR    + F4(K2 * HD);
constexpr size_t O_DEG3  = O_XI    + F4(K2 * HD);
constexpr size_t O_DIS3  = O_DEG3  + F4(1024);
constexpr size_t O_SCOEF = O_DIS3  + F4(1024);
constexpr size_t O_XG1   = O_SCOEF + F4(1024);
constexpr size_t O_XG2H  = O_XG1   + F4(K2 * UHD);
constexpr size_t O_XG2   = O_XG2H  + F4(K2 * UHD);
constexpr size_t O_EMB   = O_XG2   + F4(K2 * UHD);
constexpr size_t O_T1    = O_EMB   + F4(64);
constexpr size_t O_T2    = O_T1    + F4(64);
constexpr size_t O_NORM  = O_T2    + F4(64);   // [0]=norm1, [1]=norm2
constexpr size_t O_PM    = O_NORM  + F4(64);
constexpr size_t O_BM    = O_PM    + F4(PMN);          // float2
constexpr size_t O_P0    = O_BM    + F4(PMN) * 2;      // float2
constexpr size_t O_P1    = O_P0    + F4(PMN) * 2;      // float2
constexpr size_t O_XRT   = O_P1    + F4(PMN) * 2;
constexpr size_t O_XIT   = O_XRT   + F4(K2 * HD);
constexpr size_t O_XC    = O_XIT   + F4(K2 * HD);      // float2
constexpr size_t O_EVO   = O_XC    + F4(K2 * HD) * 2;  // float2
constexpr size_t O_AGG0  = O_EVO   + F4(K2 * HD) * 2;  // float2
constexpr size_t O_WC    = O_AGG0  + F4(K2 * HD) * 2;  // float2 256x256
constexpr size_t O_AGG1  = O_WC    + F4(HD * HD) * 2;  // float2
constexpr size_t O_MAG   = O_AGG1  + F4(K2 * HD) * 2;
constexpr size_t O_PH    = O_MAG   + F4(K2 * HD);
constexpr size_t O_GM    = O_PH    + F4(K2 * HD);
constexpr size_t O_GP    = O_GM    + F4(256);
constexpr size_t O_HM    = O_GP    + F4(256);
constexpr size_t O_HP    = O_HM    + F4(256);
constexpr size_t O_LM    = O_HP    + F4(256);
constexpr size_t O_LP    = O_LM    + F4(64);
constexpr size_t WS_NEED = O_LP    + F4(64);

// Split-K partial buffers alias the dead stage-A/B region at offset 0:
// everything below O_SRC3 is dead once the expm phase starts.
constexpr size_t O_PART  = 0;
constexpr size_t PART_SZ = (size_t)CSPLIT * PMN * 8;  // 13.77 MB
static_assert(PART_SZ <= O_SRC3, "partials must stay below live SRC3 region");

// B2/B3 (Paterson-Stockmeyer powers) alias the XRT..AGG1 region, which is
// only written AFTER the expm phase completes (stream-ordered, safe).
constexpr size_t O_B2 = O_XRT;
constexpr size_t O_B3 = O_B2 + F4(PMN) * 2;
static_assert(O_B3 + F4(PMN) * 2 <= O_MAG, "B2/B3 must fit in XRT..AGG1 region");

// ---------------- kernels ----------------

// real GEMM: C[M,N] = act(A[M,K] @ B[K,N] + bias). 64x64 tile, 4x4 per thread.
template <int ACT>
__global__ void rmm64(const float* __restrict__ A, const float* __restrict__ B,
                      const float* __restrict__ bias, float* __restrict__ C,
                      int M, int N, int K) {
  __shared__ float As[64][17];
  __shared__ float Bs[16][64];
  int t  = threadIdx.x;
  int tx = t & 15, ty = t >> 4;
  int bm = blockIdx.y * 64, bn = blockIdx.x * 64;
  float acc[4][4] = {};
  for (int kt = 0; kt < K; kt += 16) {
#pragma unroll
    for (int i = 0; i < 4; i++) {
      int l = t + i * 256;
      int kk = l & 15, mm = l >> 4;
      int gr = bm + mm;
      As[mm][kk] = (gr < M) ? A[(size_t)gr * K + kt + kk] : 0.f;
    }
#pragma unroll
    for (int i = 0; i < 4; i++) {
      int l = t + i * 256;
      int cc = l & 63, kk = l >> 6;
      int gc = bn + cc;
      Bs[kk][cc] = (gc < N) ? B[(size_t)(kt + kk) * N + gc] : 0.f;
    }
    __syncthreads();
#pragma unroll
    for (int kk = 0; kk < 16; kk++) {
      float a[4], b[4];
#pragma unroll
      for (int i = 0; i < 4; i++) a[i] = As[ty + 16 * i][kk];
#pragma unroll
      for (int j = 0; j < 4; j++) b[j] = Bs[kk][tx + 16 * j];
#pragma unroll
      for (int i = 0; i < 4; i++)
#pragma unroll
        for (int j = 0; j < 4; j++) acc[i][j] += a[i] * b[j];
    }
    __syncthreads();
  }
#pragma unroll
  for (int i = 0; i < 4; i++) {
    int r = bm + ty + 16 * i;
    if (r >= M) continue;
#pragma unroll
    for (int j = 0; j < 4; j++) {
      int c = bn + tx + 16 * j;
      if (c >= N) continue;
      float v = acc[i][j] + (bias ? bias[c] : 0.f);
      if (ACT == 1) v = fmaxf(v, 0.f);
      C[(size_t)r * N + c] = v;
    }
  }
}

// split-K complex GEMM, partial-store + register prefetch double-buffer:
// Part[z] = A[:, kz]@B[kz, :]. Tile k+1 is staged into registers while tile k
// computes from LDS, hiding global-load latency behind the FMA stream (R4:
// VALUBusy 47% -> barrier-drain bound without prefetch).
// Requires chunk % 16 == 0 and K % 16 == 0 (all call sites comply).
// __launch_bounds__(256,2): default 64-VGPR cap spills the accumulator (R1).
__global__ __launch_bounds__(256, 2) void cmm64_ps(
    const float2* __restrict__ A, const float2* __restrict__ B,
    float2* __restrict__ Part, int M, int N, int K, int chunk) {
  int k0 = blockIdx.z * chunk;
  int kend = min(K, k0 + chunk);
  __shared__ float2 As[64][17];
  __shared__ float2 Bs[16][64];
  int t  = threadIdx.x;
  int tx = t & 15, ty = t >> 4;
  int bm = blockIdx.y * 64, bn = blockIdx.x * 64;
  float2 ra[4], rb[4];
  // prefetch first tile into registers
#pragma unroll
  for (int i = 0; i < 4; i++) {
    int l = t + i * 256;
    int kk = l & 15, mm = l >> 4;
    int gr = bm + mm;
    ra[i] = (gr < M) ? A[(size_t)gr * K + k0 + kk] : make_float2(0.f, 0.f);
    int cc = l & 63, kkb = l >> 6;
    int gc = bn + cc;
    rb[i] = (gc < N) ? B[(size_t)(k0 + kkb) * N + gc] : make_float2(0.f, 0.f);
  }
  float accr[4][4] = {}, acci[4][4] = {};
  for (int kt = k0; kt < kend; kt += 16) {
    // commit staged registers to LDS
#pragma unroll
    for (int i = 0; i < 4; i++) {
      int l = t + i * 256;
      As[l >> 4][l & 15] = ra[i];
      Bs[l >> 6][l & 63] = rb[i];
    }
    __syncthreads();
    int kn = kt + 16;
    if (kn < kend) {  // issue next tile's global loads; no wait until next iter
#pragma unroll
      for (int i = 0; i < 4; i++) {
        int l = t + i * 256;
        int kk = l & 15, mm = l >> 4;
        int gr = bm + mm;
        ra[i] = (gr < M) ? A[(size_t)gr * K + kn + kk] : make_float2(0.f, 0.f);
        int cc = l & 63, kkb = l >> 6;
        int gc = bn + cc;
        rb[i] = (gc < N) ? B[(size_t)(kn + kkb) * N + gc] : make_float2(0.f, 0.f);
      }
    }
#pragma unroll
    for (int kk = 0; kk < 16; kk++) {
      float2 a[4], b[4];
#pragma unroll
      for (int i = 0; i < 4; i++) a[i] = As[ty + 16 * i][kk];
#pragma unroll
      for (int j = 0; j < 4; j++) b[j] = Bs[kk][tx + 16 * j];
#pragma unroll
      for (int i = 0; i < 4; i++)
#pragma unroll
        for (int j = 0; j < 4; j++) {
          accr[i][j] += a[i].x * b[j].x - a[i].y * b[j].y;
          acci[i][j] += a[i].x * b[j].y + a[i].y * b[j].x;
        }
    }
    __syncthreads();
  }
  float2* P = Part + (size_t)blockIdx.z * M * N;
#pragma unroll
  for (int i = 0; i < 4; i++) {
    int r = bm + ty + 16 * i;
    if (r >= M) continue;
#pragma unroll
    for (int j = 0; j < 4; j++) {
      int c = bn + tx + 16 * j;
      if (c >= N) continue;
      P[(size_t)r * N + c] = make_float2(accr[i][j], acci[i][j]);
    }
  }
}

// C = sum_z Part[z] + e0*I + e1*Bp + e2*B2p (Bp/B2p optional; PS epilogue)
__global__ void creduce(const float2* __restrict__ Part, float2* __restrict__ C,
                        int MN, int N, int S, float e0,
                        const float2* __restrict__ Bp, float e1,
                        const float2* __restrict__ B2p, float e2) {
  int idx = blockIdx.x * 256 + threadIdx.x;
  if (idx >= MN) return;
  float sr = 0.f, si = 0.f;
  for (int z = 0; z < S; z++) {
    float2 p = Part[(size_t)z * MN + idx];
    sr += p.x;
    si += p.y;
  }
  if (e0 != 0.f) {
    int r = idx / N;
    if (idx - r * N == r) sr += e0;
  }
  if (Bp) {
    float2 b = Bp[idx];
    sr += e1 * b.x;
    si += e1 * b.y;
  }
  if (B2p) {
    float2 b = B2p[idx];
    sr += e2 * b.x;
    si += e2 * b.y;
  }
  C[idx] = make_float2(sr, si);
}

// Out = e0*I + e1*B + e2*B2 (builds the top PS block D3)
__global__ void combo3(const float2* __restrict__ Bp, const float2* __restrict__ B2p,
                       float2* __restrict__ Out, int MN, int N,
                       float e0, float e1, float e2) {
  int idx = blockIdx.x * 256 + threadIdx.x;
  if (idx >= MN) return;
  float2 b = Bp[idx], b2 = B2p[idx];
  float sr = e1 * b.x + e2 * b2.x;
  float si = e1 * b.y + e2 * b2.y;
  int r = idx / N;
  if (idx - r * N == r) sr += e0;
  Out[idx] = make_float2(sr, si);
}

// deg[dst[e]] += em (em==nullptr -> 1.0)
__global__ void edge_deg(const int* __restrict__ dst, const float* __restrict__ em,
                         float* __restrict__ deg) {
  int e = blockIdx.x * 256 + threadIdx.x;
  if (e >= E) return;
  float m = em ? em[e] : 1.0f;
  if (m != 0.f) atomicAdd(&deg[dst[e]], m);
}

__global__ void deg_to_dis(const float* __restrict__ deg, float* __restrict__ dis, int n) {
  int i = blockIdx.x * 256 + threadIdx.x;
  if (i >= n) return;
  dis[i] = 1.0f / sqrtf(deg[i] + 1.0f);
}

// out[i,f] = dis[i]^2 * Hm[i,f] + bias[f]
__global__ void gcn_self(const float* __restrict__ Hm, const float* __restrict__ dis,
                         const float* __restrict__ bias, float* __restrict__ out, int F) {
  int i = blockIdx.x;
  float d2 = dis[i] * dis[i];
  for (int f = threadIdx.x; f < F; f += blockDim.x)
    out[(size_t)i * F + f] = d2 * Hm[(size_t)i * F + f] + bias[f];
}

// out[dst,f] += dis[src]*dis[dst]*em * Hm[src,f]
__global__ void gcn_scatter(const int* __restrict__ src, const int* __restrict__ dst,
                            const float* __restrict__ em, const float* __restrict__ dis,
                            const float* __restrict__ Hm, float* __restrict__ out, int F) {
  int e = blockIdx.x;
  float m = em ? em[e] : 1.0f;
  if (m == 0.f) return;
  int s = src[e], d = dst[e];
  float c = dis[s] * dis[d] * m;
  for (int f = threadIdx.x; f < F; f += blockDim.x)
    atomicAdd(&out[(size_t)d * F + f], c * Hm[(size_t)s * F + f]);
}

__global__ void relu_ip(float* __restrict__ x, int n) {
  int i = blockIdx.x * 256 + threadIdx.x;
  if (i < n) x[i] = fmaxf(x[i], 0.f);
}

// norm of weight vector (n<=256), one block
__global__ void wnorm(const float* __restrict__ w, int n, float* __restrict__ out) {
  __shared__ float red[256];
  float s = 0.f;
  for (int k = threadIdx.x; k < n; k += 256) s += w[k] * w[k];
  red[threadIdx.x] = s;
  __syncthreads();
  for (int off = 128; off > 0; off >>= 1) {
    if (threadIdx.x < off) red[threadIdx.x] += red[threadIdx.x + off];
    __syncthreads();
  }
  if (threadIdx.x == 0) out[0] = sqrtf(red[0]);
}

// per-row dot with w (raw, pre-division by norm)
__global__ void rowdot(const float* __restrict__ X, const float* __restrict__ w,
                       float* __restrict__ out, int F) {
  int i = blockIdx.x;
  __shared__ float red[256];
  float s = 0.f;
  for (int f = threadIdx.x; f < F; f += 256) s += X[(size_t)i * F + f] * w[f];
  red[threadIdx.x] = s;
  __syncthreads();
  for (int off = 128; off > 0; off >>= 1) {
    if (threadIdx.x < off) red[threadIdx.x] += red[threadIdx.x + off];
    __syncthreads();
  }
  if (threadIdx.x == 0) out[i] = red[0];
}

// exact-total-order descending bitonic sort over 4096 packed keys; emits top-k indices.
// key = (sortable_float(score) << 32) | ~index  -> ties broken toward lower index.
__global__ __launch_bounds__(1024) void bitonic_topk(const float* __restrict__ score,
                                                     int n, int* __restrict__ perm, int k) {
  __shared__ unsigned long long keys[4096];
  int t = threadIdx.x;
  for (int i = t; i < 4096; i += 1024) {
    unsigned long long kk = 0ull;
    if (i < n) {
      float f = score[i];
      unsigned u = __float_as_uint(f);
      u = (f >= 0.0f) ? (u | 0x80000000u) : ~u;
      kk = ((unsigned long long)u << 32) | (unsigned)(~(unsigned)i);
    }
    keys[i] = kk;
  }
  __syncthreads();
  for (int size = 2; size <= 4096; size <<= 1) {
    for (int stride = size >> 1; stride > 0; stride >>= 1) {
      for (int i = t; i < 2048; i += 1024) {
        int pos = ((i & ~(stride - 1)) << 1) | (i & (stride - 1));
        int partner = pos + stride;
        bool desc = (pos & size) == 0;
        unsigned long long a = keys[pos], b = keys[partner];
        if ((a < b) == desc) { keys[pos] = b; keys[partner] = a; }
      }
      __syncthreads();
    }
  }
  for (int i = t; i < k; i += 1024)
    perm[i] = (int)(~(unsigned)(keys[i] & 0xFFFFFFFFull));
}

__global__ void set_map(const int* __restrict__ perm, int* __restrict__ map, int k) {
  int i = blockIdx.x * 256 + threadIdx.x;
  if (i < k) map[perm[i]] = i;
}

// Xn[i,:] = X[perm[i],:] * tanh(dot[perm[i]] / norm)
__global__ void pool_gather(const float* __restrict__ X, const int* __restrict__ perm,
                            const float* __restrict__ dot, const float* __restrict__ normbuf,
                            float* __restrict__ Xn, int F) {
  int i = blockIdx.x;
  int p = perm[i];
  float sc = tanhf(dot[p] / normbuf[0]);
  for (int f = threadIdx.x; f < F; f += blockDim.x)
    Xn[(size_t)i * F + f] = X[(size_t)p * F + f] * sc;
}

__global__ void remap_edges(const int* __restrict__ srcIn, const int* __restrict__ dstIn,
                            const float* __restrict__ emIn, const int* __restrict__ map,
                            int* __restrict__ srcOut, int* __restrict__ dstOut,
                            float* __restrict__ emOut) {
  int e = blockIdx.x * 256 + threadIdx.x;
  if (e >= E) return;
  int ns = map[srcIn[e]], nd = map[dstIn[e]];
  float m = emIn ? emIn[e] : 1.0f;
  if (ns < 0 || nd < 0) m = 0.f;
  srcOut[e] = ns < 0 ? 0 : ns;
  dstOut[e] = nd < 0 ? 0 : nd;
  emOut[e] = m;
}

// scoef[dst] += dis[src]*dis[dst]*em
__global__ void enc_scoef(const int* __restrict__ src, const int* __restrict__ dst,
                          const float* __restrict__ em, const float* __restrict__ dis,
                          float* __restrict__ scoef) {
  int e = blockIdx.x * 256 + threadIdx.x;
  if (e >= E) return;
  float m = em[e];
  if (m == 0.f) return;
  atomicAdd(&scoef[dst[e]], dis[src[e]] * dis[dst[e]] * m);
}

// xg1[i,f] = relu((scoef[i]+dis[i]^2)*w[f] + b[f]) ; F = 64
__global__ void enc1_out(const float* __restrict__ scoef, const float* __restrict__ dis,
                         const float* __restrict__ w, const float* __restrict__ b,
                         float* __restrict__ xg1) {
  int i = blockIdx.x;
  int f = threadIdx.x;
  float s = scoef[i] + dis[i] * dis[i];
  xg1[(size_t)i * UHD + f] = fmaxf(s * w[f] + b[f], 0.f);
}

// column mean: out[c] = mean over rows of X[:,c]
__global__ void col_mean(const float* __restrict__ X, float* __restrict__ out,
                         int rows, int cols) {
  int c = blockIdx.x;
  __shared__ float red[256];
  float s = 0.f;
  for (int r = threadIdx.x; r < rows; r += 256) s += X[(size_t)r * cols + c];
  red[threadIdx.x] = s;
  __syncthreads();
  for (int off = 128; off > 0; off >>= 1) {
    if (threadIdx.x < off) red[threadIdx.x] += red[threadIdx.x + off];
    __syncthreads();
  }
  if (threadIdx.x == 0) out[c] = red[0] / (float)rows;
}

// small vec @ mat single-block: out[j] = act(sum_k v[k]*W[k*N+j] + b[j]); K,N <= 256
template <int ACT>
__global__ void vecmat(const float* __restrict__ v, const float* __restrict__ W,
                       const float* __restrict__ b, float* __restrict__ out,
                       int Kdim, int Ndim) {
  __shared__ float vs[256];
  for (int k = threadIdx.x; k < Kdim; k += blockDim.x) vs[k] = v[k];
  __syncthreads();
  for (int j = threadIdx.x; j < Ndim; j += blockDim.x) {
    float acc = b ? b[j] : 0.f;
    for (int k = 0; k < Kdim; k++) acc += vs[k] * W[(size_t)k * Ndim + j];
    out[j] = (ACT == 1) ? fmaxf(acc, 0.f) : acc;
  }
}

// wide vec @ mat with tanh: out[j] = tanh(sum_k v[k]*W[k*N+j] + b[j]); K<=64
__global__ void vecmat_tanh_wide(const float* __restrict__ v, const float* __restrict__ W,
                                 const float* __restrict__ b, float* __restrict__ out,
                                 int Kdim, int Ndim) {
  __shared__ float vs[64];
  if (threadIdx.x < Kdim) vs[threadIdx.x] = v[threadIdx.x];
  __syncthreads();
  int j = blockIdx.x * 256 + threadIdx.x;
  if (j >= Ndim) return;
  float acc = b[j];
  for (int k = 0; k < Kdim; k++) acc += vs[k] * W[(size_t)k * Ndim + j];
  out[j] = tanhf(acc);
}

// B[i,j] = scale*((pm_ij - pm_ji) + i*(pm_ij + pm_ji)), scale = 0.05*0.5/2^s
__global__ void build_B(const float* __restrict__ pm, float2* __restrict__ Bm,
                        int n, float scale) {
  int idx = blockIdx.x * 256 + threadIdx.x;
  if (idx >= n * n) return;
  int r = idx / n, c = idx - r * n;
  float pij = pm[(size_t)r * n + c];
  float pji = pm[(size_t)c * n + r];
  Bm[idx] = make_float2(scale * (pij - pji), scale * (pij + pji));
}

__global__ void pack2(const float* __restrict__ a, const float* __restrict__ b,
                      float2* __restrict__ out, int n) {
  int i = blockIdx.x * 256 + threadIdx.x;
  if (i < n) out[i] = make_float2(a[i], b[i]);
}

// agg[dst,f] += em * evo[src,f]  (complex)
__global__ void agg_scatter(const int* __restrict__ src, const int* __restrict__ dst,
                            const float* __restrict__ em, const float2* __restrict__ evo,
                            float2* __restrict__ agg, int F) {
  int e = blockIdx.x;
  float m = em[e];
  if (m == 0.f) return;
  int s = src[e], d = dst[e];
  for (int f = threadIdx.x; f < F; f += blockDim.x) {
    float2 v = evo[(size_t)s * F + f];
    atomicAdd(&agg[(size_t)d * F + f].x, m * v.x);
    atomicAdd(&agg[(size_t)d * F + f].y, m * v.y);
  }
}

// outc = agg + (xr + i*xi); mag/ph
__global__ void magph(const float2* __restrict__ agg, const float* __restrict__ xr,
                      const float* __restrict__ xi, float* __restrict__ mag,
                      float* __restrict__ ph, int n) {
  int idx = blockIdx.x * 256 + threadIdx.x;
  if (idx >= n) return;
  float2 a = agg[idx];
  float r = a.x + xr[idx];
  float im = a.y + xi[idx];
  mag[idx] = sqrtf(r * r + im * im);
  ph[idx] = atan2f(im, r);
}

__global__ void add_out(const float* __restrict__ lm, const float* __restrict__ lp,
                        float* __restrict__ out, int n) {
  int i = threadIdx.x;
  if (i < n) out[i] = lm[i] + lp[i];
}

// ---------------- host helpers ----------------
static inline int sk_chunk(int K, int S) { return (((K + S - 1) / S) + 15) & ~15; }

// ---------------- host ----------------
extern "C" void kernel_launch(void* const* d_in, const int* in_sizes, int n_in,
                              void* d_out, int out_size, void* d_ws, size_t ws_size,
                              hipStream_t stream) {
  if (ws_size < WS_NEED) return;

  const float* x       = (const float*)d_in[0];
  const int*   ei      = (const int*)d_in[1];
  const float* gcn1_w  = (const float*)d_in[2];
  const float* gcn1_b  = (const float*)d_in[3];
  const float* pool1_w = (const float*)d_in[4];
  const float* gcn2_w  = (const float*)d_in[5];
  const float* gcn2_b  = (const float*)d_in[6];
  const float* pool2_w = (const float*)d_in[7];
  const float* inr_w   = (const float*)d_in[8];
  const float* inr_b   = (const float*)d_in[9];
  const float* ini_w   = (const float*)d_in[10];
  const float* ini_b   = (const float*)d_in[11];
  const float* enc1_w  = (const float*)d_in[12];
  const float* enc1_b  = (const float*)d_in[13];
  const float* enc2_w  = (const float*)d_in[14];
  const float* enc2_b  = (const float*)d_in[15];
  const float* p1_w    = (const float*)d_in[16];
  const float* p1_b    = (const float*)d_in[17];
  const float* p2_w    = (const float*)d_in[18];
  const float* p2_b    = (const float*)d_in[19];
  const float* p3_w    = (const float*)d_in[20];
  const float* p3_b    = (const float*)d_in[21];
  const float* rt_w    = (const float*)d_in[22];
  const float* rt_b    = (const float*)d_in[23];
  const float* it_w    = (const float*)d_in[24];
  const float* it_b    = (const float*)d_in[25];
  const float* msg_wr  = (const float*)d_in[26];
  const float* msg_wi  = (const float*)d_in[27];
  const float* mc1_w   = (const float*)d_in[28];
  const float* mc1_b   = (const float*)d_in[29];
  const float* mc2_w   = (const float*)d_in[30];
  const float* mc2_b   = (const float*)d_in[31];
  const float* pc1_w   = (const float*)d_in[32];
  const float* pc1_b   = (const float*)d_in[33];
  const float* pc2_w   = (const float*)d_in[34];
  const float* pc2_b   = (const float*)d_in[35];

  char* ws = (char*)d_ws;
  float*  H1    = (float*)(ws + O_H1);
  float*  OUT1  = (float*)(ws + O_OUT1);
  float*  DEG1  = (float*)(ws + O_DEG1);
  float*  DIS1  = (float*)(ws + O_DIS1);
  float*  SC1   = (float*)(ws + O_SC1);
  int*    PERM1 = (int*)(ws + O_PERM1);
  int*    MAP1  = (int*)(ws + O_MAP1);
  float*  H1P   = (float*)(ws + O_H1P);
  int*    SRC2  = (int*)(ws + O_SRC2);
  int*    DST2  = (int*)(ws + O_DST2);
  float*  EM2   = (float*)(ws + O_EM2);
  float*  H2    = (float*)(ws + O_H2);
  float*  OUT2  = (float*)(ws + O_OUT2);
  float*  DEG2  = (float*)(ws + O_DEG2);
  float*  DIS2  = (float*)(ws + O_DIS2);
  float*  SC2   = (float*)(ws + O_SC2);
  int*    PERM2 = (int*)(ws + O_PERM2);
  int*    MAP2  = (int*)(ws + O_MAP2);
  float*  H2P   = (float*)(ws + O_H2P);
  int*    SRC3  = (int*)(ws + O_SRC3);
  int*    DST3  = (int*)(ws + O_DST3);
  float*  EM3   = (float*)(ws + O_EM3);
  float*  XRb   = (float*)(ws + O_XR);
  float*  XIb   = (float*)(ws + O_XI);
  float*  DEG3  = (float*)(ws + O_DEG3);
  float*  DIS3  = (float*)(ws + O_DIS3);
  float*  SCOEF = (float*)(ws + O_SCOEF);
  float*  XG1   = (float*)(ws + O_XG1);
  float*  XG2H  = (float*)(ws + O_XG2H);
  float*  XG2   = (float*)(ws + O_XG2);
  float*  EMB   = (float*)(ws + O_EMB);
  float*  T1    = (float*)(ws + O_T1);
  float*  T2    = (float*)(ws + O_T2);
  float*  NORM  = (float*)(ws + O_NORM);
  float*  PMV   = (float*)(ws + O_PM);
  float2* BM    = (float2*)(ws + O_BM);
  float2* P0v   = (float2*)(ws + O_P0);
  float2* P1v   = (float2*)(ws + O_P1);
  float*  XRT   = (float*)(ws + O_XRT);
  float*  XIT   = (float*)(ws + O_XIT);
  float2* XC    = (float2*)(ws + O_XC);
  float2* EVO   = (float2*)(ws + O_EVO);
  float2* AGG0  = (float2*)(ws + O_AGG0);
  float2* WC    = (float2*)(ws + O_WC);
  float2* AGG1  = (float2*)(ws + O_AGG1);
  float*  MAGB  = (float*)(ws + O_MAG);
  float*  PHB   = (float*)(ws + O_PH);
  float*  GM    = (float*)(ws + O_GM);
  float*  GP    = (float*)(ws + O_GP);
  float*  HM    = (float*)(ws + O_HM);
  float*  HP    = (float*)(ws + O_HP);
  float*  LM    = (float*)(ws + O_LM);
  float*  LP    = (float*)(ws + O_LP);
  float2* PART  = (float2*)(ws + O_PART);  // aliases dead stage-A/B buffers
  float2* B2v   = (float2*)(ws + O_B2);    // aliases XRT.. (written post-expm)
  float2* B3v   = (float2*)(ws + O_B3);

  const int* SRC1 = ei;
  const int* DST1 = ei + E;

  // ---------- Stage A: gcn1 + relu ----------
  rmm64<0><<<dim3(HD / 64, N0 / 64), 256, 0, stream>>>(x, gcn1_w, nullptr, H1, N0, HD, DIN);
  hipMemsetAsync(DEG1, 0, F4(N0), stream);
  edge_deg<<<E / 256, 256, 0, stream>>>(DST1, nullptr, DEG1);
  deg_to_dis<<<N0 / 256, 256, 0, stream>>>(DEG1, DIS1, N0);
  gcn_self<<<N0, 256, 0, stream>>>(H1, DIS1, gcn1_b, OUT1, HD);
  gcn_scatter<<<E, 256, 0, stream>>>(SRC1, DST1, nullptr, DIS1, H1, OUT1, HD);
  relu_ip<<<(N0 * HD) / 256, 256, 0, stream>>>(OUT1, N0 * HD);

  // ---------- pool1 ----------
  wnorm<<<1, 256, 0, stream>>>(pool1_w, HD, NORM);
  rowdot<<<N0, 256, 0, stream>>>(OUT1, pool1_w, SC1, HD);
  bitonic_topk<<<1, 1024, 0, stream>>>(SC1, N0, PERM1, K1);
  hipMemsetAsync(MAP1, 0xFF, F4(N0), stream);
  set_map<<<(K1 + 255) / 256, 256, 0, stream>>>(PERM1, MAP1, K1);
  pool_gather<<<K1, 256, 0, stream>>>(OUT1, PERM1, SC1, NORM, H1P, HD);
  remap_edges<<<E / 256, 256, 0, stream>>>(SRC1, DST1, nullptr, MAP1, SRC2, DST2, EM2);

  // ---------- Stage C: gcn2 + relu ----------
  rmm64<0><<<dim3(HD / 64, (K1 + 63) / 64), 256, 0, stream>>>(H1P, gcn2_w, nullptr, H2, K1, HD, HD);
  hipMemsetAsync(DEG2, 0, F4(N0), stream);
  edge_deg<<<E / 256, 256, 0, stream>>>(DST2, EM2, DEG2);
  deg_to_dis<<<(K1 + 255) / 256, 256, 0, stream>>>(DEG2, DIS2, K1);
  gcn_self<<<K1, 256, 0, stream>>>(H2, DIS2, gcn2_b, OUT2, HD);
  gcn_scatter<<<E, 256, 0, stream>>>(SRC2, DST2, EM2, DIS2, H2, OUT2, HD);
  relu_ip<<<(K1 * HD + 255) / 256, 256, 0, stream>>>(OUT2, K1 * HD);

  // ---------- pool2 ----------
  wnorm<<<1, 256, 0, stream>>>(pool2_w, HD, NORM + 1);
  rowdot<<<K1, 256, 0, stream>>>(OUT2, pool2_w, SC2, HD);
  bitonic_topk<<<1, 1024, 0, stream>>>(SC2, K1, PERM2, K2);
  hipMemsetAsync(MAP2, 0xFF, F4(N0), stream);
  set_map<<<(K2 + 255) / 256, 256, 0, stream>>>(PERM2, MAP2, K2);
  pool_gather<<<K2, 256, 0, stream>>>(OUT2, PERM2, SC2, NORM + 1, H2P, HD);
  remap_edges<<<E / 256, 256, 0, stream>>>(SRC2, DST2, EM2, MAP2, SRC3, DST3, EM3);

  // ---------- xr / xi ----------
  rmm64<0><<<dim3(HD / 64, (K2 + 63) / 64), 256, 0, stream>>>(H2P, inr_w, inr_b, XRb, K2, HD, HD);
  rmm64<0><<<dim3(HD / 64, (K2 + 63) / 64), 256, 0, stream>>>(H2P, ini_w, ini_b, XIb, K2, HD, HD);

  // ---------- encoder GCNs on pooled graph ----------
  hipMemsetAsync(DEG3, 0, F4(K2), stream);
  edge_deg<<<E / 256, 256, 0, stream>>>(DST3, EM3, DEG3);
  deg_to_dis<<<(K2 + 255) / 256, 256, 0, stream>>>(DEG3, DIS3, K2);
  hipMemsetAsync(SCOEF, 0, F4(K2), stream);
  enc_scoef<<<E / 256, 256, 0, stream>>>(SRC3, DST3, EM3, DIS3, SCOEF);
  enc1_out<<<K2, UHD, 0, stream>>>(SCOEF, DIS3, enc1_w, enc1_b, XG1);
  rmm64<0><<<dim3(UHD / 64, (K2 + 63) / 64), 256, 0, stream>>>(XG1, enc2_w, nullptr, XG2H, K2, UHD, UHD);
  gcn_self<<<K2, UHD, 0, stream>>>(XG2H, DIS3, enc2_b, XG2, UHD);
  gcn_scatter<<<E, UHD, 0, stream>>>(SRC3, DST3, EM3, DIS3, XG2H, XG2, UHD);
  col_mean<<<UHD, 256, 0, stream>>>(XG2, EMB, K2, UHD);

  // ---------- parameter MLP -> pm -> B ----------
  vecmat<1><<<1, 256, 0, stream>>>(EMB, p1_w, p1_b, T1, UHD, UHD);
  vecmat<1><<<1, 256, 0, stream>>>(T1, p2_w, p2_b, T2, UHD, UHD / 2);
  vecmat_tanh_wide<<<(PMN + 255) / 256, 256, 0, stream>>>(T2, p3_w, p3_b, PMV, UHD / 2, PMN);
  {
    const float scale = 0.05f * 0.5f / (float)(1 << EXPM_S);
    build_B<<<(PMN + 255) / 256, 256, 0, stream>>>(PMV, BM, K2, scale);
  }

  // ---------- expm: degree-11 Taylor via Paterson-Stockmeyer + 5 squarings ----
  // P = ((D3*y + D2)*y + D1)*y + D0, y = B^3, Dk = c_{3k}I + c_{3k+1}B + c_{3k+2}B^2
  const int chK2 = sk_chunk(K2, CSPLIT);          // 176
  const dim3 gK2(11, 11, CSPLIT);
  const int rgrid = (PMN + 255) / 256;
  const float c3 = 1.f / 6.f, c4 = 1.f / 24.f, c5 = 1.f / 120.f;
  const float c6 = 1.f / 720.f, c7 = 1.f / 5040.f, c8 = 1.f / 40320.f;
  const float c9 = 1.f / 362880.f, c10 = 1.f / 3628800.f, c11 = 1.f / 39916800.f;
  // B2 = B*B ; B3 = B2*B
  cmm64_ps<<<gK2, 256, 0, stream>>>(BM, BM, PART, K2, K2, K2, chK2);
  creduce<<<rgrid, 256, 0, stream>>>(PART, B2v, PMN, K2, CSPLIT, 0.f, nullptr, 0.f, nullptr, 0.f);
  cmm64_ps<<<gK2, 256, 0, stream>>>(B2v, BM, PART, K2, K2, K2, chK2);
  creduce<<<rgrid, 256, 0, stream>>>(PART, B3v, PMN, K2, CSPLIT, 0.f, nullptr, 0.f, nullptr, 0.f);
  // P0 = D3
  combo3<<<rgrid, 256, 0, stream>>>(BM, B2v, P0v, PMN, K2, c9, c10, c11);
  // P1 = P0*B3 + D2
  cmm64_ps<<<gK2, 256, 0, stream>>>(P0v, B3v, PART, K2, K2, K2, chK2);
  creduce<<<rgrid, 256, 0, stream>>>(PART, P1v, PMN, K2, CSPLIT, c6, BM, c7, B2v, c8);
  // P0 = P1*B3 + D1
  cmm64_ps<<<gK2, 256, 0, stream>>>(P1v, B3v, PART, K2, K2, K2, chK2);
  creduce<<<rgrid, 256, 0, stream>>>(PART, P0v, PMN, K2, CSPLIT, c3, BM, c4, B2v, c5);
  // P1 = P0*B3 + D0
  cmm64_ps<<<gK2, 256, 0, stream>>>(P0v, B3v, PART, K2, K2, K2, chK2);
  creduce<<<rgrid, 256, 0, stream>>>(PART, P1v, PMN, K2, CSPLIT, 1.f, BM, 1.f, B2v, 0.5f);
  // 5 squarings (B2v/B3v dead from here; XRT.. region free to be rewritten)
  float2* cur = P1v;
  float2* nxt = P0v;
  for (int t = 0; t < EXPM_S; ++t) {
    cmm64_ps<<<gK2, 256, 0, stream>>>(cur, cur, PART, K2, K2, K2, chK2);
    creduce<<<rgrid, 256, 0, stream>>>(PART, nxt, PMN, K2, CSPLIT, 0.f, nullptr, 0.f, nullptr, 0.f);
    std::swap(cur, nxt);
  }
  float2* U = cur;

  // ---------- quantum message passing ----------
  rmm64<1><<<dim3(HD / 64, (K2 + 63) / 64), 256, 0, stream>>>(XRb, rt_w, rt_b, XRT, K2, HD, HD);
  rmm64<1><<<dim3(HD / 64, (K2 + 63) / 64), 256, 0, stream>>>(XIb, it_w, it_b, XIT, K2, HD, HD);
  pack2<<<(K2 * HD + 255) / 256, 256, 0, stream>>>(XRT, XIT, XC, K2 * HD);
  {
    const int mn = K2 * HD;
    const int rg = (mn + 255) / 256;
    cmm64_ps<<<dim3(HD / 64, (K2 + 63) / 64, CSPLIT), 256, 0, stream>>>(
        U, XC, PART, K2, HD, K2, chK2);
    creduce<<<rg, 256, 0, stream>>>(PART, EVO, mn, HD, CSPLIT, 0.f, nullptr, 0.f, nullptr, 0.f);
    hipMemsetAsync(AGG0, 0, F4(K2 * HD) * 2, stream);
    agg_scatter<<<E, 256, 0, stream>>>(SRC3, DST3, EM3, EVO, AGG0, HD);
    pack2<<<(HD * HD + 255) / 256, 256, 0, stream>>>(msg_wr, msg_wi, WC, HD * HD);
    cmm64_ps<<<dim3(HD / 64, (K2 + 63) / 64, CSPLIT), 256, 0, stream>>>(
        AGG0, WC, PART, K2, HD, HD, sk_chunk(HD, CSPLIT));
    creduce<<<rg, 256, 0, stream>>>(PART, AGG1, mn, HD, CSPLIT, 0.f, nullptr, 0.f, nullptr, 0.f);
  }
  magph<<<(K2 * HD + 255) / 256, 256, 0, stream>>>(AGG1, XRb, XIb, MAGB, PHB, K2 * HD);
  col_mean<<<HD, 256, 0, stream>>>(MAGB, GM, K2, HD);
  col_mean<<<HD, 256, 0, stream>>>(PHB, GP, K2, HD);

  // ---------- classifier heads ----------
  vecmat<1><<<1, 256, 0, stream>>>(GM, mc1_w, mc1_b, HM, HD, HD / 2);
  vecmat<0><<<1, 256, 0, stream>>>(HM, mc2_w, mc2_b, LM, HD / 2, NC);
  vecmat<1><<<1, 256, 0, stream>>>(GP, pc1_w, pc1_b, HP, HD, HD / 2);
  vecmat<0><<<1, 256, 0, stream>>>(HP, pc2_w, pc2_b, LP, HD / 2, NC);
  add_out<<<1, 64, 0, stream>>>(LM, LP, (float*)d_out, NC);
}

// Round 6
// 1488.838 us; speedup vs baseline: 9.9371x; 1.0490x over previous
//
#include <hip/hip_runtime.h>
#include <cstddef>
#include <utility>

// ---------------- problem constants ----------------
constexpr int N0  = 4096;
constexpr int E   = 65536;
constexpr int DIN = 128;
constexpr int HD  = 256;   // H
constexpr int NC  = 10;
constexpr int UHD = 64;    // UH
constexpr int K1  = 3277;  // ceil(0.8*4096)
constexpr int K2  = 656;   // ceil(0.2*3277)
constexpr int PMN = K2 * K2; // 430336

// expm(A): A = 2^5*B, exp(B) via degree-11 Taylor (Paterson-Stockmeyer,
// 5 mults: B2, B3, 3 Horner steps in y=B3), then square 5 times.
// ||B|| <= 1.45 worst case; remainder ~8e-7, x2^5 ~ 2.5e-5 << 1.5e-2.
constexpr int EXPM_S = 5;

// MFMA plane geometry: all matrices padded to PLD x PLD (zeros) for the
// 656-sized GEMMs; K2=656 -> 704 = 11*64 = 22*32.
constexpr int PLD = 704;
constexpr size_t PPS = (size_t)PLD * PLD;  // elems per full-size plane

// ---------------- workspace layout ----------------
#define F4(n) ((size_t)(n) * 4)
constexpr size_t O_H1    = 0;
constexpr size_t O_OUT1  = O_H1    + F4(N0 * HD);
constexpr size_t O_DEG1  = O_OUT1  + F4(N0 * HD);
constexpr size_t O_DIS1  = O_DEG1  + F4(N0);
constexpr size_t O_SC1   = O_DIS1  + F4(N0);
constexpr size_t O_PERM1 = O_SC1   + F4(N0);
constexpr size_t O_MAP1  = O_PERM1 + F4(N0);
constexpr size_t O_H1P   = O_MAP1  + F4(N0);
constexpr size_t O_SRC2  = O_H1P   + F4(K1 * HD);
constexpr size_t O_DST2  = O_SRC2  + F4(E);
constexpr size_t O_EM2   = O_DST2  + F4(E);
constexpr size_t O_H2    = O_EM2   + F4(E);
constexpr size_t O_OUT2  = O_H2    + F4(K1 * HD);
constexpr size_t O_DEG2  = O_OUT2  + F4(K1 * HD);
constexpr size_t O_DIS2  = O_DEG2  + F4(N0);
constexpr size_t O_SC2   = O_DIS2  + F4(N0);
constexpr size_t O_PERM2 = O_SC2   + F4(N0);
constexpr size_t O_MAP2  = O_PERM2 + F4(N0);
constexpr size_t O_H2P   = O_MAP2  + F4(N0);
constexpr size_t O_SRC3  = O_H2P   + F4(K2 * HD);
constexpr size_t O_DST3  = O_SRC3  + F4(E);
constexpr size_t O_EM3   = O_DST3  + F4(E);
constexpr size_t O_XR    = O_EM3   + F4(E);
constexpr size_t O_XI    = O_XR    + F4(K2 * HD);
constexpr size_t O_DEG3  = O_XI    + F4(K2 * HD);
constexpr size_t O_DIS3  = O_DEG3  + F4(1024);
constexpr size_t O_SCOEF = O_DIS3  + F4(1024);
constexpr size_t O_XG1   = O_SCOEF + F4(1024);
constexpr size_t O_XG2H  = O_XG1   + F4(K2 * UHD);
constexpr size_t O_XG2   = O_XG2H  + F4(K2 * UHD);
constexpr size_t O_EMB   = O_XG2   + F4(K2 * UHD);
constexpr size_t O_T1    = O_EMB   + F4(64);
constexpr size_t O_T2    = O_T1    + F4(64);
constexpr size_t O_NORM  = O_T2    + F4(64);
constexpr size_t O_PM    = O_NORM  + F4(64);
constexpr size_t O_BM    = O_PM    + F4(PMN);          // float2
constexpr size_t O_P0    = O_BM    + F4(PMN) * 2;      // float2
constexpr size_t O_P1    = O_P0    + F4(PMN) * 2;      // float2
constexpr size_t O_XRT   = O_P1    + F4(PMN) * 2;
constexpr size_t O_XIT   = O_XRT   + F4(K2 * HD);
constexpr size_t O_XC    = O_XIT   + F4(K2 * HD);      // float2
constexpr size_t O_EVO   = O_XC    + F4(K2 * HD) * 2;  // float2
constexpr size_t O_AGG0  = O_EVO   + F4(K2 * HD) * 2;  // float2
constexpr size_t O_WC    = O_AGG0  + F4(K2 * HD) * 2;  // float2 256x256
constexpr size_t O_AGG1  = O_WC    + F4(HD * HD) * 2;  // float2
constexpr size_t O_MAG   = O_AGG1  + F4(K2 * HD) * 2;
constexpr size_t O_PH    = O_MAG   + F4(K2 * HD);
constexpr size_t O_GM    = O_PH    + F4(K2 * HD);
constexpr size_t O_GP    = O_GM    + F4(256);
constexpr size_t O_HM    = O_GP    + F4(256);
constexpr size_t O_HP    = O_HM    + F4(256);
constexpr size_t O_LM    = O_HP    + F4(256);
constexpr size_t O_LP    = O_LM    + F4(64);
constexpr size_t WS_NEED = O_LP    + F4(64);

// bf16 plane sets alias the dead stage-A/B region at offset 0 (everything
// below O_SRC3 is last touched before the expm phase starts).
// SA: A-operand planes [row][k] (rh, rl, ih, il). ST: B-operand planes
// TRANSPOSED [n][k]. Each set: 4 planes x PPS x 2B = 3.97 MB.
constexpr size_t O_SA = 0;
constexpr size_t O_ST = O_SA + PPS * 2 * 4;
static_assert(O_ST + PPS * 2 * 4 <= O_SRC3, "plane sets must fit in dead region");

// B2/B3 fp32 (Paterson-Stockmeyer powers) alias the XRT..AGG1 region,
// which is only written AFTER the expm phase completes.
constexpr size_t O_B2 = O_XRT;
constexpr size_t O_B3 = O_B2 + F4(PMN) * 2;
static_assert(O_B3 + F4(PMN) * 2 <= O_MAG, "B2/B3 must fit in XRT..AGG1 region");

// ---------------- bf16 helpers ----------------
typedef __attribute__((ext_vector_type(8))) short s8v;   // 8 bf16 (4 VGPRs)
typedef __attribute__((ext_vector_type(4))) float f4v;   // MFMA acc

__device__ inline unsigned short f2bf(float x) {
  unsigned u = __float_as_uint(x);
  u += 0x7FFFu + ((u >> 16) & 1u);   // round-to-nearest-even
  return (unsigned short)(u >> 16);
}
__device__ inline float bf2f(unsigned short h) {
  return __uint_as_float(((unsigned)h) << 16);
}

// ---------------- kernels ----------------

// real GEMM: C[M,N] = act(A[M,K] @ B[K,N] + bias). fp32 (pool-score path must
// stay fp32: bf16 noise would reorder near-tie top-k selections).
template <int ACT>
__global__ void rmm64(const float* __restrict__ A, const float* __restrict__ B,
                      const float* __restrict__ bias, float* __restrict__ C,
                      int M, int N, int K) {
  __shared__ float As[64][17];
  __shared__ float Bs[16][64];
  int t  = threadIdx.x;
  int tx = t & 15, ty = t >> 4;
  int bm = blockIdx.y * 64, bn = blockIdx.x * 64;
  float acc[4][4] = {};
  for (int kt = 0; kt < K; kt += 16) {
#pragma unroll
    for (int i = 0; i < 4; i++) {
      int l = t + i * 256;
      int kk = l & 15, mm = l >> 4;
      int gr = bm + mm;
      As[mm][kk] = (gr < M) ? A[(size_t)gr * K + kt + kk] : 0.f;
    }
#pragma unroll
    for (int i = 0; i < 4; i++) {
      int l = t + i * 256;
      int cc = l & 63, kk = l >> 6;
      int gc = bn + cc;
      Bs[kk][cc] = (gc < N) ? B[(size_t)(kt + kk) * N + gc] : 0.f;
    }
    __syncthreads();
#pragma unroll
    for (int kk = 0; kk < 16; kk++) {
      float a[4], b[4];
#pragma unroll
      for (int i = 0; i < 4; i++) a[i] = As[ty + 16 * i][kk];
#pragma unroll
      for (int j = 0; j < 4; j++) b[j] = Bs[kk][tx + 16 * j];
#pragma unroll
      for (int i = 0; i < 4; i++)
#pragma unroll
        for (int j = 0; j < 4; j++) acc[i][j] += a[i] * b[j];
    }
    __syncthreads();
  }
#pragma unroll
  for (int i = 0; i < 4; i++) {
    int r = bm + ty + 16 * i;
    if (r >= M) continue;
#pragma unroll
    for (int j = 0; j < 4; j++) {
      int c = bn + tx + 16 * j;
      if (c >= N) continue;
      float v = acc[i][j] + (bias ? bias[c] : 0.f);
      if (ACT == 1) v = fmaxf(v, 0.f);
      C[(size_t)r * N + c] = v;
    }
  }
}

// Split a complex fp32 matrix into 4 bf16 planes [row][col] (rh, rl, ih, il),
// zero-padded to padR x ld. x = hi + lo, |lo residual| <= 2^-18 |x|.
__global__ void split_planes(const float2* __restrict__ in, int inM, int inN,
                             unsigned short* __restrict__ out, int padR, int ld,
                             size_t ps) {
  int idx = blockIdx.x * 256 + threadIdx.x;
  if (idx >= padR * ld) return;
  int r = idx / ld, c = idx - r * ld;
  float re = 0.f, im = 0.f;
  if (r < inM && c < inN) { float2 v = in[(size_t)r * inN + c]; re = v.x; im = v.y; }
  unsigned short rh = f2bf(re);
  unsigned short rl = f2bf(re - bf2f(rh));
  unsigned short ih = f2bf(im);
  unsigned short il = f2bf(im - bf2f(ih));
  out[idx] = rh; out[ps + idx] = rl; out[2 * ps + idx] = ih; out[3 * ps + idx] = il;
}

// Transposed split: out[n*ld + k] = split(in[k][n]); tiled via LDS.
// Makes B-operand fragment loads contiguous 16B dwordx4 (8 k-consecutive).
__global__ void split_planesT(const float2* __restrict__ in, int inM, int inN,
                              unsigned short* __restrict__ out, int padR, int ld,
                              size_t ps) {
  __shared__ float2 tile[32][33];
  int tx = threadIdx.x & 31, ty = threadIdx.x >> 5;   // 32 x 8
  int k0 = blockIdx.x * 32, n0 = blockIdx.y * 32;
  for (int i = ty; i < 32; i += 8) {
    int k = k0 + i, n = n0 + tx;
    tile[i][tx] = (k < inM && n < inN) ? in[(size_t)k * inN + n]
                                       : make_float2(0.f, 0.f);
  }
  __syncthreads();
  for (int i = ty; i < 32; i += 8) {
    int n = n0 + i, k = k0 + tx;
    if (n < padR && k < ld) {
      float2 v = tile[tx][i];
      size_t o = (size_t)n * ld + k;
      unsigned short rh = f2bf(v.x);
      unsigned short rl = f2bf(v.x - bf2f(rh));
      unsigned short ih = f2bf(v.y);
      unsigned short il = f2bf(v.y - bf2f(ih));
      out[o] = rh; out[ps + o] = rl; out[2 * ps + o] = ih; out[3 * ps + o] = il;
    }
  }
}

// Complex GEMM on MFMA bf16 with 2-term split compensation.
// C[M,N] = A@B (+ e0*I + e1c*E1 + e2c*E2 epilogue).
// SA: A planes [row][k], ld=ldA, plane stride psA (rows padded >= gridY*64).
// ST: B planes transposed [n][k], ld=ldT(==Kp), plane stride psT.
// Fragment layouts (HW-verified, guide 3): A[m=lane&15][k=quad*8+j],
// B[k=quad*8+j][n=lane&15], C/D col=lane&15 row=quad*4+reg.
// re += ar*br - ai*bi ; im += ar*bi + ai*br ; each product = hh + hl + lh.
__global__ __launch_bounds__(256, 2) void cmm_bf16(
    const unsigned short* __restrict__ SA, size_t psA, int ldA,
    const unsigned short* __restrict__ ST, size_t psT, int ldT,
    float2* __restrict__ C, int M, int N, int Kp,
    const float2* __restrict__ E1, float e1c,
    const float2* __restrict__ E2, float e2c, float e0) {
  int t = threadIdx.x;
  int wave = t >> 6, lane = t & 63;
  int quad = lane >> 4, mn = lane & 15;
  int rowA = blockIdx.y * 64 + wave * 16 + mn;
  int bn = blockIdx.x * 64;
  const unsigned short* a0 = SA + (size_t)rowA * ldA;
  f4v accR[4], accI[4];
#pragma unroll
  for (int i = 0; i < 4; i++) {
    accR[i] = (f4v){0.f, 0.f, 0.f, 0.f};
    accI[i] = (f4v){0.f, 0.f, 0.f, 0.f};
  }
  for (int kt = 0; kt < Kp; kt += 32) {
    int ka = kt + quad * 8;
    s8v arh = *(const s8v*)(a0 + ka);
    s8v arl = *(const s8v*)(a0 + psA + ka);
    s8v aih = *(const s8v*)(a0 + 2 * psA + ka);
    s8v ail = *(const s8v*)(a0 + 3 * psA + ka);
    s8v nih, nil_;
#pragma unroll
    for (int q = 0; q < 8; q++) {
      nih[q]  = (short)(aih[q] ^ (short)0x8000);   // -ai (bf16 sign flip)
      nil_[q] = (short)(ail[q] ^ (short)0x8000);
    }
#pragma unroll
    for (int tl = 0; tl < 4; tl++) {
      const unsigned short* b0 = ST + (size_t)(bn + tl * 16 + mn) * ldT + ka;
      s8v brh = *(const s8v*)(b0);
      s8v brl = *(const s8v*)(b0 + psT);
      s8v bih = *(const s8v*)(b0 + 2 * psT);
      s8v bil = *(const s8v*)(b0 + 3 * psT);
      f4v r = accR[tl];
      r = __builtin_amdgcn_mfma_f32_16x16x32_bf16(arh, brh, r, 0, 0, 0);
      r = __builtin_amdgcn_mfma_f32_16x16x32_bf16(arl, brh, r, 0, 0, 0);
      r = __builtin_amdgcn_mfma_f32_16x16x32_bf16(arh, brl, r, 0, 0, 0);
      r = __builtin_amdgcn_mfma_f32_16x16x32_bf16(nih, bih, r, 0, 0, 0);
      r = __builtin_amdgcn_mfma_f32_16x16x32_bf16(nil_, bih, r, 0, 0, 0);
      r = __builtin_amdgcn_mfma_f32_16x16x32_bf16(nih, bil, r, 0, 0, 0);
      accR[tl] = r;
      f4v im = accI[tl];
      im = __builtin_amdgcn_mfma_f32_16x16x32_bf16(arh, bih, im, 0, 0, 0);
      im = __builtin_amdgcn_mfma_f32_16x16x32_bf16(arl, bih, im, 0, 0, 0);
      im = __builtin_amdgcn_mfma_f32_16x16x32_bf16(arh, bil, im, 0, 0, 0);
      im = __builtin_amdgcn_mfma_f32_16x16x32_bf16(aih, brh, im, 0, 0, 0);
      im = __builtin_amdgcn_mfma_f32_16x16x32_bf16(ail, brh, im, 0, 0, 0);
      im = __builtin_amdgcn_mfma_f32_16x16x32_bf16(aih, brl, im, 0, 0, 0);
      accI[tl] = im;
    }
  }
#pragma unroll
  for (int tl = 0; tl < 4; tl++) {
    int col = bn + tl * 16 + mn;
    if (col >= N) continue;
#pragma unroll
    for (int r = 0; r < 4; r++) {
      int row = blockIdx.y * 64 + wave * 16 + quad * 4 + r;
      if (row >= M) continue;
      float vr = accR[tl][r], vi = accI[tl][r];
      size_t o = (size_t)row * N + col;
      if (E1) { float2 b = E1[o]; vr += e1c * b.x; vi += e1c * b.y; }
      if (E2) { float2 b = E2[o]; vr += e2c * b.x; vi += e2c * b.y; }
      if (e0 != 0.f && row == col) vr += e0;
      C[o] = make_float2(vr, vi);
    }
  }
}

// deg[dst[e]] += em (em==nullptr -> 1.0)
__global__ void edge_deg(const int* __restrict__ dst, const float* __restrict__ em,
                         float* __restrict__ deg) {
  int e = blockIdx.x * 256 + threadIdx.x;
  if (e >= E) return;
  float m = em ? em[e] : 1.0f;
  if (m != 0.f) atomicAdd(&deg[dst[e]], m);
}

__global__ void deg_to_dis(const float* __restrict__ deg, float* __restrict__ dis, int n) {
  int i = blockIdx.x * 256 + threadIdx.x;
  if (i >= n) return;
  dis[i] = 1.0f / sqrtf(deg[i] + 1.0f);
}

__global__ void gcn_self(const float* __restrict__ Hm, const float* __restrict__ dis,
                         const float* __restrict__ bias, float* __restrict__ out, int F) {
  int i = blockIdx.x;
  float d2 = dis[i] * dis[i];
  for (int f = threadIdx.x; f < F; f += blockDim.x)
    out[(size_t)i * F + f] = d2 * Hm[(size_t)i * F + f] + bias[f];
}

__global__ void gcn_scatter(const int* __restrict__ src, const int* __restrict__ dst,
                            const float* __restrict__ em, const float* __restrict__ dis,
                            const float* __restrict__ Hm, float* __restrict__ out, int F) {
  int e = blockIdx.x;
  float m = em ? em[e] : 1.0f;
  if (m == 0.f) return;
  int s = src[e], d = dst[e];
  float c = dis[s] * dis[d] * m;
  for (int f = threadIdx.x; f < F; f += blockDim.x)
    atomicAdd(&out[(size_t)d * F + f], c * Hm[(size_t)s * F + f]);
}

__global__ void relu_ip(float* __restrict__ x, int n) {
  int i = blockIdx.x * 256 + threadIdx.x;
  if (i < n) x[i] = fmaxf(x[i], 0.f);
}

__global__ void wnorm(const float* __restrict__ w, int n, float* __restrict__ out) {
  __shared__ float red[256];
  float s = 0.f;
  for (int k = threadIdx.x; k < n; k += 256) s += w[k] * w[k];
  red[threadIdx.x] = s;
  __syncthreads();
  for (int off = 128; off > 0; off >>= 1) {
    if (threadIdx.x < off) red[threadIdx.x] += red[threadIdx.x + off];
    __syncthreads();
  }
  if (threadIdx.x == 0) out[0] = sqrtf(red[0]);
}

__global__ void rowdot(const float* __restrict__ X, const float* __restrict__ w,
                       float* __restrict__ out, int F) {
  int i = blockIdx.x;
  __shared__ float red[256];
  float s = 0.f;
  for (int f = threadIdx.x; f < F; f += 256) s += X[(size_t)i * F + f] * w[f];
  red[threadIdx.x] = s;
  __syncthreads();
  for (int off = 128; off > 0; off >>= 1) {
    if (threadIdx.x < off) red[threadIdx.x] += red[threadIdx.x + off];
    __syncthreads();
  }
  if (threadIdx.x == 0) out[i] = red[0];
}

// exact-total-order descending bitonic sort; key = (sortable_score<<32) | ~idx.
__global__ __launch_bounds__(1024) void bitonic_topk(const float* __restrict__ score,
                                                     int n, int* __restrict__ perm, int k) {
  __shared__ unsigned long long keys[4096];
  int t = threadIdx.x;
  for (int i = t; i < 4096; i += 1024) {
    unsigned long long kk = 0ull;
    if (i < n) {
      float f = score[i];
      unsigned u = __float_as_uint(f);
      u = (f >= 0.0f) ? (u | 0x80000000u) : ~u;
      kk = ((unsigned long long)u << 32) | (unsigned)(~(unsigned)i);
    }
    keys[i] = kk;
  }
  __syncthreads();
  for (int size = 2; size <= 4096; size <<= 1) {
    for (int stride = size >> 1; stride > 0; stride >>= 1) {
      for (int i = t; i < 2048; i += 1024) {
        int pos = ((i & ~(stride - 1)) << 1) | (i & (stride - 1));
        int partner = pos + stride;
        bool desc = (pos & size) == 0;
        unsigned long long a = keys[pos], b = keys[partner];
        if ((a < b) == desc) { keys[pos] = b; keys[partner] = a; }
      }
      __syncthreads();
    }
  }
  for (int i = t; i < k; i += 1024)
    perm[i] = (int)(~(unsigned)(keys[i] & 0xFFFFFFFFull));
}

__global__ void set_map(const int* __restrict__ perm, int* __restrict__ map, int k) {
  int i = blockIdx.x * 256 + threadIdx.x;
  if (i < k) map[perm[i]] = i;
}

__global__ void pool_gather(const float* __restrict__ X, const int* __restrict__ perm,
                            const float* __restrict__ dot, const float* __restrict__ normbuf,
                            float* __restrict__ Xn, int F) {
  int i = blockIdx.x;
  int p = perm[i];
  float sc = tanhf(dot[p] / normbuf[0]);
  for (int f = threadIdx.x; f < F; f += blockDim.x)
    Xn[(size_t)i * F + f] = X[(size_t)p * F + f] * sc;
}

__global__ void remap_edges(const int* __restrict__ srcIn, const int* __restrict__ dstIn,
                            const float* __restrict__ emIn, const int* __restrict__ map,
                            int* __restrict__ srcOut, int* __restrict__ dstOut,
                            float* __restrict__ emOut) {
  int e = blockIdx.x * 256 + threadIdx.x;
  if (e >= E) return;
  int ns = map[srcIn[e]], nd = map[dstIn[e]];
  float m = emIn ? emIn[e] : 1.0f;
  if (ns < 0 || nd < 0) m = 0.f;
  srcOut[e] = ns < 0 ? 0 : ns;
  dstOut[e] = nd < 0 ? 0 : nd;
  emOut[e] = m;
}

__global__ void enc_scoef(const int* __restrict__ src, const int* __restrict__ dst,
                          const float* __restrict__ em, const float* __restrict__ dis,
                          float* __restrict__ scoef) {
  int e = blockIdx.x * 256 + threadIdx.x;
  if (e >= E) return;
  float m = em[e];
  if (m == 0.f) return;
  atomicAdd(&scoef[dst[e]], dis[src[e]] * dis[dst[e]] * m);
}

__global__ void enc1_out(const float* __restrict__ scoef, const float* __restrict__ dis,
                         const float* __restrict__ w, const float* __restrict__ b,
                         float* __restrict__ xg1) {
  int i = blockIdx.x;
  int f = threadIdx.x;
  float s = scoef[i] + dis[i] * dis[i];
  xg1[(size_t)i * UHD + f] = fmaxf(s * w[f] + b[f], 0.f);
}

__global__ void col_mean(const float* __restrict__ X, float* __restrict__ out,
                         int rows, int cols) {
  int c = blockIdx.x;
  __shared__ float red[256];
  float s = 0.f;
  for (int r = threadIdx.x; r < rows; r += 256) s += X[(size_t)r * cols + c];
  red[threadIdx.x] = s;
  __syncthreads();
  for (int off = 128; off > 0; off >>= 1) {
    if (threadIdx.x < off) red[threadIdx.x] += red[threadIdx.x + off];
    __syncthreads();
  }
  if (threadIdx.x == 0) out[c] = red[0] / (float)rows;
}

template <int ACT>
__global__ void vecmat(const float* __restrict__ v, const float* __restrict__ W,
                       const float* __restrict__ b, float* __restrict__ out,
                       int Kdim, int Ndim) {
  __shared__ float vs[256];
  for (int k = threadIdx.x; k < Kdim; k += blockDim.x) vs[k] = v[k];
  __syncthreads();
  for (int j = threadIdx.x; j < Ndim; j += blockDim.x) {
    float acc = b ? b[j] : 0.f;
    for (int k = 0; k < Kdim; k++) acc += vs[k] * W[(size_t)k * Ndim + j];
    out[j] = (ACT == 1) ? fmaxf(acc, 0.f) : acc;
  }
}

__global__ void vecmat_tanh_wide(const float* __restrict__ v, const float* __restrict__ W,
                                 const float* __restrict__ b, float* __restrict__ out,
                                 int Kdim, int Ndim) {
  __shared__ float vs[64];
  if (threadIdx.x < Kdim) vs[threadIdx.x] = v[threadIdx.x];
  __syncthreads();
  int j = blockIdx.x * 256 + threadIdx.x;
  if (j >= Ndim) return;
  float acc = b[j];
  for (int k = 0; k < Kdim; k++) acc += vs[k] * W[(size_t)k * Ndim + j];
  out[j] = tanhf(acc);
}

__global__ void build_B(const float* __restrict__ pm, float2* __restrict__ Bm,
                        int n, float scale) {
  int idx = blockIdx.x * 256 + threadIdx.x;
  if (idx >= n * n) return;
  int r = idx / n, c = idx - r * n;
  float pij = pm[(size_t)r * n + c];
  float pji = pm[(size_t)c * n + r];
  Bm[idx] = make_float2(scale * (pij - pji), scale * (pij + pji));
}

// Out = e0*I + e1*B + e2*B2 (top PS block D3)
__global__ void combo3(const float2* __restrict__ Bp, const float2* __restrict__ B2p,
                       float2* __restrict__ Out, int MN, int N,
                       float e0, float e1, float e2) {
  int idx = blockIdx.x * 256 + threadIdx.x;
  if (idx >= MN) return;
  float2 b = Bp[idx], b2 = B2p[idx];
  float sr = e1 * b.x + e2 * b2.x;
  float si = e1 * b.y + e2 * b2.y;
  int r = idx / N;
  if (idx - r * N == r) sr += e0;
  Out[idx] = make_float2(sr, si);
}

__global__ void pack2(const float* __restrict__ a, const float* __restrict__ b,
                      float2* __restrict__ out, int n) {
  int i = blockIdx.x * 256 + threadIdx.x;
  if (i < n) out[i] = make_float2(a[i], b[i]);
}

__global__ void agg_scatter(const int* __restrict__ src, const int* __restrict__ dst,
                            const float* __restrict__ em, const float2* __restrict__ evo,
                            float2* __restrict__ agg, int F) {
  int e = blockIdx.x;
  float m = em[e];
  if (m == 0.f) return;
  int s = src[e], d = dst[e];
  for (int f = threadIdx.x; f < F; f += blockDim.x) {
    float2 v = evo[(size_t)s * F + f];
    atomicAdd(&agg[(size_t)d * F + f].x, m * v.x);
    atomicAdd(&agg[(size_t)d * F + f].y, m * v.y);
  }
}

__global__ void magph(const float2* __restrict__ agg, const float* __restrict__ xr,
                      const float* __restrict__ xi, float* __restrict__ mag,
                      float* __restrict__ ph, int n) {
  int idx = blockIdx.x * 256 + threadIdx.x;
  if (idx >= n) return;
  float2 a = agg[idx];
  float r = a.x + xr[idx];
  float im = a.y + xi[idx];
  mag[idx] = sqrtf(r * r + im * im);
  ph[idx] = atan2f(im, r);
}

__global__ void add_out(const float* __restrict__ lm, const float* __restrict__ lp,
                        float* __restrict__ out, int n) {
  int i = threadIdx.x;
  if (i < n) out[i] = lm[i] + lp[i];
}

// ---------------- host ----------------
extern "C" void kernel_launch(void* const* d_in, const int* in_sizes, int n_in,
                              void* d_out, int out_size, void* d_ws, size_t ws_size,
                              hipStream_t stream) {
  if (ws_size < WS_NEED) return;

  const float* x       = (const float*)d_in[0];
  const int*   ei      = (const int*)d_in[1];
  const float* gcn1_w  = (const float*)d_in[2];
  const float* gcn1_b  = (const float*)d_in[3];
  const float* pool1_w = (const float*)d_in[4];
  const float* gcn2_w  = (const float*)d_in[5];
  const float* gcn2_b  = (const float*)d_in[6];
  const float* pool2_w = (const float*)d_in[7];
  const float* inr_w   = (const float*)d_in[8];
  const float* inr_b   = (const float*)d_in[9];
  const float* ini_w   = (const float*)d_in[10];
  const float* ini_b   = (const float*)d_in[11];
  const float* enc1_w  = (const float*)d_in[12];
  const float* enc1_b  = (const float*)d_in[13];
  const float* enc2_w  = (const float*)d_in[14];
  const float* enc2_b  = (const float*)d_in[15];
  const float* p1_w    = (const float*)d_in[16];
  const float* p1_b    = (const float*)d_in[17];
  const float* p2_w    = (const float*)d_in[18];
  const float* p2_b    = (const float*)d_in[19];
  const float* p3_w    = (const float*)d_in[20];
  const float* p3_b    = (const float*)d_in[21];
  const float* rt_w    = (const float*)d_in[22];
  const float* rt_b    = (const float*)d_in[23];
  const float* it_w    = (const float*)d_in[24];
  const float* it_b    = (const float*)d_in[25];
  const float* msg_wr  = (const float*)d_in[26];
  const float* msg_wi  = (const float*)d_in[27];
  const float* mc1_w   = (const float*)d_in[28];
  const float* mc1_b   = (const float*)d_in[29];
  const float* mc2_w   = (const float*)d_in[30];
  const float* mc2_b   = (const float*)d_in[31];
  const float* pc1_w   = (const float*)d_in[32];
  const float* pc1_b   = (const float*)d_in[33];
  const float* pc2_w   = (const float*)d_in[34];
  const float* pc2_b   = (const float*)d_in[35];

  char* ws = (char*)d_ws;
  float*  H1    = (float*)(ws + O_H1);
  float*  OUT1  = (float*)(ws + O_OUT1);
  float*  DEG1  = (float*)(ws + O_DEG1);
  float*  DIS1  = (float*)(ws + O_DIS1);
  float*  SC1   = (float*)(ws + O_SC1);
  int*    PERM1 = (int*)(ws + O_PERM1);
  int*    MAP1  = (int*)(ws + O_MAP1);
  float*  H1P   = (float*)(ws + O_H1P);
  int*    SRC2  = (int*)(ws + O_SRC2);
  int*    DST2  = (int*)(ws + O_DST2);
  float*  EM2   = (float*)(ws + O_EM2);
  float*  H2    = (float*)(ws + O_H2);
  float*  OUT2  = (float*)(ws + O_OUT2);
  float*  DEG2  = (float*)(ws + O_DEG2);
  float*  DIS2  = (float*)(ws + O_DIS2);
  float*  SC2   = (float*)(ws + O_SC2);
  int*    PERM2 = (int*)(ws + O_PERM2);
  int*    MAP2  = (int*)(ws + O_MAP2);
  float*  H2P   = (float*)(ws + O_H2P);
  int*    SRC3  = (int*)(ws + O_SRC3);
  int*    DST3  = (int*)(ws + O_DST3);
  float*  EM3   = (float*)(ws + O_EM3);
  float*  XRb   = (float*)(ws + O_XR);
  float*  XIb   = (float*)(ws + O_XI);
  float*  DEG3  = (float*)(ws + O_DEG3);
  float*  DIS3  = (float*)(ws + O_DIS3);
  float*  SCOEF = (float*)(ws + O_SCOEF);
  float*  XG1   = (float*)(ws + O_XG1);
  float*  XG2H  = (float*)(ws + O_XG2H);
  float*  XG2   = (float*)(ws + O_XG2);
  float*  EMB   = (float*)(ws + O_EMB);
  float*  T1    = (float*)(ws + O_T1);
  float*  T2    = (float*)(ws + O_T2);
  float*  NORM  = (float*)(ws + O_NORM);
  float*  PMV   = (float*)(ws + O_PM);
  float2* BM    = (float2*)(ws + O_BM);
  float2* P0v   = (float2*)(ws + O_P0);
  float2* P1v   = (float2*)(ws + O_P1);
  float*  XRT   = (float*)(ws + O_XRT);
  float*  XIT   = (float*)(ws + O_XIT);
  float2* XC    = (float2*)(ws + O_XC);
  float2* EVO   = (float2*)(ws + O_EVO);
  float2* AGG0  = (float2*)(ws + O_AGG0);
  float2* WC    = (float2*)(ws + O_WC);
  float2* AGG1  = (float2*)(ws + O_AGG1);
  float*  MAGB  = (float*)(ws + O_MAG);
  float*  PHB   = (float*)(ws + O_PH);
  float*  GM    = (float*)(ws + O_GM);
  float*  GP    = (float*)(ws + O_GP);
  float*  HM    = (float*)(ws + O_HM);
  float*  HP    = (float*)(ws + O_HP);
  float*  LM    = (float*)(ws + O_LM);
  float*  LP    = (float*)(ws + O_LP);
  unsigned short* SA = (unsigned short*)(ws + O_SA);  // A-operand bf16 planes
  unsigned short* ST = (unsigned short*)(ws + O_ST);  // B-operand (transposed)
  float2* B2v = (float2*)(ws + O_B2);
  float2* B3v = (float2*)(ws + O_B3);

  const int* SRC1 = ei;
  const int* DST1 = ei + E;

  // ---------- Stage A: gcn1 + relu ----------
  rmm64<0><<<dim3(HD / 64, N0 / 64), 256, 0, stream>>>(x, gcn1_w, nullptr, H1, N0, HD, DIN);
  hipMemsetAsync(DEG1, 0, F4(N0), stream);
  edge_deg<<<E / 256, 256, 0, stream>>>(DST1, nullptr, DEG1);
  deg_to_dis<<<N0 / 256, 256, 0, stream>>>(DEG1, DIS1, N0);
  gcn_self<<<N0, 256, 0, stream>>>(H1, DIS1, gcn1_b, OUT1, HD);
  gcn_scatter<<<E, 256, 0, stream>>>(SRC1, DST1, nullptr, DIS1, H1, OUT1, HD);
  relu_ip<<<(N0 * HD) / 256, 256, 0, stream>>>(OUT1, N0 * HD);

  // ---------- pool1 ----------
  wnorm<<<1, 256, 0, stream>>>(pool1_w, HD, NORM);
  rowdot<<<N0, 256, 0, stream>>>(OUT1, pool1_w, SC1, HD);
  bitonic_topk<<<1, 1024, 0, stream>>>(SC1, N0, PERM1, K1);
  hipMemsetAsync(MAP1, 0xFF, F4(N0), stream);
  set_map<<<(K1 + 255) / 256, 256, 0, stream>>>(PERM1, MAP1, K1);
  pool_gather<<<K1, 256, 0, stream>>>(OUT1, PERM1, SC1, NORM, H1P, HD);
  remap_edges<<<E / 256, 256, 0, stream>>>(SRC1, DST1, nullptr, MAP1, SRC2, DST2, EM2);

  // ---------- Stage C: gcn2 + relu ----------
  rmm64<0><<<dim3(HD / 64, (K1 + 63) / 64), 256, 0, stream>>>(H1P, gcn2_w, nullptr, H2, K1, HD, HD);
  hipMemsetAsync(DEG2, 0, F4(N0), stream);
  edge_deg<<<E / 256, 256, 0, stream>>>(DST2, EM2, DEG2);
  deg_to_dis<<<(K1 + 255) / 256, 256, 0, stream>>>(DEG2, DIS2, K1);
  gcn_self<<<K1, 256, 0, stream>>>(H2, DIS2, gcn2_b, OUT2, HD);
  gcn_scatter<<<E, 256, 0, stream>>>(SRC2, DST2, EM2, DIS2, H2, OUT2, HD);
  relu_ip<<<(K1 * HD + 255) / 256, 256, 0, stream>>>(OUT2, K1 * HD);

  // ---------- pool2 ----------
  wnorm<<<1, 256, 0, stream>>>(pool2_w, HD, NORM + 1);
  rowdot<<<K1, 256, 0, stream>>>(OUT2, pool2_w, SC2, HD);
  bitonic_topk<<<1, 1024, 0, stream>>>(SC2, K1, PERM2, K2);
  hipMemsetAsync(MAP2, 0xFF, F4(N0), stream);
  set_map<<<(K2 + 255) / 256, 256, 0, stream>>>(PERM2, MAP2, K2);
  pool_gather<<<K2, 256, 0, stream>>>(OUT2, PERM2, SC2, NORM + 1, H2P, HD);
  remap_edges<<<E / 256, 256, 0, stream>>>(SRC2, DST2, EM2, MAP2, SRC3, DST3, EM3);

  // ---------- xr / xi ----------
  rmm64<0><<<dim3(HD / 64, (K2 + 63) / 64), 256, 0, stream>>>(H2P, inr_w, inr_b, XRb, K2, HD, HD);
  rmm64<0><<<dim3(HD / 64, (K2 + 63) / 64), 256, 0, stream>>>(H2P, ini_w, ini_b, XIb, K2, HD, HD);

  // ---------- encoder GCNs on pooled graph ----------
  hipMemsetAsync(DEG3, 0, F4(K2), stream);
  edge_deg<<<E / 256, 256, 0, stream>>>(DST3, EM3, DEG3);
  deg_to_dis<<<(K2 + 255) / 256, 256, 0, stream>>>(DEG3, DIS3, K2);
  hipMemsetAsync(SCOEF, 0, F4(K2), stream);
  enc_scoef<<<E / 256, 256, 0, stream>>>(SRC3, DST3, EM3, DIS3, SCOEF);
  enc1_out<<<K2, UHD, 0, stream>>>(SCOEF, DIS3, enc1_w, enc1_b, XG1);
  rmm64<0><<<dim3(UHD / 64, (K2 + 63) / 64), 256, 0, stream>>>(XG1, enc2_w, nullptr, XG2H, K2, UHD, UHD);
  gcn_self<<<K2, UHD, 0, stream>>>(XG2H, DIS3, enc2_b, XG2, UHD);
  gcn_scatter<<<E, UHD, 0, stream>>>(SRC3, DST3, EM3, DIS3, XG2H, XG2, UHD);
  col_mean<<<UHD, 256, 0, stream>>>(XG2, EMB, K2, UHD);

  // ---------- parameter MLP -> pm -> B ----------
  vecmat<1><<<1, 256, 0, stream>>>(EMB, p1_w, p1_b, T1, UHD, UHD);
  vecmat<1><<<1, 256, 0, stream>>>(T1, p2_w, p2_b, T2, UHD, UHD / 2);
  vecmat_tanh_wide<<<(PMN + 255) / 256, 256, 0, stream>>>(T2, p3_w, p3_b, PMV, UHD / 2, PMN);
  {
    const float scale = 0.05f * 0.5f / (float)(1 << EXPM_S);
    build_B<<<(PMN + 255) / 256, 256, 0, stream>>>(PMV, BM, K2, scale);
  }

  // ---------- expm via PS deg-11 + 5 squarings, all MFMA bf16-split ----------
  const int rgrid  = (PMN + 255) / 256;
  const int sgrid  = (PLD * PLD + 255) / 256;                  // full-plane split
  const dim3 tgridF((PLD + 31) / 32, (PLD + 31) / 32);          // full transpose
  const dim3 ggK2(11, 11);                                      // 656x656 out
  const float c3 = 1.f / 6.f, c4 = 1.f / 24.f, c5 = 1.f / 120.f;
  const float c6 = 1.f / 720.f, c7 = 1.f / 5040.f, c8 = 1.f / 40320.f;
  const float c9 = 1.f / 362880.f, c10 = 1.f / 3628800.f, c11 = 1.f / 39916800.f;

  // B planes (A-role and transposed B-role)
  split_planes <<<sgrid, 256, 0, stream>>>(BM, K2, K2, SA, PLD, PLD, PPS);
  split_planesT<<<tgridF, 256, 0, stream>>>(BM, K2, K2, ST, PLD, PLD, PPS);
  // B2 = B*B
  cmm_bf16<<<ggK2, 256, 0, stream>>>(SA, PPS, PLD, ST, PPS, PLD, B2v, K2, K2, PLD,
                                     nullptr, 0.f, nullptr, 0.f, 0.f);
  // B3 = B2*B
  split_planes<<<sgrid, 256, 0, stream>>>(B2v, K2, K2, SA, PLD, PLD, PPS);
  cmm_bf16<<<ggK2, 256, 0, stream>>>(SA, PPS, PLD, ST, PPS, PLD, B3v, K2, K2, PLD,
                                     nullptr, 0.f, nullptr, 0.f, 0.f);
  // ST <- B3 transposed (fixed right operand for the 3 Horner steps)
  split_planesT<<<tgridF, 256, 0, stream>>>(B3v, K2, K2, ST, PLD, PLD, PPS);
  // P0 = D3 = c9 I + c10 B + c11 B2
  combo3<<<rgrid, 256, 0, stream>>>(BM, B2v, P0v, PMN, K2, c9, c10, c11);
  // P1 = P0*B3 + (c6 I + c7 B + c8 B2)
  split_planes<<<sgrid, 256, 0, stream>>>(P0v, K2, K2, SA, PLD, PLD, PPS);
  cmm_bf16<<<ggK2, 256, 0, stream>>>(SA, PPS, PLD, ST, PPS, PLD, P1v, K2, K2, PLD,
                                     BM, c7, B2v, c8, c6);
  // P0 = P1*B3 + (c3 I + c4 B + c5 B2)
  split_planes<<<sgrid, 256, 0, stream>>>(P1v, K2, K2, SA, PLD, PLD, PPS);
  cmm_bf16<<<ggK2, 256, 0, stream>>>(SA, PPS, PLD, ST, PPS, PLD, P0v, K2, K2, PLD,
                                     BM, c4, B2v, c5, c3);
  // P1 = P0*B3 + (I + B + 0.5 B2)
  split_planes<<<sgrid, 256, 0, stream>>>(P0v, K2, K2, SA, PLD, PLD, PPS);
  cmm_bf16<<<ggK2, 256, 0, stream>>>(SA, PPS, PLD, ST, PPS, PLD, P1v, K2, K2, PLD,
                                     BM, 1.f, B2v, 0.5f, 1.f);
  // 5 squarings
  float2* cur = P1v;
  float2* nxt = P0v;
  for (int t = 0; t < EXPM_S; ++t) {
    split_planes <<<sgrid, 256, 0, stream>>>(cur, K2, K2, SA, PLD, PLD, PPS);
    split_planesT<<<tgridF, 256, 0, stream>>>(cur, K2, K2, ST, PLD, PLD, PPS);
    cmm_bf16<<<ggK2, 256, 0, stream>>>(SA, PPS, PLD, ST, PPS, PLD, nxt, K2, K2, PLD,
                                       nullptr, 0.f, nullptr, 0.f, 0.f);
    std::swap(cur, nxt);
  }
  float2* U = cur;

  // ---------- quantum message passing ----------
  rmm64<1><<<dim3(HD / 64, (K2 + 63) / 64), 256, 0, stream>>>(XRb, rt_w, rt_b, XRT, K2, HD, HD);
  rmm64<1><<<dim3(HD / 64, (K2 + 63) / 64), 256, 0, stream>>>(XIb, it_w, it_b, XIT, K2, HD, HD);
  pack2<<<(K2 * HD + 255) / 256, 256, 0, stream>>>(XRT, XIT, XC, K2 * HD);
  // EVO = U @ XC  (M=656, N=256, Kp=704)
  split_planes <<<sgrid, 256, 0, stream>>>(U, K2, K2, SA, PLD, PLD, PPS);
  split_planesT<<<dim3((PLD + 31) / 32, (HD + 31) / 32), 256, 0, stream>>>(
      XC, K2, HD, ST, HD, PLD, (size_t)HD * PLD);
  cmm_bf16<<<dim3(HD / 64, 11), 256, 0, stream>>>(
      SA, PPS, PLD, ST, (size_t)HD * PLD, PLD, EVO, K2, HD, PLD,
      nullptr, 0.f, nullptr, 0.f, 0.f);
  hipMemsetAsync(AGG0, 0, F4(K2 * HD) * 2, stream);
  agg_scatter<<<E, 256, 0, stream>>>(SRC3, DST3, EM3, EVO, AGG0, HD);
  pack2<<<(HD * HD + 255) / 256, 256, 0, stream>>>(msg_wr, msg_wi, WC, HD * HD);
  // AGG1 = AGG0 @ WC  (M=656, N=256, Kp=256)
  split_planes<<<((PLD * HD) + 255) / 256, 256, 0, stream>>>(
      AGG0, K2, HD, SA, PLD, HD, (size_t)PLD * HD);
  split_planesT<<<dim3((HD + 31) / 32, (HD + 31) / 32), 256, 0, stream>>>(
      WC, HD, HD, ST, HD, HD, (size_t)HD * HD);
  cmm_bf16<<<dim3(HD / 64, 11), 256, 0, stream>>>(
      SA, (size_t)PLD * HD, HD, ST, (size_t)HD * HD, HD, AGG1, K2, HD, HD,
      nullptr, 0.f, nullptr, 0.f, 0.f);
  magph<<<(K2 * HD + 255) / 256, 256, 0, stream>>>(AGG1, XRb, XIb, MAGB, PHB, K2 * HD);
  col_mean<<<HD, 256, 0, stream>>>(MAGB, GM, K2, HD);
  col_mean<<<HD, 256, 0, stream>>>(PHB, GP, K2, HD);

  // ---------- classifier heads ----------
  vecmat<1><<<1, 256, 0, stream>>>(GM, mc1_w, mc1_b, HM, HD, HD / 2);
  vecmat<0><<<1, 256, 0, stream>>>(HM, mc2_w, mc2_b, LM, HD / 2, NC);
  vecmat<1><<<1, 256, 0, stream>>>(GP, pc1_w, pc1_b, HP, HD, HD / 2);
  vecmat<0><<<1, 256, 0, stream>>>(HP, pc2_w, pc2_b, LP, HD / 2, NC);
  add_out<<<1, 64, 0, stream>>>(LM, LP, (float*)d_out, NC);
}

// Round 7
// 1290.321 us; speedup vs baseline: 11.4660x; 1.1539x over previous
//
#include <hip/hip_runtime.h>
#include <cstddef>
#include <utility>

// ---------------- problem constants ----------------
constexpr int N0  = 4096;
constexpr int E   = 65536;
constexpr int DIN = 128;
constexpr int HD  = 256;   // H
constexpr int NC  = 10;
constexpr int UHD = 64;    // UH
constexpr int K1  = 3277;  // ceil(0.8*4096)
constexpr int K2  = 656;   // ceil(0.2*3277)
constexpr int PMN = K2 * K2; // 430336

// expm(A): A = 2^5*B, deg-11 Taylor via Paterson-Stockmeyer + 5 squarings.
constexpr int EXPM_S = 5;

// MFMA plane geometry: 656 -> padded 704 = 11*64 = 22*32.
constexpr int PLD = 704;
constexpr size_t PPS = (size_t)PLD * PLD;

// Split-K for the MFMA GEMMs. R6: 121 blocks = 1 wave/SIMD, 586 GB/s
// outstanding-load-limited (34 MB FETCH / 66 us). 3x blocks + 2x prefetch
// raises in-flight bytes ~6x.
constexpr int CSPLIT = 3;

// ---------------- workspace layout ----------------
#define F4(n) ((size_t)(n) * 4)
constexpr size_t O_H1    = 0;
constexpr size_t O_OUT1  = O_H1    + F4(N0 * HD);
constexpr size_t O_DEG1  = O_OUT1  + F4(N0 * HD);
constexpr size_t O_DIS1  = O_DEG1  + F4(N0);
constexpr size_t O_SC1   = O_DIS1  + F4(N0);
constexpr size_t O_PERM1 = O_SC1   + F4(N0);
constexpr size_t O_MAP1  = O_PERM1 + F4(N0);
constexpr size_t O_H1P   = O_MAP1  + F4(N0);
constexpr size_t O_SRC2  = O_H1P   + F4(K1 * HD);
constexpr size_t O_DST2  = O_SRC2  + F4(E);
constexpr size_t O_EM2   = O_DST2  + F4(E);
constexpr size_t O_H2    = O_EM2   + F4(E);
constexpr size_t O_OUT2  = O_H2    + F4(K1 * HD);
constexpr size_t O_DEG2  = O_OUT2  + F4(K1 * HD);
constexpr size_t O_DIS2  = O_DEG2  + F4(N0);
constexpr size_t O_SC2   = O_DIS2  + F4(N0);
constexpr size_t O_PERM2 = O_SC2   + F4(N0);
constexpr size_t O_MAP2  = O_PERM2 + F4(N0);
constexpr size_t O_H2P   = O_MAP2  + F4(N0);
constexpr size_t O_SRC3  = O_H2P   + F4(K2 * HD);
constexpr size_t O_DST3  = O_SRC3  + F4(E);
constexpr size_t O_EM3   = O_DST3  + F4(E);
constexpr size_t O_XR    = O_EM3   + F4(E);
constexpr size_t O_XI    = O_XR    + F4(K2 * HD);
constexpr size_t O_DEG3  = O_XI    + F4(K2 * HD);
constexpr size_t O_DIS3  = O_DEG3  + F4(1024);
constexpr size_t O_SCOEF = O_DIS3  + F4(1024);
constexpr size_t O_XG1   = O_SCOEF + F4(1024);
constexpr size_t O_XG2H  = O_XG1   + F4(K2 * UHD);
constexpr size_t O_XG2   = O_XG2H  + F4(K2 * UHD);
constexpr size_t O_EMB   = O_XG2   + F4(K2 * UHD);
constexpr size_t O_T1    = O_EMB   + F4(64);
constexpr size_t O_T2    = O_T1    + F4(64);
constexpr size_t O_NORM  = O_T2    + F4(64);
constexpr size_t O_PM    = O_NORM  + F4(64);
constexpr size_t O_BM    = O_PM    + F4(PMN);          // float2
constexpr size_t O_P0    = O_BM    + F4(PMN) * 2;      // float2
constexpr size_t O_P1    = O_P0    + F4(PMN) * 2;      // float2
constexpr size_t O_XRT   = O_P1    + F4(PMN) * 2;
constexpr size_t O_XIT   = O_XRT   + F4(K2 * HD);
constexpr size_t O_XC    = O_XIT   + F4(K2 * HD);      // float2
constexpr size_t O_EVO   = O_XC    + F4(K2 * HD) * 2;  // float2
constexpr size_t O_AGG0  = O_EVO   + F4(K2 * HD) * 2;  // float2
constexpr size_t O_WC    = O_AGG0  + F4(K2 * HD) * 2;  // float2 256x256
constexpr size_t O_AGG1  = O_WC    + F4(HD * HD) * 2;  // float2
constexpr size_t O_MAG   = O_AGG1  + F4(K2 * HD) * 2;
constexpr size_t O_PH    = O_MAG   + F4(K2 * HD);
constexpr size_t O_GM    = O_PH    + F4(K2 * HD);
constexpr size_t O_GP    = O_GM    + F4(256);
constexpr size_t O_HM    = O_GP    + F4(256);
constexpr size_t O_HP    = O_HM    + F4(256);
constexpr size_t O_LM    = O_HP    + F4(256);
constexpr size_t O_LP    = O_LM    + F4(64);
constexpr size_t WS_NEED = O_LP    + F4(64);

// Dead-region aliases during expm (everything below O_SRC3 is dead by then):
// SA/ST bf16 plane sets (3.97 MB each) + split-K fp32 partials (10.3 MB).
constexpr size_t O_SA   = 0;
constexpr size_t O_ST   = O_SA + PPS * 2 * 4;
constexpr size_t O_PART = O_ST + PPS * 2 * 4;
constexpr size_t PART_SZ = (size_t)CSPLIT * PMN * 8;
static_assert(O_PART + PART_SZ <= O_SRC3, "SA/ST/PART must fit in dead region");

// B2/B3 fp32 (PS powers) alias XRT..AGG1 (written only post-expm).
constexpr size_t O_B2 = O_XRT;
constexpr size_t O_B3 = O_B2 + F4(PMN) * 2;
static_assert(O_B3 + F4(PMN) * 2 <= O_MAG, "B2/B3 must fit in XRT..AGG1 region");

// ---------------- bf16 helpers ----------------
typedef __attribute__((ext_vector_type(8))) short s8v;   // 8 bf16 (4 VGPRs)
typedef __attribute__((ext_vector_type(4))) float f4v;   // MFMA acc

__device__ inline unsigned short f2bf(float x) {
  unsigned u = __float_as_uint(x);
  u += 0x7FFFu + ((u >> 16) & 1u);
  return (unsigned short)(u >> 16);
}
__device__ inline float bf2f(unsigned short h) {
  return __uint_as_float(((unsigned)h) << 16);
}

// ---------------- kernels ----------------

// real GEMM fp32 (pool-score path must stay fp32 for exact top-k ordering).
template <int ACT>
__global__ void rmm64(const float* __restrict__ A, const float* __restrict__ B,
                      const float* __restrict__ bias, float* __restrict__ C,
                      int M, int N, int K) {
  __shared__ float As[64][17];
  __shared__ float Bs[16][64];
  int t  = threadIdx.x;
  int tx = t & 15, ty = t >> 4;
  int bm = blockIdx.y * 64, bn = blockIdx.x * 64;
  float acc[4][4] = {};
  for (int kt = 0; kt < K; kt += 16) {
#pragma unroll
    for (int i = 0; i < 4; i++) {
      int l = t + i * 256;
      int kk = l & 15, mm = l >> 4;
      int gr = bm + mm;
      As[mm][kk] = (gr < M) ? A[(size_t)gr * K + kt + kk] : 0.f;
    }
#pragma unroll
    for (int i = 0; i < 4; i++) {
      int l = t + i * 256;
      int cc = l & 63, kk = l >> 6;
      int gc = bn + cc;
      Bs[kk][cc] = (gc < N) ? B[(size_t)(kt + kk) * N + gc] : 0.f;
    }
    __syncthreads();
#pragma unroll
    for (int kk = 0; kk < 16; kk++) {
      float a[4], b[4];
#pragma unroll
      for (int i = 0; i < 4; i++) a[i] = As[ty + 16 * i][kk];
#pragma unroll
      for (int j = 0; j < 4; j++) b[j] = Bs[kk][tx + 16 * j];
#pragma unroll
      for (int i = 0; i < 4; i++)
#pragma unroll
        for (int j = 0; j < 4; j++) acc[i][j] += a[i] * b[j];
    }
    __syncthreads();
  }
#pragma unroll
  for (int i = 0; i < 4; i++) {
    int r = bm + ty + 16 * i;
    if (r >= M) continue;
#pragma unroll
    for (int j = 0; j < 4; j++) {
      int c = bn + tx + 16 * j;
      if (c >= N) continue;
      float v = acc[i][j] + (bias ? bias[c] : 0.f);
      if (ACT == 1) v = fmaxf(v, 0.f);
      C[(size_t)r * N + c] = v;
    }
  }
}

// Split complex fp32 -> 4 bf16 planes [row][col] (rh, rl, ih, il), zero-pad.
__global__ void split_planes(const float2* __restrict__ in, int inM, int inN,
                             unsigned short* __restrict__ out, int padR, int ld,
                             size_t ps) {
  int idx = blockIdx.x * 256 + threadIdx.x;
  if (idx >= padR * ld) return;
  int r = idx / ld, c = idx - r * ld;
  float re = 0.f, im = 0.f;
  if (r < inM && c < inN) { float2 v = in[(size_t)r * inN + c]; re = v.x; im = v.y; }
  unsigned short rh = f2bf(re);
  unsigned short rl = f2bf(re - bf2f(rh));
  unsigned short ih = f2bf(im);
  unsigned short il = f2bf(im - bf2f(ih));
  out[idx] = rh; out[ps + idx] = rl; out[2 * ps + idx] = ih; out[3 * ps + idx] = il;
}

// Transposed split: out[n*ld + k] = split(in[k][n]); tiled via LDS.
__global__ void split_planesT(const float2* __restrict__ in, int inM, int inN,
                              unsigned short* __restrict__ out, int padR, int ld,
                              size_t ps) {
  __shared__ float2 tile[32][33];
  int tx = threadIdx.x & 31, ty = threadIdx.x >> 5;   // 32 x 8
  int k0 = blockIdx.x * 32, n0 = blockIdx.y * 32;
  for (int i = ty; i < 32; i += 8) {
    int k = k0 + i, n = n0 + tx;
    tile[i][tx] = (k < inM && n < inN) ? in[(size_t)k * inN + n]
                                       : make_float2(0.f, 0.f);
  }
  __syncthreads();
  for (int i = ty; i < 32; i += 8) {
    int n = n0 + i, k = k0 + tx;
    if (n < padR && k < ld) {
      float2 v = tile[tx][i];
      size_t o = (size_t)n * ld + k;
      unsigned short rh = f2bf(v.x);
      unsigned short rl = f2bf(v.x - bf2f(rh));
      unsigned short ih = f2bf(v.y);
      unsigned short il = f2bf(v.y - bf2f(ih));
      out[o] = rh; out[ps + o] = rl; out[2 * ps + o] = ih; out[3 * ps + o] = il;
    }
  }
}

// Split-K complex MFMA GEMM with register double-buffer prefetch.
// Part[z] = A[:, kz] @ B[kz, :], fp32 float2 partials (plain stores).
// SA: A planes [row][k]; ST: B planes transposed [n][k].
// Fragments: A[m=lane&15][k=quad*8+j], B[k=quad*8+j][n=lane&15],
// C/D col=lane&15 row=quad*4+reg (HW-verified layouts).
// chunk % 32 == 0; chunk*(gridDim.z-1) < Kp.
__global__ __launch_bounds__(256, 2) void cmm_bf16_sk(
    const unsigned short* __restrict__ SA, size_t psA, int ldA,
    const unsigned short* __restrict__ ST, size_t psT, int ldT,
    float2* __restrict__ Part, int M, int N, int Kp, int chunk) {
  int k0 = blockIdx.z * chunk;
  int kend = min(Kp, k0 + chunk);
  int t = threadIdx.x;
  int wave = t >> 6, lane = t & 63;
  int quad = lane >> 4, mn = lane & 15;
  int rowA = blockIdx.y * 64 + wave * 16 + mn;
  int bn = blockIdx.x * 64;
  const unsigned short* a0 = SA + (size_t)rowA * ldA;
  f4v accR[4], accI[4];
#pragma unroll
  for (int i = 0; i < 4; i++) {
    accR[i] = (f4v){0.f, 0.f, 0.f, 0.f};
    accI[i] = (f4v){0.f, 0.f, 0.f, 0.f};
  }
  s8v cA[4], cB[4][4], nA[4], nB[4][4];
  {
    int ka = k0 + quad * 8;
#pragma unroll
    for (int p = 0; p < 4; p++) cA[p] = *(const s8v*)(a0 + p * psA + ka);
#pragma unroll
    for (int tl = 0; tl < 4; tl++) {
      const unsigned short* b0 = ST + (size_t)(bn + tl * 16 + mn) * ldT + ka;
#pragma unroll
      for (int p = 0; p < 4; p++) cB[tl][p] = *(const s8v*)(b0 + p * psT);
    }
  }
  for (int kt = k0; kt < kend; kt += 32) {
    int kn = kt + 32;
    if (kn < kend) {  // issue next tile's 20 loads before computing current
      int ka = kn + quad * 8;
#pragma unroll
      for (int p = 0; p < 4; p++) nA[p] = *(const s8v*)(a0 + p * psA + ka);
#pragma unroll
      for (int tl = 0; tl < 4; tl++) {
        const unsigned short* b0 = ST + (size_t)(bn + tl * 16 + mn) * ldT + ka;
#pragma unroll
        for (int p = 0; p < 4; p++) nB[tl][p] = *(const s8v*)(b0 + p * psT);
      }
    }
    s8v nih, nil_;
#pragma unroll
    for (int q = 0; q < 8; q++) {
      nih[q]  = (short)(cA[2][q] ^ (short)0x8000);   // -ai
      nil_[q] = (short)(cA[3][q] ^ (short)0x8000);
    }
#pragma unroll
    for (int tl = 0; tl < 4; tl++) {
      f4v r = accR[tl];
      r = __builtin_amdgcn_mfma_f32_16x16x32_bf16(cA[0], cB[tl][0], r, 0, 0, 0);
      r = __builtin_amdgcn_mfma_f32_16x16x32_bf16(cA[1], cB[tl][0], r, 0, 0, 0);
      r = __builtin_amdgcn_mfma_f32_16x16x32_bf16(cA[0], cB[tl][1], r, 0, 0, 0);
      r = __builtin_amdgcn_mfma_f32_16x16x32_bf16(nih, cB[tl][2], r, 0, 0, 0);
      r = __builtin_amdgcn_mfma_f32_16x16x32_bf16(nil_, cB[tl][2], r, 0, 0, 0);
      r = __builtin_amdgcn_mfma_f32_16x16x32_bf16(nih, cB[tl][3], r, 0, 0, 0);
      accR[tl] = r;
      f4v im = accI[tl];
      im = __builtin_amdgcn_mfma_f32_16x16x32_bf16(cA[0], cB[tl][2], im, 0, 0, 0);
      im = __builtin_amdgcn_mfma_f32_16x16x32_bf16(cA[1], cB[tl][2], im, 0, 0, 0);
      im = __builtin_amdgcn_mfma_f32_16x16x32_bf16(cA[0], cB[tl][3], im, 0, 0, 0);
      im = __builtin_amdgcn_mfma_f32_16x16x32_bf16(cA[2], cB[tl][0], im, 0, 0, 0);
      im = __builtin_amdgcn_mfma_f32_16x16x32_bf16(cA[3], cB[tl][0], im, 0, 0, 0);
      im = __builtin_amdgcn_mfma_f32_16x16x32_bf16(cA[2], cB[tl][1], im, 0, 0, 0);
      accI[tl] = im;
    }
    if (kn < kend) {
#pragma unroll
      for (int p = 0; p < 4; p++) cA[p] = nA[p];
#pragma unroll
      for (int tl = 0; tl < 4; tl++)
#pragma unroll
        for (int p = 0; p < 4; p++) cB[tl][p] = nB[tl][p];
    }
  }
  float2* P = Part + (size_t)blockIdx.z * M * N;
#pragma unroll
  for (int tl = 0; tl < 4; tl++) {
    int col = bn + tl * 16 + mn;
    if (col >= N) continue;
#pragma unroll
    for (int r = 0; r < 4; r++) {
      int row = blockIdx.y * 64 + wave * 16 + quad * 4 + r;
      if (row >= M) continue;
      P[(size_t)row * N + col] = make_float2(accR[tl][r], accI[tl][r]);
    }
  }
}

// C = sum_z Part[z] + e0*I + e1*E1 + e2*E2 (PS Horner epilogue folded in).
__global__ void creduce(const float2* __restrict__ Part, float2* __restrict__ C,
                        int MN, int N, int S, float e0,
                        const float2* __restrict__ E1, float e1,
                        const float2* __restrict__ E2, float e2) {
  int idx = blockIdx.x * 256 + threadIdx.x;
  if (idx >= MN) return;
  float sr = 0.f, si = 0.f;
  for (int z = 0; z < S; z++) {
    float2 p = Part[(size_t)z * MN + idx];
    sr += p.x;
    si += p.y;
  }
  if (e0 != 0.f) {
    int r = idx / N;
    if (idx - r * N == r) sr += e0;
  }
  if (E1) { float2 b = E1[idx]; sr += e1 * b.x; si += e1 * b.y; }
  if (E2) { float2 b = E2[idx]; sr += e2 * b.x; si += e2 * b.y; }
  C[idx] = make_float2(sr, si);
}

__global__ void edge_deg(const int* __restrict__ dst, const float* __restrict__ em,
                         float* __restrict__ deg) {
  int e = blockIdx.x * 256 + threadIdx.x;
  if (e >= E) return;
  float m = em ? em[e] : 1.0f;
  if (m != 0.f) atomicAdd(&deg[dst[e]], m);
}

__global__ void deg_to_dis(const float* __restrict__ deg, float* __restrict__ dis, int n) {
  int i = blockIdx.x * 256 + threadIdx.x;
  if (i >= n) return;
  dis[i] = 1.0f / sqrtf(deg[i] + 1.0f);
}

__global__ void gcn_self(const float* __restrict__ Hm, const float* __restrict__ dis,
                         const float* __restrict__ bias, float* __restrict__ out, int F) {
  int i = blockIdx.x;
  float d2 = dis[i] * dis[i];
  for (int f = threadIdx.x; f < F; f += blockDim.x)
    out[(size_t)i * F + f] = d2 * Hm[(size_t)i * F + f] + bias[f];
}

__global__ void gcn_scatter(const int* __restrict__ src, const int* __restrict__ dst,
                            const float* __restrict__ em, const float* __restrict__ dis,
                            const float* __restrict__ Hm, float* __restrict__ out, int F) {
  int e = blockIdx.x;
  float m = em ? em[e] : 1.0f;
  if (m == 0.f) return;
  int s = src[e], d = dst[e];
  float c = dis[s] * dis[d] * m;
  for (int f = threadIdx.x; f < F; f += blockDim.x)
    atomicAdd(&out[(size_t)d * F + f], c * Hm[(size_t)s * F + f]);
}

__global__ void relu_ip(float* __restrict__ x, int n) {
  int i = blockIdx.x * 256 + threadIdx.x;
  if (i < n) x[i] = fmaxf(x[i], 0.f);
}

__global__ void wnorm(const float* __restrict__ w, int n, float* __restrict__ out) {
  __shared__ float red[256];
  float s = 0.f;
  for (int k = threadIdx.x; k < n; k += 256) s += w[k] * w[k];
  red[threadIdx.x] = s;
  __syncthreads();
  for (int off = 128; off > 0; off >>= 1) {
    if (threadIdx.x < off) red[threadIdx.x] += red[threadIdx.x + off];
    __syncthreads();
  }
  if (threadIdx.x == 0) out[0] = sqrtf(red[0]);
}

__global__ void rowdot(const float* __restrict__ X, const float* __restrict__ w,
                       float* __restrict__ out, int F) {
  int i = blockIdx.x;
  __shared__ float red[256];
  float s = 0.f;
  for (int f = threadIdx.x; f < F; f += 256) s += X[(size_t)i * F + f] * w[f];
  red[threadIdx.x] = s;
  __syncthreads();
  for (int off = 128; off > 0; off >>= 1) {
    if (threadIdx.x < off) red[threadIdx.x] += red[threadIdx.x + off];
    __syncthreads();
  }
  if (threadIdx.x == 0) out[i] = red[0];
}

// exact-total-order descending bitonic sort; key = (sortable_score<<32) | ~idx.
__global__ __launch_bounds__(1024) void bitonic_topk(const float* __restrict__ score,
                                                     int n, int* __restrict__ perm, int k) {
  __shared__ unsigned long long keys[4096];
  int t = threadIdx.x;
  for (int i = t; i < 4096; i += 1024) {
    unsigned long long kk = 0ull;
    if (i < n) {
      float f = score[i];
      unsigned u = __float_as_uint(f);
      u = (f >= 0.0f) ? (u | 0x80000000u) : ~u;
      kk = ((unsigned long long)u << 32) | (unsigned)(~(unsigned)i);
    }
    keys[i] = kk;
  }
  __syncthreads();
  for (int size = 2; size <= 4096; size <<= 1) {
    for (int stride = size >> 1; stride > 0; stride >>= 1) {
      for (int i = t; i < 2048; i += 1024) {
        int pos = ((i & ~(stride - 1)) << 1) | (i & (stride - 1));
        int partner = pos + stride;
        bool desc = (pos & size) == 0;
        unsigned long long a = keys[pos], b = keys[partner];
        if ((a < b) == desc) { keys[pos] = b; keys[partner] = a; }
      }
      __syncthreads();
    }
  }
  for (int i = t; i < k; i += 1024)
    perm[i] = (int)(~(unsigned)(keys[i] & 0xFFFFFFFFull));
}

__global__ void set_map(const int* __restrict__ perm, int* __restrict__ map, int k) {
  int i = blockIdx.x * 256 + threadIdx.x;
  if (i < k) map[perm[i]] = i;
}

__global__ void pool_gather(const float* __restrict__ X, const int* __restrict__ perm,
                            const float* __restrict__ dot, const float* __restrict__ normbuf,
                            float* __restrict__ Xn, int F) {
  int i = blockIdx.x;
  int p = perm[i];
  float sc = tanhf(dot[p] / normbuf[0]);
  for (int f = threadIdx.x; f < F; f += blockDim.x)
    Xn[(size_t)i * F + f] = X[(size_t)p * F + f] * sc;
}

__global__ void remap_edges(const int* __restrict__ srcIn, const int* __restrict__ dstIn,
                            const float* __restrict__ emIn, const int* __restrict__ map,
                            int* __restrict__ srcOut, int* __restrict__ dstOut,
                            float* __restrict__ emOut) {
  int e = blockIdx.x * 256 + threadIdx.x;
  if (e >= E) return;
  int ns = map[srcIn[e]], nd = map[dstIn[e]];
  float m = emIn ? emIn[e] : 1.0f;
  if (ns < 0 || nd < 0) m = 0.f;
  srcOut[e] = ns < 0 ? 0 : ns;
  dstOut[e] = nd < 0 ? 0 : nd;
  emOut[e] = m;
}

__global__ void enc_scoef(const int* __restrict__ src, const int* __restrict__ dst,
                          const float* __restrict__ em, const float* __restrict__ dis,
                          float* __restrict__ scoef) {
  int e = blockIdx.x * 256 + threadIdx.x;
  if (e >= E) return;
  float m = em[e];
  if (m == 0.f) return;
  atomicAdd(&scoef[dst[e]], dis[src[e]] * dis[dst[e]] * m);
}

__global__ void enc1_out(const float* __restrict__ scoef, const float* __restrict__ dis,
                         const float* __restrict__ w, const float* __restrict__ b,
                         float* __restrict__ xg1) {
  int i = blockIdx.x;
  int f = threadIdx.x;
  float s = scoef[i] + dis[i] * dis[i];
  xg1[(size_t)i * UHD + f] = fmaxf(s * w[f] + b[f], 0.f);
}

__global__ void col_mean(const float* __restrict__ X, float* __restrict__ out,
                         int rows, int cols) {
  int c = blockIdx.x;
  __shared__ float red[256];
  float s = 0.f;
  for (int r = threadIdx.x; r < rows; r += 256) s += X[(size_t)r * cols + c];
  red[threadIdx.x] = s;
  __syncthreads();
  for (int off = 128; off > 0; off >>= 1) {
    if (threadIdx.x < off) red[threadIdx.x] += red[threadIdx.x + off];
    __syncthreads();
  }
  if (threadIdx.x == 0) out[c] = red[0] / (float)rows;
}

template <int ACT>
__global__ void vecmat(const float* __restrict__ v, const float* __restrict__ W,
                       const float* __restrict__ b, float* __restrict__ out,
                       int Kdim, int Ndim) {
  __shared__ float vs[256];
  for (int k = threadIdx.x; k < Kdim; k += blockDim.x) vs[k] = v[k];
  __syncthreads();
  for (int j = threadIdx.x; j < Ndim; j += blockDim.x) {
    float acc = b ? b[j] : 0.f;
    for (int k = 0; k < Kdim; k++) acc += vs[k] * W[(size_t)k * Ndim + j];
    out[j] = (ACT == 1) ? fmaxf(acc, 0.f) : acc;
  }
}

__global__ void vecmat_tanh_wide(const float* __restrict__ v, const float* __restrict__ W,
                                 const float* __restrict__ b, float* __restrict__ out,
                                 int Kdim, int Ndim) {
  __shared__ float vs[64];
  if (threadIdx.x < Kdim) vs[threadIdx.x] = v[threadIdx.x];
  __syncthreads();
  int j = blockIdx.x * 256 + threadIdx.x;
  if (j >= Ndim) return;
  float acc = b[j];
  for (int k = 0; k < Kdim; k++) acc += vs[k] * W[(size_t)k * Ndim + j];
  out[j] = tanhf(acc);
}

__global__ void build_B(const float* __restrict__ pm, float2* __restrict__ Bm,
                        int n, float scale) {
  int idx = blockIdx.x * 256 + threadIdx.x;
  if (idx >= n * n) return;
  int r = idx / n, c = idx - r * n;
  float pij = pm[(size_t)r * n + c];
  float pji = pm[(size_t)c * n + r];
  Bm[idx] = make_float2(scale * (pij - pji), scale * (pij + pji));
}

// Out = e0*I + e1*B + e2*B2 (top PS block D3)
__global__ void combo3(const float2* __restrict__ Bp, const float2* __restrict__ B2p,
                       float2* __restrict__ Out, int MN, int N,
                       float e0, float e1, float e2) {
  int idx = blockIdx.x * 256 + threadIdx.x;
  if (idx >= MN) return;
  float2 b = Bp[idx], b2 = B2p[idx];
  float sr = e1 * b.x + e2 * b2.x;
  float si = e1 * b.y + e2 * b2.y;
  int r = idx / N;
  if (idx - r * N == r) sr += e0;
  Out[idx] = make_float2(sr, si);
}

__global__ void pack2(const float* __restrict__ a, const float* __restrict__ b,
                      float2* __restrict__ out, int n) {
  int i = blockIdx.x * 256 + threadIdx.x;
  if (i < n) out[i] = make_float2(a[i], b[i]);
}

__global__ void agg_scatter(const int* __restrict__ src, const int* __restrict__ dst,
                            const float* __restrict__ em, const float2* __restrict__ evo,
                            float2* __restrict__ agg, int F) {
  int e = blockIdx.x;
  float m = em[e];
  if (m == 0.f) return;
  int s = src[e], d = dst[e];
  for (int f = threadIdx.x; f < F; f += blockDim.x) {
    float2 v = evo[(size_t)s * F + f];
    atomicAdd(&agg[(size_t)d * F + f].x, m * v.x);
    atomicAdd(&agg[(size_t)d * F + f].y, m * v.y);
  }
}

__global__ void magph(const float2* __restrict__ agg, const float* __restrict__ xr,
                      const float* __restrict__ xi, float* __restrict__ mag,
                      float* __restrict__ ph, int n) {
  int idx = blockIdx.x * 256 + threadIdx.x;
  if (idx >= n) return;
  float2 a = agg[idx];
  float r = a.x + xr[idx];
  float im = a.y + xi[idx];
  mag[idx] = sqrtf(r * r + im * im);
  ph[idx] = atan2f(im, r);
}

__global__ void add_out(const float* __restrict__ lm, const float* __restrict__ lp,
                        float* __restrict__ out, int n) {
  int i = threadIdx.x;
  if (i < n) out[i] = lm[i] + lp[i];
}

// ---------------- host helpers ----------------
static inline int sk_chunk32(int K, int S) { return (((K + S - 1) / S) + 31) & ~31; }

// ---------------- host ----------------
extern "C" void kernel_launch(void* const* d_in, const int* in_sizes, int n_in,
                              void* d_out, int out_size, void* d_ws, size_t ws_size,
                              hipStream_t stream) {
  if (ws_size < WS_NEED) return;

  const float* x       = (const float*)d_in[0];
  const int*   ei      = (const int*)d_in[1];
  const float* gcn1_w  = (const float*)d_in[2];
  const float* gcn1_b  = (const float*)d_in[3];
  const float* pool1_w = (const float*)d_in[4];
  const float* gcn2_w  = (const float*)d_in[5];
  const float* gcn2_b  = (const float*)d_in[6];
  const float* pool2_w = (const float*)d_in[7];
  const float* inr_w   = (const float*)d_in[8];
  const float* inr_b   = (const float*)d_in[9];
  const float* ini_w   = (const float*)d_in[10];
  const float* ini_b   = (const float*)d_in[11];
  const float* enc1_w  = (const float*)d_in[12];
  const float* enc1_b  = (const float*)d_in[13];
  const float* enc2_w  = (const float*)d_in[14];
  const float* enc2_b  = (const float*)d_in[15];
  const float* p1_w    = (const float*)d_in[16];
  const float* p1_b    = (const float*)d_in[17];
  const float* p2_w    = (const float*)d_in[18];
  const float* p2_b    = (const float*)d_in[19];
  const float* p3_w    = (const float*)d_in[20];
  const float* p3_b    = (const float*)d_in[21];
  const float* rt_w    = (const float*)d_in[22];
  const float* rt_b    = (const float*)d_in[23];
  const float* it_w    = (const float*)d_in[24];
  const float* it_b    = (const float*)d_in[25];
  const float* msg_wr  = (const float*)d_in[26];
  const float* msg_wi  = (const float*)d_in[27];
  const float* mc1_w   = (const float*)d_in[28];
  const float* mc1_b   = (const float*)d_in[29];
  const float* mc2_w   = (const float*)d_in[30];
  const float* mc2_b   = (const float*)d_in[31];
  const float* pc1_w   = (const float*)d_in[32];
  const float* pc1_b   = (const float*)d_in[33];
  const float* pc2_w   = (const float*)d_in[34];
  const float* pc2_b   = (const float*)d_in[35];

  char* ws = (char*)d_ws;
  float*  H1    = (float*)(ws + O_H1);
  float*  OUT1  = (float*)(ws + O_OUT1);
  float*  DEG1  = (float*)(ws + O_DEG1);
  float*  DIS1  = (float*)(ws + O_DIS1);
  float*  SC1   = (float*)(ws + O_SC1);
  int*    PERM1 = (int*)(ws + O_PERM1);
  int*    MAP1  = (int*)(ws + O_MAP1);
  float*  H1P   = (float*)(ws + O_H1P);
  int*    SRC2  = (int*)(ws + O_SRC2);
  int*    DST2  = (int*)(ws + O_DST2);
  float*  EM2   = (float*)(ws + O_EM2);
  float*  H2    = (float*)(ws + O_H2);
  float*  OUT2  = (float*)(ws + O_OUT2);
  float*  DEG2  = (float*)(ws + O_DEG2);
  float*  DIS2  = (float*)(ws + O_DIS2);
  float*  SC2   = (float*)(ws + O_SC2);
  int*    PERM2 = (int*)(ws + O_PERM2);
  int*    MAP2  = (int*)(ws + O_MAP2);
  float*  H2P   = (float*)(ws + O_H2P);
  int*    SRC3  = (int*)(ws + O_SRC3);
  int*    DST3  = (int*)(ws + O_DST3);
  float*  EM3   = (float*)(ws + O_EM3);
  float*  XRb   = (float*)(ws + O_XR);
  float*  XIb   = (float*)(ws + O_XI);
  float*  DEG3  = (float*)(ws + O_DEG3);
  float*  DIS3  = (float*)(ws + O_DIS3);
  float*  SCOEF = (float*)(ws + O_SCOEF);
  float*  XG1   = (float*)(ws + O_XG1);
  float*  XG2H  = (float*)(ws + O_XG2H);
  float*  XG2   = (float*)(ws + O_XG2);
  float*  EMB   = (float*)(ws + O_EMB);
  float*  T1    = (float*)(ws + O_T1);
  float*  T2    = (float*)(ws + O_T2);
  float*  NORM  = (float*)(ws + O_NORM);
  float*  PMV   = (float*)(ws + O_PM);
  float2* BM    = (float2*)(ws + O_BM);
  float2* P0v   = (float2*)(ws + O_P0);
  float2* P1v   = (float2*)(ws + O_P1);
  float*  XRT   = (float*)(ws + O_XRT);
  float*  XIT   = (float*)(ws + O_XIT);
  float2* XC    = (float2*)(ws + O_XC);
  float2* EVO   = (float2*)(ws + O_EVO);
  float2* AGG0  = (float2*)(ws + O_AGG0);
  float2* WC    = (float2*)(ws + O_WC);
  float2* AGG1  = (float2*)(ws + O_AGG1);
  float*  MAGB  = (float*)(ws + O_MAG);
  float*  PHB   = (float*)(ws + O_PH);
  float*  GM    = (float*)(ws + O_GM);
  float*  GP    = (float*)(ws + O_GP);
  float*  HM    = (float*)(ws + O_HM);
  float*  HP    = (float*)(ws + O_HP);
  float*  LM    = (float*)(ws + O_LM);
  float*  LP    = (float*)(ws + O_LP);
  unsigned short* SA = (unsigned short*)(ws + O_SA);
  unsigned short* ST = (unsigned short*)(ws + O_ST);
  float2* PART  = (float2*)(ws + O_PART);
  float2* B2v   = (float2*)(ws + O_B2);
  float2* B3v   = (float2*)(ws + O_B3);

  const int* SRC1 = ei;
  const int* DST1 = ei + E;

  // ---------- Stage A: gcn1 + relu ----------
  rmm64<0><<<dim3(HD / 64, N0 / 64), 256, 0, stream>>>(x, gcn1_w, nullptr, H1, N0, HD, DIN);
  hipMemsetAsync(DEG1, 0, F4(N0), stream);
  edge_deg<<<E / 256, 256, 0, stream>>>(DST1, nullptr, DEG1);
  deg_to_dis<<<N0 / 256, 256, 0, stream>>>(DEG1, DIS1, N0);
  gcn_self<<<N0, 256, 0, stream>>>(H1, DIS1, gcn1_b, OUT1, HD);
  gcn_scatter<<<E, 256, 0, stream>>>(SRC1, DST1, nullptr, DIS1, H1, OUT1, HD);
  relu_ip<<<(N0 * HD) / 256, 256, 0, stream>>>(OUT1, N0 * HD);

  // ---------- pool1 ----------
  wnorm<<<1, 256, 0, stream>>>(pool1_w, HD, NORM);
  rowdot<<<N0, 256, 0, stream>>>(OUT1, pool1_w, SC1, HD);
  bitonic_topk<<<1, 1024, 0, stream>>>(SC1, N0, PERM1, K1);
  hipMemsetAsync(MAP1, 0xFF, F4(N0), stream);
  set_map<<<(K1 + 255) / 256, 256, 0, stream>>>(PERM1, MAP1, K1);
  pool_gather<<<K1, 256, 0, stream>>>(OUT1, PERM1, SC1, NORM, H1P, HD);
  remap_edges<<<E / 256, 256, 0, stream>>>(SRC1, DST1, nullptr, MAP1, SRC2, DST2, EM2);

  // ---------- Stage C: gcn2 + relu ----------
  rmm64<0><<<dim3(HD / 64, (K1 + 63) / 64), 256, 0, stream>>>(H1P, gcn2_w, nullptr, H2, K1, HD, HD);
  hipMemsetAsync(DEG2, 0, F4(N0), stream);
  edge_deg<<<E / 256, 256, 0, stream>>>(DST2, EM2, DEG2);
  deg_to_dis<<<(K1 + 255) / 256, 256, 0, stream>>>(DEG2, DIS2, K1);
  gcn_self<<<K1, 256, 0, stream>>>(H2, DIS2, gcn2_b, OUT2, HD);
  gcn_scatter<<<E, 256, 0, stream>>>(SRC2, DST2, EM2, DIS2, H2, OUT2, HD);
  relu_ip<<<(K1 * HD + 255) / 256, 256, 0, stream>>>(OUT2, K1 * HD);

  // ---------- pool2 ----------
  wnorm<<<1, 256, 0, stream>>>(pool2_w, HD, NORM + 1);
  rowdot<<<K1, 256, 0, stream>>>(OUT2, pool2_w, SC2, HD);
  bitonic_topk<<<1, 1024, 0, stream>>>(SC2, K1, PERM2, K2);
  hipMemsetAsync(MAP2, 0xFF, F4(N0), stream);
  set_map<<<(K2 + 255) / 256, 256, 0, stream>>>(PERM2, MAP2, K2);
  pool_gather<<<K2, 256, 0, stream>>>(OUT2, PERM2, SC2, NORM + 1, H2P, HD);
  remap_edges<<<E / 256, 256, 0, stream>>>(SRC2, DST2, EM2, MAP2, SRC3, DST3, EM3);

  // ---------- xr / xi ----------
  rmm64<0><<<dim3(HD / 64, (K2 + 63) / 64), 256, 0, stream>>>(H2P, inr_w, inr_b, XRb, K2, HD, HD);
  rmm64<0><<<dim3(HD / 64, (K2 + 63) / 64), 256, 0, stream>>>(H2P, ini_w, ini_b, XIb, K2, HD, HD);

  // ---------- encoder GCNs on pooled graph ----------
  hipMemsetAsync(DEG3, 0, F4(K2), stream);
  edge_deg<<<E / 256, 256, 0, stream>>>(DST3, EM3, DEG3);
  deg_to_dis<<<(K2 + 255) / 256, 256, 0, stream>>>(DEG3, DIS3, K2);
  hipMemsetAsync(SCOEF, 0, F4(K2), stream);
  enc_scoef<<<E / 256, 256, 0, stream>>>(SRC3, DST3, EM3, DIS3, SCOEF);
  enc1_out<<<K2, UHD, 0, stream>>>(SCOEF, DIS3, enc1_w, enc1_b, XG1);
  rmm64<0><<<dim3(UHD / 64, (K2 + 63) / 64), 256, 0, stream>>>(XG1, enc2_w, nullptr, XG2H, K2, UHD, UHD);
  gcn_self<<<K2, UHD, 0, stream>>>(XG2H, DIS3, enc2_b, XG2, UHD);
  gcn_scatter<<<E, UHD, 0, stream>>>(SRC3, DST3, EM3, DIS3, XG2H, XG2, UHD);
  col_mean<<<UHD, 256, 0, stream>>>(XG2, EMB, K2, UHD);

  // ---------- parameter MLP -> pm -> B ----------
  vecmat<1><<<1, 256, 0, stream>>>(EMB, p1_w, p1_b, T1, UHD, UHD);
  vecmat<1><<<1, 256, 0, stream>>>(T1, p2_w, p2_b, T2, UHD, UHD / 2);
  vecmat_tanh_wide<<<(PMN + 255) / 256, 256, 0, stream>>>(T2, p3_w, p3_b, PMV, UHD / 2, PMN);
  {
    const float scale = 0.05f * 0.5f / (float)(1 << EXPM_S);
    build_B<<<(PMN + 255) / 256, 256, 0, stream>>>(PMV, BM, K2, scale);
  }

  // ---------- expm via PS deg-11 + 5 squarings, split-K MFMA bf16 ----------
  const int rgrid = (PMN + 255) / 256;
  const int sgrid = (PLD * PLD + 255) / 256;
  const dim3 tgridF((PLD + 31) / 32, (PLD + 31) / 32);
  const int chF = sk_chunk32(PLD, CSPLIT);   // 256
  const dim3 ggK2(11, 11, CSPLIT);
  const float c3 = 1.f / 6.f, c4 = 1.f / 24.f, c5 = 1.f / 120.f;
  const float c6 = 1.f / 720.f, c7 = 1.f / 5040.f, c8 = 1.f / 40320.f;
  const float c9 = 1.f / 362880.f, c10 = 1.f / 3628800.f, c11 = 1.f / 39916800.f;

  split_planes <<<sgrid, 256, 0, stream>>>(BM, K2, K2, SA, PLD, PLD, PPS);
  split_planesT<<<tgridF, 256, 0, stream>>>(BM, K2, K2, ST, PLD, PLD, PPS);
  // B2 = B*B
  cmm_bf16_sk<<<ggK2, 256, 0, stream>>>(SA, PPS, PLD, ST, PPS, PLD, PART, K2, K2, PLD, chF);
  creduce<<<rgrid, 256, 0, stream>>>(PART, B2v, PMN, K2, CSPLIT, 0.f, nullptr, 0.f, nullptr, 0.f);
  // B3 = B2*B
  split_planes<<<sgrid, 256, 0, stream>>>(B2v, K2, K2, SA, PLD, PLD, PPS);
  cmm_bf16_sk<<<ggK2, 256, 0, stream>>>(SA, PPS, PLD, ST, PPS, PLD, PART, K2, K2, PLD, chF);
  creduce<<<rgrid, 256, 0, stream>>>(PART, B3v, PMN, K2, CSPLIT, 0.f, nullptr, 0.f, nullptr, 0.f);
  // ST <- B3^T (fixed right operand for Horner)
  split_planesT<<<tgridF, 256, 0, stream>>>(B3v, K2, K2, ST, PLD, PLD, PPS);
  // P0 = D3 = c9 I + c10 B + c11 B2
  combo3<<<rgrid, 256, 0, stream>>>(BM, B2v, P0v, PMN, K2, c9, c10, c11);
  // P1 = P0*B3 + (c6 I + c7 B + c8 B2)
  split_planes<<<sgrid, 256, 0, stream>>>(P0v, K2, K2, SA, PLD, PLD, PPS);
  cmm_bf16_sk<<<ggK2, 256, 0, stream>>>(SA, PPS, PLD, ST, PPS, PLD, PART, K2, K2, PLD, chF);
  creduce<<<rgrid, 256, 0, stream>>>(PART, P1v, PMN, K2, CSPLIT, c6, BM, c7, B2v, c8);
  // P0 = P1*B3 + (c3 I + c4 B + c5 B2)
  split_planes<<<sgrid, 256, 0, stream>>>(P1v, K2, K2, SA, PLD, PLD, PPS);
  cmm_bf16_sk<<<ggK2, 256, 0, stream>>>(SA, PPS, PLD, ST, PPS, PLD, PART, K2, K2, PLD, chF);
  creduce<<<rgrid, 256, 0, stream>>>(PART, P0v, PMN, K2, CSPLIT, c3, BM, c4, B2v, c5);
  // P1 = P0*B3 + (I + B + 0.5 B2)
  split_planes<<<sgrid, 256, 0, stream>>>(P0v, K2, K2, SA, PLD, PLD, PPS);
  cmm_bf16_sk<<<ggK2, 256, 0, stream>>>(SA, PPS, PLD, ST, PPS, PLD, PART, K2, K2, PLD, chF);
  creduce<<<rgrid, 256, 0, stream>>>(PART, P1v, PMN, K2, CSPLIT, 1.f, BM, 1.f, B2v, 0.5f);
  // 5 squarings
  float2* cur = P1v;
  float2* nxt = P0v;
  for (int t = 0; t < EXPM_S; ++t) {
    split_planes <<<sgrid, 256, 0, stream>>>(cur, K2, K2, SA, PLD, PLD, PPS);
    split_planesT<<<tgridF, 256, 0, stream>>>(cur, K2, K2, ST, PLD, PLD, PPS);
    cmm_bf16_sk<<<ggK2, 256, 0, stream>>>(SA, PPS, PLD, ST, PPS, PLD, PART, K2, K2, PLD, chF);
    creduce<<<rgrid, 256, 0, stream>>>(PART, nxt, PMN, K2, CSPLIT, 0.f, nullptr, 0.f, nullptr, 0.f);
    std::swap(cur, nxt);
  }
  float2* U = cur;

  // ---------- quantum message passing ----------
  rmm64<1><<<dim3(HD / 64, (K2 + 63) / 64), 256, 0, stream>>>(XRb, rt_w, rt_b, XRT, K2, HD, HD);
  rmm64<1><<<dim3(HD / 64, (K2 + 63) / 64), 256, 0, stream>>>(XIb, it_w, it_b, XIT, K2, HD, HD);
  pack2<<<(K2 * HD + 255) / 256, 256, 0, stream>>>(XRT, XIT, XC, K2 * HD);
  {
    const int mn = K2 * HD;
    const int rg = (mn + 255) / 256;
    // EVO = U @ XC  (M=656, N=256, Kp=704)
    split_planes <<<sgrid, 256, 0, stream>>>(U, K2, K2, SA, PLD, PLD, PPS);
    split_planesT<<<dim3((PLD + 31) / 32, (HD + 31) / 32), 256, 0, stream>>>(
        XC, K2, HD, ST, HD, PLD, (size_t)HD * PLD);
    cmm_bf16_sk<<<dim3(HD / 64, 11, CSPLIT), 256, 0, stream>>>(
        SA, PPS, PLD, ST, (size_t)HD * PLD, PLD, PART, K2, HD, PLD, chF);
    creduce<<<rg, 256, 0, stream>>>(PART, EVO, mn, HD, CSPLIT, 0.f, nullptr, 0.f, nullptr, 0.f);
    hipMemsetAsync(AGG0, 0, F4(K2 * HD) * 2, stream);
    agg_scatter<<<E, 256, 0, stream>>>(SRC3, DST3, EM3, EVO, AGG0, HD);
    pack2<<<(HD * HD + 255) / 256, 256, 0, stream>>>(msg_wr, msg_wi, WC, HD * HD);
    // AGG1 = AGG0 @ WC  (M=656, N=256, Kp=256)
    split_planes<<<((PLD * HD) + 255) / 256, 256, 0, stream>>>(
        AGG0, K2, HD, SA, PLD, HD, (size_t)PLD * HD);
    split_planesT<<<dim3((HD + 31) / 32, (HD + 31) / 32), 256, 0, stream>>>(
        WC, HD, HD, ST, HD, HD, (size_t)HD * HD);
    cmm_bf16_sk<<<dim3(HD / 64, 11, CSPLIT), 256, 0, stream>>>(
        SA, (size_t)PLD * HD, HD, ST, (size_t)HD * HD, HD, PART, K2, HD, HD,
        sk_chunk32(HD, CSPLIT));
    creduce<<<rg, 256, 0, stream>>>(PART, AGG1, mn, HD, CSPLIT, 0.f, nullptr, 0.f, nullptr, 0.f);
  }
  magph<<<(K2 * HD + 255) / 256, 256, 0, stream>>>(AGG1, XRb, XIb, MAGB, PHB, K2 * HD);
  col_mean<<<HD, 256, 0, stream>>>(MAGB, GM, K2, HD);
  col_mean<<<HD, 256, 0, stream>>>(PHB, GP, K2, HD);

  // ---------- classifier heads ----------
  vecmat<1><<<1, 256, 0, stream>>>(GM, mc1_w, mc1_b, HM, HD, HD / 2);
  vecmat<0><<<1, 256, 0, stream>>>(HM, mc2_w, mc2_b, LM, HD / 2, NC);
  vecmat<1><<<1, 256, 0, stream>>>(GP, pc1_w, pc1_b, HP, HD, HD / 2);
  vecmat<0><<<1, 256, 0, stream>>>(HP, pc2_w, pc2_b, LP, HD / 2, NC);
  add_out<<<1, 64, 0, stream>>>(LM, LP, (float*)d_out, NC);
}

// Round 8
// 1208.534 us; speedup vs baseline: 12.2419x; 1.0677x over previous
//
#include <hip/hip_runtime.h>
#include <cstddef>
#include <utility>

// ---------------- problem constants ----------------
constexpr int N0  = 4096;
constexpr int E   = 65536;
constexpr int DIN = 128;
constexpr int HD  = 256;   // H
constexpr int NC  = 10;
constexpr int UHD = 64;    // UH
constexpr int K1  = 3277;  // ceil(0.8*4096)
constexpr int K2  = 656;   // ceil(0.2*3277)
constexpr int PMN = K2 * K2; // 430336

// expm(A): A = 2^5*B, deg-11 Taylor via Paterson-Stockmeyer + 5 squarings.
constexpr int EXPM_S = 5;

// MFMA plane geometry: 656 -> padded 704 = 11*64 = 22*32.
constexpr int PLD = 704;
constexpr size_t PPS = (size_t)PLD * PLD;

// Split-K for the MFMA GEMMs (R6/R7: 3x blocks + register prefetch).
constexpr int CSPLIT = 3;

// ---------------- workspace layout ----------------
#define F4(n) ((size_t)(n) * 4)
constexpr size_t O_H1    = 0;
constexpr size_t O_OUT1  = O_H1    + F4(N0 * HD);
constexpr size_t O_DEG1  = O_OUT1  + F4(N0 * HD);
constexpr size_t O_DIS1  = O_DEG1  + F4(N0);
constexpr size_t O_SC1   = O_DIS1  + F4(N0);
constexpr size_t O_PERM1 = O_SC1   + F4(N0);
constexpr size_t O_MAP1  = O_PERM1 + F4(N0);
constexpr size_t O_H1P   = O_MAP1  + F4(N0);
constexpr size_t O_SRC2  = O_H1P   + F4(K1 * HD);
constexpr size_t O_DST2  = O_SRC2  + F4(E);
constexpr size_t O_EM2   = O_DST2  + F4(E);
constexpr size_t O_H2    = O_EM2   + F4(E);
constexpr size_t O_OUT2  = O_H2    + F4(K1 * HD);
constexpr size_t O_DEG2  = O_OUT2  + F4(K1 * HD);
constexpr size_t O_DIS2  = O_DEG2  + F4(N0);
constexpr size_t O_SC2   = O_DIS2  + F4(N0);
constexpr size_t O_PERM2 = O_SC2   + F4(N0);
constexpr size_t O_MAP2  = O_PERM2 + F4(N0);
constexpr size_t O_H2P   = O_MAP2  + F4(N0);
constexpr size_t O_SRC3  = O_H2P   + F4(K2 * HD);
constexpr size_t O_DST3  = O_SRC3  + F4(E);
constexpr size_t O_EM3   = O_DST3  + F4(E);
constexpr size_t O_XR    = O_EM3   + F4(E);
constexpr size_t O_XI    = O_XR    + F4(K2 * HD);
constexpr size_t O_DEG3  = O_XI    + F4(K2 * HD);
constexpr size_t O_DIS3  = O_DEG3  + F4(1024);
constexpr size_t O_SCOEF = O_DIS3  + F4(1024);
constexpr size_t O_XG1   = O_SCOEF + F4(1024);
constexpr size_t O_XG2H  = O_XG1   + F4(K2 * UHD);
constexpr size_t O_XG2   = O_XG2H  + F4(K2 * UHD);
constexpr size_t O_EMB   = O_XG2   + F4(K2 * UHD);
constexpr size_t O_T1    = O_EMB   + F4(64);
constexpr size_t O_T2    = O_T1    + F4(64);
constexpr size_t O_NORM  = O_T2    + F4(64);
constexpr size_t O_PM    = O_NORM  + F4(64);
constexpr size_t O_BM    = O_PM    + F4(PMN);          // float2
constexpr size_t O_P0    = O_BM    + F4(PMN) * 2;      // float2
constexpr size_t O_P1    = O_P0    + F4(PMN) * 2;      // float2
constexpr size_t O_XRT   = O_P1    + F4(PMN) * 2;
constexpr size_t O_XIT   = O_XRT   + F4(K2 * HD);
constexpr size_t O_XC    = O_XIT   + F4(K2 * HD);      // float2
constexpr size_t O_EVO   = O_XC    + F4(K2 * HD) * 2;  // float2
constexpr size_t O_AGG0  = O_EVO   + F4(K2 * HD) * 2;  // float2
constexpr size_t O_WC    = O_AGG0  + F4(K2 * HD) * 2;  // float2 256x256
constexpr size_t O_AGG1  = O_WC    + F4(HD * HD) * 2;  // float2
constexpr size_t O_MAG   = O_AGG1  + F4(K2 * HD) * 2;
constexpr size_t O_PH    = O_MAG   + F4(K2 * HD);
constexpr size_t O_GM    = O_PH    + F4(K2 * HD);
constexpr size_t O_GP    = O_GM    + F4(256);
constexpr size_t O_HM    = O_GP    + F4(256);
constexpr size_t O_HP    = O_HM    + F4(256);
constexpr size_t O_LM    = O_HP    + F4(256);
constexpr size_t O_LP    = O_LM    + F4(64);
constexpr size_t WS_NEED = O_LP    + F4(64);

// Dead-region aliases during expm (everything below O_SRC3 is dead by then):
constexpr size_t O_SA   = 0;
constexpr size_t O_ST   = O_SA + PPS * 2 * 4;
constexpr size_t O_PART = O_ST + PPS * 2 * 4;
constexpr size_t PART_SZ = (size_t)CSPLIT * PMN * 8;
static_assert(O_PART + PART_SZ <= O_SRC3, "SA/ST/PART must fit in dead region");

// B2/B3 fp32 (PS powers) alias XRT..AGG1 (written only post-expm).
constexpr size_t O_B2 = O_XRT;
constexpr size_t O_B3 = O_B2 + F4(PMN) * 2;
static_assert(O_B3 + F4(PMN) * 2 <= O_MAG, "B2/B3 must fit in XRT..AGG1 region");

// CSR slot (R8): one reusable set, rebuilt per graph stage. Lives in the
// MAG/PH region, which is written only by magph AFTER the last CSR use
// (agg_gather). CSR3 survives the expm phase here (SA/ST/PART are below
// O_SRC3, B2/B3 in XRT..AGG1 — no overlap).
constexpr size_t O_CSR_OFF = O_MAG;                 // (N0+1) ints
constexpr size_t O_CSR_CUR = O_CSR_OFF + F4(4104);
constexpr size_t O_CSR_SRC = O_CSR_CUR + F4(4104);  // E ints
constexpr size_t O_CSR_CF  = O_CSR_SRC + F4(E);     // E floats
static_assert(O_CSR_CF + F4(E) <= O_GM, "CSR must fit in MAG/PH region");

// ---------------- bf16 helpers ----------------
typedef __attribute__((ext_vector_type(8))) short s8v;   // 8 bf16 (4 VGPRs)
typedef __attribute__((ext_vector_type(4))) float f4v;   // MFMA acc

__device__ inline unsigned short f2bf(float x) {
  unsigned u = __float_as_uint(x);
  u += 0x7FFFu + ((u >> 16) & 1u);
  return (unsigned short)(u >> 16);
}
__device__ inline float bf2f(unsigned short h) {
  return __uint_as_float(((unsigned)h) << 16);
}

// ---------------- kernels ----------------

// real GEMM fp32 (pool-score path must stay fp32 for exact top-k ordering).
template <int ACT>
__global__ void rmm64(const float* __restrict__ A, const float* __restrict__ B,
                      const float* __restrict__ bias, float* __restrict__ C,
                      int M, int N, int K) {
  __shared__ float As[64][17];
  __shared__ float Bs[16][64];
  int t  = threadIdx.x;
  int tx = t & 15, ty = t >> 4;
  int bm = blockIdx.y * 64, bn = blockIdx.x * 64;
  float acc[4][4] = {};
  for (int kt = 0; kt < K; kt += 16) {
#pragma unroll
    for (int i = 0; i < 4; i++) {
      int l = t + i * 256;
      int kk = l & 15, mm = l >> 4;
      int gr = bm + mm;
      As[mm][kk] = (gr < M) ? A[(size_t)gr * K + kt + kk] : 0.f;
    }
#pragma unroll
    for (int i = 0; i < 4; i++) {
      int l = t + i * 256;
      int cc = l & 63, kk = l >> 6;
      int gc = bn + cc;
      Bs[kk][cc] = (gc < N) ? B[(size_t)(kt + kk) * N + gc] : 0.f;
    }
    __syncthreads();
#pragma unroll
    for (int kk = 0; kk < 16; kk++) {
      float a[4], b[4];
#pragma unroll
      for (int i = 0; i < 4; i++) a[i] = As[ty + 16 * i][kk];
#pragma unroll
      for (int j = 0; j < 4; j++) b[j] = Bs[kk][tx + 16 * j];
#pragma unroll
      for (int i = 0; i < 4; i++)
#pragma unroll
        for (int j = 0; j < 4; j++) acc[i][j] += a[i] * b[j];
    }
    __syncthreads();
  }
#pragma unroll
  for (int i = 0; i < 4; i++) {
    int r = bm + ty + 16 * i;
    if (r >= M) continue;
#pragma unroll
    for (int j = 0; j < 4; j++) {
      int c = bn + tx + 16 * j;
      if (c >= N) continue;
      float v = acc[i][j] + (bias ? bias[c] : 0.f);
      if (ACT == 1) v = fmaxf(v, 0.f);
      C[(size_t)r * N + c] = v;
    }
  }
}

// Split complex fp32 -> 4 bf16 planes [row][col] (rh, rl, ih, il), zero-pad.
__global__ void split_planes(const float2* __restrict__ in, int inM, int inN,
                             unsigned short* __restrict__ out, int padR, int ld,
                             size_t ps) {
  int idx = blockIdx.x * 256 + threadIdx.x;
  if (idx >= padR * ld) return;
  int r = idx / ld, c = idx - r * ld;
  float re = 0.f, im = 0.f;
  if (r < inM && c < inN) { float2 v = in[(size_t)r * inN + c]; re = v.x; im = v.y; }
  unsigned short rh = f2bf(re);
  unsigned short rl = f2bf(re - bf2f(rh));
  unsigned short ih = f2bf(im);
  unsigned short il = f2bf(im - bf2f(ih));
  out[idx] = rh; out[ps + idx] = rl; out[2 * ps + idx] = ih; out[3 * ps + idx] = il;
}

// Transposed split: out[n*ld + k] = split(in[k][n]); tiled via LDS.
__global__ void split_planesT(const float2* __restrict__ in, int inM, int inN,
                              unsigned short* __restrict__ out, int padR, int ld,
                              size_t ps) {
  __shared__ float2 tile[32][33];
  int tx = threadIdx.x & 31, ty = threadIdx.x >> 5;   // 32 x 8
  int k0 = blockIdx.x * 32, n0 = blockIdx.y * 32;
  for (int i = ty; i < 32; i += 8) {
    int k = k0 + i, n = n0 + tx;
    tile[i][tx] = (k < inM && n < inN) ? in[(size_t)k * inN + n]
                                       : make_float2(0.f, 0.f);
  }
  __syncthreads();
  for (int i = ty; i < 32; i += 8) {
    int n = n0 + i, k = k0 + tx;
    if (n < padR && k < ld) {
      float2 v = tile[tx][i];
      size_t o = (size_t)n * ld + k;
      unsigned short rh = f2bf(v.x);
      unsigned short rl = f2bf(v.x - bf2f(rh));
      unsigned short ih = f2bf(v.y);
      unsigned short il = f2bf(v.y - bf2f(ih));
      out[o] = rh; out[ps + o] = rl; out[2 * ps + o] = ih; out[3 * ps + o] = il;
    }
  }
}

// Split-K complex MFMA GEMM with register double-buffer prefetch (R7).
__global__ __launch_bounds__(256, 2) void cmm_bf16_sk(
    const unsigned short* __restrict__ SA, size_t psA, int ldA,
    const unsigned short* __restrict__ ST, size_t psT, int ldT,
    float2* __restrict__ Part, int M, int N, int Kp, int chunk) {
  int k0 = blockIdx.z * chunk;
  int kend = min(Kp, k0 + chunk);
  int t = threadIdx.x;
  int wave = t >> 6, lane = t & 63;
  int quad = lane >> 4, mn = lane & 15;
  int rowA = blockIdx.y * 64 + wave * 16 + mn;
  int bn = blockIdx.x * 64;
  const unsigned short* a0 = SA + (size_t)rowA * ldA;
  f4v accR[4], accI[4];
#pragma unroll
  for (int i = 0; i < 4; i++) {
    accR[i] = (f4v){0.f, 0.f, 0.f, 0.f};
    accI[i] = (f4v){0.f, 0.f, 0.f, 0.f};
  }
  s8v cA[4], cB[4][4], nA[4], nB[4][4];
  {
    int ka = k0 + quad * 8;
#pragma unroll
    for (int p = 0; p < 4; p++) cA[p] = *(const s8v*)(a0 + p * psA + ka);
#pragma unroll
    for (int tl = 0; tl < 4; tl++) {
      const unsigned short* b0 = ST + (size_t)(bn + tl * 16 + mn) * ldT + ka;
#pragma unroll
      for (int p = 0; p < 4; p++) cB[tl][p] = *(const s8v*)(b0 + p * psT);
    }
  }
  for (int kt = k0; kt < kend; kt += 32) {
    int kn = kt + 32;
    if (kn < kend) {
      int ka = kn + quad * 8;
#pragma unroll
      for (int p = 0; p < 4; p++) nA[p] = *(const s8v*)(a0 + p * psA + ka);
#pragma unroll
      for (int tl = 0; tl < 4; tl++) {
        const unsigned short* b0 = ST + (size_t)(bn + tl * 16 + mn) * ldT + ka;
#pragma unroll
        for (int p = 0; p < 4; p++) nB[tl][p] = *(const s8v*)(b0 + p * psT);
      }
    }
    s8v nih, nil_;
#pragma unroll
    for (int q = 0; q < 8; q++) {
      nih[q]  = (short)(cA[2][q] ^ (short)0x8000);   // -ai
      nil_[q] = (short)(cA[3][q] ^ (short)0x8000);
    }
#pragma unroll
    for (int tl = 0; tl < 4; tl++) {
      f4v r = accR[tl];
      r = __builtin_amdgcn_mfma_f32_16x16x32_bf16(cA[0], cB[tl][0], r, 0, 0, 0);
      r = __builtin_amdgcn_mfma_f32_16x16x32_bf16(cA[1], cB[tl][0], r, 0, 0, 0);
      r = __builtin_amdgcn_mfma_f32_16x16x32_bf16(cA[0], cB[tl][1], r, 0, 0, 0);
      r = __builtin_amdgcn_mfma_f32_16x16x32_bf16(nih, cB[tl][2], r, 0, 0, 0);
      r = __builtin_amdgcn_mfma_f32_16x16x32_bf16(nil_, cB[tl][2], r, 0, 0, 0);
      r = __builtin_amdgcn_mfma_f32_16x16x32_bf16(nih, cB[tl][3], r, 0, 0, 0);
      accR[tl] = r;
      f4v im = accI[tl];
      im = __builtin_amdgcn_mfma_f32_16x16x32_bf16(cA[0], cB[tl][2], im, 0, 0, 0);
      im = __builtin_amdgcn_mfma_f32_16x16x32_bf16(cA[1], cB[tl][2], im, 0, 0, 0);
      im = __builtin_amdgcn_mfma_f32_16x16x32_bf16(cA[0], cB[tl][3], im, 0, 0, 0);
      im = __builtin_amdgcn_mfma_f32_16x16x32_bf16(cA[2], cB[tl][0], im, 0, 0, 0);
      im = __builtin_amdgcn_mfma_f32_16x16x32_bf16(cA[3], cB[tl][0], im, 0, 0, 0);
      im = __builtin_amdgcn_mfma_f32_16x16x32_bf16(cA[2], cB[tl][1], im, 0, 0, 0);
      accI[tl] = im;
    }
    if (kn < kend) {
#pragma unroll
      for (int p = 0; p < 4; p++) cA[p] = nA[p];
#pragma unroll
      for (int tl = 0; tl < 4; tl++)
#pragma unroll
        for (int p = 0; p < 4; p++) cB[tl][p] = nB[tl][p];
    }
  }
  float2* P = Part + (size_t)blockIdx.z * M * N;
#pragma unroll
  for (int tl = 0; tl < 4; tl++) {
    int col = bn + tl * 16 + mn;
    if (col >= N) continue;
#pragma unroll
    for (int r = 0; r < 4; r++) {
      int row = blockIdx.y * 64 + wave * 16 + quad * 4 + r;
      if (row >= M) continue;
      P[(size_t)row * N + col] = make_float2(accR[tl][r], accI[tl][r]);
    }
  }
}

// C = sum_z Part[z] + e0*I + e1*E1 + e2*E2 (PS Horner epilogue folded in).
__global__ void creduce(const float2* __restrict__ Part, float2* __restrict__ C,
                        int MN, int N, int S, float e0,
                        const float2* __restrict__ E1, float e1,
                        const float2* __restrict__ E2, float e2) {
  int idx = blockIdx.x * 256 + threadIdx.x;
  if (idx >= MN) return;
  float sr = 0.f, si = 0.f;
  for (int z = 0; z < S; z++) {
    float2 p = Part[(size_t)z * MN + idx];
    sr += p.x;
    si += p.y;
  }
  if (e0 != 0.f) {
    int r = idx / N;
    if (idx - r * N == r) sr += e0;
  }
  if (E1) { float2 b = E1[idx]; sr += e1 * b.x; si += e1 * b.y; }
  if (E2) { float2 b = E2[idx]; sr += e2 * b.x; si += e2 * b.y; }
  C[idx] = make_float2(sr, si);
}

// ---- CSR build (R8: replaces all edge-scatter atomics) ----

// cnt[dst[e]]++ for live edges (em==nullptr -> all live; em in {0,1}).
// Doubles as the degree computation (deg == live-edge count).
__global__ void hist_edges(const int* __restrict__ dst, const float* __restrict__ em,
                           int* __restrict__ cnt) {
  int e = blockIdx.x * 256 + threadIdx.x;
  if (e >= E) return;
  float m = em ? em[e] : 1.0f;
  if (m != 0.f) atomicAdd(&cnt[dst[e]], 1);
}

__global__ void deg_to_dis_i(const int* __restrict__ cnt, float* __restrict__ dis, int n) {
  int i = blockIdx.x * 256 + threadIdx.x;
  if (i >= n) return;
  dis[i] = 1.0f / sqrtf((float)cnt[i] + 1.0f);
}

// Exclusive scan of cnt[0..n) -> off[0..n], copy to cur. n <= 4096, 1 block.
__global__ __launch_bounds__(1024) void scan_offsets(const int* __restrict__ cnt, int n,
                                                     int* __restrict__ off,
                                                     int* __restrict__ cur) {
  __shared__ int sums[1024];
  int t = threadIdx.x;
  int base = t * 4;
  int v[4];
  int s = 0;
#pragma unroll
  for (int j = 0; j < 4; j++) {
    int i = base + j;
    v[j] = s;
    s += (i < n) ? cnt[i] : 0;
  }
  sums[t] = s;
  __syncthreads();
  for (int d = 1; d < 1024; d <<= 1) {
    int x = (t >= d) ? sums[t - d] : 0;
    __syncthreads();
    sums[t] += x;
    __syncthreads();
  }
  int pre = (t > 0) ? sums[t - 1] : 0;
#pragma unroll
  for (int j = 0; j < 4; j++) {
    int i = base + j;
    if (i < n) { int o = pre + v[j]; off[i] = o; cur[i] = o; }
  }
  if (t == 1023) off[n] = sums[1023];
}

// Bucket-fill: esrc/ecoef per live edge; ecoef = dis[s]*dis[d].
__global__ void fill_edges(const int* __restrict__ src, const int* __restrict__ dst,
                           const float* __restrict__ em, const float* __restrict__ dis,
                           int* __restrict__ cur, int* __restrict__ esrc,
                           float* __restrict__ ecoef) {
  int e = blockIdx.x * 256 + threadIdx.x;
  if (e >= E) return;
  float m = em ? em[e] : 1.0f;
  if (m == 0.f) return;
  int s = src[e], d = dst[e];
  int pos = atomicAdd(&cur[d], 1);
  esrc[pos] = s;
  ecoef[pos] = dis[s] * dis[d];
}

// Fused GCN aggregate + self-loop + bias (+relu): gather form, plain stores.
// out[i,f] = act( sum_bucket ecoef*Hm[src,f] + dis[i]^2*Hm[i,f] + bias[f] )
template <int ACT>
__global__ void gcn_gather(const int* __restrict__ off, const int* __restrict__ esrc,
                           const float* __restrict__ ecoef, const float* __restrict__ Hm,
                           const float* __restrict__ dis, const float* __restrict__ bias,
                           float* __restrict__ out, int F) {
  int i = blockIdx.x;
  int e0 = off[i], e1 = off[i + 1];
  float d2 = dis[i] * dis[i];
  for (int f = threadIdx.x; f < F; f += blockDim.x) {
    float acc = d2 * Hm[(size_t)i * F + f] + bias[f];
    for (int e = e0; e < e1; e++)
      acc += ecoef[e] * Hm[(size_t)esrc[e] * F + f];
    if (ACT == 1) acc = fmaxf(acc, 0.f);
    out[(size_t)i * F + f] = acc;
  }
}

// scoef[i] = sum of ecoef over bucket(i) (== enc_scoef result).
__global__ void scoef_gather(const int* __restrict__ off, const float* __restrict__ ecoef,
                             float* __restrict__ scoef, int n) {
  int i = blockIdx.x * 256 + threadIdx.x;
  if (i >= n) return;
  float s = 0.f;
  for (int e = off[i]; e < off[i + 1]; e++) s += ecoef[e];
  scoef[i] = s;
}

// agg[i,f] = sum_bucket evo[src,f] (complex, coef==1); covers all i (no memset).
__global__ void agg_gather(const int* __restrict__ off, const int* __restrict__ esrc,
                           const float2* __restrict__ evo, float2* __restrict__ agg,
                           int F) {
  int i = blockIdx.x;
  int e0 = off[i], e1 = off[i + 1];
  for (int f = threadIdx.x; f < F; f += blockDim.x) {
    float sr = 0.f, si = 0.f;
    for (int e = e0; e < e1; e++) {
      float2 v = evo[(size_t)esrc[e] * F + f];
      sr += v.x;
      si += v.y;
    }
    agg[(size_t)i * F + f] = make_float2(sr, si);
  }
}

__global__ void wnorm(const float* __restrict__ w, int n, float* __restrict__ out) {
  __shared__ float red[256];
  float s = 0.f;
  for (int k = threadIdx.x; k < n; k += 256) s += w[k] * w[k];
  red[threadIdx.x] = s;
  __syncthreads();
  for (int off = 128; off > 0; off >>= 1) {
    if (threadIdx.x < off) red[threadIdx.x] += red[threadIdx.x + off];
    __syncthreads();
  }
  if (threadIdx.x == 0) out[0] = sqrtf(red[0]);
}

__global__ void rowdot(const float* __restrict__ X, const float* __restrict__ w,
                       float* __restrict__ out, int F) {
  int i = blockIdx.x;
  __shared__ float red[256];
  float s = 0.f;
  for (int f = threadIdx.x; f < F; f += 256) s += X[(size_t)i * F + f] * w[f];
  red[threadIdx.x] = s;
  __syncthreads();
  for (int off = 128; off > 0; off >>= 1) {
    if (threadIdx.x < off) red[threadIdx.x] += red[threadIdx.x + off];
    __syncthreads();
  }
  if (threadIdx.x == 0) out[i] = red[0];
}

// exact-total-order descending bitonic sort; key = (sortable_score<<32) | ~idx.
__global__ __launch_bounds__(1024) void bitonic_topk(const float* __restrict__ score,
                                                     int n, int* __restrict__ perm, int k) {
  __shared__ unsigned long long keys[4096];
  int t = threadIdx.x;
  for (int i = t; i < 4096; i += 1024) {
    unsigned long long kk = 0ull;
    if (i < n) {
      float f = score[i];
      unsigned u = __float_as_uint(f);
      u = (f >= 0.0f) ? (u | 0x80000000u) : ~u;
      kk = ((unsigned long long)u << 32) | (unsigned)(~(unsigned)i);
    }
    keys[i] = kk;
  }
  __syncthreads();
  for (int size = 2; size <= 4096; size <<= 1) {
    for (int stride = size >> 1; stride > 0; stride >>= 1) {
      for (int i = t; i < 2048; i += 1024) {
        int pos = ((i & ~(stride - 1)) << 1) | (i & (stride - 1));
        int partner = pos + stride;
        bool desc = (pos & size) == 0;
        unsigned long long a = keys[pos], b = keys[partner];
        if ((a < b) == desc) { keys[pos] = b; keys[partner] = a; }
      }
      __syncthreads();
    }
  }
  for (int i = t; i < k; i += 1024)
    perm[i] = (int)(~(unsigned)(keys[i] & 0xFFFFFFFFull));
}

__global__ void set_map(const int* __restrict__ perm, int* __restrict__ map, int k) {
  int i = blockIdx.x * 256 + threadIdx.x;
  if (i < k) map[perm[i]] = i;
}

__global__ void pool_gather(const float* __restrict__ X, const int* __restrict__ perm,
                            const float* __restrict__ dot, const float* __restrict__ normbuf,
                            float* __restrict__ Xn, int F) {
  int i = blockIdx.x;
  int p = perm[i];
  float sc = tanhf(dot[p] / normbuf[0]);
  for (int f = threadIdx.x; f < F; f += blockDim.x)
    Xn[(size_t)i * F + f] = X[(size_t)p * F + f] * sc;
}

__global__ void remap_edges(const int* __restrict__ srcIn, const int* __restrict__ dstIn,
                            const float* __restrict__ emIn, const int* __restrict__ map,
                            int* __restrict__ srcOut, int* __restrict__ dstOut,
                            float* __restrict__ emOut) {
  int e = blockIdx.x * 256 + threadIdx.x;
  if (e >= E) return;
  int ns = map[srcIn[e]], nd = map[dstIn[e]];
  float m = emIn ? emIn[e] : 1.0f;
  if (ns < 0 || nd < 0) m = 0.f;
  srcOut[e] = ns < 0 ? 0 : ns;
  dstOut[e] = nd < 0 ? 0 : nd;
  emOut[e] = m;
}

__global__ void enc1_out(const float* __restrict__ scoef, const float* __restrict__ dis,
                         const float* __restrict__ w, const float* __restrict__ b,
                         float* __restrict__ xg1) {
  int i = blockIdx.x;
  int f = threadIdx.x;
  float s = scoef[i] + dis[i] * dis[i];
  xg1[(size_t)i * UHD + f] = fmaxf(s * w[f] + b[f], 0.f);
}

__global__ void col_mean(const float* __restrict__ X, float* __restrict__ out,
                         int rows, int cols) {
  int c = blockIdx.x;
  __shared__ float red[256];
  float s = 0.f;
  for (int r = threadIdx.x; r < rows; r += 256) s += X[(size_t)r * cols + c];
  red[threadIdx.x] = s;
  __syncthreads();
  for (int off = 128; off > 0; off >>= 1) {
    if (threadIdx.x < off) red[threadIdx.x] += red[threadIdx.x + off];
    __syncthreads();
  }
  if (threadIdx.x == 0) out[c] = red[0] / (float)rows;
}

template <int ACT>
__global__ void vecmat(const float* __restrict__ v, const float* __restrict__ W,
                       const float* __restrict__ b, float* __restrict__ out,
                       int Kdim, int Ndim) {
  __shared__ float vs[256];
  for (int k = threadIdx.x; k < Kdim; k += blockDim.x) vs[k] = v[k];
  __syncthreads();
  for (int j = threadIdx.x; j < Ndim; j += blockDim.x) {
    float acc = b ? b[j] : 0.f;
    for (int k = 0; k < Kdim; k++) acc += vs[k] * W[(size_t)k * Ndim + j];
    out[j] = (ACT == 1) ? fmaxf(acc, 0.f) : acc;
  }
}

__global__ void vecmat_tanh_wide(const float* __restrict__ v, const float* __restrict__ W,
                                 const float* __restrict__ b, float* __restrict__ out,
                                 int Kdim, int Ndim) {
  __shared__ float vs[64];
  if (threadIdx.x < Kdim) vs[threadIdx.x] = v[threadIdx.x];
  __syncthreads();
  int j = blockIdx.x * 256 + threadIdx.x;
  if (j >= Ndim) return;
  float acc = b[j];
  for (int k = 0; k < Kdim; k++) acc += vs[k] * W[(size_t)k * Ndim + j];
  out[j] = tanhf(acc);
}

__global__ void build_B(const float* __restrict__ pm, float2* __restrict__ Bm,
                        int n, float scale) {
  int idx = blockIdx.x * 256 + threadIdx.x;
  if (idx >= n * n) return;
  int r = idx / n, c = idx - r * n;
  float pij = pm[(size_t)r * n + c];
  float pji = pm[(size_t)c * n + r];
  Bm[idx] = make_float2(scale * (pij - pji), scale * (pij + pji));
}

// Out = e0*I + e1*B + e2*B2 (top PS block D3)
__global__ void combo3(const float2* __restrict__ Bp, const float2* __restrict__ B2p,
                       float2* __restrict__ Out, int MN, int N,
                       float e0, float e1, float e2) {
  int idx = blockIdx.x * 256 + threadIdx.x;
  if (idx >= MN) return;
  float2 b = Bp[idx], b2 = B2p[idx];
  float sr = e1 * b.x + e2 * b2.x;
  float si = e1 * b.y + e2 * b2.y;
  int r = idx / N;
  if (idx - r * N == r) sr += e0;
  Out[idx] = make_float2(sr, si);
}

__global__ void pack2(const float* __restrict__ a, const float* __restrict__ b,
                      float2* __restrict__ out, int n) {
  int i = blockIdx.x * 256 + threadIdx.x;
  if (i < n) out[i] = make_float2(a[i], b[i]);
}

__global__ void magph(const float2* __restrict__ agg, const float* __restrict__ xr,
                      const float* __restrict__ xi, float* __restrict__ mag,
                      float* __restrict__ ph, int n) {
  int idx = blockIdx.x * 256 + threadIdx.x;
  if (idx >= n) return;
  float2 a = agg[idx];
  float r = a.x + xr[idx];
  float im = a.y + xi[idx];
  mag[idx] = sqrtf(r * r + im * im);
  ph[idx] = atan2f(im, r);
}

__global__ void add_out(const float* __restrict__ lm, const float* __restrict__ lp,
                        float* __restrict__ out, int n) {
  int i = threadIdx.x;
  if (i < n) out[i] = lm[i] + lp[i];
}

// ---------------- host helpers ----------------
static inline int sk_chunk32(int K, int S) { return (((K + S - 1) / S) + 31) & ~31; }

// ---------------- host ----------------
extern "C" void kernel_launch(void* const* d_in, const int* in_sizes, int n_in,
                              void* d_out, int out_size, void* d_ws, size_t ws_size,
                              hipStream_t stream) {
  if (ws_size < WS_NEED) return;

  const float* x       = (const float*)d_in[0];
  const int*   ei      = (const int*)d_in[1];
  const float* gcn1_w  = (const float*)d_in[2];
  const float* gcn1_b  = (const float*)d_in[3];
  const float* pool1_w = (const float*)d_in[4];
  const float* gcn2_w  = (const float*)d_in[5];
  const float* gcn2_b  = (const float*)d_in[6];
  const float* pool2_w = (const float*)d_in[7];
  const float* inr_w   = (const float*)d_in[8];
  const float* inr_b   = (const float*)d_in[9];
  const float* ini_w   = (const float*)d_in[10];
  const float* ini_b   = (const float*)d_in[11];
  const float* enc1_w  = (const float*)d_in[12];
  const float* enc1_b  = (const float*)d_in[13];
  const float* enc2_w  = (const float*)d_in[14];
  const float* enc2_b  = (const float*)d_in[15];
  const float* p1_w    = (const float*)d_in[16];
  const float* p1_b    = (const float*)d_in[17];
  const float* p2_w    = (const float*)d_in[18];
  const float* p2_b    = (const float*)d_in[19];
  const float* p3_w    = (const float*)d_in[20];
  const float* p3_b    = (const float*)d_in[21];
  const float* rt_w    = (const float*)d_in[22];
  const float* rt_b    = (const float*)d_in[23];
  const float* it_w    = (const float*)d_in[24];
  const float* it_b    = (const float*)d_in[25];
  const float* msg_wr  = (const float*)d_in[26];
  const float* msg_wi  = (const float*)d_in[27];
  const float* mc1_w   = (const float*)d_in[28];
  const float* mc1_b   = (const float*)d_in[29];
  const float* mc2_w   = (const float*)d_in[30];
  const float* mc2_b   = (const float*)d_in[31];
  const float* pc1_w   = (const float*)d_in[32];
  const float* pc1_b   = (const float*)d_in[33];
  const float* pc2_w   = (const float*)d_in[34];
  const float* pc2_b   = (const float*)d_in[35];

  char* ws = (char*)d_ws;
  float*  H1    = (float*)(ws + O_H1);
  float*  OUT1  = (float*)(ws + O_OUT1);
  int*    CNT1  = (int*)(ws + O_DEG1);
  float*  DIS1  = (float*)(ws + O_DIS1);
  float*  SC1   = (float*)(ws + O_SC1);
  int*    PERM1 = (int*)(ws + O_PERM1);
  int*    MAP1  = (int*)(ws + O_MAP1);
  float*  H1P   = (float*)(ws + O_H1P);
  int*    SRC2  = (int*)(ws + O_SRC2);
  int*    DST2  = (int*)(ws + O_DST2);
  float*  EM2   = (float*)(ws + O_EM2);
  float*  H2    = (float*)(ws + O_H2);
  float*  OUT2  = (float*)(ws + O_OUT2);
  int*    CNT2  = (int*)(ws + O_DEG2);
  float*  DIS2  = (float*)(ws + O_DIS2);
  float*  SC2   = (float*)(ws + O_SC2);
  int*    PERM2 = (int*)(ws + O_PERM2);
  int*    MAP2  = (int*)(ws + O_MAP2);
  float*  H2P   = (float*)(ws + O_H2P);
  int*    SRC3  = (int*)(ws + O_SRC3);
  int*    DST3  = (int*)(ws + O_DST3);
  float*  EM3   = (float*)(ws + O_EM3);
  float*  XRb   = (float*)(ws + O_XR);
  float*  XIb   = (float*)(ws + O_XI);
  int*    CNT3  = (int*)(ws + O_DEG3);
  float*  DIS3  = (float*)(ws + O_DIS3);
  float*  SCOEF = (float*)(ws + O_SCOEF);
  float*  XG1   = (float*)(ws + O_XG1);
  float*  XG2H  = (float*)(ws + O_XG2H);
  float*  XG2   = (float*)(ws + O_XG2);
  float*  EMB   = (float*)(ws + O_EMB);
  float*  T1    = (float*)(ws + O_T1);
  float*  T2    = (float*)(ws + O_T2);
  float*  NORM  = (float*)(ws + O_NORM);
  float*  PMV   = (float*)(ws + O_PM);
  float2* BM    = (float2*)(ws + O_BM);
  float2* P0v   = (float2*)(ws + O_P0);
  float2* P1v   = (float2*)(ws + O_P1);
  float*  XRT   = (float*)(ws + O_XRT);
  float*  XIT   = (float*)(ws + O_XIT);
  float2* XC    = (float2*)(ws + O_XC);
  float2* EVO   = (float2*)(ws + O_EVO);
  float2* AGG0  = (float2*)(ws + O_AGG0);
  float2* WC    = (float2*)(ws + O_WC);
  float2* AGG1  = (float2*)(ws + O_AGG1);
  float*  MAGB  = (float*)(ws + O_MAG);
  float*  PHB   = (float*)(ws + O_PH);
  float*  GM    = (float*)(ws + O_GM);
  float*  GP    = (float*)(ws + O_GP);
  float*  HM    = (float*)(ws + O_HM);
  float*  HP    = (float*)(ws + O_HP);
  float*  LM    = (float*)(ws + O_LM);
  float*  LP    = (float*)(ws + O_LP);
  unsigned short* SA = (unsigned short*)(ws + O_SA);
  unsigned short* ST = (unsigned short*)(ws + O_ST);
  float2* PART  = (float2*)(ws + O_PART);
  float2* B2v   = (float2*)(ws + O_B2);
  float2* B3v   = (float2*)(ws + O_B3);
  int*    COFF  = (int*)(ws + O_CSR_OFF);
  int*    CCUR  = (int*)(ws + O_CSR_CUR);
  int*    CSRC  = (int*)(ws + O_CSR_SRC);
  float*  CCOEF = (float*)(ws + O_CSR_CF);

  const int* SRC1 = ei;
  const int* DST1 = ei + E;
  const int eg = E / 256;

  // ---------- Stage A: gcn1 (CSR gather, fused self+bias+relu) ----------
  rmm64<0><<<dim3(HD / 64, N0 / 64), 256, 0, stream>>>(x, gcn1_w, nullptr, H1, N0, HD, DIN);
  hipMemsetAsync(CNT1, 0, F4(N0), stream);
  hist_edges<<<eg, 256, 0, stream>>>(DST1, nullptr, CNT1);
  deg_to_dis_i<<<N0 / 256, 256, 0, stream>>>(CNT1, DIS1, N0);
  scan_offsets<<<1, 1024, 0, stream>>>(CNT1, N0, COFF, CCUR);
  fill_edges<<<eg, 256, 0, stream>>>(SRC1, DST1, nullptr, DIS1, CCUR, CSRC, CCOEF);
  gcn_gather<1><<<N0, 256, 0, stream>>>(COFF, CSRC, CCOEF, H1, DIS1, gcn1_b, OUT1, HD);

  // ---------- pool1 ----------
  wnorm<<<1, 256, 0, stream>>>(pool1_w, HD, NORM);
  rowdot<<<N0, 256, 0, stream>>>(OUT1, pool1_w, SC1, HD);
  bitonic_topk<<<1, 1024, 0, stream>>>(SC1, N0, PERM1, K1);
  hipMemsetAsync(MAP1, 0xFF, F4(N0), stream);
  set_map<<<(K1 + 255) / 256, 256, 0, stream>>>(PERM1, MAP1, K1);
  pool_gather<<<K1, 256, 0, stream>>>(OUT1, PERM1, SC1, NORM, H1P, HD);
  remap_edges<<<eg, 256, 0, stream>>>(SRC1, DST1, nullptr, MAP1, SRC2, DST2, EM2);

  // ---------- Stage C: gcn2 (CSR gather) ----------
  rmm64<0><<<dim3(HD / 64, (K1 + 63) / 64), 256, 0, stream>>>(H1P, gcn2_w, nullptr, H2, K1, HD, HD);
  hipMemsetAsync(CNT2, 0, F4(K1), stream);
  hist_edges<<<eg, 256, 0, stream>>>(DST2, EM2, CNT2);
  deg_to_dis_i<<<(K1 + 255) / 256, 256, 0, stream>>>(CNT2, DIS2, K1);
  scan_offsets<<<1, 1024, 0, stream>>>(CNT2, K1, COFF, CCUR);
  fill_edges<<<eg, 256, 0, stream>>>(SRC2, DST2, EM2, DIS2, CCUR, CSRC, CCOEF);
  gcn_gather<1><<<K1, 256, 0, stream>>>(COFF, CSRC, CCOEF, H2, DIS2, gcn2_b, OUT2, HD);

  // ---------- pool2 ----------
  wnorm<<<1, 256, 0, stream>>>(pool2_w, HD, NORM + 1);
  rowdot<<<K1, 256, 0, stream>>>(OUT2, pool2_w, SC2, HD);
  bitonic_topk<<<1, 1024, 0, stream>>>(SC2, K1, PERM2, K2);
  hipMemsetAsync(MAP2, 0xFF, F4(N0), stream);
  set_map<<<(K2 + 255) / 256, 256, 0, stream>>>(PERM2, MAP2, K2);
  pool_gather<<<K2, 256, 0, stream>>>(OUT2, PERM2, SC2, NORM + 1, H2P, HD);
  remap_edges<<<eg, 256, 0, stream>>>(SRC2, DST2, EM2, MAP2, SRC3, DST3, EM3);

  // ---------- xr / xi ----------
  rmm64<0><<<dim3(HD / 64, (K2 + 63) / 64), 256, 0, stream>>>(H2P, inr_w, inr_b, XRb, K2, HD, HD);
  rmm64<0><<<dim3(HD / 64, (K2 + 63) / 64), 256, 0, stream>>>(H2P, ini_w, ini_b, XIb, K2, HD, HD);

  // ---------- CSR3 (persists through expm; lives in MAG/PH region) ----------
  hipMemsetAsync(CNT3, 0, F4(K2), stream);
  hist_edges<<<eg, 256, 0, stream>>>(DST3, EM3, CNT3);
  deg_to_dis_i<<<(K2 + 255) / 256, 256, 0, stream>>>(CNT3, DIS3, K2);
  scan_offsets<<<1, 1024, 0, stream>>>(CNT3, K2, COFF, CCUR);
  fill_edges<<<eg, 256, 0, stream>>>(SRC3, DST3, EM3, DIS3, CCUR, CSRC, CCOEF);

  // ---------- encoder GCNs on pooled graph ----------
  scoef_gather<<<(K2 + 255) / 256, 256, 0, stream>>>(COFF, CCOEF, SCOEF, K2);
  enc1_out<<<K2, UHD, 0, stream>>>(SCOEF, DIS3, enc1_w, enc1_b, XG1);
  rmm64<0><<<dim3(UHD / 64, (K2 + 63) / 64), 256, 0, stream>>>(XG1, enc2_w, nullptr, XG2H, K2, UHD, UHD);
  gcn_gather<0><<<K2, 64, 0, stream>>>(COFF, CSRC, CCOEF, XG2H, DIS3, enc2_b, XG2, UHD);
  col_mean<<<UHD, 256, 0, stream>>>(XG2, EMB, K2, UHD);

  // ---------- parameter MLP -> pm -> B ----------
  vecmat<1><<<1, 256, 0, stream>>>(EMB, p1_w, p1_b, T1, UHD, UHD);
  vecmat<1><<<1, 256, 0, stream>>>(T1, p2_w, p2_b, T2, UHD, UHD / 2);
  vecmat_tanh_wide<<<(PMN + 255) / 256, 256, 0, stream>>>(T2, p3_w, p3_b, PMV, UHD / 2, PMN);
  {
    const float scale = 0.05f * 0.5f / (float)(1 << EXPM_S);
    build_B<<<(PMN + 255) / 256, 256, 0, stream>>>(PMV, BM, K2, scale);
  }

  // ---------- expm via PS deg-11 + 5 squarings, split-K MFMA bf16 ----------
  const int rgrid = (PMN + 255) / 256;
  const int sgrid = (PLD * PLD + 255) / 256;
  const dim3 tgridF((PLD + 31) / 32, (PLD + 31) / 32);
  const int chF = sk_chunk32(PLD, CSPLIT);   // 256
  const dim3 ggK2(11, 11, CSPLIT);
  const float c3 = 1.f / 6.f, c4 = 1.f / 24.f, c5 = 1.f / 120.f;
  const float c6 = 1.f / 720.f, c7 = 1.f / 5040.f, c8 = 1.f / 40320.f;
  const float c9 = 1.f / 362880.f, c10 = 1.f / 3628800.f, c11 = 1.f / 39916800.f;

  split_planes <<<sgrid, 256, 0, stream>>>(BM, K2, K2, SA, PLD, PLD, PPS);
  split_planesT<<<tgridF, 256, 0, stream>>>(BM, K2, K2, ST, PLD, PLD, PPS);
  cmm_bf16_sk<<<ggK2, 256, 0, stream>>>(SA, PPS, PLD, ST, PPS, PLD, PART, K2, K2, PLD, chF);
  creduce<<<rgrid, 256, 0, stream>>>(PART, B2v, PMN, K2, CSPLIT, 0.f, nullptr, 0.f, nullptr, 0.f);
  split_planes<<<sgrid, 256, 0, stream>>>(B2v, K2, K2, SA, PLD, PLD, PPS);
  cmm_bf16_sk<<<ggK2, 256, 0, stream>>>(SA, PPS, PLD, ST, PPS, PLD, PART, K2, K2, PLD, chF);
  creduce<<<rgrid, 256, 0, stream>>>(PART, B3v, PMN, K2, CSPLIT, 0.f, nullptr, 0.f, nullptr, 0.f);
  split_planesT<<<tgridF, 256, 0, stream>>>(B3v, K2, K2, ST, PLD, PLD, PPS);
  combo3<<<rgrid, 256, 0, stream>>>(BM, B2v, P0v, PMN, K2, c9, c10, c11);
  split_planes<<<sgrid, 256, 0, stream>>>(P0v, K2, K2, SA, PLD, PLD, PPS);
  cmm_bf16_sk<<<ggK2, 256, 0, stream>>>(SA, PPS, PLD, ST, PPS, PLD, PART, K2, K2, PLD, chF);
  creduce<<<rgrid, 256, 0, stream>>>(PART, P1v, PMN, K2, CSPLIT, c6, BM, c7, B2v, c8);
  split_planes<<<sgrid, 256, 0, stream>>>(P1v, K2, K2, SA, PLD, PLD, PPS);
  cmm_bf16_sk<<<ggK2, 256, 0, stream>>>(SA, PPS, PLD, ST, PPS, PLD, PART, K2, K2, PLD, chF);
  creduce<<<rgrid, 256, 0, stream>>>(PART, P0v, PMN, K2, CSPLIT, c3, BM, c4, B2v, c5);
  split_planes<<<sgrid, 256, 0, stream>>>(P0v, K2, K2, SA, PLD, PLD, PPS);
  cmm_bf16_sk<<<ggK2, 256, 0, stream>>>(SA, PPS, PLD, ST, PPS, PLD, PART, K2, K2, PLD, chF);
  creduce<<<rgrid, 256, 0, stream>>>(PART, P1v, PMN, K2, CSPLIT, 1.f, BM, 1.f, B2v, 0.5f);
  float2* cur = P1v;
  float2* nxt = P0v;
  for (int t = 0; t < EXPM_S; ++t) {
    split_planes <<<sgrid, 256, 0, stream>>>(cur, K2, K2, SA, PLD, PLD, PPS);
    split_planesT<<<tgridF, 256, 0, stream>>>(cur, K2, K2, ST, PLD, PLD, PPS);
    cmm_bf16_sk<<<ggK2, 256, 0, stream>>>(SA, PPS, PLD, ST, PPS, PLD, PART, K2, K2, PLD, chF);
    creduce<<<rgrid, 256, 0, stream>>>(PART, nxt, PMN, K2, CSPLIT, 0.f, nullptr, 0.f, nullptr, 0.f);
    std::swap(cur, nxt);
  }
  float2* U = cur;

  // ---------- quantum message passing ----------
  rmm64<1><<<dim3(HD / 64, (K2 + 63) / 64), 256, 0, stream>>>(XRb, rt_w, rt_b, XRT, K2, HD, HD);
  rmm64<1><<<dim3(HD / 64, (K2 + 63) / 64), 256, 0, stream>>>(XIb, it_w, it_b, XIT, K2, HD, HD);
  pack2<<<(K2 * HD + 255) / 256, 256, 0, stream>>>(XRT, XIT, XC, K2 * HD);
  {
    const int mn = K2 * HD;
    const int rg = (mn + 255) / 256;
    // EVO = U @ XC  (M=656, N=256, Kp=704)
    split_planes <<<sgrid, 256, 0, stream>>>(U, K2, K2, SA, PLD, PLD, PPS);
    split_planesT<<<dim3((PLD + 31) / 32, (HD + 31) / 32), 256, 0, stream>>>(
        XC, K2, HD, ST, HD, PLD, (size_t)HD * PLD);
    cmm_bf16_sk<<<dim3(HD / 64, 11, CSPLIT), 256, 0, stream>>>(
        SA, PPS, PLD, ST, (size_t)HD * PLD, PLD, PART, K2, HD, PLD, chF);
    creduce<<<rg, 256, 0, stream>>>(PART, EVO, mn, HD, CSPLIT, 0.f, nullptr, 0.f, nullptr, 0.f);
    // AGG0 = scatter-free gather of EVO over graph3
    agg_gather<<<K2, 256, 0, stream>>>(COFF, CSRC, EVO, AGG0, HD);
    pack2<<<(HD * HD + 255) / 256, 256, 0, stream>>>(msg_wr, msg_wi, WC, HD * HD);
    // AGG1 = AGG0 @ WC  (M=656, N=256, Kp=256)
    split_planes<<<((PLD * HD) + 255) / 256, 256, 0, stream>>>(
        AGG0, K2, HD, SA, PLD, HD, (size_t)PLD * HD);
    split_planesT<<<dim3((HD + 31) / 32, (HD + 31) / 32), 256, 0, stream>>>(
        WC, HD, HD, ST, HD, HD, (size_t)HD * HD);
    cmm_bf16_sk<<<dim3(HD / 64, 11, CSPLIT), 256, 0, stream>>>(
        SA, (size_t)PLD * HD, HD, ST, (size_t)HD * HD, HD, PART, K2, HD, HD,
        sk_chunk32(HD, CSPLIT));
    creduce<<<rg, 256, 0, stream>>>(PART, AGG1, mn, HD, CSPLIT, 0.f, nullptr, 0.f, nullptr, 0.f);
  }
  // magph writes MAGB/PHB, overwriting the CSR slot — CSR is dead now.
  magph<<<(K2 * HD + 255) / 256, 256, 0, stream>>>(AGG1, XRb, XIb, MAGB, PHB, K2 * HD);
  col_mean<<<HD, 256, 0, stream>>>(MAGB, GM, K2, HD);
  col_mean<<<HD, 256, 0, stream>>>(PHB, GP, K2, HD);

  // ---------- classifier heads ----------
  vecmat<1><<<1, 256, 0, stream>>>(GM, mc1_w, mc1_b, HM, HD, HD / 2);
  vecmat<0><<<1, 256, 0, stream>>>(HM, mc2_w, mc2_b, LM, HD / 2, NC);
  vecmat<1><<<1, 256, 0, stream>>>(GP, pc1_w, pc1_b, HP, HD, HD / 2);
  vecmat<0><<<1, 256, 0, stream>>>(HP, pc2_w, pc2_b, LP, HD / 2, NC);
  add_out<<<1, 64, 0, stream>>>(LM, LP, (float*)d_out, NC);
}

// Round 9
// 1157.008 us; speedup vs baseline: 12.7871x; 1.0445x over previous
//
#include <hip/hip_runtime.h>
#include <cstddef>
#include <utility>

// ---------------- problem constants ----------------
constexpr int N0  = 4096;
constexpr int E   = 65536;
constexpr int DIN = 128;
constexpr int HD  = 256;   // H
constexpr int NC  = 10;
constexpr int UHD = 64;    // UH
constexpr int K1  = 3277;  // ceil(0.8*4096)
constexpr int K2  = 656;   // ceil(0.2*3277)
constexpr int PMN = K2 * K2; // 430336

// expm(A): A = 2^5*B, deg-11 Taylor (PS) then 5 squarings; the 5th squaring
// is folded into the EVO product: EVO = S@(S@XC) with S = exp(A)^(1/2).
constexpr int EXPM_SQ = 4;   // explicit squarings

// MFMA plane geometry: 656 -> padded 704 = 11*64 = 22*32.
constexpr int PLD = 704;
constexpr size_t PPS = (size_t)PLD * PLD;

// Split-K. R8: z must be blockIdx.x (fastest linear dim) and CSPLIT | 8 so the
// round-robin block->XCD map gives each XCD a single k-slice (2.2 MB < 4 MB L2).
constexpr int CSPLIT = 4;

// ---------------- workspace layout ----------------
#define F4(n) ((size_t)(n) * 4)
constexpr size_t O_H1    = 0;
constexpr size_t O_OUT1  = O_H1    + F4(N0 * HD);
constexpr size_t O_DEG1  = O_OUT1  + F4(N0 * HD);
constexpr size_t O_DIS1  = O_DEG1  + F4(N0);
constexpr size_t O_SC1   = O_DIS1  + F4(N0);
constexpr size_t O_PERM1 = O_SC1   + F4(N0);
constexpr size_t O_MAP1  = O_PERM1 + F4(N0);
constexpr size_t O_H1P   = O_MAP1  + F4(N0);
constexpr size_t O_SRC2  = O_H1P   + F4(K1 * HD);
constexpr size_t O_DST2  = O_SRC2  + F4(E);
constexpr size_t O_EM2   = O_DST2  + F4(E);
constexpr size_t O_H2    = O_EM2   + F4(E);
constexpr size_t O_OUT2  = O_H2    + F4(K1 * HD);
constexpr size_t O_DEG2  = O_OUT2  + F4(K1 * HD);
constexpr size_t O_DIS2  = O_DEG2  + F4(N0);
constexpr size_t O_SC2   = O_DIS2  + F4(N0);
constexpr size_t O_PERM2 = O_SC2   + F4(N0);
constexpr size_t O_MAP2  = O_PERM2 + F4(N0);
constexpr size_t O_H2P   = O_MAP2  + F4(N0);
constexpr size_t O_SRC3  = O_H2P   + F4(K2 * HD);
constexpr size_t O_DST3  = O_SRC3  + F4(E);
constexpr size_t O_EM3   = O_DST3  + F4(E);
constexpr size_t O_XR    = O_EM3   + F4(E);
constexpr size_t O_XI    = O_XR    + F4(K2 * HD);
constexpr size_t O_DEG3  = O_XI    + F4(K2 * HD);
constexpr size_t O_DIS3  = O_DEG3  + F4(1024);
constexpr size_t O_SCOEF = O_DIS3  + F4(1024);
constexpr size_t O_XG1   = O_SCOEF + F4(1024);
constexpr size_t O_XG2H  = O_XG1   + F4(K2 * UHD);
constexpr size_t O_XG2   = O_XG2H  + F4(K2 * UHD);
constexpr size_t O_EMB   = O_XG2   + F4(K2 * UHD);
constexpr size_t O_T1    = O_EMB   + F4(64);
constexpr size_t O_T2    = O_T1    + F4(64);
constexpr size_t O_NORM  = O_T2    + F4(64);
constexpr size_t O_PM    = O_NORM  + F4(64);
constexpr size_t O_BM    = O_PM    + F4(PMN);          // float2
constexpr size_t O_P0    = O_BM    + F4(PMN) * 2;      // float2
constexpr size_t O_P1    = O_P0    + F4(PMN) * 2;      // float2
constexpr size_t O_XRT   = O_P1    + F4(PMN) * 2;
constexpr size_t O_XIT   = O_XRT   + F4(K2 * HD);
constexpr size_t O_XC    = O_XIT   + F4(K2 * HD);      // float2
constexpr size_t O_EVO   = O_XC    + F4(K2 * HD) * 2;  // float2
constexpr size_t O_AGG0  = O_EVO   + F4(K2 * HD) * 2;  // float2
constexpr size_t O_WC    = O_AGG0  + F4(K2 * HD) * 2;  // float2 256x256
constexpr size_t O_AGG1  = O_WC    + F4(HD * HD) * 2;  // float2
constexpr size_t O_MAG   = O_AGG1  + F4(K2 * HD) * 2;
constexpr size_t O_PH    = O_MAG   + F4(K2 * HD);
constexpr size_t O_GM    = O_PH    + F4(K2 * HD);
constexpr size_t O_GP    = O_GM    + F4(256);
constexpr size_t O_HM    = O_GP    + F4(256);
constexpr size_t O_HP    = O_HM    + F4(256);
constexpr size_t O_LM    = O_HP    + F4(256);
constexpr size_t O_LP    = O_LM    + F4(64);
constexpr size_t WS_NEED = O_LP    + F4(64);

// SA/ST bf16 plane sets in the dead stage-A/B region (below O_SRC3, dead
// before the expm phase).
constexpr size_t O_SA = 0;
constexpr size_t O_ST = O_SA + PPS * 2 * 4;
static_assert(O_ST + PPS * 2 * 4 <= O_SRC3, "SA/ST must fit in dead region");

// B2/B3 fp32 (PS powers) alias XRT..AGG1 (written only post-expm).
constexpr size_t O_B2 = O_XRT;
constexpr size_t O_B3 = O_B2 + F4(PMN) * 2;
static_assert(O_B3 + F4(PMN) * 2 <= O_MAG, "B2/B3 must fit in XRT..AGG1 region");

// CSR slot in the MAG/PH region (written only by magph, after last CSR use).
constexpr size_t O_CSR_OFF = O_MAG;                 // (N0+1) ints
constexpr size_t O_CSR_CUR = O_CSR_OFF + F4(4104);
constexpr size_t O_CSR_SRC = O_CSR_CUR + F4(4104);  // E ints
constexpr size_t O_CSR_CF  = O_CSR_SRC + F4(E);     // E floats
static_assert(O_CSR_CF + F4(E) <= O_GM, "CSR must fit in MAG/PH region");

// Extension region past WS_NEED (R8: harness poison fill shows ws_size
// ~268 MB; guard at runtime). Holds split-K partials (CSPLIT=4).
constexpr size_t O_PARTX  = (WS_NEED + 255) & ~(size_t)255;
constexpr size_t PART_SZ  = (size_t)CSPLIT * PMN * 8;
constexpr size_t WS_TOTAL = O_PARTX + PART_SZ;

// ---------------- bf16 helpers ----------------
typedef __attribute__((ext_vector_type(8))) short s8v;   // 8 bf16 (4 VGPRs)
typedef __attribute__((ext_vector_type(4))) float f4v;   // MFMA acc

__device__ inline unsigned short f2bf(float x) {
  unsigned u = __float_as_uint(x);
  u += 0x7FFFu + ((u >> 16) & 1u);
  return (unsigned short)(u >> 16);
}
__device__ inline float bf2f(unsigned short h) {
  return __uint_as_float(((unsigned)h) << 16);
}
__device__ inline void split4(float re, float im, unsigned short* out,
                              size_t ps, size_t o) {
  unsigned short rh = f2bf(re);
  unsigned short rl = f2bf(re - bf2f(rh));
  unsigned short ih = f2bf(im);
  unsigned short il = f2bf(im - bf2f(ih));
  out[o] = rh; out[ps + o] = rl; out[2 * ps + o] = ih; out[3 * ps + o] = il;
}

// ---------------- kernels ----------------

// real GEMM fp32 (pool-score path stays fp32 for exact top-k ordering).
// CS/CO: output written to C[(r*N+c)*CS + CO] (CS=2 interleaves into float2).
template <int ACT>
__global__ void rmm64(const float* __restrict__ A, const float* __restrict__ B,
                      const float* __restrict__ bias, float* __restrict__ C,
                      int M, int N, int K, int CS, int CO) {
  __shared__ float As[64][17];
  __shared__ float Bs[16][64];
  int t  = threadIdx.x;
  int tx = t & 15, ty = t >> 4;
  int bm = blockIdx.y * 64, bn = blockIdx.x * 64;
  float acc[4][4] = {};
  for (int kt = 0; kt < K; kt += 16) {
#pragma unroll
    for (int i = 0; i < 4; i++) {
      int l = t + i * 256;
      int kk = l & 15, mm = l >> 4;
      int gr = bm + mm;
      As[mm][kk] = (gr < M) ? A[(size_t)gr * K + kt + kk] : 0.f;
    }
#pragma unroll
    for (int i = 0; i < 4; i++) {
      int l = t + i * 256;
      int cc = l & 63, kk = l >> 6;
      int gc = bn + cc;
      Bs[kk][cc] = (gc < N) ? B[(size_t)(kt + kk) * N + gc] : 0.f;
    }
    __syncthreads();
#pragma unroll
    for (int kk = 0; kk < 16; kk++) {
      float a[4], b[4];
#pragma unroll
      for (int i = 0; i < 4; i++) a[i] = As[ty + 16 * i][kk];
#pragma unroll
      for (int j = 0; j < 4; j++) b[j] = Bs[kk][tx + 16 * j];
#pragma unroll
      for (int i = 0; i < 4; i++)
#pragma unroll
        for (int j = 0; j < 4; j++) acc[i][j] += a[i] * b[j];
    }
    __syncthreads();
  }
#pragma unroll
  for (int i = 0; i < 4; i++) {
    int r = bm + ty + 16 * i;
    if (r >= M) continue;
#pragma unroll
    for (int j = 0; j < 4; j++) {
      int c = bn + tx + 16 * j;
      if (c >= N) continue;
      float v = acc[i][j] + (bias ? bias[c] : 0.f);
      if (ACT == 1) v = fmaxf(v, 0.f);
      C[((size_t)r * N + c) * CS + CO] = v;
    }
  }
}

// Split complex fp32 -> 4 bf16 planes [row][col], zero-pad.
__global__ void split_planes(const float2* __restrict__ in, int inM, int inN,
                             unsigned short* __restrict__ out, int padR, int ld,
                             size_t ps) {
  int idx = blockIdx.x * 256 + threadIdx.x;
  if (idx >= padR * ld) return;
  int r = idx / ld, c = idx - r * ld;
  float re = 0.f, im = 0.f;
  if (r < inM && c < inN) { float2 v = in[(size_t)r * inN + c]; re = v.x; im = v.y; }
  split4(re, im, out, ps, idx);
}

// Transposed split: out[n*ld + k] = split(in[k][n]); tiled via LDS.
__global__ void split_planesT(const float2* __restrict__ in, int inM, int inN,
                              unsigned short* __restrict__ out, int padR, int ld,
                              size_t ps) {
  __shared__ float2 tile[32][33];
  int tx = threadIdx.x & 31, ty = threadIdx.x >> 5;   // 32 x 8
  int k0 = blockIdx.x * 32, n0 = blockIdx.y * 32;
  for (int i = ty; i < 32; i += 8) {
    int k = k0 + i, n = n0 + tx;
    tile[i][tx] = (k < inM && n < inN) ? in[(size_t)k * inN + n]
                                       : make_float2(0.f, 0.f);
  }
  __syncthreads();
  for (int i = ty; i < 32; i += 8) {
    int n = n0 + i, k = k0 + tx;
    if (n < padR && k < ld)
      split4(tile[tx][i].x, tile[tx][i].y, out, ps, (size_t)n * ld + k);
  }
}

// Transposed split from two real fp32 matrices (re, im): W = re + i*im.
__global__ void split_planesT2(const float* __restrict__ re, const float* __restrict__ im,
                               int inM, int inN, unsigned short* __restrict__ out,
                               int padR, int ld, size_t ps) {
  __shared__ float2 tile[32][33];
  int tx = threadIdx.x & 31, ty = threadIdx.x >> 5;
  int k0 = blockIdx.x * 32, n0 = blockIdx.y * 32;
  for (int i = ty; i < 32; i += 8) {
    int k = k0 + i, n = n0 + tx;
    tile[i][tx] = (k < inM && n < inN)
        ? make_float2(re[(size_t)k * inN + n], im[(size_t)k * inN + n])
        : make_float2(0.f, 0.f);
  }
  __syncthreads();
  for (int i = ty; i < 32; i += 8) {
    int n = n0 + i, k = k0 + tx;
    if (n < padR && k < ld)
      split4(tile[tx][i].x, tile[tx][i].y, out, ps, (size_t)n * ld + k);
  }
}

// Split-K complex MFMA GEMM with register double-buffer prefetch.
// z = blockIdx.x (fastest linear dim -> XCD %CSPLIT affinity, R8).
__global__ __launch_bounds__(256, 2) void cmm_bf16_sk(
    const unsigned short* __restrict__ SA, size_t psA, int ldA,
    const unsigned short* __restrict__ ST, size_t psT, int ldT,
    float2* __restrict__ Part, int M, int N, int Kp, int chunk) {
  int k0 = blockIdx.x * chunk;
  int kend = min(Kp, k0 + chunk);
  int t = threadIdx.x;
  int wave = t >> 6, lane = t & 63;
  int quad = lane >> 4, mn = lane & 15;
  int rowA = blockIdx.z * 64 + wave * 16 + mn;
  int bn = blockIdx.y * 64;
  const unsigned short* a0 = SA + (size_t)rowA * ldA;
  f4v accR[4], accI[4];
#pragma unroll
  for (int i = 0; i < 4; i++) {
    accR[i] = (f4v){0.f, 0.f, 0.f, 0.f};
    accI[i] = (f4v){0.f, 0.f, 0.f, 0.f};
  }
  s8v cA[4], cB[4][4], nA[4], nB[4][4];
  {
    int ka = k0 + quad * 8;
#pragma unroll
    for (int p = 0; p < 4; p++) cA[p] = *(const s8v*)(a0 + p * psA + ka);
#pragma unroll
    for (int tl = 0; tl < 4; tl++) {
      const unsigned short* b0 = ST + (size_t)(bn + tl * 16 + mn) * ldT + ka;
#pragma unroll
      for (int p = 0; p < 4; p++) cB[tl][p] = *(const s8v*)(b0 + p * psT);
    }
  }
  for (int kt = k0; kt < kend; kt += 32) {
    int kn = kt + 32;
    if (kn < kend) {
      int ka = kn + quad * 8;
#pragma unroll
      for (int p = 0; p < 4; p++) nA[p] = *(const s8v*)(a0 + p * psA + ka);
#pragma unroll
      for (int tl = 0; tl < 4; tl++) {
        const unsigned short* b0 = ST + (size_t)(bn + tl * 16 + mn) * ldT + ka;
#pragma unroll
        for (int p = 0; p < 4; p++) nB[tl][p] = *(const s8v*)(b0 + p * psT);
      }
    }
    s8v nih, nil_;
#pragma unroll
    for (int q = 0; q < 8; q++) {
      nih[q]  = (short)(cA[2][q] ^ (short)0x8000);   // -ai
      nil_[q] = (short)(cA[3][q] ^ (short)0x8000);
    }
#pragma unroll
    for (int tl = 0; tl < 4; tl++) {
      f4v r = accR[tl];
      r = __builtin_amdgcn_mfma_f32_16x16x32_bf16(cA[0], cB[tl][0], r, 0, 0, 0);
      r = __builtin_amdgcn_mfma_f32_16x16x32_bf16(cA[1], cB[tl][0], r, 0, 0, 0);
      r = __builtin_amdgcn_mfma_f32_16x16x32_bf16(cA[0], cB[tl][1], r, 0, 0, 0);
      r = __builtin_amdgcn_mfma_f32_16x16x32_bf16(nih, cB[tl][2], r, 0, 0, 0);
      r = __builtin_amdgcn_mfma_f32_16x16x32_bf16(nil_, cB[tl][2], r, 0, 0, 0);
      r = __builtin_amdgcn_mfma_f32_16x16x32_bf16(nih, cB[tl][3], r, 0, 0, 0);
      accR[tl] = r;
      f4v im = accI[tl];
      im = __builtin_amdgcn_mfma_f32_16x16x32_bf16(cA[0], cB[tl][2], im, 0, 0, 0);
      im = __builtin_amdgcn_mfma_f32_16x16x32_bf16(cA[1], cB[tl][2], im, 0, 0, 0);
      im = __builtin_amdgcn_mfma_f32_16x16x32_bf16(cA[0], cB[tl][3], im, 0, 0, 0);
      im = __builtin_amdgcn_mfma_f32_16x16x32_bf16(cA[2], cB[tl][0], im, 0, 0, 0);
      im = __builtin_amdgcn_mfma_f32_16x16x32_bf16(cA[3], cB[tl][0], im, 0, 0, 0);
      im = __builtin_amdgcn_mfma_f32_16x16x32_bf16(cA[2], cB[tl][1], im, 0, 0, 0);
      accI[tl] = im;
    }
    if (kn < kend) {
#pragma unroll
      for (int p = 0; p < 4; p++) cA[p] = nA[p];
#pragma unroll
      for (int tl = 0; tl < 4; tl++)
#pragma unroll
        for (int p = 0; p < 4; p++) cB[tl][p] = nB[tl][p];
    }
  }
  float2* P = Part + (size_t)blockIdx.x * M * N;
#pragma unroll
  for (int tl = 0; tl < 4; tl++) {
    int col = bn + tl * 16 + mn;
    if (col >= N) continue;
#pragma unroll
    for (int r = 0; r < 4; r++) {
      int row = blockIdx.z * 64 + wave * 16 + quad * 4 + r;
      if (row >= M) continue;
      P[(size_t)row * N + col] = make_float2(accR[tl][r], accI[tl][r]);
    }
  }
}

// Plain reduce: C = sum_z Part[z] + e0*I + e1*E1 + e2*E2.
__global__ void creduce(const float2* __restrict__ Part, float2* __restrict__ C,
                        int MN, int N, int S, float e0,
                        const float2* __restrict__ E1, float e1,
                        const float2* __restrict__ E2, float e2) {
  int idx = blockIdx.x * 256 + threadIdx.x;
  if (idx >= MN) return;
  float sr = 0.f, si = 0.f;
  for (int z = 0; z < S; z++) {
    float2 p = Part[(size_t)z * MN + idx];
    sr += p.x;
    si += p.y;
  }
  if (e0 != 0.f) {
    int r = idx / N;
    if (idx - r * N == r) sr += e0;
  }
  if (E1) { float2 b = E1[idx]; sr += e1 * b.x; si += e1 * b.y; }
  if (E2) { float2 b = E2[idx]; sr += e2 * b.x; si += e2 * b.y; }
  C[idx] = make_float2(sr, si);
}

// Fused reduce + epilogue + bf16 plane split (SA layout [row][k]).
// Indexed over padded padR x ld domain; pad cells write zero planes only.
__global__ void creduce_split(const float2* __restrict__ Part, float2* __restrict__ C,
                              unsigned short* __restrict__ planes, size_t ps,
                              int M, int N, int padR, int ld, int S, float e0,
                              const float2* __restrict__ E1, float e1,
                              const float2* __restrict__ E2, float e2) {
  int idx = blockIdx.x * 256 + threadIdx.x;
  if (idx >= padR * ld) return;
  int r = idx / ld, c = idx - r * ld;
  float sr = 0.f, si = 0.f;
  if (r < M && c < N) {
    size_t o = (size_t)r * N + c;
    size_t MN = (size_t)M * N;
    for (int z = 0; z < S; z++) {
      float2 p = Part[z * MN + o];
      sr += p.x;
      si += p.y;
    }
    if (e0 != 0.f && r == c) sr += e0;
    if (E1) { float2 b = E1[o]; sr += e1 * b.x; si += e1 * b.y; }
    if (E2) { float2 b = E2[o]; sr += e2 * b.x; si += e2 * b.y; }
    C[o] = make_float2(sr, si);
  }
  split4(sr, si, planes, ps, idx);
}

// D3 = e0*I + e1*B + e2*B2, fp32 out + bf16 planes (SA layout).
__global__ void combo3_split(const float2* __restrict__ Bp, const float2* __restrict__ B2p,
                             float2* __restrict__ Out, unsigned short* __restrict__ planes,
                             size_t ps, int M, int N, int padR, int ld,
                             float e0, float e1, float e2) {
  int idx = blockIdx.x * 256 + threadIdx.x;
  if (idx >= padR * ld) return;
  int r = idx / ld, c = idx - r * ld;
  float sr = 0.f, si = 0.f;
  if (r < M && c < N) {
    size_t o = (size_t)r * N + c;
    float2 b = Bp[o], b2 = B2p[o];
    sr = e1 * b.x + e2 * b2.x;
    si = e1 * b.y + e2 * b2.y;
    if (r == c) sr += e0;
    Out[o] = make_float2(sr, si);
  }
  split4(sr, si, planes, ps, idx);
}

// ---- CSR build ----
__global__ void hist_edges(const int* __restrict__ dst, const float* __restrict__ em,
                           int* __restrict__ cnt) {
  int e = blockIdx.x * 256 + threadIdx.x;
  if (e >= E) return;
  float m = em ? em[e] : 1.0f;
  if (m != 0.f) atomicAdd(&cnt[dst[e]], 1);
}

// Exclusive scan of cnt -> off/cur, plus dis[i] = rsqrt(cnt[i]+1). 1 block.
__global__ __launch_bounds__(1024) void scan_offsets(const int* __restrict__ cnt, int n,
                                                     int* __restrict__ off,
                                                     int* __restrict__ cur,
                                                     float* __restrict__ dis) {
  __shared__ int sums[1024];
  int t = threadIdx.x;
  int base = t * 4;
  int v[4];
  int s = 0;
#pragma unroll
  for (int j = 0; j < 4; j++) {
    int i = base + j;
    int ci = (i < n) ? cnt[i] : 0;
    if (i < n) dis[i] = 1.0f / sqrtf((float)ci + 1.0f);
    v[j] = s;
    s += ci;
  }
  sums[t] = s;
  __syncthreads();
  for (int d = 1; d < 1024; d <<= 1) {
    int x = (t >= d) ? sums[t - d] : 0;
    __syncthreads();
    sums[t] += x;
    __syncthreads();
  }
  int pre = (t > 0) ? sums[t - 1] : 0;
#pragma unroll
  for (int j = 0; j < 4; j++) {
    int i = base + j;
    if (i < n) { int o = pre + v[j]; off[i] = o; cur[i] = o; }
  }
  if (t == 1023) off[n] = sums[1023];
}

__global__ void fill_edges(const int* __restrict__ src, const int* __restrict__ dst,
                           const float* __restrict__ em, const float* __restrict__ dis,
                           int* __restrict__ cur, int* __restrict__ esrc,
                           float* __restrict__ ecoef) {
  int e = blockIdx.x * 256 + threadIdx.x;
  if (e >= E) return;
  float m = em ? em[e] : 1.0f;
  if (m == 0.f) return;
  int s = src[e], d = dst[e];
  int pos = atomicAdd(&cur[d], 1);
  esrc[pos] = s;
  ecoef[pos] = dis[s] * dis[d];
}

// Fused GCN aggregate + self-loop + bias (+relu), gather form.
template <int ACT>
__global__ void gcn_gather(const int* __restrict__ off, const int* __restrict__ esrc,
                           const float* __restrict__ ecoef, const float* __restrict__ Hm,
                           const float* __restrict__ dis, const float* __restrict__ bias,
                           float* __restrict__ out, int F) {
  int i = blockIdx.x;
  int e0 = off[i], e1 = off[i + 1];
  float d2 = dis[i] * dis[i];
  for (int f = threadIdx.x; f < F; f += blockDim.x) {
    float acc = d2 * Hm[(size_t)i * F + f] + bias[f];
    for (int e = e0; e < e1; e++)
      acc += ecoef[e] * Hm[(size_t)esrc[e] * F + f];
    if (ACT == 1) acc = fmaxf(acc, 0.f);
    out[(size_t)i * F + f] = acc;
  }
}

// enc1 with scoef fused: one wave per node; butterfly-reduce bucket sum.
__global__ void enc1_fused(const int* __restrict__ off, const float* __restrict__ ecoef,
                           const float* __restrict__ dis, const float* __restrict__ w,
                           const float* __restrict__ b, float* __restrict__ xg1) {
  int i = blockIdx.x;
  int lane = threadIdx.x;   // 64 = one wave
  float s = 0.f;
  for (int e = off[i] + lane; e < off[i + 1]; e += 64) s += ecoef[e];
#pragma unroll
  for (int d = 32; d > 0; d >>= 1) s += __shfl_xor(s, d, 64);
  float sc = s + dis[i] * dis[i];
  xg1[(size_t)i * UHD + lane] = fmaxf(sc * w[lane] + b[lane], 0.f);
}

// Gather of EVO over graph3 fused with bf16 plane split (SA layout [row][k],
// ld=F, rows padded to padR). Pad rows write zero planes.
__global__ void agg_gather_split(const int* __restrict__ off, const int* __restrict__ esrc,
                                 const float2* __restrict__ evo,
                                 unsigned short* __restrict__ planes, size_t ps,
                                 int F, int M) {
  int i = blockIdx.x;
  if (i >= M) {
    for (int f = threadIdx.x; f < F; f += blockDim.x)
      split4(0.f, 0.f, planes, ps, (size_t)i * F + f);
    return;
  }
  int e0 = off[i], e1 = off[i + 1];
  for (int f = threadIdx.x; f < F; f += blockDim.x) {
    float sr = 0.f, si = 0.f;
    for (int e = e0; e < e1; e++) {
      float2 v = evo[(size_t)esrc[e] * F + f];
      sr += v.x;
      si += v.y;
    }
    split4(sr, si, planes, ps, (size_t)i * F + f);
  }
}

__global__ void wnorm(const float* __restrict__ w, int n, float* __restrict__ out) {
  __shared__ float red[256];
  float s = 0.f;
  for (int k = threadIdx.x; k < n; k += 256) s += w[k] * w[k];
  red[threadIdx.x] = s;
  __syncthreads();
  for (int off = 128; off > 0; off >>= 1) {
    if (threadIdx.x < off) red[threadIdx.x] += red[threadIdx.x + off];
    __syncthreads();
  }
  if (threadIdx.x == 0) out[0] = sqrtf(red[0]);
}

__global__ void rowdot(const float* __restrict__ X, const float* __restrict__ w,
                       float* __restrict__ out, int F) {
  int i = blockIdx.x;
  __shared__ float red[256];
  float s = 0.f;
  for (int f = threadIdx.x; f < F; f += 256) s += X[(size_t)i * F + f] * w[f];
  red[threadIdx.x] = s;
  __syncthreads();
  for (int off = 128; off > 0; off >>= 1) {
    if (threadIdx.x < off) red[threadIdx.x] += red[threadIdx.x + off];
    __syncthreads();
  }
  if (threadIdx.x == 0) out[i] = red[0];
}

// exact-total-order descending bitonic sort; key = (sortable_score<<32) | ~idx.
__global__ __launch_bounds__(1024) void bitonic_topk(const float* __restrict__ score,
                                                     int n, int* __restrict__ perm, int k) {
  __shared__ unsigned long long keys[4096];
  int t = threadIdx.x;
  for (int i = t; i < 4096; i += 1024) {
    unsigned long long kk = 0ull;
    if (i < n) {
      float f = score[i];
      unsigned u = __float_as_uint(f);
      u = (f >= 0.0f) ? (u | 0x80000000u) : ~u;
      kk = ((unsigned long long)u << 32) | (unsigned)(~(unsigned)i);
    }
    keys[i] = kk;
  }
  __syncthreads();
  for (int size = 2; size <= 4096; size <<= 1) {
    for (int stride = size >> 1; stride > 0; stride >>= 1) {
      for (int i = t; i < 2048; i += 1024) {
        int pos = ((i & ~(stride - 1)) << 1) | (i & (stride - 1));
        int partner = pos + stride;
        bool desc = (pos & size) == 0;
        unsigned long long a = keys[pos], b = keys[partner];
        if ((a < b) == desc) { keys[pos] = b; keys[partner] = a; }
      }
      __syncthreads();
    }
  }
  for (int i = t; i < k; i += 1024)
    perm[i] = (int)(~(unsigned)(keys[i] & 0xFFFFFFFFull));
}

__global__ void set_map(const int* __restrict__ perm, int* __restrict__ map, int k) {
  int i = blockIdx.x * 256 + threadIdx.x;
  if (i < k) map[perm[i]] = i;
}

__global__ void pool_gather(const float* __restrict__ X, const int* __restrict__ perm,
                            const float* __restrict__ dot, const float* __restrict__ normbuf,
                            float* __restrict__ Xn, int F) {
  int i = blockIdx.x;
  int p = perm[i];
  float sc = tanhf(dot[p] / normbuf[0]);
  for (int f = threadIdx.x; f < F; f += blockDim.x)
    Xn[(size_t)i * F + f] = X[(size_t)p * F + f] * sc;
}

__global__ void remap_edges(const int* __restrict__ srcIn, const int* __restrict__ dstIn,
                            const float* __restrict__ emIn, const int* __restrict__ map,
                            int* __restrict__ srcOut, int* __restrict__ dstOut,
                            float* __restrict__ emOut) {
  int e = blockIdx.x * 256 + threadIdx.x;
  if (e >= E) return;
  int ns = map[srcIn[e]], nd = map[dstIn[e]];
  float m = emIn ? emIn[e] : 1.0f;
  if (ns < 0 || nd < 0) m = 0.f;
  srcOut[e] = ns < 0 ? 0 : ns;
  dstOut[e] = nd < 0 ? 0 : nd;
  emOut[e] = m;
}

__global__ void col_mean(const float* __restrict__ X, float* __restrict__ out,
                         int rows, int cols) {
  int c = blockIdx.x;
  __shared__ float red[256];
  float s = 0.f;
  for (int r = threadIdx.x; r < rows; r += 256) s += X[(size_t)r * cols + c];
  red[threadIdx.x] = s;
  __syncthreads();
  for (int off = 128; off > 0; off >>= 1) {
    if (threadIdx.x < off) red[threadIdx.x] += red[threadIdx.x + off];
    __syncthreads();
  }
  if (threadIdx.x == 0) out[c] = red[0] / (float)rows;
}

template <int ACT>
__global__ void vecmat(const float* __restrict__ v, const float* __restrict__ W,
                       const float* __restrict__ b, float* __restrict__ out,
                       int Kdim, int Ndim) {
  __shared__ float vs[256];
  for (int k = threadIdx.x; k < Kdim; k += blockDim.x) vs[k] = v[k];
  __syncthreads();
  for (int j = threadIdx.x; j < Ndim; j += blockDim.x) {
    float acc = b ? b[j] : 0.f;
    for (int k = 0; k < Kdim; k++) acc += vs[k] * W[(size_t)k * Ndim + j];
    out[j] = (ACT == 1) ? fmaxf(acc, 0.f) : acc;
  }
}

__global__ void vecmat_tanh_wide(const float* __restrict__ v, const float* __restrict__ W,
                                 const float* __restrict__ b, float* __restrict__ out,
                                 int Kdim, int Ndim) {
  __shared__ float vs[64];
  if (threadIdx.x < Kdim) vs[threadIdx.x] = v[threadIdx.x];
  __syncthreads();
  int j = blockIdx.x * 256 + threadIdx.x;
  if (j >= Ndim) return;
  float acc = b[j];
  for (int k = 0; k < Kdim; k++) acc += vs[k] * W[(size_t)k * Ndim + j];
  out[j] = tanhf(acc);
}

__global__ void build_B(const float* __restrict__ pm, float2* __restrict__ Bm,
                        int n, float scale) {
  int idx = blockIdx.x * 256 + threadIdx.x;
  if (idx >= n * n) return;
  int r = idx / n, c = idx - r * n;
  float pij = pm[(size_t)r * n + c];
  float pji = pm[(size_t)c * n + r];
  Bm[idx] = make_float2(scale * (pij - pji), scale * (pij + pji));
}

__global__ void magph(const float2* __restrict__ agg, const float* __restrict__ xr,
                      const float* __restrict__ xi, float* __restrict__ mag,
                      float* __restrict__ ph, int n) {
  int idx = blockIdx.x * 256 + threadIdx.x;
  if (idx >= n) return;
  float2 a = agg[idx];
  float r = a.x + xr[idx];
  float im = a.y + xi[idx];
  mag[idx] = sqrtf(r * r + im * im);
  ph[idx] = atan2f(im, r);
}

__global__ void add_out(const float* __restrict__ lm, const float* __restrict__ lp,
                        float* __restrict__ out, int n) {
  int i = threadIdx.x;
  if (i < n) out[i] = lm[i] + lp[i];
}

// ---------------- host helpers ----------------
static inline int sk_chunk32(int K, int S) { return (((K + S - 1) / S) + 31) & ~31; }

// ---------------- host ----------------
extern "C" void kernel_launch(void* const* d_in, const int* in_sizes, int n_in,
                              void* d_out, int out_size, void* d_ws, size_t ws_size,
                              hipStream_t stream) {
  if (ws_size < WS_TOTAL) return;

  const float* x       = (const float*)d_in[0];
  const int*   ei      = (const int*)d_in[1];
  const float* gcn1_w  = (const float*)d_in[2];
  const float* gcn1_b  = (const float*)d_in[3];
  const float* pool1_w = (const float*)d_in[4];
  const float* gcn2_w  = (const float*)d_in[5];
  const float* gcn2_b  = (const float*)d_in[6];
  const float* pool2_w = (const float*)d_in[7];
  const float* inr_w   = (const float*)d_in[8];
  const float* inr_b   = (const float*)d_in[9];
  const float* ini_w   = (const float*)d_in[10];
  const float* ini_b   = (const float*)d_in[11];
  const float* enc1_w  = (const float*)d_in[12];
  const float* enc1_b  = (const float*)d_in[13];
  const float* enc2_w  = (const float*)d_in[14];
  const float* enc2_b  = (const float*)d_in[15];
  const float* p1_w    = (const float*)d_in[16];
  const float* p1_b    = (const float*)d_in[17];
  const float* p2_w    = (const float*)d_in[18];
  const float* p2_b    = (const float*)d_in[19];
  const float* p3_w    = (const float*)d_in[20];
  const float* p3_b    = (const float*)d_in[21];
  const float* rt_w    = (const float*)d_in[22];
  const float* rt_b    = (const float*)d_in[23];
  const float* it_w    = (const float*)d_in[24];
  const float* it_b    = (const float*)d_in[25];
  const float* msg_wr  = (const float*)d_in[26];
  const float* msg_wi  = (const float*)d_in[27];
  const float* mc1_w   = (const float*)d_in[28];
  const float* mc1_b   = (const float*)d_in[29];
  const float* mc2_w   = (const float*)d_in[30];
  const float* mc2_b   = (const float*)d_in[31];
  const float* pc1_w   = (const float*)d_in[32];
  const float* pc1_b   = (const float*)d_in[33];
  const float* pc2_w   = (const float*)d_in[34];
  const float* pc2_b   = (const float*)d_in[35];

  char* ws = (char*)d_ws;
  float*  H1    = (float*)(ws + O_H1);
  float*  OUT1  = (float*)(ws + O_OUT1);
  int*    CNT1  = (int*)(ws + O_DEG1);
  float*  DIS1  = (float*)(ws + O_DIS1);
  float*  SC1   = (float*)(ws + O_SC1);
  int*    PERM1 = (int*)(ws + O_PERM1);
  int*    MAP1  = (int*)(ws + O_MAP1);
  float*  H1P   = (float*)(ws + O_H1P);
  int*    SRC2  = (int*)(ws + O_SRC2);
  int*    DST2  = (int*)(ws + O_DST2);
  float*  EM2   = (float*)(ws + O_EM2);
  float*  H2    = (float*)(ws + O_H2);
  float*  OUT2  = (float*)(ws + O_OUT2);
  int*    CNT2  = (int*)(ws + O_DEG2);
  float*  DIS2  = (float*)(ws + O_DIS2);
  float*  SC2   = (float*)(ws + O_SC2);
  int*    PERM2 = (int*)(ws + O_PERM2);
  int*    MAP2  = (int*)(ws + O_MAP2);
  float*  H2P   = (float*)(ws + O_H2P);
  int*    SRC3  = (int*)(ws + O_SRC3);
  int*    DST3  = (int*)(ws + O_DST3);
  float*  EM3   = (float*)(ws + O_EM3);
  float*  XRb   = (float*)(ws + O_XR);
  float*  XIb   = (float*)(ws + O_XI);
  int*    CNT3  = (int*)(ws + O_DEG3);
  float*  DIS3  = (float*)(ws + O_DIS3);
  float*  XG1   = (float*)(ws + O_XG1);
  float*  XG2H  = (float*)(ws + O_XG2H);
  float*  XG2   = (float*)(ws + O_XG2);
  float*  EMB   = (float*)(ws + O_EMB);
  float*  T1    = (float*)(ws + O_T1);
  float*  T2    = (float*)(ws + O_T2);
  float*  NORM  = (float*)(ws + O_NORM);
  float*  PMV   = (float*)(ws + O_PM);
  float2* BM    = (float2*)(ws + O_BM);
  float2* P0v   = (float2*)(ws + O_P0);
  float2* P1v   = (float2*)(ws + O_P1);
  float2* XC    = (float2*)(ws + O_XC);
  float2* EVO   = (float2*)(ws + O_EVO);
  float2* AGG1  = (float2*)(ws + O_AGG1);
  float*  MAGB  = (float*)(ws + O_MAG);
  float*  PHB   = (float*)(ws + O_PH);
  float*  GM    = (float*)(ws + O_GM);
  float*  GP    = (float*)(ws + O_GP);
  float*  HM    = (float*)(ws + O_HM);
  float*  HP    = (float*)(ws + O_HP);
  float*  LM    = (float*)(ws + O_LM);
  float*  LP    = (float*)(ws + O_LP);
  unsigned short* SA = (unsigned short*)(ws + O_SA);
  unsigned short* ST = (unsigned short*)(ws + O_ST);
  float2* PART  = (float2*)(ws + O_PARTX);
  float2* B2v   = (float2*)(ws + O_B2);
  float2* B3v   = (float2*)(ws + O_B3);
  int*    COFF  = (int*)(ws + O_CSR_OFF);
  int*    CCUR  = (int*)(ws + O_CSR_CUR);
  int*    CSRC  = (int*)(ws + O_CSR_SRC);
  float*  CCOEF = (float*)(ws + O_CSR_CF);

  const int* SRC1 = ei;
  const int* DST1 = ei + E;
  const int eg = E / 256;

  // ---------- Stage A: gcn1 (CSR gather) ----------
  rmm64<0><<<dim3(HD / 64, N0 / 64), 256, 0, stream>>>(x, gcn1_w, nullptr, H1, N0, HD, DIN, 1, 0);
  hipMemsetAsync(CNT1, 0, F4(N0), stream);
  hist_edges<<<eg, 256, 0, stream>>>(DST1, nullptr, CNT1);
  scan_offsets<<<1, 1024, 0, stream>>>(CNT1, N0, COFF, CCUR, DIS1);
  fill_edges<<<eg, 256, 0, stream>>>(SRC1, DST1, nullptr, DIS1, CCUR, CSRC, CCOEF);
  gcn_gather<1><<<N0, 256, 0, stream>>>(COFF, CSRC, CCOEF, H1, DIS1, gcn1_b, OUT1, HD);

  // ---------- pool1 ----------
  wnorm<<<1, 256, 0, stream>>>(pool1_w, HD, NORM);
  rowdot<<<N0, 256, 0, stream>>>(OUT1, pool1_w, SC1, HD);
  bitonic_topk<<<1, 1024, 0, stream>>>(SC1, N0, PERM1, K1);
  hipMemsetAsync(MAP1, 0xFF, F4(N0), stream);
  set_map<<<(K1 + 255) / 256, 256, 0, stream>>>(PERM1, MAP1, K1);
  pool_gather<<<K1, 256, 0, stream>>>(OUT1, PERM1, SC1, NORM, H1P, HD);
  remap_edges<<<eg, 256, 0, stream>>>(SRC1, DST1, nullptr, MAP1, SRC2, DST2, EM2);

  // ---------- Stage C: gcn2 (CSR gather) ----------
  rmm64<0><<<dim3(HD / 64, (K1 + 63) / 64), 256, 0, stream>>>(H1P, gcn2_w, nullptr, H2, K1, HD, HD, 1, 0);
  hipMemsetAsync(CNT2, 0, F4(K1), stream);
  hist_edges<<<eg, 256, 0, stream>>>(DST2, EM2, CNT2);
  scan_offsets<<<1, 1024, 0, stream>>>(CNT2, K1, COFF, CCUR, DIS2);
  fill_edges<<<eg, 256, 0, stream>>>(SRC2, DST2, EM2, DIS2, CCUR, CSRC, CCOEF);
  gcn_gather<1><<<K1, 256, 0, stream>>>(COFF, CSRC, CCOEF, H2, DIS2, gcn2_b, OUT2, HD);

  // ---------- pool2 ----------
  wnorm<<<1, 256, 0, stream>>>(pool2_w, HD, NORM + 1);
  rowdot<<<K1, 256, 0, stream>>>(OUT2, pool2_w, SC2, HD);
  bitonic_topk<<<1, 1024, 0, stream>>>(SC2, K1, PERM2, K2);
  hipMemsetAsync(MAP2, 0xFF, F4(N0), stream);
  set_map<<<(K2 + 255) / 256, 256, 0, stream>>>(PERM2, MAP2, K2);
  pool_gather<<<K2, 256, 0, stream>>>(OUT2, PERM2, SC2, NORM + 1, H2P, HD);
  remap_edges<<<eg, 256, 0, stream>>>(SRC2, DST2, EM2, MAP2, SRC3, DST3, EM3);

  // ---------- xr / xi ----------
  rmm64<0><<<dim3(HD / 64, (K2 + 63) / 64), 256, 0, stream>>>(H2P, inr_w, inr_b, XRb, K2, HD, HD, 1, 0);
  rmm64<0><<<dim3(HD / 64, (K2 + 63) / 64), 256, 0, stream>>>(H2P, ini_w, ini_b, XIb, K2, HD, HD, 1, 0);

  // ---------- CSR3 (persists through expm; lives in MAG/PH region) ----------
  hipMemsetAsync(CNT3, 0, F4(K2), stream);
  hist_edges<<<eg, 256, 0, stream>>>(DST3, EM3, CNT3);
  scan_offsets<<<1, 1024, 0, stream>>>(CNT3, K2, COFF, CCUR, DIS3);
  fill_edges<<<eg, 256, 0, stream>>>(SRC3, DST3, EM3, DIS3, CCUR, CSRC, CCOEF);

  // ---------- encoder GCNs on pooled graph ----------
  enc1_fused<<<K2, 64, 0, stream>>>(COFF, CCOEF, DIS3, enc1_w, enc1_b, XG1);
  rmm64<0><<<dim3(UHD / 64, (K2 + 63) / 64), 256, 0, stream>>>(XG1, enc2_w, nullptr, XG2H, K2, UHD, UHD, 1, 0);
  gcn_gather<0><<<K2, 64, 0, stream>>>(COFF, CSRC, CCOEF, XG2H, DIS3, enc2_b, XG2, UHD);
  col_mean<<<UHD, 256, 0, stream>>>(XG2, EMB, K2, UHD);

  // ---------- parameter MLP -> pm -> B ----------
  vecmat<1><<<1, 256, 0, stream>>>(EMB, p1_w, p1_b, T1, UHD, UHD);
  vecmat<1><<<1, 256, 0, stream>>>(T1, p2_w, p2_b, T2, UHD, UHD / 2);
  vecmat_tanh_wide<<<(PMN + 255) / 256, 256, 0, stream>>>(T2, p3_w, p3_b, PMV, UHD / 2, PMN);
  build_B<<<(PMN + 255) / 256, 256, 0, stream>>>(PMV, BM, K2, 0.05f * 0.5f / 32.0f);

  // ---------- expm via PS deg-11 + 4 squarings (5th folded into EVO) ----------
  const int rgrid = (PMN + 255) / 256;
  const int sgrid = (PLD * PLD + 255) / 256;
  const dim3 tgridF((PLD + 31) / 32, (PLD + 31) / 32);
  const int chF = sk_chunk32(PLD, CSPLIT);   // 192
  const dim3 gBig(CSPLIT, 11, 11);           // z first -> XCD k-slice affinity
  const float c3 = 1.f / 6.f, c4 = 1.f / 24.f, c5 = 1.f / 120.f;
  const float c6 = 1.f / 720.f, c7 = 1.f / 5040.f, c8 = 1.f / 40320.f;
  const float c9 = 1.f / 362880.f, c10 = 1.f / 3628800.f, c11 = 1.f / 39916800.f;

  split_planes <<<sgrid, 256, 0, stream>>>(BM, K2, K2, SA, PLD, PLD, PPS);
  split_planesT<<<tgridF, 256, 0, stream>>>(BM, K2, K2, ST, PLD, PLD, PPS);
  // B2 = B*B  (creduce_split: B2v fp32 + SA <- B2 planes)
  cmm_bf16_sk<<<gBig, 256, 0, stream>>>(SA, PPS, PLD, ST, PPS, PLD, PART, K2, K2, PLD, chF);
  creduce_split<<<sgrid, 256, 0, stream>>>(PART, B2v, SA, PPS, K2, K2, PLD, PLD, CSPLIT,
                                           0.f, nullptr, 0.f, nullptr, 0.f);
  // B3 = B2*B ; ST <- B3^T (fixed right operand for Horner)
  cmm_bf16_sk<<<gBig, 256, 0, stream>>>(SA, PPS, PLD, ST, PPS, PLD, PART, K2, K2, PLD, chF);
  creduce<<<rgrid, 256, 0, stream>>>(PART, B3v, PMN, K2, CSPLIT, 0.f, nullptr, 0.f, nullptr, 0.f);
  split_planesT<<<tgridF, 256, 0, stream>>>(B3v, K2, K2, ST, PLD, PLD, PPS);
  // P0 = D3 (fp32 + SA planes)
  combo3_split<<<sgrid, 256, 0, stream>>>(BM, B2v, P0v, SA, PPS, K2, K2, PLD, PLD, c9, c10, c11);
  // P1 = P0*B3 + D2 ; P0 = P1*B3 + D1 ; P1 = P0*B3 + D0 (planes chained via SA)
  cmm_bf16_sk<<<gBig, 256, 0, stream>>>(SA, PPS, PLD, ST, PPS, PLD, PART, K2, K2, PLD, chF);
  creduce_split<<<sgrid, 256, 0, stream>>>(PART, P1v, SA, PPS, K2, K2, PLD, PLD, CSPLIT,
                                           c6, BM, c7, B2v, c8);
  cmm_bf16_sk<<<gBig, 256, 0, stream>>>(SA, PPS, PLD, ST, PPS, PLD, PART, K2, K2, PLD, chF);
  creduce_split<<<sgrid, 256, 0, stream>>>(PART, P0v, SA, PPS, K2, K2, PLD, PLD, CSPLIT,
                                           c3, BM, c4, B2v, c5);
  cmm_bf16_sk<<<gBig, 256, 0, stream>>>(SA, PPS, PLD, ST, PPS, PLD, PART, K2, K2, PLD, chF);
  creduce_split<<<sgrid, 256, 0, stream>>>(PART, P1v, SA, PPS, K2, K2, PLD, PLD, CSPLIT,
                                           1.f, BM, 1.f, B2v, 0.5f);
  // 4 squarings; SA planes maintained by creduce_split, ST rebuilt per step
  float2* cur = P1v;
  float2* nxt = P0v;
  for (int t = 0; t < EXPM_SQ; ++t) {
    split_planesT<<<tgridF, 256, 0, stream>>>(cur, K2, K2, ST, PLD, PLD, PPS);
    cmm_bf16_sk<<<gBig, 256, 0, stream>>>(SA, PPS, PLD, ST, PPS, PLD, PART, K2, K2, PLD, chF);
    creduce_split<<<sgrid, 256, 0, stream>>>(PART, nxt, SA, PPS, K2, K2, PLD, PLD, CSPLIT,
                                             0.f, nullptr, 0.f, nullptr, 0.f);
    std::swap(cur, nxt);
  }
  // cur = S (= U^(1/2)); SA holds S planes.

  // ---------- quantum message passing: EVO = S@(S@XC) ----------
  rmm64<1><<<dim3(HD / 64, (K2 + 63) / 64), 256, 0, stream>>>(XRb, rt_w, rt_b, (float*)XC, K2, HD, HD, 2, 0);
  rmm64<1><<<dim3(HD / 64, (K2 + 63) / 64), 256, 0, stream>>>(XIb, it_w, it_b, (float*)XC, K2, HD, HD, 2, 1);
  {
    const int mn = K2 * HD;
    const int rg = (mn + 255) / 256;
    const dim3 gSkin(CSPLIT, HD / 64, 11);
    const size_t psX = (size_t)HD * PLD;
    // T = S @ XC
    split_planesT<<<dim3((PLD + 31) / 32, (HD + 31) / 32), 256, 0, stream>>>(
        XC, K2, HD, ST, HD, PLD, psX);
    cmm_bf16_sk<<<gSkin, 256, 0, stream>>>(SA, PPS, PLD, ST, psX, PLD, PART, K2, HD, PLD, chF);
    creduce<<<rg, 256, 0, stream>>>(PART, EVO, mn, HD, CSPLIT, 0.f, nullptr, 0.f, nullptr, 0.f);
    // EVO = S @ T (reuse SA = S planes)
    split_planesT<<<dim3((PLD + 31) / 32, (HD + 31) / 32), 256, 0, stream>>>(
        EVO, K2, HD, ST, HD, PLD, psX);
    cmm_bf16_sk<<<gSkin, 256, 0, stream>>>(SA, PPS, PLD, ST, psX, PLD, PART, K2, HD, PLD, chF);
    creduce<<<rg, 256, 0, stream>>>(PART, EVO, mn, HD, CSPLIT, 0.f, nullptr, 0.f, nullptr, 0.f);
    // AGG0 planes directly from graph gather (no fp32 intermediate)
    const size_t psG = (size_t)PLD * HD;
    agg_gather_split<<<PLD, 256, 0, stream>>>(COFF, CSRC, EVO, SA, psG, HD, K2);
    // W = msg_wr + i*msg_wi, transposed-split directly from the two real mats
    split_planesT2<<<dim3((HD + 31) / 32, (HD + 31) / 32), 256, 0, stream>>>(
        msg_wr, msg_wi, HD, HD, ST, HD, HD, (size_t)HD * HD);
    cmm_bf16_sk<<<gSkin, 256, 0, stream>>>(SA, psG, HD, ST, (size_t)HD * HD, HD, PART,
                                           K2, HD, HD, sk_chunk32(HD, CSPLIT));
    creduce<<<rg, 256, 0, stream>>>(PART, AGG1, mn, HD, CSPLIT, 0.f, nullptr, 0.f, nullptr, 0.f);
  }
  // magph overwrites the CSR slot — CSR dead now.
  magph<<<(K2 * HD + 255) / 256, 256, 0, stream>>>(AGG1, XRb, XIb, MAGB, PHB, K2 * HD);
  col_mean<<<HD, 256, 0, stream>>>(MAGB, GM, K2, HD);
  col_mean<<<HD, 256, 0, stream>>>(PHB, GP, K2, HD);

  // ---------- classifier heads ----------
  vecmat<1><<<1, 256, 0, stream>>>(GM, mc1_w, mc1_b, HM, HD, HD / 2);
  vecmat<0><<<1, 256, 0, stream>>>(HM, mc2_w, mc2_b, LM, HD / 2, NC);
  vecmat<1><<<1, 256, 0, stream>>>(GP, pc1_w, pc1_b, HP, HD, HD / 2);
  vecmat<0><<<1, 256, 0, stream>>>(HP, pc2_w, pc2_b, LP, HD / 2, NC);
  add_out<<<1, 64, 0, stream>>>(LM, LP, (float*)d_out, NC);
}

// Round 10
// 1091.209 us; speedup vs baseline: 13.5582x; 1.0603x over previous
//
#include <hip/hip_runtime.h>
#include <cstddef>
#include <utility>

// ---------------- problem constants ----------------
constexpr int N0  = 4096;
constexpr int E   = 65536;
constexpr int DIN = 128;
constexpr int HD  = 256;   // H
constexpr int NC  = 10;
constexpr int UHD = 64;    // UH
constexpr int K1  = 3277;  // ceil(0.8*4096)
constexpr int K2  = 656;   // ceil(0.2*3277)
constexpr int PMN = K2 * K2; // 430336

// expm(A): A = 2^5*B, deg-11 Taylor (PS) then 5 squarings; the 5th squaring
// is folded into the EVO product: EVO = S@(S@XC) with S = exp(A)^(1/2).
constexpr int EXPM_SQ = 4;   // explicit squarings

// MFMA plane geometry: 656 -> padded 704 = 11*64 = 22*32.
constexpr int PLD = 704;
constexpr size_t PPS = (size_t)PLD * PLD;

// Split-K. R9: 484 blocks = 1.9 blocks/CU = 2 waves/SIMD -> latency-bound
// (Occupancy 10.7%). CSPLIT=8 gives 968 blocks (~4 blocks/CU) and still one
// k-slice per XCD (z = blockIdx.x, CSPLIT | 8; slice ~1 MB < 4 MB L2).
constexpr int CSPLIT = 8;

// ---------------- workspace layout ----------------
#define F4(n) ((size_t)(n) * 4)
constexpr size_t O_H1    = 0;
constexpr size_t O_OUT1  = O_H1    + F4(N0 * HD);
constexpr size_t O_DEG1  = O_OUT1  + F4(N0 * HD);
constexpr size_t O_DIS1  = O_DEG1  + F4(N0);
constexpr size_t O_SC1   = O_DIS1  + F4(N0);
constexpr size_t O_PERM1 = O_SC1   + F4(N0);
constexpr size_t O_MAP1  = O_PERM1 + F4(N0);
constexpr size_t O_H1P   = O_MAP1  + F4(N0);
constexpr size_t O_SRC2  = O_H1P   + F4(K1 * HD);
constexpr size_t O_DST2  = O_SRC2  + F4(E);
constexpr size_t O_EM2   = O_DST2  + F4(E);
constexpr size_t O_H2    = O_EM2   + F4(E);
constexpr size_t O_OUT2  = O_H2    + F4(K1 * HD);
constexpr size_t O_DEG2  = O_OUT2  + F4(K1 * HD);
constexpr size_t O_DIS2  = O_DEG2  + F4(N0);
constexpr size_t O_SC2   = O_DIS2  + F4(N0);
constexpr size_t O_PERM2 = O_SC2   + F4(N0);
constexpr size_t O_MAP2  = O_PERM2 + F4(N0);
constexpr size_t O_H2P   = O_MAP2  + F4(N0);
constexpr size_t O_SRC3  = O_H2P   + F4(K2 * HD);
constexpr size_t O_DST3  = O_SRC3  + F4(E);
constexpr size_t O_EM3   = O_DST3  + F4(E);
constexpr size_t O_XR    = O_EM3   + F4(E);
constexpr size_t O_XI    = O_XR    + F4(K2 * HD);
constexpr size_t O_DEG3  = O_XI    + F4(K2 * HD);
constexpr size_t O_DIS3  = O_DEG3  + F4(1024);
constexpr size_t O_SCOEF = O_DIS3  + F4(1024);
constexpr size_t O_XG1   = O_SCOEF + F4(1024);
constexpr size_t O_XG2H  = O_XG1   + F4(K2 * UHD);
constexpr size_t O_XG2   = O_XG2H  + F4(K2 * UHD);
constexpr size_t O_EMB   = O_XG2   + F4(K2 * UHD);
constexpr size_t O_T1    = O_EMB   + F4(64);
constexpr size_t O_T2    = O_T1    + F4(64);
constexpr size_t O_NORM  = O_T2    + F4(64);
constexpr size_t O_PM    = O_NORM  + F4(64);
constexpr size_t O_BM    = O_PM    + F4(PMN);          // float2
constexpr size_t O_P0    = O_BM    + F4(PMN) * 2;      // float2
constexpr size_t O_P1    = O_P0    + F4(PMN) * 2;      // float2
constexpr size_t O_XRT   = O_P1    + F4(PMN) * 2;
constexpr size_t O_XIT   = O_XRT   + F4(K2 * HD);
constexpr size_t O_XC    = O_XIT   + F4(K2 * HD);      // float2
constexpr size_t O_EVO   = O_XC    + F4(K2 * HD) * 2;  // float2
constexpr size_t O_AGG0  = O_EVO   + F4(K2 * HD) * 2;  // float2
constexpr size_t O_WC    = O_AGG0  + F4(K2 * HD) * 2;  // float2 256x256
constexpr size_t O_AGG1  = O_WC    + F4(HD * HD) * 2;  // float2
constexpr size_t O_MAG   = O_AGG1  + F4(K2 * HD) * 2;
constexpr size_t O_PH    = O_MAG   + F4(K2 * HD);
constexpr size_t O_GM    = O_PH    + F4(K2 * HD);
constexpr size_t O_GP    = O_GM    + F4(256);
constexpr size_t O_HM    = O_GP    + F4(256);
constexpr size_t O_HP    = O_HM    + F4(256);
constexpr size_t O_LM    = O_HP    + F4(256);
constexpr size_t O_LP    = O_LM    + F4(64);
constexpr size_t WS_NEED = O_LP    + F4(64);

// SA/ST bf16 plane sets in the dead stage-A/B region (below O_SRC3, dead
// before the expm phase).
constexpr size_t O_SA = 0;
constexpr size_t O_ST = O_SA + PPS * 2 * 4;
static_assert(O_ST + PPS * 2 * 4 <= O_SRC3, "SA/ST must fit in dead region");

// B2/B3 fp32 (PS powers) alias XRT..AGG1 (written only post-expm).
constexpr size_t O_B2 = O_XRT;
constexpr size_t O_B3 = O_B2 + F4(PMN) * 2;
static_assert(O_B3 + F4(PMN) * 2 <= O_MAG, "B2/B3 must fit in XRT..AGG1 region");

// CSR slot in the MAG/PH region (written only by magph, after last CSR use).
constexpr size_t O_CSR_OFF = O_MAG;                 // (N0+1) ints
constexpr size_t O_CSR_CUR = O_CSR_OFF + F4(4104);
constexpr size_t O_CSR_SRC = O_CSR_CUR + F4(4104);  // E ints
constexpr size_t O_CSR_CF  = O_CSR_SRC + F4(E);     // E floats
static_assert(O_CSR_CF + F4(E) <= O_GM, "CSR must fit in MAG/PH region");

// Extension region past WS_NEED (harness ws_size ~268 MB; runtime-guarded).
constexpr size_t O_PARTX  = (WS_NEED + 255) & ~(size_t)255;
constexpr size_t PART_SZ  = (size_t)CSPLIT * PMN * 8;   // 27.5 MB
constexpr size_t WS_TOTAL = O_PARTX + PART_SZ;

// ---------------- bf16 helpers ----------------
typedef __attribute__((ext_vector_type(8))) short s8v;   // 8 bf16 (4 VGPRs)
typedef __attribute__((ext_vector_type(4))) float f4v;   // MFMA acc

__device__ inline unsigned short f2bf(float x) {
  unsigned u = __float_as_uint(x);
  u += 0x7FFFu + ((u >> 16) & 1u);
  return (unsigned short)(u >> 16);
}
__device__ inline float bf2f(unsigned short h) {
  return __uint_as_float(((unsigned)h) << 16);
}
__device__ inline void split4(float re, float im, unsigned short* out,
                              size_t ps, size_t o) {
  unsigned short rh = f2bf(re);
  unsigned short rl = f2bf(re - bf2f(rh));
  unsigned short ih = f2bf(im);
  unsigned short il = f2bf(im - bf2f(ih));
  out[o] = rh; out[ps + o] = rl; out[2 * ps + o] = ih; out[3 * ps + o] = il;
}

// ---------------- kernels ----------------

// real GEMM fp32 (pool-score path stays fp32 for exact top-k ordering).
// CS/CO: output written to C[(r*N+c)*CS + CO] (CS=2 interleaves into float2).
template <int ACT>
__global__ void rmm64(const float* __restrict__ A, const float* __restrict__ B,
                      const float* __restrict__ bias, float* __restrict__ C,
                      int M, int N, int K, int CS, int CO) {
  __shared__ float As[64][17];
  __shared__ float Bs[16][64];
  int t  = threadIdx.x;
  int tx = t & 15, ty = t >> 4;
  int bm = blockIdx.y * 64, bn = blockIdx.x * 64;
  float acc[4][4] = {};
  for (int kt = 0; kt < K; kt += 16) {
#pragma unroll
    for (int i = 0; i < 4; i++) {
      int l = t + i * 256;
      int kk = l & 15, mm = l >> 4;
      int gr = bm + mm;
      As[mm][kk] = (gr < M) ? A[(size_t)gr * K + kt + kk] : 0.f;
    }
#pragma unroll
    for (int i = 0; i < 4; i++) {
      int l = t + i * 256;
      int cc = l & 63, kk = l >> 6;
      int gc = bn + cc;
      Bs[kk][cc] = (gc < N) ? B[(size_t)(kt + kk) * N + gc] : 0.f;
    }
    __syncthreads();
#pragma unroll
    for (int kk = 0; kk < 16; kk++) {
      float a[4], b[4];
#pragma unroll
      for (int i = 0; i < 4; i++) a[i] = As[ty + 16 * i][kk];
#pragma unroll
      for (int j = 0; j < 4; j++) b[j] = Bs[kk][tx + 16 * j];
#pragma unroll
      for (int i = 0; i < 4; i++)
#pragma unroll
        for (int j = 0; j < 4; j++) acc[i][j] += a[i] * b[j];
    }
    __syncthreads();
  }
#pragma unroll
  for (int i = 0; i < 4; i++) {
    int r = bm + ty + 16 * i;
    if (r >= M) continue;
#pragma unroll
    for (int j = 0; j < 4; j++) {
      int c = bn + tx + 16 * j;
      if (c >= N) continue;
      float v = acc[i][j] + (bias ? bias[c] : 0.f);
      if (ACT == 1) v = fmaxf(v, 0.f);
      C[((size_t)r * N + c) * CS + CO] = v;
    }
  }
}

// Split complex fp32 -> 4 bf16 planes [row][col], zero-pad.
__global__ void split_planes(const float2* __restrict__ in, int inM, int inN,
                             unsigned short* __restrict__ out, int padR, int ld,
                             size_t ps) {
  int idx = blockIdx.x * 256 + threadIdx.x;
  if (idx >= padR * ld) return;
  int r = idx / ld, c = idx - r * ld;
  float re = 0.f, im = 0.f;
  if (r < inM && c < inN) { float2 v = in[(size_t)r * inN + c]; re = v.x; im = v.y; }
  split4(re, im, out, ps, idx);
}

// Transposed split: out[n*ld + k] = split(in[k][n]); tiled via LDS.
__global__ void split_planesT(const float2* __restrict__ in, int inM, int inN,
                              unsigned short* __restrict__ out, int padR, int ld,
                              size_t ps) {
  __shared__ float2 tile[32][33];
  int tx = threadIdx.x & 31, ty = threadIdx.x >> 5;   // 32 x 8
  int k0 = blockIdx.x * 32, n0 = blockIdx.y * 32;
  for (int i = ty; i < 32; i += 8) {
    int k = k0 + i, n = n0 + tx;
    tile[i][tx] = (k < inM && n < inN) ? in[(size_t)k * inN + n]
                                       : make_float2(0.f, 0.f);
  }
  __syncthreads();
  for (int i = ty; i < 32; i += 8) {
    int n = n0 + i, k = k0 + tx;
    if (n < padR && k < ld)
      split4(tile[tx][i].x, tile[tx][i].y, out, ps, (size_t)n * ld + k);
  }
}

// Transposed split from two real fp32 matrices (re, im): W = re + i*im.
__global__ void split_planesT2(const float* __restrict__ re, const float* __restrict__ im,
                               int inM, int inN, unsigned short* __restrict__ out,
                               int padR, int ld, size_t ps) {
  __shared__ float2 tile[32][33];
  int tx = threadIdx.x & 31, ty = threadIdx.x >> 5;
  int k0 = blockIdx.x * 32, n0 = blockIdx.y * 32;
  for (int i = ty; i < 32; i += 8) {
    int k = k0 + i, n = n0 + tx;
    tile[i][tx] = (k < inM && n < inN)
        ? make_float2(re[(size_t)k * inN + n], im[(size_t)k * inN + n])
        : make_float2(0.f, 0.f);
  }
  __syncthreads();
  for (int i = ty; i < 32; i += 8) {
    int n = n0 + i, k = k0 + tx;
    if (n < padR && k < ld)
      split4(tile[tx][i].x, tile[tx][i].y, out, ps, (size_t)n * ld + k);
  }
}

// Split-K complex MFMA GEMM with register double-buffer prefetch.
// z = blockIdx.x (fastest linear dim -> XCD k-slice affinity, CSPLIT | 8).
__global__ __launch_bounds__(256, 2) void cmm_bf16_sk(
    const unsigned short* __restrict__ SA, size_t psA, int ldA,
    const unsigned short* __restrict__ ST, size_t psT, int ldT,
    float2* __restrict__ Part, int M, int N, int Kp, int chunk) {
  int k0 = blockIdx.x * chunk;
  int kend = min(Kp, k0 + chunk);
  int t = threadIdx.x;
  int wave = t >> 6, lane = t & 63;
  int quad = lane >> 4, mn = lane & 15;
  int rowA = blockIdx.z * 64 + wave * 16 + mn;
  int bn = blockIdx.y * 64;
  const unsigned short* a0 = SA + (size_t)rowA * ldA;
  f4v accR[4], accI[4];
#pragma unroll
  for (int i = 0; i < 4; i++) {
    accR[i] = (f4v){0.f, 0.f, 0.f, 0.f};
    accI[i] = (f4v){0.f, 0.f, 0.f, 0.f};
  }
  s8v cA[4], cB[4][4], nA[4], nB[4][4];
  {
    int ka = k0 + quad * 8;
#pragma unroll
    for (int p = 0; p < 4; p++) cA[p] = *(const s8v*)(a0 + p * psA + ka);
#pragma unroll
    for (int tl = 0; tl < 4; tl++) {
      const unsigned short* b0 = ST + (size_t)(bn + tl * 16 + mn) * ldT + ka;
#pragma unroll
      for (int p = 0; p < 4; p++) cB[tl][p] = *(const s8v*)(b0 + p * psT);
    }
  }
  for (int kt = k0; kt < kend; kt += 32) {
    int kn = kt + 32;
    if (kn < kend) {
      int ka = kn + quad * 8;
#pragma unroll
      for (int p = 0; p < 4; p++) nA[p] = *(const s8v*)(a0 + p * psA + ka);
#pragma unroll
      for (int tl = 0; tl < 4; tl++) {
        const unsigned short* b0 = ST + (size_t)(bn + tl * 16 + mn) * ldT + ka;
#pragma unroll
        for (int p = 0; p < 4; p++) nB[tl][p] = *(const s8v*)(b0 + p * psT);
      }
    }
    s8v nih, nil_;
#pragma unroll
    for (int q = 0; q < 8; q++) {
      nih[q]  = (short)(cA[2][q] ^ (short)0x8000);   // -ai
      nil_[q] = (short)(cA[3][q] ^ (short)0x8000);
    }
#pragma unroll
    for (int tl = 0; tl < 4; tl++) {
      f4v r = accR[tl];
      r = __builtin_amdgcn_mfma_f32_16x16x32_bf16(cA[0], cB[tl][0], r, 0, 0, 0);
      r = __builtin_amdgcn_mfma_f32_16x16x32_bf16(cA[1], cB[tl][0], r, 0, 0, 0);
      r = __builtin_amdgcn_mfma_f32_16x16x32_bf16(cA[0], cB[tl][1], r, 0, 0, 0);
      r = __builtin_amdgcn_mfma_f32_16x16x32_bf16(nih, cB[tl][2], r, 0, 0, 0);
      r = __builtin_amdgcn_mfma_f32_16x16x32_bf16(nil_, cB[tl][2], r, 0, 0, 0);
      r = __builtin_amdgcn_mfma_f32_16x16x32_bf16(nih, cB[tl][3], r, 0, 0, 0);
      accR[tl] = r;
      f4v im = accI[tl];
      im = __builtin_amdgcn_mfma_f32_16x16x32_bf16(cA[0], cB[tl][2], im, 0, 0, 0);
      im = __builtin_amdgcn_mfma_f32_16x16x32_bf16(cA[1], cB[tl][2], im, 0, 0, 0);
      im = __builtin_amdgcn_mfma_f32_16x16x32_bf16(cA[0], cB[tl][3], im, 0, 0, 0);
      im = __builtin_amdgcn_mfma_f32_16x16x32_bf16(cA[2], cB[tl][0], im, 0, 0, 0);
      im = __builtin_amdgcn_mfma_f32_16x16x32_bf16(cA[3], cB[tl][0], im, 0, 0, 0);
      im = __builtin_amdgcn_mfma_f32_16x16x32_bf16(cA[2], cB[tl][1], im, 0, 0, 0);
      accI[tl] = im;
    }
    if (kn < kend) {
#pragma unroll
      for (int p = 0; p < 4; p++) cA[p] = nA[p];
#pragma unroll
      for (int tl = 0; tl < 4; tl++)
#pragma unroll
        for (int p = 0; p < 4; p++) cB[tl][p] = nB[tl][p];
    }
  }
  float2* P = Part + (size_t)blockIdx.x * M * N;
#pragma unroll
  for (int tl = 0; tl < 4; tl++) {
    int col = bn + tl * 16 + mn;
    if (col >= N) continue;
#pragma unroll
    for (int r = 0; r < 4; r++) {
      int row = blockIdx.z * 64 + wave * 16 + quad * 4 + r;
      if (row >= M) continue;
      P[(size_t)row * N + col] = make_float2(accR[tl][r], accI[tl][r]);
    }
  }
}

// Plain reduce: C = sum_z Part[z] + e0*I + e1*E1 + e2*E2.
__global__ void creduce(const float2* __restrict__ Part, float2* __restrict__ C,
                        int MN, int N, int S, float e0,
                        const float2* __restrict__ E1, float e1,
                        const float2* __restrict__ E2, float e2) {
  int idx = blockIdx.x * 256 + threadIdx.x;
  if (idx >= MN) return;
  float sr = 0.f, si = 0.f;
  for (int z = 0; z < S; z++) {
    float2 p = Part[(size_t)z * MN + idx];
    sr += p.x;
    si += p.y;
  }
  if (e0 != 0.f) {
    int r = idx / N;
    if (idx - r * N == r) sr += e0;
  }
  if (E1) { float2 b = E1[idx]; sr += e1 * b.x; si += e1 * b.y; }
  if (E2) { float2 b = E2[idx]; sr += e2 * b.x; si += e2 * b.y; }
  C[idx] = make_float2(sr, si);
}

// Fused reduce + epilogue + bf16 plane split (SA layout [row][k]).
__global__ void creduce_split(const float2* __restrict__ Part, float2* __restrict__ C,
                              unsigned short* __restrict__ planes, size_t ps,
                              int M, int N, int padR, int ld, int S, float e0,
                              const float2* __restrict__ E1, float e1,
                              const float2* __restrict__ E2, float e2) {
  int idx = blockIdx.x * 256 + threadIdx.x;
  if (idx >= padR * ld) return;
  int r = idx / ld, c = idx - r * ld;
  float sr = 0.f, si = 0.f;
  if (r < M && c < N) {
    size_t o = (size_t)r * N + c;
    size_t MN = (size_t)M * N;
    for (int z = 0; z < S; z++) {
      float2 p = Part[z * MN + o];
      sr += p.x;
      si += p.y;
    }
    if (e0 != 0.f && r == c) sr += e0;
    if (E1) { float2 b = E1[o]; sr += e1 * b.x; si += e1 * b.y; }
    if (E2) { float2 b = E2[o]; sr += e2 * b.x; si += e2 * b.y; }
    C[o] = make_float2(sr, si);
  }
  split4(sr, si, planes, ps, idx);
}

// D3 = e0*I + e1*B + e2*B2, fp32 out + bf16 planes (SA layout).
__global__ void combo3_split(const float2* __restrict__ Bp, const float2* __restrict__ B2p,
                             float2* __restrict__ Out, unsigned short* __restrict__ planes,
                             size_t ps, int M, int N, int padR, int ld,
                             float e0, float e1, float e2) {
  int idx = blockIdx.x * 256 + threadIdx.x;
  if (idx >= padR * ld) return;
  int r = idx / ld, c = idx - r * ld;
  float sr = 0.f, si = 0.f;
  if (r < M && c < N) {
    size_t o = (size_t)r * N + c;
    float2 b = Bp[o], b2 = B2p[o];
    sr = e1 * b.x + e2 * b2.x;
    si = e1 * b.y + e2 * b2.y;
    if (r == c) sr += e0;
    Out[o] = make_float2(sr, si);
  }
  split4(sr, si, planes, ps, idx);
}

// ---- CSR build ----
__global__ void hist_edges(const int* __restrict__ dst, const float* __restrict__ em,
                           int* __restrict__ cnt) {
  int e = blockIdx.x * 256 + threadIdx.x;
  if (e >= E) return;
  float m = em ? em[e] : 1.0f;
  if (m != 0.f) atomicAdd(&cnt[dst[e]], 1);
}

// Exclusive scan of cnt -> off/cur, plus dis[i] = rsqrt(cnt[i]+1). 1 block.
__global__ __launch_bounds__(1024) void scan_offsets(const int* __restrict__ cnt, int n,
                                                     int* __restrict__ off,
                                                     int* __restrict__ cur,
                                                     float* __restrict__ dis) {
  __shared__ int sums[1024];
  int t = threadIdx.x;
  int base = t * 4;
  int v[4];
  int s = 0;
#pragma unroll
  for (int j = 0; j < 4; j++) {
    int i = base + j;
    int ci = (i < n) ? cnt[i] : 0;
    if (i < n) dis[i] = 1.0f / sqrtf((float)ci + 1.0f);
    v[j] = s;
    s += ci;
  }
  sums[t] = s;
  __syncthreads();
  for (int d = 1; d < 1024; d <<= 1) {
    int x = (t >= d) ? sums[t - d] : 0;
    __syncthreads();
    sums[t] += x;
    __syncthreads();
  }
  int pre = (t > 0) ? sums[t - 1] : 0;
#pragma unroll
  for (int j = 0; j < 4; j++) {
    int i = base + j;
    if (i < n) { int o = pre + v[j]; off[i] = o; cur[i] = o; }
  }
  if (t == 1023) off[n] = sums[1023];
}

__global__ void fill_edges(const int* __restrict__ src, const int* __restrict__ dst,
                           const float* __restrict__ em, const float* __restrict__ dis,
                           int* __restrict__ cur, int* __restrict__ esrc,
                           float* __restrict__ ecoef) {
  int e = blockIdx.x * 256 + threadIdx.x;
  if (e >= E) return;
  float m = em ? em[e] : 1.0f;
  if (m == 0.f) return;
  int s = src[e], d = dst[e];
  int pos = atomicAdd(&cur[d], 1);
  esrc[pos] = s;
  ecoef[pos] = dis[s] * dis[d];
}

// Fused GCN aggregate + self-loop + bias (+relu), gather form.
template <int ACT>
__global__ void gcn_gather(const int* __restrict__ off, const int* __restrict__ esrc,
                           const float* __restrict__ ecoef, const float* __restrict__ Hm,
                           const float* __restrict__ dis, const float* __restrict__ bias,
                           float* __restrict__ out, int F) {
  int i = blockIdx.x;
  int e0 = off[i], e1 = off[i + 1];
  float d2 = dis[i] * dis[i];
  for (int f = threadIdx.x; f < F; f += blockDim.x) {
    float acc = d2 * Hm[(size_t)i * F + f] + bias[f];
    for (int e = e0; e < e1; e++)
      acc += ecoef[e] * Hm[(size_t)esrc[e] * F + f];
    if (ACT == 1) acc = fmaxf(acc, 0.f);
    out[(size_t)i * F + f] = acc;
  }
}

// enc1 with scoef fused: one wave per node; butterfly-reduce bucket sum.
__global__ void enc1_fused(const int* __restrict__ off, const float* __restrict__ ecoef,
                           const float* __restrict__ dis, const float* __restrict__ w,
                           const float* __restrict__ b, float* __restrict__ xg1) {
  int i = blockIdx.x;
  int lane = threadIdx.x;   // 64 = one wave
  float s = 0.f;
  for (int e = off[i] + lane; e < off[i + 1]; e += 64) s += ecoef[e];
#pragma unroll
  for (int d = 32; d > 0; d >>= 1) s += __shfl_xor(s, d, 64);
  float sc = s + dis[i] * dis[i];
  xg1[(size_t)i * UHD + lane] = fmaxf(sc * w[lane] + b[lane], 0.f);
}

// Gather of EVO over graph3 fused with bf16 plane split (SA layout [row][k]).
__global__ void agg_gather_split(const int* __restrict__ off, const int* __restrict__ esrc,
                                 const float2* __restrict__ evo,
                                 unsigned short* __restrict__ planes, size_t ps,
                                 int F, int M) {
  int i = blockIdx.x;
  if (i >= M) {
    for (int f = threadIdx.x; f < F; f += blockDim.x)
      split4(0.f, 0.f, planes, ps, (size_t)i * F + f);
    return;
  }
  int e0 = off[i], e1 = off[i + 1];
  for (int f = threadIdx.x; f < F; f += blockDim.x) {
    float sr = 0.f, si = 0.f;
    for (int e = e0; e < e1; e++) {
      float2 v = evo[(size_t)esrc[e] * F + f];
      sr += v.x;
      si += v.y;
    }
    split4(sr, si, planes, ps, (size_t)i * F + f);
  }
}

__global__ void wnorm(const float* __restrict__ w, int n, float* __restrict__ out) {
  __shared__ float red[256];
  float s = 0.f;
  for (int k = threadIdx.x; k < n; k += 256) s += w[k] * w[k];
  red[threadIdx.x] = s;
  __syncthreads();
  for (int off = 128; off > 0; off >>= 1) {
    if (threadIdx.x < off) red[threadIdx.x] += red[threadIdx.x + off];
    __syncthreads();
  }
  if (threadIdx.x == 0) out[0] = sqrtf(red[0]);
}

__global__ void rowdot(const float* __restrict__ X, const float* __restrict__ w,
                       float* __restrict__ out, int F) {
  int i = blockIdx.x;
  __shared__ float red[256];
  float s = 0.f;
  for (int f = threadIdx.x; f < F; f += 256) s += X[(size_t)i * F + f] * w[f];
  red[threadIdx.x] = s;
  __syncthreads();
  for (int off = 128; off > 0; off >>= 1) {
    if (threadIdx.x < off) red[threadIdx.x] += red[threadIdx.x + off];
    __syncthreads();
  }
  if (threadIdx.x == 0) out[i] = red[0];
}

// Exact-total-order descending bitonic sort. Epilogue also writes the full
// node->rank map (rank if kept, -1 otherwise — every real node appears exactly
// once in the sorted keys, so no memset needed) and zeroes the next stage's
// CNT array (R10: kills 2 memsets + set_map per pool stage).
__global__ __launch_bounds__(1024) void bitonic_topk(const float* __restrict__ score,
                                                     int n, int* __restrict__ perm, int k,
                                                     int* __restrict__ map,
                                                     int* __restrict__ cntz, int ncnt) {
  __shared__ unsigned long long keys[4096];
  int t = threadIdx.x;
  for (int i = t; i < 4096; i += 1024) {
    unsigned long long kk = 0ull;
    if (i < n) {
      float f = score[i];
      unsigned u = __float_as_uint(f);
      u = (f >= 0.0f) ? (u | 0x80000000u) : ~u;
      kk = ((unsigned long long)u << 32) | (unsigned)(~(unsigned)i);
    }
    keys[i] = kk;
  }
  __syncthreads();
  for (int size = 2; size <= 4096; size <<= 1) {
    for (int stride = size >> 1; stride > 0; stride >>= 1) {
      for (int i = t; i < 2048; i += 1024) {
        int pos = ((i & ~(stride - 1)) << 1) | (i & (stride - 1));
        int partner = pos + stride;
        bool desc = (pos & size) == 0;
        unsigned long long a = keys[pos], b = keys[partner];
        if ((a < b) == desc) { keys[pos] = b; keys[partner] = a; }
      }
      __syncthreads();
    }
  }
  for (int i = t; i < 4096; i += 1024) {
    int idx = (int)(~(unsigned)(keys[i] & 0xFFFFFFFFull));
    if (idx >= 0) map[idx] = (i < k) ? i : -1;   // padding slots decode to -1
    if (i < k) perm[i] = idx;
  }
  for (int i = t; i < ncnt; i += 1024) cntz[i] = 0;
}

__global__ void pool_gather(const float* __restrict__ X, const int* __restrict__ perm,
                            const float* __restrict__ dot, const float* __restrict__ normbuf,
                            float* __restrict__ Xn, int F) {
  int i = blockIdx.x;
  int p = perm[i];
  float sc = tanhf(dot[p] / normbuf[0]);
  for (int f = threadIdx.x; f < F; f += blockDim.x)
    Xn[(size_t)i * F + f] = X[(size_t)p * F + f] * sc;
}

// Fused remap + histogram of remapped dst (cnt must be pre-zeroed).
__global__ void remap_hist(const int* __restrict__ srcIn, const int* __restrict__ dstIn,
                           const float* __restrict__ emIn, const int* __restrict__ map,
                           int* __restrict__ srcOut, int* __restrict__ dstOut,
                           float* __restrict__ emOut, int* __restrict__ cnt) {
  int e = blockIdx.x * 256 + threadIdx.x;
  if (e >= E) return;
  int ns = map[srcIn[e]], nd = map[dstIn[e]];
  float m = emIn ? emIn[e] : 1.0f;
  if (ns < 0 || nd < 0) m = 0.f;
  srcOut[e] = ns < 0 ? 0 : ns;
  dstOut[e] = nd < 0 ? 0 : nd;
  emOut[e] = m;
  if (m != 0.f) atomicAdd(&cnt[nd], 1);
}

__global__ void col_mean(const float* __restrict__ X, float* __restrict__ out,
                         int rows, int cols) {
  int c = blockIdx.x;
  __shared__ float red[256];
  float s = 0.f;
  for (int r = threadIdx.x; r < rows; r += 256) s += X[(size_t)r * cols + c];
  red[threadIdx.x] = s;
  __syncthreads();
  for (int off = 128; off > 0; off >>= 1) {
    if (threadIdx.x < off) red[threadIdx.x] += red[threadIdx.x + off];
    __syncthreads();
  }
  if (threadIdx.x == 0) out[c] = red[0] / (float)rows;
}

template <int ACT>
__global__ void vecmat(const float* __restrict__ v, const float* __restrict__ W,
                       const float* __restrict__ b, float* __restrict__ out,
                       int Kdim, int Ndim) {
  __shared__ float vs[256];
  for (int k = threadIdx.x; k < Kdim; k += blockDim.x) vs[k] = v[k];
  __syncthreads();
  for (int j = threadIdx.x; j < Ndim; j += blockDim.x) {
    float acc = b ? b[j] : 0.f;
    for (int k = 0; k < Kdim; k++) acc += vs[k] * W[(size_t)k * Ndim + j];
    out[j] = (ACT == 1) ? fmaxf(acc, 0.f) : acc;
  }
}

__global__ void vecmat_tanh_wide(const float* __restrict__ v, const float* __restrict__ W,
                                 const float* __restrict__ b, float* __restrict__ out,
                                 int Kdim, int Ndim) {
  __shared__ float vs[64];
  if (threadIdx.x < Kdim) vs[threadIdx.x] = v[threadIdx.x];
  __syncthreads();
  int j = blockIdx.x * 256 + threadIdx.x;
  if (j >= Ndim) return;
  float acc = b[j];
  for (int k = 0; k < Kdim; k++) acc += vs[k] * W[(size_t)k * Ndim + j];
  out[j] = tanhf(acc);
}

__global__ void build_B(const float* __restrict__ pm, float2* __restrict__ Bm,
                        int n, float scale) {
  int idx = blockIdx.x * 256 + threadIdx.x;
  if (idx >= n * n) return;
  int r = idx / n, c = idx - r * n;
  float pij = pm[(size_t)r * n + c];
  float pji = pm[(size_t)c * n + r];
  Bm[idx] = make_float2(scale * (pij - pji), scale * (pij + pji));
}

__global__ void magph(const float2* __restrict__ agg, const float* __restrict__ xr,
                      const float* __restrict__ xi, float* __restrict__ mag,
                      float* __restrict__ ph, int n) {
  int idx = blockIdx.x * 256 + threadIdx.x;
  if (idx >= n) return;
  float2 a = agg[idx];
  float r = a.x + xr[idx];
  float im = a.y + xi[idx];
  mag[idx] = sqrtf(r * r + im * im);
  ph[idx] = atan2f(im, r);
}

// Fused classifier heads: out = (relu(GM@mc1+b)@mc2+b) + (relu(GP@pc1+b)@pc2+b).
// One block; replaces 4 vecmats + add_out (R10 dispatch-tail cut).
__global__ __launch_bounds__(256) void heads_fused(
    const float* __restrict__ GM, const float* __restrict__ GP,
    const float* __restrict__ mc1_w, const float* __restrict__ mc1_b,
    const float* __restrict__ mc2_w, const float* __restrict__ mc2_b,
    const float* __restrict__ pc1_w, const float* __restrict__ pc1_b,
    const float* __restrict__ pc2_w, const float* __restrict__ pc2_b,
    float* __restrict__ out) {
  __shared__ float g[256], h[128], acc[NC];
  int t = threadIdx.x;
  if (t < NC) acc[t] = 0.f;
  for (int pass = 0; pass < 2; pass++) {
    const float* gv = pass ? GP : GM;
    const float* w1 = pass ? pc1_w : mc1_w;
    const float* b1 = pass ? pc1_b : mc1_b;
    const float* w2 = pass ? pc2_w : mc2_w;
    const float* b2 = pass ? pc2_b : mc2_b;
    g[t] = gv[t];
    __syncthreads();
    if (t < 128) {
      float s = b1[t];
      for (int k = 0; k < 256; k++) s += g[k] * w1[(size_t)k * 128 + t];
      h[t] = fmaxf(s, 0.f);
    }
    __syncthreads();
    if (t < NC) {
      float s = b2[t];
      for (int k = 0; k < 128; k++) s += h[k] * w2[(size_t)k * NC + t];
      acc[t] += s;
    }
    __syncthreads();
  }
  if (t < NC) out[t] = acc[t];
}

// ---------------- host helpers ----------------
static inline int sk_chunk32(int K, int S) { return (((K + S - 1) / S) + 31) & ~31; }

// ---------------- host ----------------
extern "C" void kernel_launch(void* const* d_in, const int* in_sizes, int n_in,
                              void* d_out, int out_size, void* d_ws, size_t ws_size,
                              hipStream_t stream) {
  if (ws_size < WS_TOTAL) return;

  const float* x       = (const float*)d_in[0];
  const int*   ei      = (const int*)d_in[1];
  const float* gcn1_w  = (const float*)d_in[2];
  const float* gcn1_b  = (const float*)d_in[3];
  const float* pool1_w = (const float*)d_in[4];
  const float* gcn2_w  = (const float*)d_in[5];
  const float* gcn2_b  = (const float*)d_in[6];
  const float* pool2_w = (const float*)d_in[7];
  const float* inr_w   = (const float*)d_in[8];
  const float* inr_b   = (const float*)d_in[9];
  const float* ini_w   = (const float*)d_in[10];
  const float* ini_b   = (const float*)d_in[11];
  const float* enc1_w  = (const float*)d_in[12];
  const float* enc1_b  = (const float*)d_in[13];
  const float* enc2_w  = (const float*)d_in[14];
  const float* enc2_b  = (const float*)d_in[15];
  const float* p1_w    = (const float*)d_in[16];
  const float* p1_b    = (const float*)d_in[17];
  const float* p2_w    = (const float*)d_in[18];
  const float* p2_b    = (const float*)d_in[19];
  const float* p3_w    = (const float*)d_in[20];
  const float* p3_b    = (const float*)d_in[21];
  const float* rt_w    = (const float*)d_in[22];
  const float* rt_b    = (const float*)d_in[23];
  const float* it_w    = (const float*)d_in[24];
  const float* it_b    = (const float*)d_in[25];
  const float* msg_wr  = (const float*)d_in[26];
  const float* msg_wi  = (const float*)d_in[27];
  const float* mc1_w   = (const float*)d_in[28];
  const float* mc1_b   = (const float*)d_in[29];
  const float* mc2_w   = (const float*)d_in[30];
  const float* mc2_b   = (const float*)d_in[31];
  const float* pc1_w   = (const float*)d_in[32];
  const float* pc1_b   = (const float*)d_in[33];
  const float* pc2_w   = (const float*)d_in[34];
  const float* pc2_b   = (const float*)d_in[35];

  char* ws = (char*)d_ws;
  float*  H1    = (float*)(ws + O_H1);
  float*  OUT1  = (float*)(ws + O_OUT1);
  int*    CNT1  = (int*)(ws + O_DEG1);
  float*  DIS1  = (float*)(ws + O_DIS1);
  float*  SC1   = (float*)(ws + O_SC1);
  int*    PERM1 = (int*)(ws + O_PERM1);
  int*    MAP1  = (int*)(ws + O_MAP1);
  float*  H1P   = (float*)(ws + O_H1P);
  int*    SRC2  = (int*)(ws + O_SRC2);
  int*    DST2  = (int*)(ws + O_DST2);
  float*  EM2   = (float*)(ws + O_EM2);
  float*  H2    = (float*)(ws + O_H2);
  float*  OUT2  = (float*)(ws + O_OUT2);
  int*    CNT2  = (int*)(ws + O_DEG2);
  float*  DIS2  = (float*)(ws + O_DIS2);
  float*  SC2   = (float*)(ws + O_SC2);
  int*    PERM2 = (int*)(ws + O_PERM2);
  int*    MAP2  = (int*)(ws + O_MAP2);
  float*  H2P   = (float*)(ws + O_H2P);
  int*    SRC3  = (int*)(ws + O_SRC3);
  int*    DST3  = (int*)(ws + O_DST3);
  float*  EM3   = (float*)(ws + O_EM3);
  float*  XRb   = (float*)(ws + O_XR);
  float*  XIb   = (float*)(ws + O_XI);
  int*    CNT3  = (int*)(ws + O_DEG3);
  float*  DIS3  = (float*)(ws + O_DIS3);
  float*  XG1   = (float*)(ws + O_XG1);
  float*  XG2H  = (float*)(ws + O_XG2H);
  float*  XG2   = (float*)(ws + O_XG2);
  float*  EMB   = (float*)(ws + O_EMB);
  float*  T1    = (float*)(ws + O_T1);
  float*  T2    = (float*)(ws + O_T2);
  float*  NORM  = (float*)(ws + O_NORM);
  float*  PMV   = (float*)(ws + O_PM);
  float2* BM    = (float2*)(ws + O_BM);
  float2* P0v   = (float2*)(ws + O_P0);
  float2* P1v   = (float2*)(ws + O_P1);
  float2* XC    = (float2*)(ws + O_XC);
  float2* EVO   = (float2*)(ws + O_EVO);
  float2* AGG1  = (float2*)(ws + O_AGG1);
  float*  MAGB  = (float*)(ws + O_MAG);
  float*  PHB   = (float*)(ws + O_PH);
  float*  GM    = (float*)(ws + O_GM);
  float*  GP    = (float*)(ws + O_GP);
  unsigned short* SA = (unsigned short*)(ws + O_SA);
  unsigned short* ST = (unsigned short*)(ws + O_ST);
  float2* PART  = (float2*)(ws + O_PARTX);
  float2* B2v   = (float2*)(ws + O_B2);
  float2* B3v   = (float2*)(ws + O_B3);
  int*    COFF  = (int*)(ws + O_CSR_OFF);
  int*    CCUR  = (int*)(ws + O_CSR_CUR);
  int*    CSRC  = (int*)(ws + O_CSR_SRC);
  float*  CCOEF = (float*)(ws + O_CSR_CF);

  const int* SRC1 = ei;
  const int* DST1 = ei + E;
  const int eg = E / 256;

  // ---------- Stage A: gcn1 (CSR gather) ----------
  rmm64<0><<<dim3(HD / 64, N0 / 64), 256, 0, stream>>>(x, gcn1_w, nullptr, H1, N0, HD, DIN, 1, 0);
  hipMemsetAsync(CNT1, 0, F4(N0), stream);
  hist_edges<<<eg, 256, 0, stream>>>(DST1, nullptr, CNT1);
  scan_offsets<<<1, 1024, 0, stream>>>(CNT1, N0, COFF, CCUR, DIS1);
  fill_edges<<<eg, 256, 0, stream>>>(SRC1, DST1, nullptr, DIS1, CCUR, CSRC, CCOEF);
  gcn_gather<1><<<N0, 256, 0, stream>>>(COFF, CSRC, CCOEF, H1, DIS1, gcn1_b, OUT1, HD);

  // ---------- pool1 (sort writes MAP1 fully + zeroes CNT2) ----------
  wnorm<<<1, 256, 0, stream>>>(pool1_w, HD, NORM);
  rowdot<<<N0, 256, 0, stream>>>(OUT1, pool1_w, SC1, HD);
  bitonic_topk<<<1, 1024, 0, stream>>>(SC1, N0, PERM1, K1, MAP1, CNT2, K1);
  pool_gather<<<K1, 256, 0, stream>>>(OUT1, PERM1, SC1, NORM, H1P, HD);
  remap_hist<<<eg, 256, 0, stream>>>(SRC1, DST1, nullptr, MAP1, SRC2, DST2, EM2, CNT2);

  // ---------- Stage C: gcn2 (CSR gather) ----------
  rmm64<0><<<dim3(HD / 64, (K1 + 63) / 64), 256, 0, stream>>>(H1P, gcn2_w, nullptr, H2, K1, HD, HD, 1, 0);
  scan_offsets<<<1, 1024, 0, stream>>>(CNT2, K1, COFF, CCUR, DIS2);
  fill_edges<<<eg, 256, 0, stream>>>(SRC2, DST2, EM2, DIS2, CCUR, CSRC, CCOEF);
  gcn_gather<1><<<K1, 256, 0, stream>>>(COFF, CSRC, CCOEF, H2, DIS2, gcn2_b, OUT2, HD);

  // ---------- pool2 (sort writes MAP2 + zeroes CNT3) ----------
  wnorm<<<1, 256, 0, stream>>>(pool2_w, HD, NORM + 1);
  rowdot<<<K1, 256, 0, stream>>>(OUT2, pool2_w, SC2, HD);
  bitonic_topk<<<1, 1024, 0, stream>>>(SC2, K1, PERM2, K2, MAP2, CNT3, K2);
  pool_gather<<<K2, 256, 0, stream>>>(OUT2, PERM2, SC2, NORM + 1, H2P, HD);
  remap_hist<<<eg, 256, 0, stream>>>(SRC2, DST2, EM2, MAP2, SRC3, DST3, EM3, CNT3);

  // ---------- xr / xi ----------
  rmm64<0><<<dim3(HD / 64, (K2 + 63) / 64), 256, 0, stream>>>(H2P, inr_w, inr_b, XRb, K2, HD, HD, 1, 0);
  rmm64<0><<<dim3(HD / 64, (K2 + 63) / 64), 256, 0, stream>>>(H2P, ini_w, ini_b, XIb, K2, HD, HD, 1, 0);

  // ---------- CSR3 (persists through expm; lives in MAG/PH region) ----------
  scan_offsets<<<1, 1024, 0, stream>>>(CNT3, K2, COFF, CCUR, DIS3);
  fill_edges<<<eg, 256, 0, stream>>>(SRC3, DST3, EM3, DIS3, CCUR, CSRC, CCOEF);

  // ---------- encoder GCNs on pooled graph ----------
  enc1_fused<<<K2, 64, 0, stream>>>(COFF, CCOEF, DIS3, enc1_w, enc1_b, XG1);
  rmm64<0><<<dim3(UHD / 64, (K2 + 63) / 64), 256, 0, stream>>>(XG1, enc2_w, nullptr, XG2H, K2, UHD, UHD, 1, 0);
  gcn_gather<0><<<K2, 64, 0, stream>>>(COFF, CSRC, CCOEF, XG2H, DIS3, enc2_b, XG2, UHD);
  col_mean<<<UHD, 256, 0, stream>>>(XG2, EMB, K2, UHD);

  // ---------- parameter MLP -> pm -> B ----------
  vecmat<1><<<1, 256, 0, stream>>>(EMB, p1_w, p1_b, T1, UHD, UHD);
  vecmat<1><<<1, 256, 0, stream>>>(T1, p2_w, p2_b, T2, UHD, UHD / 2);
  vecmat_tanh_wide<<<(PMN + 255) / 256, 256, 0, stream>>>(T2, p3_w, p3_b, PMV, UHD / 2, PMN);
  build_B<<<(PMN + 255) / 256, 256, 0, stream>>>(PMV, BM, K2, 0.05f * 0.5f / 32.0f);

  // ---------- expm via PS deg-11 + 4 squarings (5th folded into EVO) ----------
  const int rgrid = (PMN + 255) / 256;
  const int sgrid = (PLD * PLD + 255) / 256;
  const dim3 tgridF((PLD + 31) / 32, (PLD + 31) / 32);
  const int chF = sk_chunk32(PLD, CSPLIT);   // 96
  const dim3 gBig(CSPLIT, 11, 11);           // z first -> XCD k-slice affinity
  const float c3 = 1.f / 6.f, c4 = 1.f / 24.f, c5 = 1.f / 120.f;
  const float c6 = 1.f / 720.f, c7 = 1.f / 5040.f, c8 = 1.f / 40320.f;
  const float c9 = 1.f / 362880.f, c10 = 1.f / 3628800.f, c11 = 1.f / 39916800.f;

  split_planes <<<sgrid, 256, 0, stream>>>(BM, K2, K2, SA, PLD, PLD, PPS);
  split_planesT<<<tgridF, 256, 0, stream>>>(BM, K2, K2, ST, PLD, PLD, PPS);
  // B2 = B*B  (creduce_split: B2v fp32 + SA <- B2 planes)
  cmm_bf16_sk<<<gBig, 256, 0, stream>>>(SA, PPS, PLD, ST, PPS, PLD, PART, K2, K2, PLD, chF);
  creduce_split<<<sgrid, 256, 0, stream>>>(PART, B2v, SA, PPS, K2, K2, PLD, PLD, CSPLIT,
                                           0.f, nullptr, 0.f, nullptr, 0.f);
  // B3 = B2*B ; ST <- B3^T (fixed right operand for Horner)
  cmm_bf16_sk<<<gBig, 256, 0, stream>>>(SA, PPS, PLD, ST, PPS, PLD, PART, K2, K2, PLD, chF);
  creduce<<<rgrid, 256, 0, stream>>>(PART, B3v, PMN, K2, CSPLIT, 0.f, nullptr, 0.f, nullptr, 0.f);
  split_planesT<<<tgridF, 256, 0, stream>>>(B3v, K2, K2, ST, PLD, PLD, PPS);
  // P0 = D3 (fp32 + SA planes)
  combo3_split<<<sgrid, 256, 0, stream>>>(BM, B2v, P0v, SA, PPS, K2, K2, PLD, PLD, c9, c10, c11);
  // Horner: P1 = P0*B3 + D2 ; P0 = P1*B3 + D1 ; P1 = P0*B3 + D0
  cmm_bf16_sk<<<gBig, 256, 0, stream>>>(SA, PPS, PLD, ST, PPS, PLD, PART, K2, K2, PLD, chF);
  creduce_split<<<sgrid, 256, 0, stream>>>(PART, P1v, SA, PPS, K2, K2, PLD, PLD, CSPLIT,
                                           c6, BM, c7, B2v, c8);
  cmm_bf16_sk<<<gBig, 256, 0, stream>>>(SA, PPS, PLD, ST, PPS, PLD, PART, K2, K2, PLD, chF);
  creduce_split<<<sgrid, 256, 0, stream>>>(PART, P0v, SA, PPS, K2, K2, PLD, PLD, CSPLIT,
                                           c3, BM, c4, B2v, c5);
  cmm_bf16_sk<<<gBig, 256, 0, stream>>>(SA, PPS, PLD, ST, PPS, PLD, PART, K2, K2, PLD, chF);
  creduce_split<<<sgrid, 256, 0, stream>>>(PART, P1v, SA, PPS, K2, K2, PLD, PLD, CSPLIT,
                                           1.f, BM, 1.f, B2v, 0.5f);
  // 4 squarings; SA planes maintained by creduce_split, ST rebuilt per step
  float2* cur = P1v;
  float2* nxt = P0v;
  for (int t = 0; t < EXPM_SQ; ++t) {
    split_planesT<<<tgridF, 256, 0, stream>>>(cur, K2, K2, ST, PLD, PLD, PPS);
    cmm_bf16_sk<<<gBig, 256, 0, stream>>>(SA, PPS, PLD, ST, PPS, PLD, PART, K2, K2, PLD, chF);
    creduce_split<<<sgrid, 256, 0, stream>>>(PART, nxt, SA, PPS, K2, K2, PLD, PLD, CSPLIT,
                                             0.f, nullptr, 0.f, nullptr, 0.f);
    std::swap(cur, nxt);
  }
  // cur = S (= U^(1/2)); SA holds S planes.

  // ---------- quantum message passing: EVO = S@(S@XC) ----------
  rmm64<1><<<dim3(HD / 64, (K2 + 63) / 64), 256, 0, stream>>>(XRb, rt_w, rt_b, (float*)XC, K2, HD, HD, 2, 0);
  rmm64<1><<<dim3(HD / 64, (K2 + 63) / 64), 256, 0, stream>>>(XIb, it_w, it_b, (float*)XC, K2, HD, HD, 2, 1);
  {
    const int mn = K2 * HD;
    const int rg = (mn + 255) / 256;
    const dim3 gSkin(CSPLIT, HD / 64, 11);
    const size_t psX = (size_t)HD * PLD;
    // T = S @ XC
    split_planesT<<<dim3((PLD + 31) / 32, (HD + 31) / 32), 256, 0, stream>>>(
        XC, K2, HD, ST, HD, PLD, psX);
    cmm_bf16_sk<<<gSkin, 256, 0, stream>>>(SA, PPS, PLD, ST, psX, PLD, PART, K2, HD, PLD, chF);
    creduce<<<rg, 256, 0, stream>>>(PART, EVO, mn, HD, CSPLIT, 0.f, nullptr, 0.f, nullptr, 0.f);
    // EVO = S @ T (reuse SA = S planes)
    split_planesT<<<dim3((PLD + 31) / 32, (HD + 31) / 32), 256, 0, stream>>>(
        EVO, K2, HD, ST, HD, PLD, psX);
    cmm_bf16_sk<<<gSkin, 256, 0, stream>>>(SA, PPS, PLD, ST, psX, PLD, PART, K2, HD, PLD, chF);
    creduce<<<rg, 256, 0, stream>>>(PART, EVO, mn, HD, CSPLIT, 0.f, nullptr, 0.f, nullptr, 0.f);
    // AGG0 planes directly from graph gather (no fp32 intermediate)
    const size_t psG = (size_t)PLD * HD;
    agg_gather_split<<<PLD, 256, 0, stream>>>(COFF, CSRC, EVO, SA, psG, HD, K2);
    // W = msg_wr + i*msg_wi, transposed-split directly from the two real mats
    split_planesT2<<<dim3((HD + 31) / 32, (HD + 31) / 32), 256, 0, stream>>>(
        msg_wr, msg_wi, HD, HD, ST, HD, HD, (size_t)HD * HD);
    cmm_bf16_sk<<<gSkin, 256, 0, stream>>>(SA, psG, HD, ST, (size_t)HD * HD, HD, PART,
                                           K2, HD, HD, sk_chunk32(HD, CSPLIT));
    creduce<<<rg, 256, 0, stream>>>(PART, AGG1, mn, HD, CSPLIT, 0.f, nullptr, 0.f, nullptr, 0.f);
  }
  // magph overwrites the CSR slot — CSR dead now.
  magph<<<(K2 * HD + 255) / 256, 256, 0, stream>>>(AGG1, XRb, XIb, MAGB, PHB, K2 * HD);
  col_mean<<<HD, 256, 0, stream>>>(MAGB, GM, K2, HD);
  col_mean<<<HD, 256, 0, stream>>>(PHB, GP, K2, HD);

  // ---------- fused classifier heads ----------
  heads_fused<<<1, 256, 0, stream>>>(GM, GP, mc1_w, mc1_b, mc2_w, mc2_b,
                                     pc1_w, pc1_b, pc2_w, pc2_b, (float*)d_out);
}